// Round 1
// baseline (4200.194 us; speedup 1.0000x reference)
//
#include <hip/hip_runtime.h>
#include <cstddef>

__device__ __forceinline__ float gelu_f(float x){
  return 0.5f * x * (1.0f + erff(x * 0.7071067811865476f));
}

// ---------------- patch conv 8x8 stride8 (+coord channels) + gelu -> p1 (32,32,32,35)
__global__ __launch_bounds__(64)
void k_patch(const float* __restrict__ x, const float* __restrict__ pw,
             const float* __restrict__ pb, float* __restrict__ p1)
{
  __shared__ float v[448];
  const int nb = blockIdx.x;
  const int j = nb & 31, i = (nb >> 5) & 31, n = nb >> 10;
  const int b = n >> 2, t = n & 3;
  const int tid = threadIdx.x;
  for (int l = tid; l < 448; l += 64) {
    const int dy = l / 56, r = l - dy * 56, dx = r / 7, c = r - dx * 7;
    const int Y = i * 8 + dy, X = j * 8 + dx;
    float val;
    if (c < 4)       val = x[((((size_t)b * 256 + Y) * 256 + X) * 4 + t) * 4 + c];
    else if (c == 4) val = (float)Y * (1.0f / 255.0f);
    else if (c == 5) val = (float)X * (1.0f / 255.0f);
    else             val = (float)t * (1.0f / 3.0f);
    v[l] = val;
  }
  __syncthreads();
  if (tid < 35) {
    float acc = pb[tid];
    #pragma unroll 4
    for (int l = 0; l < 448; ++l) acc = fmaf(v[l], pw[l * 35 + tid], acc);
    p1[((size_t)n * 1024 + i * 32 + j) * 35 + tid] = gelu_f(acc);
  }
}

// ---------------- 1x1 conv 35->512 + bias + pos_embed, * temb, store (b,hw,t,e)
__global__ __launch_bounds__(64)
void k_embed(const float* __restrict__ p1, const float* __restrict__ w,
             const float* __restrict__ bb, const float* __restrict__ pos,
             const float* __restrict__ gamma, float* __restrict__ h0)
{
  __shared__ float v[35];
  const int nb = blockIdx.x;
  const int j = nb & 31, i = (nb >> 5) & 31, n = nb >> 10;
  const int b = n >> 2, t = n & 3;
  const int tid = threadIdx.x;
  if (tid < 35) v[tid] = p1[((size_t)n * 1024 + i * 32 + j) * 35 + tid];
  __syncthreads();
  const float tv = (float)t * (1.0f / 3.0f);
  const size_t outbase = (((size_t)b * 1024 + i * 32 + j) * 4 + t) * 512;
  const int hw = i * 32 + j;
  for (int e = tid; e < 512; e += 64) {
    float acc = bb[e];
    #pragma unroll 5
    for (int k = 0; k < 35; ++k) acc = fmaf(v[k], w[k * 512 + e], acc);
    acc += pos[(size_t)hw * 512 + e];
    acc *= cosf(tv * gamma[e]);
    h0[outbase + e] = acc;
  }
}

// ---------------- generic fp32 GEMM: C[z] = A[z] @ B[z] (+bias)(gelu)(+Res)
// 64x64 tile, 256 thr, 4x4 micro. Requires M%64==0, N%64==0, K%16==0.
template<int BIAS, int GELU, int RES>
__global__ __launch_bounds__(256)
void k_gemm(const float* __restrict__ A, const float* __restrict__ B,
            float* __restrict__ C, const float* __restrict__ bias,
            const float* __restrict__ Res,
            int M, int N, int K, int lda, int ldb, int ldc,
            long long sAz, long long sBz, long long sCz, int sBiasZ)
{
  __shared__ float As[16][68];
  __shared__ float Bs[16][68];
  const int z = blockIdx.z;
  A += (size_t)z * sAz;
  B += (size_t)z * sBz;
  const int n0 = blockIdx.x * 64, m0 = blockIdx.y * 64;
  const int tid = threadIdx.x;
  const int tx = tid & 15, ty = tid >> 4;
  const int amm = tid >> 2, akb = (tid & 3) << 2;
  const int bkk = tid >> 4, bnb = (tid & 15) << 2;
  float acc[4][4] = {};
  for (int k0 = 0; k0 < K; k0 += 16) {
    const float4 av = *(const float4*)(A + (size_t)(m0 + amm) * lda + k0 + akb);
    const float4 bv = *(const float4*)(B + (size_t)(k0 + bkk) * ldb + n0 + bnb);
    As[akb + 0][amm] = av.x;
    As[akb + 1][amm] = av.y;
    As[akb + 2][amm] = av.z;
    As[akb + 3][amm] = av.w;
    *(float4*)(&Bs[bkk][bnb]) = bv;
    __syncthreads();
    #pragma unroll
    for (int kk = 0; kk < 16; ++kk) {
      const float4 a4 = *(const float4*)(&As[kk][ty * 4]);
      const float4 b4 = *(const float4*)(&Bs[kk][tx * 4]);
      const float a_[4] = {a4.x, a4.y, a4.z, a4.w};
      const float b_[4] = {b4.x, b4.y, b4.z, b4.w};
      #pragma unroll
      for (int i = 0; i < 4; ++i)
        #pragma unroll
        for (int jj = 0; jj < 4; ++jj)
          acc[i][jj] = fmaf(a_[i], b_[jj], acc[i][jj]);
    }
    __syncthreads();
  }
  float4 bv4 = make_float4(0.f, 0.f, 0.f, 0.f);
  if (BIAS) bv4 = *(const float4*)(bias + (size_t)z * sBiasZ + n0 + tx * 4);
  #pragma unroll
  for (int i = 0; i < 4; ++i) {
    const size_t ci = (size_t)z * sCz + (size_t)(m0 + ty * 4 + i) * ldc + n0 + tx * 4;
    float4 o;
    o.x = acc[i][0] + bv4.x; o.y = acc[i][1] + bv4.y;
    o.z = acc[i][2] + bv4.z; o.w = acc[i][3] + bv4.w;
    if (GELU) { o.x = gelu_f(o.x); o.y = gelu_f(o.y); o.z = gelu_f(o.z); o.w = gelu_f(o.w); }
    if (RES) {
      const float4 r = *(const float4*)(Res + ci);
      o.x += r.x; o.y += r.y; o.z += r.z; o.w += r.w;
    }
    *(float4*)(C + ci) = o;
  }
}

// ---------------- GroupNorm (groups=8 over 512ch, mean over h,w,64ch): split reduce
__global__ __launch_bounds__(256)
void k_gn_part(const float* __restrict__ in, float* __restrict__ part)
{
  __shared__ float r1[256], r2[256];
  const int blk = blockIdx.x;                       // b*128 + g*16 + s
  const int s = blk & 15, g = (blk >> 4) & 7, b = blk >> 7;
  const int tid = threadIdx.x;
  const int cc = tid & 63, pp = tid >> 6;
  const float* base = in + ((size_t)b * 1024 + s * 64) * 512 + g * 64;
  float s1 = 0.f, s2 = 0.f;
  for (int p = pp; p < 64; p += 4) {
    const float v = base[(size_t)p * 512 + cc];
    s1 += v; s2 += v * v;
  }
  r1[tid] = s1; r2[tid] = s2;
  __syncthreads();
  for (int o = 128; o > 0; o >>= 1) {
    if (tid < o) { r1[tid] += r1[tid + o]; r2[tid] += r2[tid + o]; }
    __syncthreads();
  }
  if (tid == 0) { part[blk] = r1[0]; part[1024 + blk] = r2[0]; }
}

__global__ __launch_bounds__(256)
void k_gn_apply(const float* __restrict__ in, const float* __restrict__ part,
                const float* __restrict__ sc, const float* __restrict__ bi,
                float* __restrict__ out)
{
  const int blk = blockIdx.x;
  const int s = blk & 15, g = (blk >> 4) & 7, b = blk >> 7;
  float s1 = 0.f, s2 = 0.f;
  #pragma unroll
  for (int q = 0; q < 16; ++q) {
    s1 += part[(b * 8 + g) * 16 + q];
    s2 += part[1024 + (b * 8 + g) * 16 + q];
  }
  const float mu = s1 * (1.0f / 65536.0f);
  const float var = s2 * (1.0f / 65536.0f) - mu * mu;
  const float rs = rsqrtf(var + 1e-5f);
  const int tid = threadIdx.x;
  const int cc = tid & 63, pp = tid >> 6;
  const float sca = sc[g * 64 + cc] * rs;
  const float sh = bi[g * 64 + cc] - mu * sca;
  const float* base = in + ((size_t)b * 1024 + s * 64) * 512 + g * 64;
  float* ob = out + ((size_t)b * 1024 + s * 64) * 512 + g * 64;
  for (int p = pp; p < 64; p += 4)
    ob[(size_t)p * 512 + cc] = fmaf(base[(size_t)p * 512 + cc], sca, sh);
}

// ---------------- forward DFT stage A: over y (e^{-i 2pi kh y/32}), kh=0..15
__global__ __launch_bounds__(256)
void k_dft_a(const float* __restrict__ z, float* __restrict__ Ar, float* __restrict__ Ai)
{
  __shared__ float ct[512], st[512];
  const int tid = threadIdx.x;
  for (int q = tid; q < 512; q += 256) {
    const int k = q >> 5, y = q & 31;
    const float ang = (float)((k * y) & 31) * 0.19634954084936207f;
    ct[q] = cosf(ang); st[q] = sinf(ang);
  }
  __syncthreads();
  const int blk = blockIdx.x;                    // b*64 + x*2 + half
  const int half = blk & 1, x = (blk >> 1) & 31, b = blk >> 6;
  const int c = half * 256 + tid;
  float ar[16], ai[16];
  #pragma unroll
  for (int k = 0; k < 16; ++k) { ar[k] = 0.f; ai[k] = 0.f; }
  const float* zp = z + ((size_t)b * 1024 + x) * 512 + c;
  for (int y = 0; y < 32; ++y) {
    const float v = zp[(size_t)y * 32 * 512];
    #pragma unroll
    for (int k = 0; k < 16; ++k) {
      ar[k] = fmaf(v, ct[k * 32 + y], ar[k]);
      ai[k] = fmaf(-v, st[k * 32 + y], ai[k]);
    }
  }
  #pragma unroll
  for (int k = 0; k < 16; ++k) {
    const size_t o = (((size_t)b * 16 + k) * 32 + x) * 512 + c;
    Ar[o] = ar[k]; Ai[o] = ai[k];
  }
}

// ---------------- forward DFT stage B: over x, write stacked X (blk,pos,[re|im]) /32
__global__ __launch_bounds__(256)
void k_dft_b(const float* __restrict__ Ar, const float* __restrict__ Ai, float* __restrict__ X)
{
  __shared__ float ct[512], st[512];
  const int tid = threadIdx.x;
  for (int q = tid; q < 512; q += 256) {
    const int k = q >> 5, xx = q & 31;
    const float ang = (float)((k * xx) & 31) * 0.19634954084936207f;
    ct[q] = cosf(ang); st[q] = sinf(ang);
  }
  __syncthreads();
  const int blk = blockIdx.x;                    // b*32 + kh*2 + half
  const int half = blk & 1, kh = (blk >> 1) & 15, b = blk >> 5;
  const int c = half * 256 + tid;
  float gr[16], gi[16];
  #pragma unroll
  for (int k = 0; k < 16; ++k) { gr[k] = 0.f; gi[k] = 0.f; }
  const float* arp = Ar + (((size_t)b * 16 + kh) * 32) * 512 + c;
  const float* aip = Ai + (((size_t)b * 16 + kh) * 32) * 512 + c;
  for (int x = 0; x < 32; ++x) {
    const float vr = arp[(size_t)x * 512], vi = aip[(size_t)x * 512];
    #pragma unroll
    for (int k = 0; k < 16; ++k) {
      const float cc_ = ct[k * 32 + x], ss = st[k * 32 + x];
      gr[k] += vr * cc_ + vi * ss;
      gi[k] += vi * cc_ - vr * ss;
    }
  }
  const int blkc = c >> 6, ii = c & 63;
  #pragma unroll
  for (int k = 0; k < 16; ++k) {
    const size_t pos = (size_t)b * 256 + kh * 16 + k;
    float* xp = X + ((size_t)blkc * 2048 + pos) * 128 + ii;
    xp[0]  = gr[k] * (1.0f / 32.0f);
    xp[64] = gi[k] * (1.0f / 32.0f);
  }
}

// ---------------- build stacked complex weights S1R|S1I|S2R|S2I (each 8x128x64)
__global__ __launch_bounds__(256)
void k_mode_prep(const float* __restrict__ aw1_d, const float* __restrict__ aw2_d,
                 float* __restrict__ S)
{
  const int idx = blockIdx.x * 256 + threadIdx.x;   // 65536
  const int blk = idx >> 13;
  const int rem = idx & 8191;
  const int k = rem >> 6, o = rem & 63;
  const bool hi = (k >= 64);
  const int i = hi ? k - 64 : k;
  const int wo = (blk * 64 + i) * 64 + o;
  const float w1r = aw1_d[wo],          w1i = aw1_d[32768 + wo];
  const float w2r = aw2_d[wo],          w2i = aw2_d[32768 + wo];
  S[idx]           = hi ? -w1i : w1r;
  S[65536 + idx]   = hi ?  w1r : w1i;
  S[131072 + idx]  = hi ? -w2i : w2r;
  S[196608 + idx]  = hi ?  w2r : w2i;
}

// ---------------- inverse DFT stage D: T = sum_kw c_kw G e^{+i 2pi kw x/32}
__global__ __launch_bounds__(256)
void k_idft_d(const float* __restrict__ O2r, const float* __restrict__ O2i,
              float* __restrict__ Tr, float* __restrict__ Ti)
{
  __shared__ float ct[512], st[512];
  const int tid = threadIdx.x;
  for (int q = tid; q < 512; q += 256) {
    const int kw = q >> 5, xx = q & 31;
    const float w = (kw == 0) ? 1.0f : 2.0f;
    const float ang = (float)((kw * xx) & 31) * 0.19634954084936207f;
    ct[q] = w * cosf(ang); st[q] = w * sinf(ang);
  }
  __syncthreads();
  const int blk = blockIdx.x;                   // b*32 + kh*2 + half
  const int half = blk & 1, kh = (blk >> 1) & 15, b = blk >> 5;
  const int c = half * 256 + tid;
  float gr[16], gi[16];
  #pragma unroll
  for (int kw = 0; kw < 16; ++kw) {
    const size_t pos = (size_t)b * 256 + kh * 16 + kw;
    gr[kw] = O2r[pos * 512 + c];
    gi[kw] = O2i[pos * 512 + c];
  }
  for (int x = 0; x < 32; ++x) {
    float tr = 0.f, ti = 0.f;
    #pragma unroll
    for (int kw = 0; kw < 16; ++kw) {
      const float cc_ = ct[kw * 32 + x], ss = st[kw * 32 + x];
      tr += gr[kw] * cc_ - gi[kw] * ss;
      ti += gi[kw] * cc_ + gr[kw] * ss;
    }
    const size_t o = (((size_t)b * 16 + kh) * 32 + x) * 512 + c;
    Tr[o] = tr; Ti[o] = ti;
  }
}

// ---------------- inverse DFT stage E: out = (1/32) sum_kh Re(T e^{+i..}) + residual z
__global__ __launch_bounds__(256)
void k_idft_e(const float* __restrict__ Tr, const float* __restrict__ Ti,
              const float* __restrict__ zin, float* __restrict__ za)
{
  __shared__ float ct[512], st[512];
  const int tid = threadIdx.x;
  for (int q = tid; q < 512; q += 256) {
    const int k = q >> 5, y = q & 31;
    const float ang = (float)((k * y) & 31) * 0.19634954084936207f;
    ct[q] = cosf(ang); st[q] = sinf(ang);
  }
  __syncthreads();
  const int blk = blockIdx.x;                  // b*64 + x*2 + half
  const int half = blk & 1, x = (blk >> 1) & 31, b = blk >> 6;
  const int c = half * 256 + tid;
  float trv[16], tiv[16];
  #pragma unroll
  for (int k = 0; k < 16; ++k) {
    const size_t o = (((size_t)b * 16 + k) * 32 + x) * 512 + c;
    trv[k] = Tr[o]; tiv[k] = Ti[o];
  }
  for (int y = 0; y < 32; ++y) {
    float v = 0.f;
    #pragma unroll
    for (int k = 0; k < 16; ++k)
      v += trv[k] * ct[k * 32 + y] - tiv[k] * st[k * 32 + y];
    const size_t o = ((size_t)b * 1024 + y * 32 + x) * 512 + c;
    za[o] = v * (1.0f / 32.0f) + zin[o];
  }
}

// ---------------- cls mean over 1024 tokens
__global__ __launch_bounds__(256)
void k_clsmean(const float* __restrict__ h, float* __restrict__ ctok)
{
  const int blk = blockIdx.x;                 // b*2 + half
  const int half = blk & 1, b = blk >> 1;
  const int c = half * 256 + threadIdx.x;
  float s = 0.f;
  const float* p = h + (size_t)b * 1024 * 512 + c;
  for (int r = 0; r < 1024; ++r) s += p[(size_t)r * 512];
  ctok[b * 512 + c] = s * (1.0f / 1024.0f);
}

// ---------------- cls 3-layer MLP -> d_out[2097152 + b*12 + k]
__global__ __launch_bounds__(512)
void k_cls(const float* __restrict__ tok,
           const float* __restrict__ w1, const float* __restrict__ b1,
           const float* __restrict__ w2, const float* __restrict__ b2,
           const float* __restrict__ w3, const float* __restrict__ b3,
           float* __restrict__ outp)
{
  __shared__ float tv[512], c1[512], c2[512];
  const int b = blockIdx.x, tid = threadIdx.x;
  tv[tid] = tok[b * 512 + tid];
  __syncthreads();
  float a = b1[tid];
  for (int i = 0; i < 512; ++i) a = fmaf(tv[i], w1[i * 512 + tid], a);
  c1[tid] = gelu_f(a);
  __syncthreads();
  a = b2[tid];
  for (int i = 0; i < 512; ++i) a = fmaf(c1[i], w2[i * 512 + tid], a);
  c2[tid] = gelu_f(a);
  __syncthreads();
  if (tid < 12) {
    a = b3[tid];
    for (int i = 0; i < 512; ++i) a = fmaf(c2[i], w3[i * 12 + tid], a);
    outp[2097152 + b * 12 + tid] = a;
  }
}

// ---------------- transpose dec_w (2048x512 -> 512x2048)
__global__ __launch_bounds__(256)
void k_decw_t(const float* __restrict__ w, float* __restrict__ wt)
{
  const int idx = blockIdx.x * 256 + threadIdx.x;   // 1048576
  const int o = idx >> 11, n = idx & 2047;
  wt[idx] = w[(size_t)n * 512 + o];
}

// ---------------- decoder tail: virtual y1 = gelu(D1 + dec_b); conv3x3+gelu; 1x1 -> out
__global__ __launch_bounds__(512)
void k_dec(const float* __restrict__ D1, const float* __restrict__ dec_b,
           const float* __restrict__ c3w, const float* __restrict__ c3b,
           const float* __restrict__ c1w, const float* __restrict__ c1b,
           float* __restrict__ outp)
{
  __shared__ float it[3][18][32];
  __shared__ float wt[9216];
  __shared__ float y2t[16][32];
  const int blk = blockIdx.x;                  // b*4096 + Y*16 + xs
  const int xs = blk & 15, Y = (blk >> 4) & 255, b = blk >> 12;
  const int X0 = xs * 16;
  const int tid = threadIdx.x;
  for (int q = tid; q < 9216; q += 512) wt[q] = c3w[q];
  for (int q = tid; q < 1728; q += 512) {
    const int r = q / 576, rem = q - r * 576, px = rem >> 5, cc = rem & 31;
    const int Yg = Y + r - 1, Xg = X0 + px - 1;
    float v = 0.f;
    if (Yg >= 0 && Yg < 256 && Xg >= 0 && Xg < 256) {
      const int i = Yg >> 3, dy = Yg & 7, jj = Xg >> 3, dx = Xg & 7;
      v = gelu_f(D1[((size_t)b * 1024 + i * 32 + jj) * 2048 + (dy * 8 + dx) * 32 + cc] + dec_b[cc]);
    }
    it[r][px][cc] = v;
  }
  __syncthreads();
  {
    const int px = tid >> 5, co = tid & 31;
    float acc = c3b[co];
    #pragma unroll
    for (int dy = 0; dy < 3; ++dy)
      #pragma unroll
      for (int dx = 0; dx < 3; ++dx) {
        #pragma unroll 8
        for (int ci = 0; ci < 32; ++ci)
          acc = fmaf(it[dy][px + dx][ci], wt[((dy * 3 + dx) * 32 + ci) * 32 + co], acc);
      }
    y2t[px][co] = gelu_f(acc);
  }
  __syncthreads();
  if (tid < 64) {
    const int px = tid >> 2, oc = tid & 3;
    float acc = c1b[oc];
    #pragma unroll
    for (int ci = 0; ci < 32; ++ci) acc = fmaf(y2t[px][ci], c1w[ci * 4 + oc], acc);
    outp[(((size_t)b * 256 + Y) * 256 + X0 + px) * 4 + oc] = acc;
  }
}

extern "C" void kernel_launch(void* const* d_in, const int* in_sizes, int n_in,
                              void* d_out, int out_size, void* d_ws, size_t ws_size,
                              hipStream_t stream)
{
  (void)in_sizes; (void)n_in; (void)out_size; (void)ws_size;
  const float* x      = (const float*)d_in[0];
  const float* patch_w= (const float*)d_in[1];
  const float* patch_b= (const float*)d_in[2];
  const float* p1_w   = (const float*)d_in[3];
  const float* p1_b   = (const float*)d_in[4];
  const float* pos    = (const float*)d_in[5];
  const float* tagg_w = (const float*)d_in[6];
  const float* gamma  = (const float*)d_in[7];
  const float* gn1_s  = (const float*)d_in[8];
  const float* gn1_b  = (const float*)d_in[9];
  const float* aw1    = (const float*)d_in[10];
  const float* ab1    = (const float*)d_in[11];
  const float* aw2    = (const float*)d_in[12];
  const float* ab2    = (const float*)d_in[13];
  const float* gn2_s  = (const float*)d_in[14];
  const float* gn2_b  = (const float*)d_in[15];
  const float* mw1    = (const float*)d_in[16];
  const float* mb1    = (const float*)d_in[17];
  const float* mw2    = (const float*)d_in[18];
  const float* mb2    = (const float*)d_in[19];
  const float* cls_w1 = (const float*)d_in[20];
  const float* cls_b1 = (const float*)d_in[21];
  const float* cls_w2 = (const float*)d_in[22];
  const float* cls_b2 = (const float*)d_in[23];
  const float* cls_w3 = (const float*)d_in[24];
  const float* cls_b3 = (const float*)d_in[25];
  const float* dec_w  = (const float*)d_in[26];
  const float* dec_b  = (const float*)d_in[27];
  const float* c3_w   = (const float*)d_in[28];
  const float* c3_b   = (const float*)d_in[29];
  const float* c1_w   = (const float*)d_in[30];
  const float* c1_b   = (const float*)d_in[31];

  float* W   = (float*)d_ws;
  float* P1  = W;                       // 1,146,880
  float* H   = W + 1146880;             // 4,194,304
  float* ZR  = W + 5341184;             // 16,777,216  (h0 / D1 / Z,ZA,Z2,U)
  float* Z   = ZR;
  float* ZA  = ZR + 4194304;
  float* Z2  = ZR + 8388608;
  float* U   = ZR + 12582912;
  float* AR  = Z2;                       // alias (dead when gn2 runs) ; also Tr
  float* AI  = Z2 + 2097152;             // also Ti
  float* X   = U;                        // stacked modes; later O2R/O2I
  float* O1  = U + 2097152;
  float* S   = W + 22118400;             // 262,144
  float* WDT = W + 22380544;             // 1,048,576
  float* CT  = W + 23429120;             // 4,096
  float* PART= W + 23433216;             // 2,048
  float* H0  = ZR;                        // token embed before tagg
  float* D1  = ZR;                        // decoder GEMM out
  float* out = (float*)d_out;

  k_patch<<<32768, 64, 0, stream>>>(x, patch_w, patch_b, P1);
  k_embed<<<32768, 64, 0, stream>>>(P1, p1_w, p1_b, pos, gamma, H0);
  k_gemm<0,0,0><<<dim3(8,128,1),256,0,stream>>>(H0, tagg_w, H, nullptr, nullptr,
      8192, 512, 2048, 2048, 512, 512, 0, 0, 0, 0);

  for (int d = 0; d < 12; ++d) {
    k_gn_part<<<1024,256,0,stream>>>(H, PART);
    k_gn_apply<<<1024,256,0,stream>>>(H, PART, gn1_s + d*512, gn1_b + d*512, Z);
    k_dft_a<<<512,256,0,stream>>>(Z, AR, AI);
    k_dft_b<<<256,256,0,stream>>>(AR, AI, X);
    k_mode_prep<<<256,256,0,stream>>>(aw1 + (size_t)d*65536, aw2 + (size_t)d*65536, S);
    const float* ab1_d = ab1 + d*1024;
    const float* ab2_d = ab2 + d*1024;
    k_gemm<1,1,0><<<dim3(1,32,8),256,0,stream>>>(X, S,          O1,      ab1_d,      nullptr,
        2048, 64, 128, 128, 64, 128, 262144LL, 8192LL, 262144LL, 64);
    k_gemm<1,1,0><<<dim3(1,32,8),256,0,stream>>>(X, S + 65536,  O1 + 64, ab1_d + 512, nullptr,
        2048, 64, 128, 128, 64, 128, 262144LL, 8192LL, 262144LL, 64);
    k_gemm<1,0,0><<<dim3(1,32,8),256,0,stream>>>(O1, S + 131072, X,           ab2_d,      nullptr,
        2048, 64, 128, 128, 64, 512, 262144LL, 8192LL, 64LL, 64);
    k_gemm<1,0,0><<<dim3(1,32,8),256,0,stream>>>(O1, S + 196608, X + 1048576, ab2_d + 512, nullptr,
        2048, 64, 128, 128, 64, 512, 262144LL, 8192LL, 64LL, 64);
    k_idft_d<<<256,256,0,stream>>>(X, X + 1048576, AR, AI);
    k_idft_e<<<512,256,0,stream>>>(AR, AI, Z, ZA);
    k_gn_part<<<1024,256,0,stream>>>(ZA, PART);
    k_gn_apply<<<1024,256,0,stream>>>(ZA, PART, gn2_s + d*512, gn2_b + d*512, Z2);
    k_gemm<1,1,0><<<dim3(8,128,1),256,0,stream>>>(Z2, mw1 + (size_t)d*262144, U, mb1 + d*512, nullptr,
        8192, 512, 512, 512, 512, 512, 0, 0, 0, 0);
    k_gemm<1,0,1><<<dim3(8,128,1),256,0,stream>>>(U, mw2 + (size_t)d*262144, H, mb2 + d*512, H,
        8192, 512, 512, 512, 512, 512, 0, 0, 0, 0);
  }

  k_clsmean<<<16,256,0,stream>>>(H, CT);
  k_cls<<<8,512,0,stream>>>(CT, cls_w1, cls_b1, cls_w2, cls_b2, cls_w3, cls_b3, out);
  k_decw_t<<<4096,256,0,stream>>>(dec_w, WDT);
  k_gemm<0,0,0><<<dim3(32,128,1),256,0,stream>>>(H, WDT, D1, nullptr, nullptr,
      8192, 2048, 512, 512, 2048, 2048, 0, 0, 0, 0);
  k_dec<<<32768,512,0,stream>>>(D1, dec_b, c3_w, c3_b, c1_w, c1_b, out);
}

// Round 2
// 2705.184 us; speedup vs baseline: 1.5526x; 1.5526x over previous
//
#include <hip/hip_runtime.h>
#include <cstddef>

typedef __attribute__((ext_vector_type(8))) short bh8;
typedef __attribute__((ext_vector_type(4))) float f4;

__device__ __forceinline__ float gelu_f(float x){
  return 0.5f * x * (1.0f + erff(x * 0.7071067811865476f));
}

__device__ __forceinline__ unsigned short f2bf(float f){
  unsigned int u = __float_as_uint(f);
  unsigned int r = (u + 0x7FFFu + ((u >> 16) & 1u)) >> 16;
  return (unsigned short)r;
}

__device__ __forceinline__ f4 mfma16(bh8 a, bh8 b, f4 c){
  return __builtin_amdgcn_mfma_f32_16x16x32_bf16(a, b, c, 0, 0, 0);
}

// ---------------- patch conv 8x8 stride8 (+coord channels) + gelu -> p1 (32,32,32,35)
__global__ __launch_bounds__(64)
void k_patch(const float* __restrict__ x, const float* __restrict__ pw,
             const float* __restrict__ pb, float* __restrict__ p1)
{
  __shared__ float v[448];
  const int nb = blockIdx.x;
  const int j = nb & 31, i = (nb >> 5) & 31, n = nb >> 10;
  const int b = n >> 2, t = n & 3;
  const int tid = threadIdx.x;
  for (int l = tid; l < 448; l += 64) {
    const int dy = l / 56, r = l - dy * 56, dx = r / 7, c = r - dx * 7;
    const int Y = i * 8 + dy, X = j * 8 + dx;
    float val;
    if (c < 4)       val = x[((((size_t)b * 256 + Y) * 256 + X) * 4 + t) * 4 + c];
    else if (c == 4) val = (float)Y * (1.0f / 255.0f);
    else if (c == 5) val = (float)X * (1.0f / 255.0f);
    else             val = (float)t * (1.0f / 3.0f);
    v[l] = val;
  }
  __syncthreads();
  if (tid < 35) {
    float acc = pb[tid];
    #pragma unroll 4
    for (int l = 0; l < 448; ++l) acc = fmaf(v[l], pw[l * 35 + tid], acc);
    p1[((size_t)n * 1024 + i * 32 + j) * 35 + tid] = gelu_f(acc);
  }
}

// ---------------- 1x1 conv 35->512 + bias + pos_embed, * temb, store (b,hw,t,e)
__global__ __launch_bounds__(64)
void k_embed(const float* __restrict__ p1, const float* __restrict__ w,
             const float* __restrict__ bb, const float* __restrict__ pos,
             const float* __restrict__ gamma, float* __restrict__ h0)
{
  __shared__ float v[35];
  const int nb = blockIdx.x;
  const int j = nb & 31, i = (nb >> 5) & 31, n = nb >> 10;
  const int b = n >> 2, t = n & 3;
  const int tid = threadIdx.x;
  if (tid < 35) v[tid] = p1[((size_t)n * 1024 + i * 32 + j) * 35 + tid];
  __syncthreads();
  const float tv = (float)t * (1.0f / 3.0f);
  const size_t outbase = (((size_t)b * 1024 + i * 32 + j) * 4 + t) * 512;
  const int hw = i * 32 + j;
  for (int e = tid; e < 512; e += 64) {
    float acc = bb[e];
    #pragma unroll 5
    for (int k = 0; k < 35; ++k) acc = fmaf(v[k], w[k * 512 + e], acc);
    acc += pos[(size_t)hw * 512 + e];
    acc *= cosf(tv * gamma[e]);
    h0[outbase + e] = acc;
  }
}

// ---------------- weight prep: fp32 [K][N] -> bf16 [N][K]
__global__ __launch_bounds__(256)
void k_cvt_trans(const float* __restrict__ in, unsigned short* __restrict__ out,
                 int K, int N, long long sIn, long long sOut)
{
  __shared__ float tile[32][33];
  const int z = blockIdx.z;
  in  += (size_t)z * sIn;
  out += (size_t)z * sOut;
  const int n0 = blockIdx.x * 32, k0 = blockIdx.y * 32;
  const int tx = threadIdx.x & 31, ty = threadIdx.x >> 5;
  #pragma unroll
  for (int i = 0; i < 4; ++i)
    tile[ty + i * 8][tx] = in[(size_t)(k0 + ty + i * 8) * N + n0 + tx];
  __syncthreads();
  #pragma unroll
  for (int i = 0; i < 4; ++i)
    out[(size_t)(n0 + ty + i * 8) * K + k0 + tx] = f2bf(tile[tx][ty + i * 8]);
}

// ---------------- plain fp32 -> bf16 convert
__global__ __launch_bounds__(256)
void k_cvt(const float* __restrict__ in, unsigned short* __restrict__ out, int n)
{
  const int idx = blockIdx.x * 256 + threadIdx.x;
  if (idx < n) out[idx] = f2bf(in[idx]);
}

// ---------------- conv3x3 weight prep: c3_w[(kb*32+ci)*32+co] -> w3t[kb][co][ci] bf16
__global__ __launch_bounds__(256)
void k_prep_w3(const float* __restrict__ w, unsigned short* __restrict__ out)
{
  const int idx = blockIdx.x * 256 + threadIdx.x;
  if (idx < 9216) {
    const int kb = idx >> 10, co = (idx >> 5) & 31, ci = idx & 31;
    out[idx] = f2bf(w[(kb * 32 + ci) * 32 + co]);
  }
}

// ---------------- bf16 MFMA GEMM: C = A(f32,MxK) @ Bt(bf16,[N][K])^T
// 64x64 tile, 4 waves; per wave: 16 rows x 64 cols (4 col-tiles of 16x16x32 MFMA).
// DEC=1: fused gelu(+dec_b[c&31]) epilogue scattered to pixel-layout bf16 Y1.
template<int BIAS, int GELU, int RES, int DEC>
__global__ __launch_bounds__(256)
void k_mgemm(const float* __restrict__ A, const unsigned short* __restrict__ Bt,
             float* __restrict__ C, const float* __restrict__ bias,
             const float* __restrict__ Res, unsigned short* __restrict__ Y1,
             int K, int lda, int ldc)
{
  __shared__ __align__(16) unsigned short As[64 * 40];
  __shared__ __align__(16) unsigned short Bs[64 * 40];
  const int m0 = blockIdx.y * 64, n0 = blockIdx.x * 64;
  const int tid = threadIdx.x;
  const int w = tid >> 6, l = tid & 63;
  const int lr = l & 15, lh = l >> 4;
  const int sr = tid >> 2, skq = (tid & 3) * 8;
  f4 acc[4] = {};
  for (int k0 = 0; k0 < K; k0 += 32) {
    const float* ap = A + (size_t)(m0 + sr) * lda + k0 + skq;
    const float4 a0 = *(const float4*)ap;
    const float4 a1 = *(const float4*)(ap + 4);
    bh8 av;
    av[0] = (short)f2bf(a0.x); av[1] = (short)f2bf(a0.y);
    av[2] = (short)f2bf(a0.z); av[3] = (short)f2bf(a0.w);
    av[4] = (short)f2bf(a1.x); av[5] = (short)f2bf(a1.y);
    av[6] = (short)f2bf(a1.z); av[7] = (short)f2bf(a1.w);
    *(bh8*)(&As[sr * 40 + skq]) = av;
    const uint4 bv = *(const uint4*)(Bt + (size_t)(n0 + sr) * K + k0 + skq);
    *(uint4*)(&Bs[sr * 40 + skq]) = bv;
    __syncthreads();
    const bh8 af = *(const bh8*)(&As[(w * 16 + lr) * 40 + lh * 8]);
    #pragma unroll
    for (int ct = 0; ct < 4; ++ct) {
      const bh8 bf = *(const bh8*)(&Bs[(ct * 16 + lr) * 40 + lh * 8]);
      acc[ct] = mfma16(af, bf, acc[ct]);
    }
    __syncthreads();
  }
  #pragma unroll
  for (int ct = 0; ct < 4; ++ct) {
    const int col = n0 + ct * 16 + lr;
    float bv = 0.f;
    if (BIAS) bv = bias[col];
    if (DEC)  bv = bias[col & 31];
    #pragma unroll
    for (int r = 0; r < 4; ++r) {
      const int row = m0 + w * 16 + lh * 4 + r;
      float v = acc[ct][r] + bv;
      if (GELU || DEC) v = gelu_f(v);
      if (DEC) {
        const int bb = row >> 10, hw = row & 1023, ii = hw >> 5, jj = hw & 31;
        const int dxy = col >> 5, dy = dxy >> 3, dx = dxy & 7, cc = col & 31;
        Y1[(((size_t)(bb * 256 + ii * 8 + dy)) * 256 + jj * 8 + dx) * 32 + cc] = f2bf(v);
      } else {
        const size_t ci = (size_t)row * ldc + col;
        if (RES) v += Res[ci];
        C[ci] = v;
      }
    }
  }
}

// ---------------- decoder tail: conv3x3 (MFMA implicit-im2col) + gelu + 1x1 -> out
__global__ __launch_bounds__(256)
void k_tail(const unsigned short* __restrict__ Y1, const unsigned short* __restrict__ w3t,
            const float* __restrict__ c1w, const float* __restrict__ c1b,
            float* __restrict__ outp)
{
  __shared__ __align__(16) char lbuf[256 * 33 * 4];   // union: it(bf16 halo) / y2(f32)
  __shared__ float c1s[128];
  unsigned short* it = (unsigned short*)lbuf;
  float* y2 = (float*)lbuf;
  const int bx = blockIdx.x;
  const int b = bx >> 8, ty = (bx >> 4) & 15, tx = bx & 15;
  const int Y0 = ty * 16, X0 = tx * 16;
  const int tid = threadIdx.x;
  const int w = tid >> 6, l = tid & 63, lr = l & 15, lh = l >> 4;

  if (tid < 128) c1s[tid] = c1w[tid];
  // stage 18x18x32 bf16 halo tile (rows padded to 40 ushort)
  for (int idx = tid; idx < 1296; idx += 256) {
    const int r = idx / 72, rem = idx - r * 72, c = rem >> 2, q = rem & 3;
    const int Yg = Y0 + r - 1, Xg = X0 + c - 1;
    uint4 v = make_uint4(0u, 0u, 0u, 0u);
    if (Yg >= 0 && Yg < 256 && Xg >= 0 && Xg < 256)
      v = *(const uint4*)(Y1 + (((size_t)(b * 256 + Yg)) * 256 + Xg) * 32 + q * 8);
    *(uint4*)(&it[(r * 18 + c) * 40 + q * 8]) = v;
  }
  // B fragments (conv weights) to registers: 2 co-tiles x 9 taps
  bh8 bw[2][9];
  #pragma unroll
  for (int ct = 0; ct < 2; ++ct)
    #pragma unroll
    for (int kb = 0; kb < 9; ++kb)
      bw[ct][kb] = *(const bh8*)(w3t + (size_t)(kb * 32 + ct * 16 + lr) * 32 + lh * 8);
  __syncthreads();

  f4 acc[4][2] = {};
  #pragma unroll
  for (int kb = 0; kb < 9; ++kb) {
    const int dy = kb / 3, dx = kb % 3;
    #pragma unroll
    for (int yy = 0; yy < 4; ++yy) {
      const int y = w * 4 + yy;
      const bh8 af = *(const bh8*)(&it[((y + dy) * 18 + lr + dx) * 40 + lh * 8]);
      acc[yy][0] = mfma16(af, bw[0][kb], acc[yy][0]);
      acc[yy][1] = mfma16(af, bw[1][kb], acc[yy][1]);
    }
  }
  __syncthreads();
  // y2 = gelu(conv3x3) -> LDS [px][33]
  #pragma unroll
  for (int yy = 0; yy < 4; ++yy) {
    const int y = w * 4 + yy;
    #pragma unroll
    for (int ct = 0; ct < 2; ++ct)
      #pragma unroll
      for (int r = 0; r < 4; ++r)
        y2[(y * 16 + lh * 4 + r) * 33 + ct * 16 + lr] = gelu_f(acc[yy][ct][r]);
  }
  __syncthreads();
  // 1x1: 32 -> 4, float4 store
  const int py = tid >> 4, px = tid & 15;
  float o0 = c1b[0], o1 = c1b[1], o2 = c1b[2], o3 = c1b[3];
  #pragma unroll 8
  for (int ci = 0; ci < 32; ++ci) {
    const float v = y2[tid * 33 + ci];
    o0 = fmaf(v, c1s[ci * 4 + 0], o0);
    o1 = fmaf(v, c1s[ci * 4 + 1], o1);
    o2 = fmaf(v, c1s[ci * 4 + 2], o2);
    o3 = fmaf(v, c1s[ci * 4 + 3], o3);
  }
  float4 ov; ov.x = o0; ov.y = o1; ov.z = o2; ov.w = o3;
  *(float4*)(outp + (((size_t)(b * 256 + Y0 + py)) * 256 + X0 + px) * 4) = ov;
}

// ---------------- generic fp32 GEMM (kept for AFNO block-MLPs)
template<int BIAS, int GELU, int RES>
__global__ __launch_bounds__(256)
void k_gemm(const float* __restrict__ A, const float* __restrict__ B,
            float* __restrict__ C, const float* __restrict__ bias,
            const float* __restrict__ Res,
            int M, int N, int K, int lda, int ldb, int ldc,
            long long sAz, long long sBz, long long sCz, int sBiasZ)
{
  __shared__ float As[16][68];
  __shared__ float Bs[16][68];
  const int z = blockIdx.z;
  A += (size_t)z * sAz;
  B += (size_t)z * sBz;
  const int n0 = blockIdx.x * 64, m0 = blockIdx.y * 64;
  const int tid = threadIdx.x;
  const int tx = tid & 15, ty = tid >> 4;
  const int amm = tid >> 2, akb = (tid & 3) << 2;
  const int bkk = tid >> 4, bnb = (tid & 15) << 2;
  float acc[4][4] = {};
  for (int k0 = 0; k0 < K; k0 += 16) {
    const float4 av = *(const float4*)(A + (size_t)(m0 + amm) * lda + k0 + akb);
    const float4 bv = *(const float4*)(B + (size_t)(k0 + bkk) * ldb + n0 + bnb);
    As[akb + 0][amm] = av.x;
    As[akb + 1][amm] = av.y;
    As[akb + 2][amm] = av.z;
    As[akb + 3][amm] = av.w;
    *(float4*)(&Bs[bkk][bnb]) = bv;
    __syncthreads();
    #pragma unroll
    for (int kk = 0; kk < 16; ++kk) {
      const float4 a4 = *(const float4*)(&As[kk][ty * 4]);
      const float4 b4 = *(const float4*)(&Bs[kk][tx * 4]);
      const float a_[4] = {a4.x, a4.y, a4.z, a4.w};
      const float b_[4] = {b4.x, b4.y, b4.z, b4.w};
      #pragma unroll
      for (int i = 0; i < 4; ++i)
        #pragma unroll
        for (int jj = 0; jj < 4; ++jj)
          acc[i][jj] = fmaf(a_[i], b_[jj], acc[i][jj]);
    }
    __syncthreads();
  }
  float4 bv4 = make_float4(0.f, 0.f, 0.f, 0.f);
  if (BIAS) bv4 = *(const float4*)(bias + (size_t)z * sBiasZ + n0 + tx * 4);
  #pragma unroll
  for (int i = 0; i < 4; ++i) {
    const size_t ci = (size_t)z * sCz + (size_t)(m0 + ty * 4 + i) * ldc + n0 + tx * 4;
    float4 o;
    o.x = acc[i][0] + bv4.x; o.y = acc[i][1] + bv4.y;
    o.z = acc[i][2] + bv4.z; o.w = acc[i][3] + bv4.w;
    if (GELU) { o.x = gelu_f(o.x); o.y = gelu_f(o.y); o.z = gelu_f(o.z); o.w = gelu_f(o.w); }
    if (RES) {
      const float4 r = *(const float4*)(Res + ci);
      o.x += r.x; o.y += r.y; o.z += r.z; o.w += r.w;
    }
    *(float4*)(C + ci) = o;
  }
}

// ---------------- GroupNorm split reduce
__global__ __launch_bounds__(256)
void k_gn_part(const float* __restrict__ in, float* __restrict__ part)
{
  __shared__ float r1[256], r2[256];
  const int blk = blockIdx.x;
  const int s = blk & 15, g = (blk >> 4) & 7, b = blk >> 7;
  const int tid = threadIdx.x;
  const int cc = tid & 63, pp = tid >> 6;
  const float* base = in + ((size_t)b * 1024 + s * 64) * 512 + g * 64;
  float s1 = 0.f, s2 = 0.f;
  for (int p = pp; p < 64; p += 4) {
    const float v = base[(size_t)p * 512 + cc];
    s1 += v; s2 += v * v;
  }
  r1[tid] = s1; r2[tid] = s2;
  __syncthreads();
  for (int o = 128; o > 0; o >>= 1) {
    if (tid < o) { r1[tid] += r1[tid + o]; r2[tid] += r2[tid + o]; }
    __syncthreads();
  }
  if (tid == 0) { part[blk] = r1[0]; part[1024 + blk] = r2[0]; }
}

__global__ __launch_bounds__(256)
void k_gn_apply(const float* __restrict__ in, const float* __restrict__ part,
                const float* __restrict__ sc, const float* __restrict__ bi,
                float* __restrict__ out)
{
  const int blk = blockIdx.x;
  const int s = blk & 15, g = (blk >> 4) & 7, b = blk >> 7;
  float s1 = 0.f, s2 = 0.f;
  #pragma unroll
  for (int q = 0; q < 16; ++q) {
    s1 += part[(b * 8 + g) * 16 + q];
    s2 += part[1024 + (b * 8 + g) * 16 + q];
  }
  const float mu = s1 * (1.0f / 65536.0f);
  const float var = s2 * (1.0f / 65536.0f) - mu * mu;
  const float rs = rsqrtf(var + 1e-5f);
  const int tid = threadIdx.x;
  const int cc = tid & 63, pp = tid >> 6;
  const float sca = sc[g * 64 + cc] * rs;
  const float sh = bi[g * 64 + cc] - mu * sca;
  const float* base = in + ((size_t)b * 1024 + s * 64) * 512 + g * 64;
  float* ob = out + ((size_t)b * 1024 + s * 64) * 512 + g * 64;
  for (int p = pp; p < 64; p += 4)
    ob[(size_t)p * 512 + cc] = fmaf(base[(size_t)p * 512 + cc], sca, sh);
}

// ---------------- forward DFT stage A
__global__ __launch_bounds__(256)
void k_dft_a(const float* __restrict__ z, float* __restrict__ Ar, float* __restrict__ Ai)
{
  __shared__ float ct[512], st[512];
  const int tid = threadIdx.x;
  for (int q = tid; q < 512; q += 256) {
    const int k = q >> 5, y = q & 31;
    const float ang = (float)((k * y) & 31) * 0.19634954084936207f;
    ct[q] = cosf(ang); st[q] = sinf(ang);
  }
  __syncthreads();
  const int blk = blockIdx.x;
  const int half = blk & 1, x = (blk >> 1) & 31, b = blk >> 6;
  const int c = half * 256 + tid;
  float ar[16], ai[16];
  #pragma unroll
  for (int k = 0; k < 16; ++k) { ar[k] = 0.f; ai[k] = 0.f; }
  const float* zp = z + ((size_t)b * 1024 + x) * 512 + c;
  for (int y = 0; y < 32; ++y) {
    const float v = zp[(size_t)y * 32 * 512];
    #pragma unroll
    for (int k = 0; k < 16; ++k) {
      ar[k] = fmaf(v, ct[k * 32 + y], ar[k]);
      ai[k] = fmaf(-v, st[k * 32 + y], ai[k]);
    }
  }
  #pragma unroll
  for (int k = 0; k < 16; ++k) {
    const size_t o = (((size_t)b * 16 + k) * 32 + x) * 512 + c;
    Ar[o] = ar[k]; Ai[o] = ai[k];
  }
}

// ---------------- forward DFT stage B
__global__ __launch_bounds__(256)
void k_dft_b(const float* __restrict__ Ar, const float* __restrict__ Ai, float* __restrict__ X)
{
  __shared__ float ct[512], st[512];
  const int tid = threadIdx.x;
  for (int q = tid; q < 512; q += 256) {
    const int k = q >> 5, xx = q & 31;
    const float ang = (float)((k * xx) & 31) * 0.19634954084936207f;
    ct[q] = cosf(ang); st[q] = sinf(ang);
  }
  __syncthreads();
  const int blk = blockIdx.x;
  const int half = blk & 1, kh = (blk >> 1) & 15, b = blk >> 5;
  const int c = half * 256 + tid;
  float gr[16], gi[16];
  #pragma unroll
  for (int k = 0; k < 16; ++k) { gr[k] = 0.f; gi[k] = 0.f; }
  const float* arp = Ar + (((size_t)b * 16 + kh) * 32) * 512 + c;
  const float* aip = Ai + (((size_t)b * 16 + kh) * 32) * 512 + c;
  for (int x = 0; x < 32; ++x) {
    const float vr = arp[(size_t)x * 512], vi = aip[(size_t)x * 512];
    #pragma unroll
    for (int k = 0; k < 16; ++k) {
      const float cc_ = ct[k * 32 + x], ss = st[k * 32 + x];
      gr[k] += vr * cc_ + vi * ss;
      gi[k] += vi * cc_ - vr * ss;
    }
  }
  const int blkc = c >> 6, ii = c & 63;
  #pragma unroll
  for (int k = 0; k < 16; ++k) {
    const size_t pos = (size_t)b * 256 + kh * 16 + k;
    float* xp = X + ((size_t)blkc * 2048 + pos) * 128 + ii;
    xp[0]  = gr[k] * (1.0f / 32.0f);
    xp[64] = gi[k] * (1.0f / 32.0f);
  }
}

// ---------------- stacked complex AFNO weights
__global__ __launch_bounds__(256)
void k_mode_prep(const float* __restrict__ aw1_d, const float* __restrict__ aw2_d,
                 float* __restrict__ S)
{
  const int idx = blockIdx.x * 256 + threadIdx.x;
  const int blk = idx >> 13;
  const int rem = idx & 8191;
  const int k = rem >> 6, o = rem & 63;
  const bool hi = (k >= 64);
  const int i = hi ? k - 64 : k;
  const int wo = (blk * 64 + i) * 64 + o;
  const float w1r = aw1_d[wo],          w1i = aw1_d[32768 + wo];
  const float w2r = aw2_d[wo],          w2i = aw2_d[32768 + wo];
  S[idx]           = hi ? -w1i : w1r;
  S[65536 + idx]   = hi ?  w1r : w1i;
  S[131072 + idx]  = hi ? -w2i : w2r;
  S[196608 + idx]  = hi ?  w2r : w2i;
}

// ---------------- inverse DFT stage D
__global__ __launch_bounds__(256)
void k_idft_d(const float* __restrict__ O2r, const float* __restrict__ O2i,
              float* __restrict__ Tr, float* __restrict__ Ti)
{
  __shared__ float ct[512], st[512];
  const int tid = threadIdx.x;
  for (int q = tid; q < 512; q += 256) {
    const int kw = q >> 5, xx = q & 31;
    const float w = (kw == 0) ? 1.0f : 2.0f;
    const float ang = (float)((kw * xx) & 31) * 0.19634954084936207f;
    ct[q] = w * cosf(ang); st[q] = w * sinf(ang);
  }
  __syncthreads();
  const int blk = blockIdx.x;
  const int half = blk & 1, kh = (blk >> 1) & 15, b = blk >> 5;
  const int c = half * 256 + tid;
  float gr[16], gi[16];
  #pragma unroll
  for (int kw = 0; kw < 16; ++kw) {
    const size_t pos = (size_t)b * 256 + kh * 16 + kw;
    gr[kw] = O2r[pos * 512 + c];
    gi[kw] = O2i[pos * 512 + c];
  }
  for (int x = 0; x < 32; ++x) {
    float tr = 0.f, ti = 0.f;
    #pragma unroll
    for (int kw = 0; kw < 16; ++kw) {
      const float cc_ = ct[kw * 32 + x], ss = st[kw * 32 + x];
      tr += gr[kw] * cc_ - gi[kw] * ss;
      ti += gi[kw] * cc_ + gr[kw] * ss;
    }
    const size_t o = (((size_t)b * 16 + kh) * 32 + x) * 512 + c;
    Tr[o] = tr; Ti[o] = ti;
  }
}

// ---------------- inverse DFT stage E (+residual)
__global__ __launch_bounds__(256)
void k_idft_e(const float* __restrict__ Tr, const float* __restrict__ Ti,
              const float* __restrict__ zin, float* __restrict__ za)
{
  __shared__ float ct[512], st[512];
  const int tid = threadIdx.x;
  for (int q = tid; q < 512; q += 256) {
    const int k = q >> 5, y = q & 31;
    const float ang = (float)((k * y) & 31) * 0.19634954084936207f;
    ct[q] = cosf(ang); st[q] = sinf(ang);
  }
  __syncthreads();
  const int blk = blockIdx.x;
  const int half = blk & 1, x = (blk >> 1) & 31, b = blk >> 6;
  const int c = half * 256 + tid;
  float trv[16], tiv[16];
  #pragma unroll
  for (int k = 0; k < 16; ++k) {
    const size_t o = (((size_t)b * 16 + k) * 32 + x) * 512 + c;
    trv[k] = Tr[o]; tiv[k] = Ti[o];
  }
  for (int y = 0; y < 32; ++y) {
    float v = 0.f;
    #pragma unroll
    for (int k = 0; k < 16; ++k)
      v += trv[k] * ct[k * 32 + y] - tiv[k] * st[k * 32 + y];
    const size_t o = ((size_t)b * 1024 + y * 32 + x) * 512 + c;
    za[o] = v * (1.0f / 32.0f) + zin[o];
  }
}

// ---------------- cls mean
__global__ __launch_bounds__(256)
void k_clsmean(const float* __restrict__ h, float* __restrict__ ctok)
{
  const int blk = blockIdx.x;
  const int half = blk & 1, b = blk >> 1;
  const int c = half * 256 + threadIdx.x;
  float s = 0.f;
  const float* p = h + (size_t)b * 1024 * 512 + c;
  for (int r = 0; r < 1024; ++r) s += p[(size_t)r * 512];
  ctok[b * 512 + c] = s * (1.0f / 1024.0f);
}

// ---------------- cls MLP
__global__ __launch_bounds__(512)
void k_cls(const float* __restrict__ tok,
           const float* __restrict__ w1, const float* __restrict__ b1,
           const float* __restrict__ w2, const float* __restrict__ b2,
           const float* __restrict__ w3, const float* __restrict__ b3,
           float* __restrict__ outp)
{
  __shared__ float tv[512], c1[512], c2[512];
  const int b = blockIdx.x, tid = threadIdx.x;
  tv[tid] = tok[b * 512 + tid];
  __syncthreads();
  float a = b1[tid];
  for (int i = 0; i < 512; ++i) a = fmaf(tv[i], w1[i * 512 + tid], a);
  c1[tid] = gelu_f(a);
  __syncthreads();
  a = b2[tid];
  for (int i = 0; i < 512; ++i) a = fmaf(c1[i], w2[i * 512 + tid], a);
  c2[tid] = gelu_f(a);
  __syncthreads();
  if (tid < 12) {
    a = b3[tid];
    for (int i = 0; i < 512; ++i) a = fmaf(c2[i], w3[i * 12 + tid], a);
    outp[2097152 + b * 12 + tid] = a;
  }
}

extern "C" void kernel_launch(void* const* d_in, const int* in_sizes, int n_in,
                              void* d_out, int out_size, void* d_ws, size_t ws_size,
                              hipStream_t stream)
{
  (void)in_sizes; (void)n_in; (void)out_size; (void)ws_size;
  const float* x      = (const float*)d_in[0];
  const float* patch_w= (const float*)d_in[1];
  const float* patch_b= (const float*)d_in[2];
  const float* p1_w   = (const float*)d_in[3];
  const float* p1_b   = (const float*)d_in[4];
  const float* pos    = (const float*)d_in[5];
  const float* tagg_w = (const float*)d_in[6];
  const float* gamma  = (const float*)d_in[7];
  const float* gn1_s  = (const float*)d_in[8];
  const float* gn1_b  = (const float*)d_in[9];
  const float* aw1    = (const float*)d_in[10];
  const float* ab1    = (const float*)d_in[11];
  const float* aw2    = (const float*)d_in[12];
  const float* ab2    = (const float*)d_in[13];
  const float* gn2_s  = (const float*)d_in[14];
  const float* gn2_b  = (const float*)d_in[15];
  const float* mw1    = (const float*)d_in[16];
  const float* mb1    = (const float*)d_in[17];
  const float* mw2    = (const float*)d_in[18];
  const float* mb2    = (const float*)d_in[19];
  const float* cls_w1 = (const float*)d_in[20];
  const float* cls_b1 = (const float*)d_in[21];
  const float* cls_w2 = (const float*)d_in[22];
  const float* cls_b2 = (const float*)d_in[23];
  const float* cls_w3 = (const float*)d_in[24];
  const float* cls_b3 = (const float*)d_in[25];
  const float* dec_w  = (const float*)d_in[26];
  const float* dec_b  = (const float*)d_in[27];
  const float* c3_w   = (const float*)d_in[28];
  const float* c3_b   = (const float*)d_in[29];
  const float* c1_w   = (const float*)d_in[30];
  const float* c1_b   = (const float*)d_in[31];

  float* W   = (float*)d_ws;
  float* P1  = W;                        // 1,146,880 f
  float* H   = W + 1146880;              // 4,194,304 f
  float* ZR  = W + 5341184;              // 16,777,216 f
  float* Z   = ZR;
  float* ZA  = ZR + 4194304;
  float* Z2  = ZR + 8388608;
  float* U   = ZR + 12582912;
  float* AR  = Z2;
  float* AI  = Z2 + 2097152;
  float* X   = U;
  float* O1  = U + 2097152;
  float* S   = W + 22118400;             // 262,144 f
  float* CT  = W + 22380544;             // 4,096 f
  float* PART= W + 22384640;             // 2,048 f
  unsigned short* U16   = (unsigned short*)(W + 22386688);
  unsigned short* taggT = U16;                 // 1,048,576
  unsigned short* mwT1  = U16 + 1048576;       // 3,145,728
  unsigned short* mwT2  = U16 + 4194304;       // 3,145,728
  unsigned short* decC  = U16 + 7340032;       // 1,048,576
  unsigned short* w3t   = U16 + 8388608;       // 9,216 (pad 16,384)
  float* H0  = ZR;
  unsigned short* Y1 = (unsigned short*)ZR;    // 16,777,216 u16 (decoder stage only)
  float* out = (float*)d_out;

  // ---- weight prep (bf16, [N][K] layouts)
  k_cvt_trans<<<dim3(16,64,1),256,0,stream>>>(tagg_w, taggT, 2048, 512, 0, 0);
  k_cvt_trans<<<dim3(16,16,12),256,0,stream>>>(mw1, mwT1, 512, 512, 262144, 262144);
  k_cvt_trans<<<dim3(16,16,12),256,0,stream>>>(mw2, mwT2, 512, 512, 262144, 262144);
  k_cvt<<<4096,256,0,stream>>>(dec_w, decC, 1048576);
  k_prep_w3<<<36,256,0,stream>>>(c3_w, w3t);

  // ---- encoder
  k_patch<<<32768, 64, 0, stream>>>(x, patch_w, patch_b, P1);
  k_embed<<<32768, 64, 0, stream>>>(P1, p1_w, p1_b, pos, gamma, H0);
  k_mgemm<0,0,0,0><<<dim3(8,128),256,0,stream>>>(H0, taggT, H, nullptr, nullptr, nullptr,
      2048, 2048, 512);

  for (int d = 0; d < 12; ++d) {
    k_gn_part<<<1024,256,0,stream>>>(H, PART);
    k_gn_apply<<<1024,256,0,stream>>>(H, PART, gn1_s + d*512, gn1_b + d*512, Z);
    k_dft_a<<<512,256,0,stream>>>(Z, AR, AI);
    k_dft_b<<<256,256,0,stream>>>(AR, AI, X);
    k_mode_prep<<<256,256,0,stream>>>(aw1 + (size_t)d*65536, aw2 + (size_t)d*65536, S);
    const float* ab1_d = ab1 + d*1024;
    const float* ab2_d = ab2 + d*1024;
    k_gemm<1,1,0><<<dim3(1,32,8),256,0,stream>>>(X, S,          O1,      ab1_d,      nullptr,
        2048, 64, 128, 128, 64, 128, 262144LL, 8192LL, 262144LL, 64);
    k_gemm<1,1,0><<<dim3(1,32,8),256,0,stream>>>(X, S + 65536,  O1 + 64, ab1_d + 512, nullptr,
        2048, 64, 128, 128, 64, 128, 262144LL, 8192LL, 262144LL, 64);
    k_gemm<1,0,0><<<dim3(1,32,8),256,0,stream>>>(O1, S + 131072, X,           ab2_d,      nullptr,
        2048, 64, 128, 128, 64, 512, 262144LL, 8192LL, 64LL, 64);
    k_gemm<1,0,0><<<dim3(1,32,8),256,0,stream>>>(O1, S + 196608, X + 1048576, ab2_d + 512, nullptr,
        2048, 64, 128, 128, 64, 512, 262144LL, 8192LL, 64LL, 64);
    k_idft_d<<<256,256,0,stream>>>(X, X + 1048576, AR, AI);
    k_idft_e<<<512,256,0,stream>>>(AR, AI, Z, ZA);
    k_gn_part<<<1024,256,0,stream>>>(ZA, PART);
    k_gn_apply<<<1024,256,0,stream>>>(ZA, PART, gn2_s + d*512, gn2_b + d*512, Z2);
    k_mgemm<1,1,0,0><<<dim3(8,128),256,0,stream>>>(Z2, mwT1 + (size_t)d*262144, U,
        mb1 + d*512, nullptr, nullptr, 512, 512, 512);
    k_mgemm<1,0,1,0><<<dim3(8,128),256,0,stream>>>(U, mwT2 + (size_t)d*262144, H,
        mb2 + d*512, H, nullptr, 512, 512, 512);
  }

  k_clsmean<<<16,256,0,stream>>>(H, CT);
  k_cls<<<8,512,0,stream>>>(CT, cls_w1, cls_b1, cls_w2, cls_b2, cls_w3, cls_b3, out);
  // decoder: GEMM with fused gelu(+dec_b) -> pixel-layout bf16 Y1, then conv tail
  k_mgemm<0,0,0,1><<<dim3(32,128),256,0,stream>>>(H, decC, nullptr, dec_b, nullptr, Y1,
      512, 512, 0);
  k_tail<<<2048,256,0,stream>>>(Y1, w3t, c1_w, c1_b, out);
}

// Round 3
// 2037.830 us; speedup vs baseline: 2.0611x; 1.3275x over previous
//
#include <hip/hip_runtime.h>
#include <cstddef>

typedef __attribute__((ext_vector_type(8))) short bh8;
typedef __attribute__((ext_vector_type(4))) float f4;

__device__ __forceinline__ float gelu_f(float x){
  return 0.5f * x * (1.0f + erff(x * 0.7071067811865476f));
}

__device__ __forceinline__ unsigned short f2bf(float f){
  unsigned int u = __float_as_uint(f);
  unsigned int r = (u + 0x7FFFu + ((u >> 16) & 1u)) >> 16;
  return (unsigned short)r;
}

__device__ __forceinline__ f4 mfma16(bh8 a, bh8 b, f4 c){
  return __builtin_amdgcn_mfma_f32_16x16x32_bf16(a, b, c, 0, 0, 0);
}

// ---------------- im2col pack: x -> bf16 imat [32768][448]
// col layout: [0,256): px*4+c (data);  [256,320): gx per px; [320,384): gy; [384,448): gz
__global__ __launch_bounds__(256)
void k_pack(const float* __restrict__ x, unsigned short* __restrict__ imat)
{
  const int nb = blockIdx.x;                 // b*1024 + i*32 + j
  const int j = nb & 31, i = (nb >> 5) & 31, b = nb >> 10;
  const int tid = threadIdx.x;
  const int tl = tid >> 6, px = tid & 63;
  const int dy = px >> 3, dx = px & 7;
  const int Y = i * 8 + dy, X = j * 8 + dx;
  const float4 v = *(const float4*)(x + (((size_t)(b * 256 + Y)) * 256 + X) * 16 + tl * 4);
  const size_t row = (size_t)nb * 4 + tl;
  ushort4 ov;
  ov.x = f2bf(v.x); ov.y = f2bf(v.y); ov.z = f2bf(v.z); ov.w = f2bf(v.w);
  *(ushort4*)(imat + row * 448 + px * 4) = ov;
  for (int q = tid; q < 768; q += 256) {
    const int tt = q / 192, r = q - tt * 192;
    const int sec = r >> 6, p2 = r & 63;
    float val;
    if (sec == 0)      val = (float)(i * 8 + (p2 >> 3)) * (1.0f / 255.0f);
    else if (sec == 1) val = (float)(j * 8 + (p2 & 7)) * (1.0f / 255.0f);
    else               val = (float)tt * (1.0f / 3.0f);
    imat[((size_t)nb * 4 + tt) * 448 + 256 + sec * 64 + p2] = f2bf(val);
  }
}

// ---------------- prep Bt_patch [64][448] (+ padded bias) matching k_pack col order
__global__ __launch_bounds__(256)
void k_prep_btp(const float* __restrict__ pw, const float* __restrict__ pb,
                unsigned short* __restrict__ btp, float* __restrict__ pbp)
{
  const int idx = blockIdx.x * 256 + threadIdx.x;   // 28672
  if (idx < 28672) {
    const int n = idx / 448, k = idx - (idx / 448) * 448;
    int l;
    if (k < 256) { const int pxx = k >> 2, c = k & 3; l = pxx * 7 + c; }
    else { const int sec = (k - 256) >> 6, p2 = (k - 256) & 63; l = p2 * 7 + 4 + sec; }
    btp[n * 448 + k] = (n < 35) ? f2bf(pw[l * 35 + n]) : (unsigned short)0;
  }
  if (idx < 64) pbp[idx] = (idx < 35) ? pb[idx] : 0.0f;
}

// ---------------- prep Bt_embed [512][64] (zero pad k>=35)
__global__ __launch_bounds__(256)
void k_prep_bte(const float* __restrict__ w, unsigned short* __restrict__ bte)
{
  const int idx = blockIdx.x * 256 + threadIdx.x;   // 32768
  const int n = idx >> 6, k = idx & 63;
  bte[idx] = (k < 35) ? f2bf(w[k * 512 + n]) : (unsigned short)0;
}

// ---------------- temb table [4][512]
__global__ __launch_bounds__(256)
void k_temb(const float* __restrict__ gamma, float* __restrict__ temb)
{
  const int idx = blockIdx.x * 256 + threadIdx.x;   // 2048
  const int t = idx >> 9, e = idx & 511;
  temb[idx] = cosf((float)t * (1.0f / 3.0f) * gamma[e]);
}

// ---------------- weight prep: fp32 [K][N] -> bf16 [N][K]
__global__ __launch_bounds__(256)
void k_cvt_trans(const float* __restrict__ in, unsigned short* __restrict__ out,
                 int K, int N, long long sIn, long long sOut)
{
  __shared__ float tile[32][33];
  const int z = blockIdx.z;
  in  += (size_t)z * sIn;
  out += (size_t)z * sOut;
  const int n0 = blockIdx.x * 32, k0 = blockIdx.y * 32;
  const int tx = threadIdx.x & 31, ty = threadIdx.x >> 5;
  #pragma unroll
  for (int i = 0; i < 4; ++i)
    tile[ty + i * 8][tx] = in[(size_t)(k0 + ty + i * 8) * N + n0 + tx];
  __syncthreads();
  #pragma unroll
  for (int i = 0; i < 4; ++i)
    out[(size_t)(n0 + ty + i * 8) * K + k0 + tx] = f2bf(tile[tx][ty + i * 8]);
}

__global__ __launch_bounds__(256)
void k_cvt(const float* __restrict__ in, unsigned short* __restrict__ out, int n)
{
  const int idx = blockIdx.x * 256 + threadIdx.x;
  if (idx < n) out[idx] = f2bf(in[idx]);
}

__global__ __launch_bounds__(256)
void k_prep_w3(const float* __restrict__ w, unsigned short* __restrict__ out)
{
  const int idx = blockIdx.x * 256 + threadIdx.x;
  if (idx < 9216) {
    const int kb = idx >> 10, co = (idx >> 5) & 31, ci = idx & 31;
    out[idx] = f2bf(w[(kb * 32 + ci) * 32 + co]);
  }
}

// ---------------- bf16 MFMA GEMM, 64x64 tile.
// ABF: A dtype (1=bf16, 0=fp32 w/ inline cvt). OMODE: 0=f32 C (+RES), 1=bf16 OB,
// 2=EMB (bf16, +bias+pos, *temb), 3=DEC (gelu(+dec_b) -> pixel-scatter bf16)
template<int ABF, int BIAS, int GELU, int RES, int OMODE>
__global__ __launch_bounds__(256)
void k_mgemm(const void* __restrict__ Av, const unsigned short* __restrict__ Bt,
             float* __restrict__ C, const float* __restrict__ bias,
             const float* __restrict__ Res, unsigned short* __restrict__ OB,
             const float* __restrict__ pos, const float* __restrict__ temb,
             int K, int lda, int ldc)
{
  __shared__ __align__(16) unsigned short As[64 * 40];
  __shared__ __align__(16) unsigned short Bs[64 * 40];
  const int m0 = blockIdx.y * 64, n0 = blockIdx.x * 64;
  const int tid = threadIdx.x;
  const int w = tid >> 6, l = tid & 63;
  const int lr = l & 15, lh = l >> 4;
  const int sr = tid >> 2, skq = (tid & 3) * 8;
  f4 acc[4] = {};
  for (int k0 = 0; k0 < K; k0 += 32) {
    if (ABF) {
      const unsigned short* A = (const unsigned short*)Av;
      const uint4 av = *(const uint4*)(A + (size_t)(m0 + sr) * lda + k0 + skq);
      *(uint4*)(&As[sr * 40 + skq]) = av;
    } else {
      const float* A = (const float*)Av;
      const float* ap = A + (size_t)(m0 + sr) * lda + k0 + skq;
      const float4 a0 = *(const float4*)ap;
      const float4 a1 = *(const float4*)(ap + 4);
      bh8 avv;
      avv[0] = (short)f2bf(a0.x); avv[1] = (short)f2bf(a0.y);
      avv[2] = (short)f2bf(a0.z); avv[3] = (short)f2bf(a0.w);
      avv[4] = (short)f2bf(a1.x); avv[5] = (short)f2bf(a1.y);
      avv[6] = (short)f2bf(a1.z); avv[7] = (short)f2bf(a1.w);
      *(bh8*)(&As[sr * 40 + skq]) = avv;
    }
    const uint4 bv = *(const uint4*)(Bt + (size_t)(n0 + sr) * K + k0 + skq);
    *(uint4*)(&Bs[sr * 40 + skq]) = bv;
    __syncthreads();
    const bh8 af = *(const bh8*)(&As[(w * 16 + lr) * 40 + lh * 8]);
    #pragma unroll
    for (int ct = 0; ct < 4; ++ct) {
      const bh8 bf = *(const bh8*)(&Bs[(ct * 16 + lr) * 40 + lh * 8]);
      acc[ct] = mfma16(af, bf, acc[ct]);
    }
    __syncthreads();
  }
  #pragma unroll
  for (int ct = 0; ct < 4; ++ct) {
    const int col = n0 + ct * 16 + lr;
    float bv = 0.f;
    if (BIAS) bv = bias[col];
    if (OMODE == 3) bv = bias[col & 31];
    #pragma unroll
    for (int r = 0; r < 4; ++r) {
      const int row = m0 + w * 16 + lh * 4 + r;
      float v = acc[ct][r] + bv;
      if (GELU) v = gelu_f(v);
      if (OMODE == 2) {
        const int hw = (row >> 2) & 1023, t = row & 3;
        v = (v + pos[(size_t)hw * 512 + col]) * temb[t * 512 + col];
        OB[(size_t)row * 512 + col] = f2bf(v);
      } else if (OMODE == 1) {
        OB[(size_t)row * ldc + col] = f2bf(v);
      } else if (OMODE == 3) {
        const int bb = row >> 10, hw = row & 1023, ii = hw >> 5, jj = hw & 31;
        const int dxy = col >> 5, dy = dxy >> 3, dx = dxy & 7, cc = col & 31;
        OB[(((size_t)(bb * 256 + ii * 8 + dy)) * 256 + jj * 8 + dx) * 32 + cc] = f2bf(v);
      } else {
        const size_t ci = (size_t)row * ldc + col;
        if (RES) v += Res[ci];
        C[ci] = v;
      }
    }
  }
}

// ---------------- decoder tail: conv3x3 (MFMA implicit-im2col) + gelu + 1x1 -> out
__global__ __launch_bounds__(256)
void k_tail(const unsigned short* __restrict__ Y1, const unsigned short* __restrict__ w3t,
            const float* __restrict__ c1w, const float* __restrict__ c1b,
            float* __restrict__ outp)
{
  __shared__ __align__(16) char lbuf[256 * 33 * 4];
  __shared__ float c1s[128];
  unsigned short* it = (unsigned short*)lbuf;
  float* y2 = (float*)lbuf;
  const int bx = blockIdx.x;
  const int b = bx >> 8, ty = (bx >> 4) & 15, tx = bx & 15;
  const int Y0 = ty * 16, X0 = tx * 16;
  const int tid = threadIdx.x;
  const int w = tid >> 6, l = tid & 63, lr = l & 15, lh = l >> 4;

  if (tid < 128) c1s[tid] = c1w[tid];
  for (int idx = tid; idx < 1296; idx += 256) {
    const int r = idx / 72, rem = idx - r * 72, c = rem >> 2, q = rem & 3;
    const int Yg = Y0 + r - 1, Xg = X0 + c - 1;
    uint4 v = make_uint4(0u, 0u, 0u, 0u);
    if (Yg >= 0 && Yg < 256 && Xg >= 0 && Xg < 256)
      v = *(const uint4*)(Y1 + (((size_t)(b * 256 + Yg)) * 256 + Xg) * 32 + q * 8);
    *(uint4*)(&it[(r * 18 + c) * 40 + q * 8]) = v;
  }
  bh8 bw[2][9];
  #pragma unroll
  for (int ct = 0; ct < 2; ++ct)
    #pragma unroll
    for (int kb = 0; kb < 9; ++kb)
      bw[ct][kb] = *(const bh8*)(w3t + (size_t)(kb * 32 + ct * 16 + lr) * 32 + lh * 8);
  __syncthreads();

  f4 acc[4][2] = {};
  #pragma unroll
  for (int kb = 0; kb < 9; ++kb) {
    const int dy = kb / 3, dx = kb % 3;
    #pragma unroll
    for (int yy = 0; yy < 4; ++yy) {
      const int y = w * 4 + yy;
      const bh8 af = *(const bh8*)(&it[((y + dy) * 18 + lr + dx) * 40 + lh * 8]);
      acc[yy][0] = mfma16(af, bw[0][kb], acc[yy][0]);
      acc[yy][1] = mfma16(af, bw[1][kb], acc[yy][1]);
    }
  }
  __syncthreads();
  #pragma unroll
  for (int yy = 0; yy < 4; ++yy) {
    const int y = w * 4 + yy;
    #pragma unroll
    for (int ct = 0; ct < 2; ++ct)
      #pragma unroll
      for (int r = 0; r < 4; ++r)
        y2[(y * 16 + lh * 4 + r) * 33 + ct * 16 + lr] = gelu_f(acc[yy][ct][r]);
  }
  __syncthreads();
  const int py = tid >> 4, px = tid & 15;
  float o0 = c1b[0], o1 = c1b[1], o2 = c1b[2], o3 = c1b[3];
  #pragma unroll 8
  for (int ci = 0; ci < 32; ++ci) {
    const float v = y2[tid * 33 + ci];
    o0 = fmaf(v, c1s[ci * 4 + 0], o0);
    o1 = fmaf(v, c1s[ci * 4 + 1], o1);
    o2 = fmaf(v, c1s[ci * 4 + 2], o2);
    o3 = fmaf(v, c1s[ci * 4 + 3], o3);
  }
  float4 ov; ov.x = o0; ov.y = o1; ov.z = o2; ov.w = o3;
  *(float4*)(outp + (((size_t)(b * 256 + Y0 + py)) * 256 + X0 + px) * 4) = ov;
}

// ---------------- generic fp32 GEMM (AFNO merged stages)
template<int BIAS, int GELU, int RES>
__global__ __launch_bounds__(256)
void k_gemm(const float* __restrict__ A, const float* __restrict__ B,
            float* __restrict__ C, const float* __restrict__ bias,
            const float* __restrict__ Res,
            int M, int N, int K, int lda, int ldb, int ldc,
            long long sAz, long long sBz, long long sCz, int sBiasZ)
{
  __shared__ float As[16][68];
  __shared__ float Bs[16][68];
  const int z = blockIdx.z;
  A += (size_t)z * sAz;
  B += (size_t)z * sBz;
  const int n0 = blockIdx.x * 64, m0 = blockIdx.y * 64;
  const int tid = threadIdx.x;
  const int tx = tid & 15, ty = tid >> 4;
  const int amm = tid >> 2, akb = (tid & 3) << 2;
  const int bkk = tid >> 4, bnb = (tid & 15) << 2;
  float acc[4][4] = {};
  for (int k0 = 0; k0 < K; k0 += 16) {
    const float4 av = *(const float4*)(A + (size_t)(m0 + amm) * lda + k0 + akb);
    const float4 bv = *(const float4*)(B + (size_t)(k0 + bkk) * ldb + n0 + bnb);
    As[akb + 0][amm] = av.x;
    As[akb + 1][amm] = av.y;
    As[akb + 2][amm] = av.z;
    As[akb + 3][amm] = av.w;
    *(float4*)(&Bs[bkk][bnb]) = bv;
    __syncthreads();
    #pragma unroll
    for (int kk = 0; kk < 16; ++kk) {
      const float4 a4 = *(const float4*)(&As[kk][ty * 4]);
      const float4 b4 = *(const float4*)(&Bs[kk][tx * 4]);
      const float a_[4] = {a4.x, a4.y, a4.z, a4.w};
      const float b_[4] = {b4.x, b4.y, b4.z, b4.w};
      #pragma unroll
      for (int i = 0; i < 4; ++i)
        #pragma unroll
        for (int jj = 0; jj < 4; ++jj)
          acc[i][jj] = fmaf(a_[i], b_[jj], acc[i][jj]);
    }
    __syncthreads();
  }
  float4 bv4 = make_float4(0.f, 0.f, 0.f, 0.f);
  if (BIAS) bv4 = *(const float4*)(bias + (size_t)z * sBiasZ + n0 + tx * 4);
  #pragma unroll
  for (int i = 0; i < 4; ++i) {
    const size_t ci = (size_t)z * sCz + (size_t)(m0 + ty * 4 + i) * ldc + n0 + tx * 4;
    float4 o;
    o.x = acc[i][0] + bv4.x; o.y = acc[i][1] + bv4.y;
    o.z = acc[i][2] + bv4.z; o.w = acc[i][3] + bv4.w;
    if (GELU) { o.x = gelu_f(o.x); o.y = gelu_f(o.y); o.z = gelu_f(o.z); o.w = gelu_f(o.w); }
    if (RES) {
      const float4 r = *(const float4*)(Res + ci);
      o.x += r.x; o.y += r.y; o.z += r.z; o.w += r.w;
    }
    *(float4*)(C + ci) = o;
  }
}

// ---------------- GroupNorm partial sums
__global__ __launch_bounds__(256)
void k_gn_part(const float* __restrict__ in, float* __restrict__ part)
{
  __shared__ float r1[256], r2[256];
  const int blk = blockIdx.x;
  const int s = blk & 15, g = (blk >> 4) & 7, b = blk >> 7;
  const int tid = threadIdx.x;
  const int cc = tid & 63, pp = tid >> 6;
  const float* base = in + ((size_t)b * 1024 + s * 64) * 512 + g * 64;
  float s1 = 0.f, s2 = 0.f;
  for (int p = pp; p < 64; p += 4) {
    const float v = base[(size_t)p * 512 + cc];
    s1 += v; s2 += v * v;
  }
  r1[tid] = s1; r2[tid] = s2;
  __syncthreads();
  for (int o = 128; o > 0; o >>= 1) {
    if (tid < o) { r1[tid] += r1[tid + o]; r2[tid] += r2[tid + o]; }
    __syncthreads();
  }
  if (tid == 0) { part[blk] = r1[0]; part[1024 + blk] = r2[0]; }
}

__device__ __forceinline__ void gn_coef(const float* part, const float* sc,
                                        const float* bi, int b, int c,
                                        float& sca, float& sh)
{
  const int g = c >> 6;
  float s1 = 0.f, s2 = 0.f;
  #pragma unroll
  for (int q = 0; q < 16; ++q) {
    s1 += part[(b * 8 + g) * 16 + q];
    s2 += part[1024 + (b * 8 + g) * 16 + q];
  }
  const float mu = s1 * (1.0f / 65536.0f);
  const float var = s2 * (1.0f / 65536.0f) - mu * mu;
  const float rs = rsqrtf(var + 1e-5f);
  sca = sc[c] * rs;
  sh = bi[c] - mu * sca;
}

// ---------------- gn2 apply -> bf16
__global__ __launch_bounds__(256)
void k_gn_apply_bf(const float* __restrict__ in, const float* __restrict__ part,
                   const float* __restrict__ sc, const float* __restrict__ bi,
                   unsigned short* __restrict__ out)
{
  const int blk = blockIdx.x;
  const int s = blk & 15, g = (blk >> 4) & 7, b = blk >> 7;
  const int tid = threadIdx.x;
  const int cc = tid & 63, pp = tid >> 6;
  float sca, sh;
  gn_coef(part, sc, bi, b, g * 64 + cc, sca, sh);
  const float* base = in + ((size_t)b * 1024 + s * 64) * 512 + g * 64;
  unsigned short* ob = out + ((size_t)b * 1024 + s * 64) * 512 + g * 64;
  for (int p = pp; p < 64; p += 4)
    ob[(size_t)p * 512 + cc] = f2bf(fmaf(base[(size_t)p * 512 + cc], sca, sh));
}

// ---------------- forward DFT stage A with fused gn1 affine
__global__ __launch_bounds__(256)
void k_dft_a(const float* __restrict__ H, const float* __restrict__ part,
             const float* __restrict__ sc, const float* __restrict__ bi,
             float* __restrict__ Ar, float* __restrict__ Ai)
{
  __shared__ float ct[512], st[512];
  const int tid = threadIdx.x;
  for (int q = tid; q < 512; q += 256) {
    const int k = q >> 5, y = q & 31;
    const float ang = (float)((k * y) & 31) * 0.19634954084936207f;
    ct[q] = cosf(ang); st[q] = sinf(ang);
  }
  __syncthreads();
  const int blk = blockIdx.x;
  const int half = blk & 1, x = (blk >> 1) & 31, b = blk >> 6;
  const int c = half * 256 + tid;
  float sca, sh;
  gn_coef(part, sc, bi, b, c, sca, sh);
  float ar[16], ai[16];
  #pragma unroll
  for (int k = 0; k < 16; ++k) { ar[k] = 0.f; ai[k] = 0.f; }
  const float* zp = H + ((size_t)b * 1024 + x) * 512 + c;
  for (int y = 0; y < 32; ++y) {
    const float v = fmaf(zp[(size_t)y * 32 * 512], sca, sh);
    #pragma unroll
    for (int k = 0; k < 16; ++k) {
      ar[k] = fmaf(v, ct[k * 32 + y], ar[k]);
      ai[k] = fmaf(-v, st[k * 32 + y], ai[k]);
    }
  }
  #pragma unroll
  for (int k = 0; k < 16; ++k) {
    const size_t o = (((size_t)b * 16 + k) * 32 + x) * 512 + c;
    Ar[o] = ar[k]; Ai[o] = ai[k];
  }
}

// ---------------- forward DFT stage B -> stacked X [z][2048][128]
__global__ __launch_bounds__(256)
void k_dft_b(const float* __restrict__ Ar, const float* __restrict__ Ai, float* __restrict__ X)
{
  __shared__ float ct[512], st[512];
  const int tid = threadIdx.x;
  for (int q = tid; q < 512; q += 256) {
    const int k = q >> 5, xx = q & 31;
    const float ang = (float)((k * xx) & 31) * 0.19634954084936207f;
    ct[q] = cosf(ang); st[q] = sinf(ang);
  }
  __syncthreads();
  const int blk = blockIdx.x;
  const int half = blk & 1, kh = (blk >> 1) & 15, b = blk >> 5;
  const int c = half * 256 + tid;
  float gr[16], gi[16];
  #pragma unroll
  for (int k = 0; k < 16; ++k) { gr[k] = 0.f; gi[k] = 0.f; }
  const float* arp = Ar + (((size_t)b * 16 + kh) * 32) * 512 + c;
  const float* aip = Ai + (((size_t)b * 16 + kh) * 32) * 512 + c;
  for (int x = 0; x < 32; ++x) {
    const float vr = arp[(size_t)x * 512], vi = aip[(size_t)x * 512];
    #pragma unroll
    for (int k = 0; k < 16; ++k) {
      const float cc_ = ct[k * 32 + x], ss = st[k * 32 + x];
      gr[k] += vr * cc_ + vi * ss;
      gi[k] += vi * cc_ - vr * ss;
    }
  }
  const int blkc = c >> 6, ii = c & 63;
  #pragma unroll
  for (int k = 0; k < 16; ++k) {
    const size_t pos = (size_t)b * 256 + kh * 16 + k;
    float* xp = X + ((size_t)blkc * 2048 + pos) * 128 + ii;
    xp[0]  = gr[k] * (1.0f / 32.0f);
    xp[64] = gi[k] * (1.0f / 32.0f);
  }
}

// ---------------- merged AFNO weights: S[2][8][128][128] + SB[2][8][128]
__global__ __launch_bounds__(256)
void k_mode_prep2(const float* __restrict__ aw1_d, const float* __restrict__ aw2_d,
                  const float* __restrict__ ab1_d, const float* __restrict__ ab2_d,
                  float* __restrict__ S, float* __restrict__ SB)
{
  const int idx = blockIdx.x * 256 + threadIdx.x;   // 262144
  const int s = idx >> 17;
  const int blk = (idx >> 14) & 7;
  const int k = (idx >> 7) & 127;
  const int q = idx & 127;
  const float* aw = s ? aw2_d : aw1_d;
  const int i = k & 63, o = q & 63;
  const float wr = aw[(blk * 64 + i) * 64 + o];
  const float wi = aw[32768 + (blk * 64 + i) * 64 + o];
  float val;
  if (q < 64) val = (k < 64) ? wr : -wi;
  else        val = (k < 64) ? wi :  wr;
  S[idx] = val;
  if (idx < 2048) {
    const int s2 = idx >> 10, r2 = idx & 1023, b2 = r2 >> 7, q2 = r2 & 127;
    const float* ab = s2 ? ab2_d : ab1_d;
    SB[idx] = (q2 < 64) ? ab[b2 * 64 + q2] : ab[512 + b2 * 64 + (q2 - 64)];
  }
}

// ---------------- inverse DFT stage D (reads stacked X2 [z][2048][128])
__global__ __launch_bounds__(256)
void k_idft_d(const float* __restrict__ X2, float* __restrict__ Tr, float* __restrict__ Ti)
{
  __shared__ float ct[512], st[512];
  const int tid = threadIdx.x;
  for (int q = tid; q < 512; q += 256) {
    const int kw = q >> 5, xx = q & 31;
    const float w = (kw == 0) ? 1.0f : 2.0f;
    const float ang = (float)((kw * xx) & 31) * 0.19634954084936207f;
    ct[q] = w * cosf(ang); st[q] = w * sinf(ang);
  }
  __syncthreads();
  const int blk = blockIdx.x;
  const int half = blk & 1, kh = (blk >> 1) & 15, b = blk >> 5;
  const int c = half * 256 + tid;
  const int blkc = c >> 6, ii = c & 63;
  float gr[16], gi[16];
  #pragma unroll
  for (int kw = 0; kw < 16; ++kw) {
    const size_t pos = (size_t)b * 256 + kh * 16 + kw;
    gr[kw] = X2[((size_t)blkc * 2048 + pos) * 128 + ii];
    gi[kw] = X2[((size_t)blkc * 2048 + pos) * 128 + 64 + ii];
  }
  for (int x = 0; x < 32; ++x) {
    float tr = 0.f, ti = 0.f;
    #pragma unroll
    for (int kw = 0; kw < 16; ++kw) {
      const float cc_ = ct[kw * 32 + x], ss = st[kw * 32 + x];
      tr += gr[kw] * cc_ - gi[kw] * ss;
      ti += gi[kw] * cc_ + gr[kw] * ss;
    }
    const size_t o = (((size_t)b * 16 + kh) * 32 + x) * 512 + c;
    Tr[o] = tr; Ti[o] = ti;
  }
}

// ---------------- inverse DFT stage E + fused gn1-affine residual
__global__ __launch_bounds__(256)
void k_idft_e(const float* __restrict__ Tr, const float* __restrict__ Ti,
              const float* __restrict__ H, const float* __restrict__ part,
              const float* __restrict__ sc, const float* __restrict__ bi,
              float* __restrict__ za)
{
  __shared__ float ct[512], st[512];
  const int tid = threadIdx.x;
  for (int q = tid; q < 512; q += 256) {
    const int k = q >> 5, y = q & 31;
    const float ang = (float)((k * y) & 31) * 0.19634954084936207f;
    ct[q] = cosf(ang); st[q] = sinf(ang);
  }
  __syncthreads();
  const int blk = blockIdx.x;
  const int half = blk & 1, x = (blk >> 1) & 31, b = blk >> 6;
  const int c = half * 256 + tid;
  float sca, sh;
  gn_coef(part, sc, bi, b, c, sca, sh);
  float trv[16], tiv[16];
  #pragma unroll
  for (int k = 0; k < 16; ++k) {
    const size_t o = (((size_t)b * 16 + k) * 32 + x) * 512 + c;
    trv[k] = Tr[o]; tiv[k] = Ti[o];
  }
  for (int y = 0; y < 32; ++y) {
    float v = 0.f;
    #pragma unroll
    for (int k = 0; k < 16; ++k)
      v += trv[k] * ct[k * 32 + y] - tiv[k] * st[k * 32 + y];
    const size_t o = ((size_t)b * 1024 + y * 32 + x) * 512 + c;
    za[o] = v * (1.0f / 32.0f) + fmaf(H[o], sca, sh);
  }
}

// ---------------- cls mean
__global__ __launch_bounds__(256)
void k_clsmean(const float* __restrict__ h, float* __restrict__ ctok)
{
  const int blk = blockIdx.x;
  const int half = blk & 1, b = blk >> 1;
  const int c = half * 256 + threadIdx.x;
  float s = 0.f;
  const float* p = h + (size_t)b * 1024 * 512 + c;
  for (int r = 0; r < 1024; ++r) s += p[(size_t)r * 512];
  ctok[b * 512 + c] = s * (1.0f / 1024.0f);
}

// ---------------- cls MLP
__global__ __launch_bounds__(512)
void k_cls(const float* __restrict__ tok,
           const float* __restrict__ w1, const float* __restrict__ b1,
           const float* __restrict__ w2, const float* __restrict__ b2,
           const float* __restrict__ w3, const float* __restrict__ b3,
           float* __restrict__ outp)
{
  __shared__ float tv[512], c1[512], c2[512];
  const int b = blockIdx.x, tid = threadIdx.x;
  tv[tid] = tok[b * 512 + tid];
  __syncthreads();
  float a = b1[tid];
  for (int i = 0; i < 512; ++i) a = fmaf(tv[i], w1[i * 512 + tid], a);
  c1[tid] = gelu_f(a);
  __syncthreads();
  a = b2[tid];
  for (int i = 0; i < 512; ++i) a = fmaf(c1[i], w2[i * 512 + tid], a);
  c2[tid] = gelu_f(a);
  __syncthreads();
  if (tid < 12) {
    a = b3[tid];
    for (int i = 0; i < 512; ++i) a = fmaf(c2[i], w3[i * 12 + tid], a);
    outp[2097152 + b * 12 + tid] = a;
  }
}

extern "C" void kernel_launch(void* const* d_in, const int* in_sizes, int n_in,
                              void* d_out, int out_size, void* d_ws, size_t ws_size,
                              hipStream_t stream)
{
  (void)in_sizes; (void)n_in; (void)out_size; (void)ws_size;
  const float* x      = (const float*)d_in[0];
  const float* patch_w= (const float*)d_in[1];
  const float* patch_b= (const float*)d_in[2];
  const float* p1_w   = (const float*)d_in[3];
  const float* p1_b   = (const float*)d_in[4];
  const float* pos    = (const float*)d_in[5];
  const float* tagg_w = (const float*)d_in[6];
  const float* gamma  = (const float*)d_in[7];
  const float* gn1_s  = (const float*)d_in[8];
  const float* gn1_b  = (const float*)d_in[9];
  const float* aw1    = (const float*)d_in[10];
  const float* ab1    = (const float*)d_in[11];
  const float* aw2    = (const float*)d_in[12];
  const float* ab2    = (const float*)d_in[13];
  const float* gn2_s  = (const float*)d_in[14];
  const float* gn2_b  = (const float*)d_in[15];
  const float* mw1    = (const float*)d_in[16];
  const float* mb1    = (const float*)d_in[17];
  const float* mw2    = (const float*)d_in[18];
  const float* mb2    = (const float*)d_in[19];
  const float* cls_w1 = (const float*)d_in[20];
  const float* cls_b1 = (const float*)d_in[21];
  const float* cls_w2 = (const float*)d_in[22];
  const float* cls_b2 = (const float*)d_in[23];
  const float* cls_w3 = (const float*)d_in[24];
  const float* cls_b3 = (const float*)d_in[25];
  const float* dec_w  = (const float*)d_in[26];
  const float* dec_b  = (const float*)d_in[27];
  const float* c3_w   = (const float*)d_in[28];
  const float* c3_b   = (const float*)d_in[29];
  const float* c1_w   = (const float*)d_in[30];
  const float* c1_b   = (const float*)d_in[31];

  float* W    = (float*)d_ws;
  float* H    = W;                       // 4,194,304
  float* AR   = W + 4194304;             // 2,097,152  (Ar/Tr)
  float* AI   = W + 6291456;             // 2,097,152  (Ai/Ti)
  float* X    = W + 8388608;             // 2,097,152  (modes; Z2b bf16)
  float* O1   = W + 10485760;            // 2,097,152  (O1; U bf16; P1b bf16)
  float* S    = W + 12582912;            // 262,144
  float* SB   = W + 12845056;            // 2,048
  float* PART = W + 12847104;            // 2,048
  float* CT   = W + 12849152;            // 4,096
  float* TEMB = W + 12853248;            // 2,048
  float* PBP  = W + 12855296;            // 64
  float* R1   = W + 12855360;            // 8,388,608 (imat/H0b/ZA/Y1)
  unsigned short* taggT = (unsigned short*)(W + 21243968);   // 1,048,576 sh
  unsigned short* mwT1  = (unsigned short*)(W + 21768256);   // 3,145,728 sh
  unsigned short* mwT2  = (unsigned short*)(W + 23341120);   // 3,145,728 sh
  unsigned short* decC  = (unsigned short*)(W + 24913984);   // 1,048,576 sh
  unsigned short* w3t   = (unsigned short*)(W + 25438272);   // 16,384 sh
  unsigned short* btp   = (unsigned short*)(W + 25446464);   // 28,672 sh
  unsigned short* bte   = (unsigned short*)(W + 25460800);   // 32,768 sh

  unsigned short* imat = (unsigned short*)R1;
  unsigned short* H0b  = (unsigned short*)R1;
  unsigned short* Y1   = (unsigned short*)R1;
  float* ZA = R1;
  unsigned short* P1b = (unsigned short*)O1;
  unsigned short* Z2b = (unsigned short*)X;
  unsigned short* Ub  = (unsigned short*)O1;
  float* out = (float*)d_out;

  // ---- weight prep
  k_cvt_trans<<<dim3(16,64,1),256,0,stream>>>(tagg_w, taggT, 2048, 512, 0, 0);
  k_cvt_trans<<<dim3(16,16,12),256,0,stream>>>(mw1, mwT1, 512, 512, 262144, 262144);
  k_cvt_trans<<<dim3(16,16,12),256,0,stream>>>(mw2, mwT2, 512, 512, 262144, 262144);
  k_cvt<<<4096,256,0,stream>>>(dec_w, decC, 1048576);
  k_prep_w3<<<36,256,0,stream>>>(c3_w, w3t);
  k_prep_btp<<<112,256,0,stream>>>(patch_w, patch_b, btp, PBP);
  k_prep_bte<<<128,256,0,stream>>>(p1_w, bte);
  k_temb<<<8,256,0,stream>>>(gamma, TEMB);

  // ---- encoder: im2col + 2 MFMA GEMMs + tagg
  k_pack<<<8192,256,0,stream>>>(x, imat);
  k_mgemm<1,1,1,0,1><<<dim3(1,512),256,0,stream>>>(imat, btp, nullptr, PBP, nullptr,
      P1b, nullptr, nullptr, 448, 448, 64);
  k_mgemm<1,1,0,0,2><<<dim3(8,512),256,0,stream>>>(P1b, bte, nullptr, p1_b, nullptr,
      H0b, pos, TEMB, 64, 64, 512);
  k_mgemm<1,0,0,0,0><<<dim3(8,128),256,0,stream>>>(H0b, taggT, H, nullptr, nullptr,
      nullptr, nullptr, nullptr, 2048, 2048, 512);

  for (int d = 0; d < 12; ++d) {
    k_gn_part<<<1024,256,0,stream>>>(H, PART);
    k_dft_a<<<512,256,0,stream>>>(H, PART, gn1_s + d*512, gn1_b + d*512, AR, AI);
    k_dft_b<<<256,256,0,stream>>>(AR, AI, X);
    k_mode_prep2<<<1024,256,0,stream>>>(aw1 + (size_t)d*65536, aw2 + (size_t)d*65536,
        ab1 + d*1024, ab2 + d*1024, S, SB);
    k_gemm<1,1,0><<<dim3(2,32,8),256,0,stream>>>(X, S, O1, SB, nullptr,
        2048, 128, 128, 128, 128, 128, 262144LL, 16384LL, 262144LL, 128);
    k_gemm<1,0,0><<<dim3(2,32,8),256,0,stream>>>(O1, S + 131072, X, SB + 1024, nullptr,
        2048, 128, 128, 128, 128, 128, 262144LL, 16384LL, 262144LL, 128);
    k_idft_d<<<256,256,0,stream>>>(X, AR, AI);
    k_idft_e<<<512,256,0,stream>>>(AR, AI, H, PART, gn1_s + d*512, gn1_b + d*512, ZA);
    k_gn_part<<<1024,256,0,stream>>>(ZA, PART);
    k_gn_apply_bf<<<1024,256,0,stream>>>(ZA, PART, gn2_s + d*512, gn2_b + d*512, Z2b);
    k_mgemm<1,1,1,0,1><<<dim3(8,128),256,0,stream>>>(Z2b, mwT1 + (size_t)d*262144, nullptr,
        mb1 + d*512, nullptr, Ub, nullptr, nullptr, 512, 512, 512);
    k_mgemm<1,1,0,1,0><<<dim3(8,128),256,0,stream>>>(Ub, mwT2 + (size_t)d*262144, H,
        mb2 + d*512, H, nullptr, nullptr, nullptr, 512, 512, 512);
  }

  k_clsmean<<<16,256,0,stream>>>(H, CT);
  k_cls<<<8,512,0,stream>>>(CT, cls_w1, cls_b1, cls_w2, cls_b2, cls_w3, cls_b3, out);
  k_mgemm<0,0,1,0,3><<<dim3(32,128),256,0,stream>>>(H, decC, nullptr, dec_b, nullptr,
      Y1, nullptr, nullptr, 512, 512, 0);
  k_tail<<<2048,256,0,stream>>>(Y1, w3t, c1_w, c1_b, out);
}

// Round 4
// 1909.234 us; speedup vs baseline: 2.1999x; 1.0674x over previous
//
#include <hip/hip_runtime.h>
#include <cstddef>

typedef __attribute__((ext_vector_type(8))) short bh8;
typedef __attribute__((ext_vector_type(4))) float f4;

__device__ __forceinline__ float gelu_f(float x){
  return 0.5f * x * (1.0f + erff(x * 0.7071067811865476f));
}

__device__ __forceinline__ unsigned short f2bf(float f){
  unsigned int u = __float_as_uint(f);
  unsigned int r = (u + 0x7FFFu + ((u >> 16) & 1u)) >> 16;
  return (unsigned short)r;
}

__device__ __forceinline__ float bf2f(unsigned short u){
  return __uint_as_float(((unsigned int)u) << 16);
}

__device__ __forceinline__ f4 mfma16(bh8 a, bh8 b, f4 c){
  return __builtin_amdgcn_mfma_f32_16x16x32_bf16(a, b, c, 0, 0, 0);
}

// ---------------- im2col pack: x -> bf16 imat [32768][448]
__global__ __launch_bounds__(256)
void k_pack(const float* __restrict__ x, unsigned short* __restrict__ imat)
{
  const int nb = blockIdx.x;                 // b*1024 + i*32 + j
  const int j = nb & 31, i = (nb >> 5) & 31, b = nb >> 10;
  const int tid = threadIdx.x;
  const int tl = tid >> 6, px = tid & 63;
  const int dy = px >> 3, dx = px & 7;
  const int Y = i * 8 + dy, X = j * 8 + dx;
  const float4 v = *(const float4*)(x + (((size_t)(b * 256 + Y)) * 256 + X) * 16 + tl * 4);
  const size_t row = (size_t)nb * 4 + tl;
  ushort4 ov;
  ov.x = f2bf(v.x); ov.y = f2bf(v.y); ov.z = f2bf(v.z); ov.w = f2bf(v.w);
  *(ushort4*)(imat + row * 448 + px * 4) = ov;
  for (int q = tid; q < 768; q += 256) {
    const int tt = q / 192, r = q - tt * 192;
    const int sec = r >> 6, p2 = r & 63;
    float val;
    if (sec == 0)      val = (float)(i * 8 + (p2 >> 3)) * (1.0f / 255.0f);
    else if (sec == 1) val = (float)(j * 8 + (p2 & 7)) * (1.0f / 255.0f);
    else               val = (float)tt * (1.0f / 3.0f);
    imat[((size_t)nb * 4 + tt) * 448 + 256 + sec * 64 + p2] = f2bf(val);
  }
}

// ---------------- prep Bt_patch [64][448] (+ padded bias)
__global__ __launch_bounds__(256)
void k_prep_btp(const float* __restrict__ pw, const float* __restrict__ pb,
                unsigned short* __restrict__ btp, float* __restrict__ pbp)
{
  const int idx = blockIdx.x * 256 + threadIdx.x;   // 28672
  if (idx < 28672) {
    const int n = idx / 448, k = idx - (idx / 448) * 448;
    int l;
    if (k < 256) { const int pxx = k >> 2, c = k & 3; l = pxx * 7 + c; }
    else { const int sec = (k - 256) >> 6, p2 = (k - 256) & 63; l = p2 * 7 + 4 + sec; }
    btp[n * 448 + k] = (n < 35) ? f2bf(pw[l * 35 + n]) : (unsigned short)0;
  }
  if (idx < 64) pbp[idx] = (idx < 35) ? pb[idx] : 0.0f;
}

// ---------------- prep Bt_embed [512][64]
__global__ __launch_bounds__(256)
void k_prep_bte(const float* __restrict__ w, unsigned short* __restrict__ bte)
{
  const int idx = blockIdx.x * 256 + threadIdx.x;   // 32768
  const int n = idx >> 6, k = idx & 63;
  bte[idx] = (k < 35) ? f2bf(w[k * 512 + n]) : (unsigned short)0;
}

// ---------------- temb table [4][512]
__global__ __launch_bounds__(256)
void k_temb(const float* __restrict__ gamma, float* __restrict__ temb)
{
  const int idx = blockIdx.x * 256 + threadIdx.x;   // 2048
  const int t = idx >> 9, e = idx & 511;
  temb[idx] = cosf((float)t * (1.0f / 3.0f) * gamma[e]);
}

// ---------------- weight prep: fp32 [K][N] -> bf16 [N][K]
__global__ __launch_bounds__(256)
void k_cvt_trans(const float* __restrict__ in, unsigned short* __restrict__ out,
                 int K, int N, long long sIn, long long sOut)
{
  __shared__ float tile[32][33];
  const int z = blockIdx.z;
  in  += (size_t)z * sIn;
  out += (size_t)z * sOut;
  const int n0 = blockIdx.x * 32, k0 = blockIdx.y * 32;
  const int tx = threadIdx.x & 31, ty = threadIdx.x >> 5;
  #pragma unroll
  for (int i = 0; i < 4; ++i)
    tile[ty + i * 8][tx] = in[(size_t)(k0 + ty + i * 8) * N + n0 + tx];
  __syncthreads();
  #pragma unroll
  for (int i = 0; i < 4; ++i)
    out[(size_t)(n0 + ty + i * 8) * K + k0 + tx] = f2bf(tile[tx][ty + i * 8]);
}

__global__ __launch_bounds__(256)
void k_cvt(const float* __restrict__ in, unsigned short* __restrict__ out, int n)
{
  const int idx = blockIdx.x * 256 + threadIdx.x;
  if (idx < n) out[idx] = f2bf(in[idx]);
}

__global__ __launch_bounds__(256)
void k_prep_w3(const float* __restrict__ w, unsigned short* __restrict__ out)
{
  const int idx = blockIdx.x * 256 + threadIdx.x;
  if (idx < 9216) {
    const int kb = idx >> 10, co = (idx >> 5) & 31, ci = idx & 31;
    out[idx] = f2bf(w[(kb * 32 + ci) * 32 + co]);
  }
}

// ---------------- bf16 MFMA GEMM, 64x64 tile, z-batched.
// ABF: 1=bf16 A, 0=fp32 A, 2=fp32 A with fused GN affine (gnc).
// OMODE: 0=f32 C (+RES), 1=bf16 OB, 2=EMB, 3=DEC pixel-scatter
template<int ABF, int BIAS, int GELU, int RES, int OMODE>
__global__ __launch_bounds__(256)
void k_mgemm(const void* __restrict__ Av, const unsigned short* __restrict__ Bt,
             float* __restrict__ C, const float* __restrict__ bias,
             const float* __restrict__ Res, unsigned short* __restrict__ OB,
             const float* __restrict__ pos, const float* __restrict__ temb,
             const float* __restrict__ gnc,
             int K, int lda, int ldc,
             long long zsA, long long zsB, long long zsC, int zsBias)
{
  __shared__ __align__(16) unsigned short As[64 * 40];
  __shared__ __align__(16) unsigned short Bs[64 * 40];
  const int z = blockIdx.z;
  Bt += (size_t)z * zsB;
  if (BIAS) bias += (size_t)z * zsBias;
  if (OMODE == 0) C += (size_t)z * zsC; else OB += (size_t)z * zsC;
  const int m0 = blockIdx.y * 64, n0 = blockIdx.x * 64;
  const int tid = threadIdx.x;
  const int w = tid >> 6, l = tid & 63;
  const int lr = l & 15, lh = l >> 4;
  const int sr = tid >> 2, skq = (tid & 3) * 8;
  f4 acc[4] = {};
  for (int k0 = 0; k0 < K; k0 += 32) {
    if (ABF == 1) {
      const unsigned short* A = (const unsigned short*)Av + (size_t)z * zsA;
      const uint4 av = *(const uint4*)(A + (size_t)(m0 + sr) * lda + k0 + skq);
      *(uint4*)(&As[sr * 40 + skq]) = av;
    } else {
      const float* A = (const float*)Av + (size_t)z * zsA;
      const float* ap = A + (size_t)(m0 + sr) * lda + k0 + skq;
      float4 a0 = *(const float4*)ap;
      float4 a1 = *(const float4*)(ap + 4);
      if (ABF == 2) {
        const int bb = (m0 + sr) >> 10;
        const float4 s0 = *(const float4*)(gnc + bb * 512 + k0 + skq);
        const float4 s1 = *(const float4*)(gnc + bb * 512 + k0 + skq + 4);
        const float4 h0 = *(const float4*)(gnc + 4096 + bb * 512 + k0 + skq);
        const float4 h1 = *(const float4*)(gnc + 4096 + bb * 512 + k0 + skq + 4);
        a0.x = fmaf(a0.x, s0.x, h0.x); a0.y = fmaf(a0.y, s0.y, h0.y);
        a0.z = fmaf(a0.z, s0.z, h0.z); a0.w = fmaf(a0.w, s0.w, h0.w);
        a1.x = fmaf(a1.x, s1.x, h1.x); a1.y = fmaf(a1.y, s1.y, h1.y);
        a1.z = fmaf(a1.z, s1.z, h1.z); a1.w = fmaf(a1.w, s1.w, h1.w);
      }
      bh8 avv;
      avv[0] = (short)f2bf(a0.x); avv[1] = (short)f2bf(a0.y);
      avv[2] = (short)f2bf(a0.z); avv[3] = (short)f2bf(a0.w);
      avv[4] = (short)f2bf(a1.x); avv[5] = (short)f2bf(a1.y);
      avv[6] = (short)f2bf(a1.z); avv[7] = (short)f2bf(a1.w);
      *(bh8*)(&As[sr * 40 + skq]) = avv;
    }
    const uint4 bv = *(const uint4*)(Bt + (size_t)(n0 + sr) * K + k0 + skq);
    *(uint4*)(&Bs[sr * 40 + skq]) = bv;
    __syncthreads();
    const bh8 af = *(const bh8*)(&As[(w * 16 + lr) * 40 + lh * 8]);
    #pragma unroll
    for (int ct = 0; ct < 4; ++ct) {
      const bh8 bf = *(const bh8*)(&Bs[(ct * 16 + lr) * 40 + lh * 8]);
      acc[ct] = mfma16(af, bf, acc[ct]);
    }
    __syncthreads();
  }
  #pragma unroll
  for (int ct = 0; ct < 4; ++ct) {
    const int col = n0 + ct * 16 + lr;
    float bv = 0.f;
    if (BIAS) bv = bias[col];
    if (OMODE == 3) bv = bias[col & 31];
    #pragma unroll
    for (int r = 0; r < 4; ++r) {
      const int row = m0 + w * 16 + lh * 4 + r;
      float v = acc[ct][r] + bv;
      if (GELU) v = gelu_f(v);
      if (OMODE == 2) {
        const int hw = (row >> 2) & 1023, t = row & 3;
        v = (v + pos[(size_t)hw * 512 + col]) * temb[t * 512 + col];
        OB[(size_t)row * 512 + col] = f2bf(v);
      } else if (OMODE == 1) {
        OB[(size_t)row * ldc + col] = f2bf(v);
      } else if (OMODE == 3) {
        const int bb = row >> 10, hw = row & 1023, ii = hw >> 5, jj = hw & 31;
        const int dxy = col >> 5, dy = dxy >> 3, dx = dxy & 7, cc = col & 31;
        OB[(((size_t)(bb * 256 + ii * 8 + dy)) * 256 + jj * 8 + dx) * 32 + cc] = f2bf(v);
      } else {
        const size_t ci = (size_t)row * ldc + col;
        if (RES) v += Res[ci];
        C[ci] = v;
      }
    }
  }
}

// ---------------- decoder tail: conv3x3 (MFMA) + gelu + 1x1 -> out
__global__ __launch_bounds__(256)
void k_tail(const unsigned short* __restrict__ Y1, const unsigned short* __restrict__ w3t,
            const float* __restrict__ c1w, const float* __restrict__ c1b,
            float* __restrict__ outp)
{
  __shared__ __align__(16) char lbuf[256 * 33 * 4];
  __shared__ float c1s[128];
  unsigned short* it = (unsigned short*)lbuf;
  float* y2 = (float*)lbuf;
  const int bx = blockIdx.x;
  const int b = bx >> 8, ty = (bx >> 4) & 15, tx = bx & 15;
  const int Y0 = ty * 16, X0 = tx * 16;
  const int tid = threadIdx.x;
  const int w = tid >> 6, l = tid & 63, lr = l & 15, lh = l >> 4;

  if (tid < 128) c1s[tid] = c1w[tid];
  for (int idx = tid; idx < 1296; idx += 256) {
    const int r = idx / 72, rem = idx - r * 72, c = rem >> 2, q = rem & 3;
    const int Yg = Y0 + r - 1, Xg = X0 + c - 1;
    uint4 v = make_uint4(0u, 0u, 0u, 0u);
    if (Yg >= 0 && Yg < 256 && Xg >= 0 && Xg < 256)
      v = *(const uint4*)(Y1 + (((size_t)(b * 256 + Yg)) * 256 + Xg) * 32 + q * 8);
    *(uint4*)(&it[(r * 18 + c) * 40 + q * 8]) = v;
  }
  bh8 bw[2][9];
  #pragma unroll
  for (int ct = 0; ct < 2; ++ct)
    #pragma unroll
    for (int kb = 0; kb < 9; ++kb)
      bw[ct][kb] = *(const bh8*)(w3t + (size_t)(kb * 32 + ct * 16 + lr) * 32 + lh * 8);
  __syncthreads();

  f4 acc[4][2] = {};
  #pragma unroll
  for (int kb = 0; kb < 9; ++kb) {
    const int dy = kb / 3, dx = kb % 3;
    #pragma unroll
    for (int yy = 0; yy < 4; ++yy) {
      const int y = w * 4 + yy;
      const bh8 af = *(const bh8*)(&it[((y + dy) * 18 + lr + dx) * 40 + lh * 8]);
      acc[yy][0] = mfma16(af, bw[0][kb], acc[yy][0]);
      acc[yy][1] = mfma16(af, bw[1][kb], acc[yy][1]);
    }
  }
  __syncthreads();
  #pragma unroll
  for (int yy = 0; yy < 4; ++yy) {
    const int y = w * 4 + yy;
    #pragma unroll
    for (int ct = 0; ct < 2; ++ct)
      #pragma unroll
      for (int r = 0; r < 4; ++r)
        y2[(y * 16 + lh * 4 + r) * 33 + ct * 16 + lr] = gelu_f(acc[yy][ct][r]);
  }
  __syncthreads();
  const int py = tid >> 4, px = tid & 15;
  float o0 = c1b[0], o1 = c1b[1], o2 = c1b[2], o3 = c1b[3];
  #pragma unroll 8
  for (int ci = 0; ci < 32; ++ci) {
    const float v = y2[tid * 33 + ci];
    o0 = fmaf(v, c1s[ci * 4 + 0], o0);
    o1 = fmaf(v, c1s[ci * 4 + 1], o1);
    o2 = fmaf(v, c1s[ci * 4 + 2], o2);
    o3 = fmaf(v, c1s[ci * 4 + 3], o3);
  }
  float4 ov; ov.x = o0; ov.y = o1; ov.z = o2; ov.w = o3;
  *(float4*)(outp + (((size_t)(b * 256 + Y0 + py)) * 256 + X0 + px) * 4) = ov;
}

// ---------------- GroupNorm partial sums
__global__ __launch_bounds__(256)
void k_gn_part(const float* __restrict__ in, float* __restrict__ part)
{
  __shared__ float r1[256], r2[256];
  const int blk = blockIdx.x;
  const int s = blk & 15, g = (blk >> 4) & 7, b = blk >> 7;
  const int tid = threadIdx.x;
  const int cc = tid & 63, pp = tid >> 6;
  const float* base = in + ((size_t)b * 1024 + s * 64) * 512 + g * 64;
  float s1 = 0.f, s2 = 0.f;
  for (int p = pp; p < 64; p += 4) {
    const float v = base[(size_t)p * 512 + cc];
    s1 += v; s2 += v * v;
  }
  r1[tid] = s1; r2[tid] = s2;
  __syncthreads();
  for (int o = 128; o > 0; o >>= 1) {
    if (tid < o) { r1[tid] += r1[tid + o]; r2[tid] += r2[tid + o]; }
    __syncthreads();
  }
  if (tid == 0) { part[blk] = r1[0]; part[1024 + blk] = r2[0]; }
}

__device__ __forceinline__ void gn_coef(const float* part, const float* sc,
                                        const float* bi, int b, int c,
                                        float& sca, float& sh)
{
  const int g = c >> 6;
  float s1 = 0.f, s2 = 0.f;
  #pragma unroll
  for (int q = 0; q < 16; ++q) {
    s1 += part[(b * 8 + g) * 16 + q];
    s2 += part[1024 + (b * 8 + g) * 16 + q];
  }
  const float mu = s1 * (1.0f / 65536.0f);
  const float var = s2 * (1.0f / 65536.0f) - mu * mu;
  const float rs = rsqrtf(var + 1e-5f);
  sca = sc[c] * rs;
  sh = bi[c] - mu * sca;
}

// ---------------- gn coef table (8 x 512 sca / sh)
__global__ __launch_bounds__(256)
void k_gn_coef(const float* __restrict__ part, const float* __restrict__ sc,
               const float* __restrict__ bi, float* __restrict__ gnc)
{
  const int idx = blockIdx.x * 256 + threadIdx.x;   // 4096
  const int b = idx >> 9, c = idx & 511;
  float sca, sh;
  gn_coef(part, sc, bi, b, c, sca, sh);
  gnc[idx] = sca; gnc[4096 + idx] = sh;
}

// ---------------- forward DFT stage A with fused gn1 affine
__global__ __launch_bounds__(256)
void k_dft_a(const float* __restrict__ H, const float* __restrict__ part,
             const float* __restrict__ sc, const float* __restrict__ bi,
             float* __restrict__ Ar, float* __restrict__ Ai)
{
  __shared__ float ct[512], st[512];
  const int tid = threadIdx.x;
  for (int q = tid; q < 512; q += 256) {
    const int k = q >> 5, y = q & 31;
    const float ang = (float)((k * y) & 31) * 0.19634954084936207f;
    ct[q] = cosf(ang); st[q] = sinf(ang);
  }
  __syncthreads();
  const int blk = blockIdx.x;
  const int half = blk & 1, x = (blk >> 1) & 31, b = blk >> 6;
  const int c = half * 256 + tid;
  float sca, sh;
  gn_coef(part, sc, bi, b, c, sca, sh);
  float ar[16], ai[16];
  #pragma unroll
  for (int k = 0; k < 16; ++k) { ar[k] = 0.f; ai[k] = 0.f; }
  const float* zp = H + ((size_t)b * 1024 + x) * 512 + c;
  for (int y = 0; y < 32; ++y) {
    const float v = fmaf(zp[(size_t)y * 32 * 512], sca, sh);
    #pragma unroll
    for (int k = 0; k < 16; ++k) {
      ar[k] = fmaf(v, ct[k * 32 + y], ar[k]);
      ai[k] = fmaf(-v, st[k * 32 + y], ai[k]);
    }
  }
  #pragma unroll
  for (int k = 0; k < 16; ++k) {
    const size_t o = (((size_t)b * 16 + k) * 32 + x) * 512 + c;
    Ar[o] = ar[k]; Ai[o] = ai[k];
  }
}

// ---------------- forward DFT stage B -> stacked bf16 X [z][2048][128]
__global__ __launch_bounds__(256)
void k_dft_b(const float* __restrict__ Ar, const float* __restrict__ Ai,
             unsigned short* __restrict__ X)
{
  __shared__ float ct[512], st[512];
  const int tid = threadIdx.x;
  for (int q = tid; q < 512; q += 256) {
    const int k = q >> 5, xx = q & 31;
    const float ang = (float)((k * xx) & 31) * 0.19634954084936207f;
    ct[q] = cosf(ang); st[q] = sinf(ang);
  }
  __syncthreads();
  const int blk = blockIdx.x;
  const int half = blk & 1, kh = (blk >> 1) & 15, b = blk >> 5;
  const int c = half * 256 + tid;
  float gr[16], gi[16];
  #pragma unroll
  for (int k = 0; k < 16; ++k) { gr[k] = 0.f; gi[k] = 0.f; }
  const float* arp = Ar + (((size_t)b * 16 + kh) * 32) * 512 + c;
  const float* aip = Ai + (((size_t)b * 16 + kh) * 32) * 512 + c;
  for (int x = 0; x < 32; ++x) {
    const float vr = arp[(size_t)x * 512], vi = aip[(size_t)x * 512];
    #pragma unroll
    for (int k = 0; k < 16; ++k) {
      const float cc_ = ct[k * 32 + x], ss = st[k * 32 + x];
      gr[k] += vr * cc_ + vi * ss;
      gi[k] += vi * cc_ - vr * ss;
    }
  }
  const int blkc = c >> 6, ii = c & 63;
  #pragma unroll
  for (int k = 0; k < 16; ++k) {
    const size_t pos = (size_t)b * 256 + kh * 16 + k;
    unsigned short* xp = X + ((size_t)blkc * 2048 + pos) * 128 + ii;
    xp[0]  = f2bf(gr[k] * (1.0f / 32.0f));
    xp[64] = f2bf(gi[k] * (1.0f / 32.0f));
  }
}

// ---------------- merged AFNO weights: Sb bf16 [2][8][128(out)][128(in)] + SB f32
__global__ __launch_bounds__(256)
void k_mode_prep3(const float* __restrict__ aw1_d, const float* __restrict__ aw2_d,
                  const float* __restrict__ ab1_d, const float* __restrict__ ab2_d,
                  unsigned short* __restrict__ Sb, float* __restrict__ SB)
{
  const int idx = blockIdx.x * 256 + threadIdx.x;   // 262144
  const int s = idx >> 17;
  const int blk = (idx >> 14) & 7;
  const int n = (idx >> 7) & 127;   // output col
  const int kk = idx & 127;         // input row
  const float* aw = s ? aw2_d : aw1_d;
  const int i = kk & 63, o = n & 63;
  const float wr = aw[(blk * 64 + i) * 64 + o];
  const float wi = aw[32768 + (blk * 64 + i) * 64 + o];
  float val;
  if (n < 64) val = (kk < 64) ? wr : -wi;
  else        val = (kk < 64) ? wi :  wr;
  Sb[idx] = f2bf(val);
  if (idx < 2048) {
    const int s2 = idx >> 10, r2 = idx & 1023, b2 = r2 >> 7, q2 = r2 & 127;
    const float* ab = s2 ? ab2_d : ab1_d;
    SB[idx] = (q2 < 64) ? ab[b2 * 64 + q2] : ab[512 + b2 * 64 + (q2 - 64)];
  }
}

// ---------------- inverse DFT stage D (reads bf16 X2 [z][2048][128])
__global__ __launch_bounds__(256)
void k_idft_d(const unsigned short* __restrict__ X2, float* __restrict__ Tr,
              float* __restrict__ Ti)
{
  __shared__ float ct[512], st[512];
  const int tid = threadIdx.x;
  for (int q = tid; q < 512; q += 256) {
    const int kw = q >> 5, xx = q & 31;
    const float w = (kw == 0) ? 1.0f : 2.0f;
    const float ang = (float)((kw * xx) & 31) * 0.19634954084936207f;
    ct[q] = w * cosf(ang); st[q] = w * sinf(ang);
  }
  __syncthreads();
  const int blk = blockIdx.x;
  const int half = blk & 1, kh = (blk >> 1) & 15, b = blk >> 5;
  const int c = half * 256 + tid;
  const int blkc = c >> 6, ii = c & 63;
  float gr[16], gi[16];
  #pragma unroll
  for (int kw = 0; kw < 16; ++kw) {
    const size_t pos = (size_t)b * 256 + kh * 16 + kw;
    gr[kw] = bf2f(X2[((size_t)blkc * 2048 + pos) * 128 + ii]);
    gi[kw] = bf2f(X2[((size_t)blkc * 2048 + pos) * 128 + 64 + ii]);
  }
  for (int x = 0; x < 32; ++x) {
    float tr = 0.f, ti = 0.f;
    #pragma unroll
    for (int kw = 0; kw < 16; ++kw) {
      const float cc_ = ct[kw * 32 + x], ss = st[kw * 32 + x];
      tr += gr[kw] * cc_ - gi[kw] * ss;
      ti += gi[kw] * cc_ + gr[kw] * ss;
    }
    const size_t o = (((size_t)b * 16 + kh) * 32 + x) * 512 + c;
    Tr[o] = tr; Ti[o] = ti;
  }
}

// ---------------- inverse DFT stage E + fused gn1-affine residual
__global__ __launch_bounds__(256)
void k_idft_e(const float* __restrict__ Tr, const float* __restrict__ Ti,
              const float* __restrict__ H, const float* __restrict__ part,
              const float* __restrict__ sc, const float* __restrict__ bi,
              float* __restrict__ za)
{
  __shared__ float ct[512], st[512];
  const int tid = threadIdx.x;
  for (int q = tid; q < 512; q += 256) {
    const int k = q >> 5, y = q & 31;
    const float ang = (float)((k * y) & 31) * 0.19634954084936207f;
    ct[q] = cosf(ang); st[q] = sinf(ang);
  }
  __syncthreads();
  const int blk = blockIdx.x;
  const int half = blk & 1, x = (blk >> 1) & 31, b = blk >> 6;
  const int c = half * 256 + tid;
  float sca, sh;
  gn_coef(part, sc, bi, b, c, sca, sh);
  float trv[16], tiv[16];
  #pragma unroll
  for (int k = 0; k < 16; ++k) {
    const size_t o = (((size_t)b * 16 + k) * 32 + x) * 512 + c;
    trv[k] = Tr[o]; tiv[k] = Ti[o];
  }
  for (int y = 0; y < 32; ++y) {
    float v = 0.f;
    #pragma unroll
    for (int k = 0; k < 16; ++k)
      v += trv[k] * ct[k * 32 + y] - tiv[k] * st[k * 32 + y];
    const size_t o = ((size_t)b * 1024 + y * 32 + x) * 512 + c;
    za[o] = v * (1.0f / 32.0f) + fmaf(H[o], sca, sh);
  }
}

// ---------------- cls mean partials: PART2[b][16][512]
__global__ __launch_bounds__(256)
void k_clsmean_p(const float* __restrict__ h, float* __restrict__ part2)
{
  const int blk = blockIdx.x;                 // b*16 + ch
  const int ch = blk & 15, b = blk >> 4;
  const int tid = threadIdx.x;
  const float* p = h + (size_t)b * 524288 + (size_t)ch * 64 * 512;
  #pragma unroll
  for (int half = 0; half < 2; ++half) {
    const int c = half * 256 + tid;
    float s = 0.f;
    for (int r = 0; r < 64; ++r) s += p[r * 512 + c];
    part2[(size_t)blk * 512 + c] = s;
  }
}

// ---------------- cls layers 1/2: 64 blocks, 4 thr/output
template<int FIRST>
__global__ __launch_bounds__(256)
void k_cls_l(const float* __restrict__ src, const float* __restrict__ Wm,
             const float* __restrict__ bb, float* __restrict__ Cout)
{
  __shared__ float tok[512];
  __shared__ float red[256];
  const int b = blockIdx.y, oc = blockIdx.x;
  const int tid = threadIdx.x;
  for (int i = tid; i < 512; i += 256) {
    if (FIRST) {
      float s = 0.f;
      #pragma unroll
      for (int ch = 0; ch < 16; ++ch) s += src[((b * 16 + ch) << 9) + i];
      tok[i] = s * (1.0f / 1024.0f);
    } else {
      tok[i] = src[b * 512 + i];
    }
  }
  __syncthreads();
  const int to = tid & 63, iq = tid >> 6;
  const int o = oc * 64 + to;
  float acc = 0.f;
  for (int i = iq * 128; i < iq * 128 + 128; ++i)
    acc = fmaf(tok[i], Wm[(size_t)i * 512 + o], acc);
  red[tid] = acc;
  __syncthreads();
  if (tid < 64) {
    const float v = red[tid] + red[tid + 64] + red[tid + 128] + red[tid + 192] + bb[o];
    Cout[b * 512 + o] = gelu_f(v);
  }
}

// ---------------- cls layer 3: wave per output
__global__ __launch_bounds__(768)
void k_cls3(const float* __restrict__ C2, const float* __restrict__ w3,
            const float* __restrict__ b3, float* __restrict__ outp)
{
  const int b = blockIdx.x, tid = threadIdx.x;
  const int o = tid >> 6, lane = tid & 63;
  float acc = 0.f;
  for (int i = lane; i < 512; i += 64)
    acc = fmaf(C2[b * 512 + i], w3[i * 12 + o], acc);
  #pragma unroll
  for (int s = 32; s > 0; s >>= 1) acc += __shfl_xor(acc, s, 64);
  if (lane == 0) outp[2097152 + b * 12 + o] = acc + b3[o];
}

extern "C" void kernel_launch(void* const* d_in, const int* in_sizes, int n_in,
                              void* d_out, int out_size, void* d_ws, size_t ws_size,
                              hipStream_t stream)
{
  (void)in_sizes; (void)n_in; (void)out_size; (void)ws_size;
  const float* x      = (const float*)d_in[0];
  const float* patch_w= (const float*)d_in[1];
  const float* patch_b= (const float*)d_in[2];
  const float* p1_w   = (const float*)d_in[3];
  const float* p1_b   = (const float*)d_in[4];
  const float* pos    = (const float*)d_in[5];
  const float* tagg_w = (const float*)d_in[6];
  const float* gamma  = (const float*)d_in[7];
  const float* gn1_s  = (const float*)d_in[8];
  const float* gn1_b  = (const float*)d_in[9];
  const float* aw1    = (const float*)d_in[10];
  const float* ab1    = (const float*)d_in[11];
  const float* aw2    = (const float*)d_in[12];
  const float* ab2    = (const float*)d_in[13];
  const float* gn2_s  = (const float*)d_in[14];
  const float* gn2_b  = (const float*)d_in[15];
  const float* mw1    = (const float*)d_in[16];
  const float* mb1    = (const float*)d_in[17];
  const float* mw2    = (const float*)d_in[18];
  const float* mb2    = (const float*)d_in[19];
  const float* cls_w1 = (const float*)d_in[20];
  const float* cls_b1 = (const float*)d_in[21];
  const float* cls_w2 = (const float*)d_in[22];
  const float* cls_b2 = (const float*)d_in[23];
  const float* cls_w3 = (const float*)d_in[24];
  const float* cls_b3 = (const float*)d_in[25];
  const float* dec_w  = (const float*)d_in[26];
  const float* dec_b  = (const float*)d_in[27];
  const float* c3_w   = (const float*)d_in[28];
  const float* c3_b   = (const float*)d_in[29];
  const float* c1_w   = (const float*)d_in[30];
  const float* c1_b   = (const float*)d_in[31];

  float* W    = (float*)d_ws;
  float* H    = W;                       // 4,194,304
  float* AR   = W + 4194304;             // 2,097,152  (Ar/Tr)
  float* AI   = W + 6291456;             // 2,097,152  (Ai/Ti)
  float* X    = W + 8388608;             // 2,097,152  (Xb/X2b bf16)
  float* O1   = W + 10485760;            // 2,097,152  (O1b/Ub bf16)
  float* S    = W + 12582912;            // 262,144    (Sb bf16)
  float* SB   = W + 12845056;            // 2,048
  float* PART = W + 12847104;            // 2,048
  float* TEMB = W + 12849152;            // 2,048
  float* PBP  = W + 12851200;            // 64
  float* R1   = W + 12851264;            // 8,388,608 (imat/H0b/ZA/Y1)
  unsigned short* taggT = (unsigned short*)(W + 21239872);   // 1,048,576 sh
  unsigned short* mwT1  = (unsigned short*)(W + 21764160);   // 3,145,728 sh
  unsigned short* mwT2  = (unsigned short*)(W + 23337024);   // 3,145,728 sh
  unsigned short* decC  = (unsigned short*)(W + 24909888);   // 1,048,576 sh
  unsigned short* w3t   = (unsigned short*)(W + 25434176);   // 16,384 sh
  unsigned short* btp   = (unsigned short*)(W + 25442368);   // 28,672 sh
  unsigned short* bte   = (unsigned short*)(W + 25456704);   // 32,768 sh
  float* PART2 = W + 25473088;           // 65,536
  float* GNC   = W + 25538624;           // 8,192
  float* C1    = W + 25546816;           // 4,096
  float* C2    = W + 25550912;           // 4,096

  unsigned short* imat = (unsigned short*)R1;
  unsigned short* H0b  = (unsigned short*)R1;
  unsigned short* Y1   = (unsigned short*)R1;
  float* ZA = R1;
  unsigned short* P1b = (unsigned short*)O1;
  unsigned short* Xb  = (unsigned short*)X;
  unsigned short* X2b = Xb + 2097152;
  unsigned short* O1b = (unsigned short*)O1;
  unsigned short* Ub  = (unsigned short*)O1;
  unsigned short* Sb  = (unsigned short*)S;
  float* out = (float*)d_out;

  // ---- weight prep
  k_cvt_trans<<<dim3(16,64,1),256,0,stream>>>(tagg_w, taggT, 2048, 512, 0, 0);
  k_cvt_trans<<<dim3(16,16,12),256,0,stream>>>(mw1, mwT1, 512, 512, 262144, 262144);
  k_cvt_trans<<<dim3(16,16,12),256,0,stream>>>(mw2, mwT2, 512, 512, 262144, 262144);
  k_cvt<<<4096,256,0,stream>>>(dec_w, decC, 1048576);
  k_prep_w3<<<36,256,0,stream>>>(c3_w, w3t);
  k_prep_btp<<<112,256,0,stream>>>(patch_w, patch_b, btp, PBP);
  k_prep_bte<<<128,256,0,stream>>>(p1_w, bte);
  k_temb<<<8,256,0,stream>>>(gamma, TEMB);

  // ---- encoder
  k_pack<<<8192,256,0,stream>>>(x, imat);
  k_mgemm<1,1,1,0,1><<<dim3(1,512),256,0,stream>>>(imat, btp, nullptr, PBP, nullptr,
      P1b, nullptr, nullptr, nullptr, 448, 448, 64, 0, 0, 0, 0);
  k_mgemm<1,1,0,0,2><<<dim3(8,512),256,0,stream>>>(P1b, bte, nullptr, p1_b, nullptr,
      H0b, pos, TEMB, nullptr, 64, 64, 512, 0, 0, 0, 0);
  k_mgemm<1,0,0,0,0><<<dim3(8,128),256,0,stream>>>(H0b, taggT, H, nullptr, nullptr,
      nullptr, nullptr, nullptr, nullptr, 2048, 2048, 512, 0, 0, 0, 0);

  for (int d = 0; d < 12; ++d) {
    k_gn_part<<<1024,256,0,stream>>>(H, PART);
    k_dft_a<<<512,256,0,stream>>>(H, PART, gn1_s + d*512, gn1_b + d*512, AR, AI);
    k_dft_b<<<256,256,0,stream>>>(AR, AI, Xb);
    k_mode_prep3<<<1024,256,0,stream>>>(aw1 + (size_t)d*65536, aw2 + (size_t)d*65536,
        ab1 + d*1024, ab2 + d*1024, Sb, SB);
    k_mgemm<1,1,1,0,1><<<dim3(2,32,8),256,0,stream>>>(Xb, Sb, nullptr, SB, nullptr,
        O1b, nullptr, nullptr, nullptr, 128, 128, 128, 262144LL, 16384LL, 262144LL, 128);
    k_mgemm<1,1,0,0,1><<<dim3(2,32,8),256,0,stream>>>(O1b, Sb + 131072, nullptr, SB + 1024,
        nullptr, X2b, nullptr, nullptr, nullptr, 128, 128, 128, 262144LL, 16384LL, 262144LL, 128);
    k_idft_d<<<256,256,0,stream>>>(X2b, AR, AI);
    k_idft_e<<<512,256,0,stream>>>(AR, AI, H, PART, gn1_s + d*512, gn1_b + d*512, ZA);
    k_gn_part<<<1024,256,0,stream>>>(ZA, PART);
    k_gn_coef<<<16,256,0,stream>>>(PART, gn2_s + d*512, gn2_b + d*512, GNC);
    k_mgemm<2,1,1,0,1><<<dim3(8,128),256,0,stream>>>(ZA, mwT1 + (size_t)d*262144, nullptr,
        mb1 + d*512, nullptr, Ub, nullptr, nullptr, GNC, 512, 512, 512, 0, 0, 0, 0);
    k_mgemm<1,1,0,1,0><<<dim3(8,128),256,0,stream>>>(Ub, mwT2 + (size_t)d*262144, H,
        mb2 + d*512, H, nullptr, nullptr, nullptr, nullptr, 512, 512, 512, 0, 0, 0, 0);
  }

  k_clsmean_p<<<128,256,0,stream>>>(H, PART2);
  k_cls_l<1><<<dim3(8,8),256,0,stream>>>(PART2, cls_w1, cls_b1, C1);
  k_cls_l<0><<<dim3(8,8),256,0,stream>>>(C1, cls_w2, cls_b2, C2);
  k_cls3<<<8,768,0,stream>>>(C2, cls_w3, cls_b3, out);
  k_mgemm<0,0,1,0,3><<<dim3(32,128),256,0,stream>>>(H, decC, nullptr, dec_b, nullptr,
      Y1, nullptr, nullptr, nullptr, 512, 512, 0, 0, 0, 0, 0);
  k_tail<<<2048,256,0,stream>>>(Y1, w3t, c1_w, c1_b, out);
}

// Round 5
// 1892.521 us; speedup vs baseline: 2.2194x; 1.0088x over previous
//
#include <hip/hip_runtime.h>
#include <cstddef>

typedef __attribute__((ext_vector_type(8))) short bh8;
typedef __attribute__((ext_vector_type(4))) float f4;

__device__ __forceinline__ float gelu_f(float x){
  return 0.5f * x * (1.0f + erff(x * 0.7071067811865476f));
}

__device__ __forceinline__ unsigned short f2bf(float f){
  unsigned int u = __float_as_uint(f);
  unsigned int r = (u + 0x7FFFu + ((u >> 16) & 1u)) >> 16;
  return (unsigned short)r;
}

__device__ __forceinline__ float bf2f(unsigned short u){
  return __uint_as_float(((unsigned int)u) << 16);
}

__device__ __forceinline__ f4 mfma16(bh8 a, bh8 b, f4 c){
  return __builtin_amdgcn_mfma_f32_16x16x32_bf16(a, b, c, 0, 0, 0);
}

__device__ __forceinline__ void gll16(const unsigned short* src, unsigned short* dst){
  __builtin_amdgcn_global_load_lds(
      (const __attribute__((address_space(1))) unsigned int*)src,
      (__attribute__((address_space(3))) unsigned int*)dst, 16, 0, 0);
}

// ================= big bf16 MFMA GEMM: 128x128 tile, BK=64, global_load_lds + XOR swizzle
// A [M][K] bf16 (lda=K), Bt [N][K] bf16. OMODE: 0=plain f32 C; 1=bias+gelu->bf16 OB;
// 2=bias + Res -> f32 C; 3=DEC gelu(+bias[col&31]) -> pixel-scatter bf16 OB.
template<int OMODE>
__global__ __launch_bounds__(256)
void k_bgemm(const unsigned short* __restrict__ A, const unsigned short* __restrict__ Bt,
             float* __restrict__ C, unsigned short* __restrict__ OB,
             const float* __restrict__ bias, const float* __restrict__ Res,
             int K, int ldc)
{
  __shared__ __align__(16) unsigned short As[8192];   // [128][64] swizzled
  __shared__ __align__(16) unsigned short Bs[8192];
  const int m0 = blockIdx.y * 128, n0 = blockIdx.x * 128;
  const int tid = threadIdx.x;
  const int w = tid >> 6, lane = tid & 63;
  const int lr = lane & 15, lh = lane >> 4;
  const int wr = w >> 1, wc = w & 1;
  f4 acc[4][4] = {};

  for (int k0 = 0; k0 < K; k0 += 64) {
    #pragma unroll
    for (int i = 0; i < 4; ++i) {
      const int q = (w * 4 + i) * 64 + lane;      // chunk id 0..1023
      const int r = q >> 3, s = q & 7;
      const int c = s ^ (r & 7);
      gll16(A + (size_t)(m0 + r) * K + k0 + c * 8, &As[(w * 4 + i) * 512]);
    }
    #pragma unroll
    for (int i = 0; i < 4; ++i) {
      const int q = (w * 4 + i) * 64 + lane;
      const int r = q >> 3, s = q & 7;
      const int c = s ^ (r & 7);
      gll16(Bt + (size_t)(n0 + r) * K + k0 + c * 8, &Bs[(w * 4 + i) * 512]);
    }
    __syncthreads();
    #pragma unroll
    for (int kk = 0; kk < 2; ++kk) {
      bh8 af[4], bf[4];
      #pragma unroll
      for (int mi = 0; mi < 4; ++mi) {
        const int R = wr * 64 + mi * 16 + lr;
        af[mi] = *(const bh8*)((const char*)As + R * 128 + (((kk * 4 + lh) ^ (R & 7)) * 16));
      }
      #pragma unroll
      for (int ni = 0; ni < 4; ++ni) {
        const int R = wc * 64 + ni * 16 + lr;
        bf[ni] = *(const bh8*)((const char*)Bs + R * 128 + (((kk * 4 + lh) ^ (R & 7)) * 16));
      }
      #pragma unroll
      for (int mi = 0; mi < 4; ++mi)
        #pragma unroll
        for (int ni = 0; ni < 4; ++ni)
          acc[mi][ni] = mfma16(af[mi], bf[ni], acc[mi][ni]);
    }
    __syncthreads();
  }

  #pragma unroll
  for (int ni = 0; ni < 4; ++ni) {
    const int col = n0 + wc * 64 + ni * 16 + lr;
    float bv = 0.f;
    if (OMODE == 1 || OMODE == 2) bv = bias[col];
    if (OMODE == 3) bv = bias[col & 31];
    #pragma unroll
    for (int mi = 0; mi < 4; ++mi) {
      #pragma unroll
      for (int r = 0; r < 4; ++r) {
        const int row = m0 + wr * 64 + mi * 16 + lh * 4 + r;
        float v = acc[mi][ni][r] + bv;
        if (OMODE == 0) {
          C[(size_t)row * ldc + col] = v;
        } else if (OMODE == 1) {
          OB[(size_t)row * ldc + col] = f2bf(gelu_f(v));
        } else if (OMODE == 2) {
          const size_t ci = (size_t)row * ldc + col;
          C[ci] = v + Res[ci];
        } else {
          v = gelu_f(v);
          const int bb = row >> 10, hw = row & 1023, ii = hw >> 5, jj = hw & 31;
          const int dxy = col >> 5, dy = dxy >> 3, dx = dxy & 7, cc = col & 31;
          OB[(((size_t)(bb * 256 + ii * 8 + dy)) * 256 + jj * 8 + dx) * 32 + cc] = f2bf(v);
        }
      }
    }
  }
}

// ---------------- im2col pack: x -> bf16 imat [32768][448]
__global__ __launch_bounds__(256)
void k_pack(const float* __restrict__ x, unsigned short* __restrict__ imat)
{
  const int nb = blockIdx.x;
  const int j = nb & 31, i = (nb >> 5) & 31, b = nb >> 10;
  const int tid = threadIdx.x;
  const int tl = tid >> 6, px = tid & 63;
  const int dy = px >> 3, dx = px & 7;
  const int Y = i * 8 + dy, X = j * 8 + dx;
  const float4 v = *(const float4*)(x + (((size_t)(b * 256 + Y)) * 256 + X) * 16 + tl * 4);
  const size_t row = (size_t)nb * 4 + tl;
  ushort4 ov;
  ov.x = f2bf(v.x); ov.y = f2bf(v.y); ov.z = f2bf(v.z); ov.w = f2bf(v.w);
  *(ushort4*)(imat + row * 448 + px * 4) = ov;
  for (int q = tid; q < 768; q += 256) {
    const int tt = q / 192, r = q - tt * 192;
    const int sec = r >> 6, p2 = r & 63;
    float val;
    if (sec == 0)      val = (float)(i * 8 + (p2 >> 3)) * (1.0f / 255.0f);
    else if (sec == 1) val = (float)(j * 8 + (p2 & 7)) * (1.0f / 255.0f);
    else               val = (float)tt * (1.0f / 3.0f);
    imat[((size_t)nb * 4 + tt) * 448 + 256 + sec * 64 + p2] = f2bf(val);
  }
}

// ---------------- prep Bt_patch [64][448] (+ padded bias)
__global__ __launch_bounds__(256)
void k_prep_btp(const float* __restrict__ pw, const float* __restrict__ pb,
                unsigned short* __restrict__ btp, float* __restrict__ pbp)
{
  const int idx = blockIdx.x * 256 + threadIdx.x;
  if (idx < 28672) {
    const int n = idx / 448, k = idx - (idx / 448) * 448;
    int l;
    if (k < 256) { const int pxx = k >> 2, c = k & 3; l = pxx * 7 + c; }
    else { const int sec = (k - 256) >> 6, p2 = (k - 256) & 63; l = p2 * 7 + 4 + sec; }
    btp[n * 448 + k] = (n < 35) ? f2bf(pw[l * 35 + n]) : (unsigned short)0;
  }
  if (idx < 64) pbp[idx] = (idx < 35) ? pb[idx] : 0.0f;
}

// ---------------- prep Bt_embed [512][64]
__global__ __launch_bounds__(256)
void k_prep_bte(const float* __restrict__ w, unsigned short* __restrict__ bte)
{
  const int idx = blockIdx.x * 256 + threadIdx.x;
  const int n = idx >> 6, k = idx & 63;
  bte[idx] = (k < 35) ? f2bf(w[k * 512 + n]) : (unsigned short)0;
}

// ---------------- temb table [4][512]
__global__ __launch_bounds__(256)
void k_temb(const float* __restrict__ gamma, float* __restrict__ temb)
{
  const int idx = blockIdx.x * 256 + threadIdx.x;
  const int t = idx >> 9, e = idx & 511;
  temb[idx] = cosf((float)t * (1.0f / 3.0f) * gamma[e]);
}

// ---------------- weight prep: fp32 [K][N] -> bf16 [N][K]
__global__ __launch_bounds__(256)
void k_cvt_trans(const float* __restrict__ in, unsigned short* __restrict__ out,
                 int K, int N, long long sIn, long long sOut)
{
  __shared__ float tile[32][33];
  const int z = blockIdx.z;
  in  += (size_t)z * sIn;
  out += (size_t)z * sOut;
  const int n0 = blockIdx.x * 32, k0 = blockIdx.y * 32;
  const int tx = threadIdx.x & 31, ty = threadIdx.x >> 5;
  #pragma unroll
  for (int i = 0; i < 4; ++i)
    tile[ty + i * 8][tx] = in[(size_t)(k0 + ty + i * 8) * N + n0 + tx];
  __syncthreads();
  #pragma unroll
  for (int i = 0; i < 4; ++i)
    out[(size_t)(n0 + ty + i * 8) * K + k0 + tx] = f2bf(tile[tx][ty + i * 8]);
}

__global__ __launch_bounds__(256)
void k_cvt(const float* __restrict__ in, unsigned short* __restrict__ out, int n)
{
  const int idx = blockIdx.x * 256 + threadIdx.x;
  if (idx < n) out[idx] = f2bf(in[idx]);
}

__global__ __launch_bounds__(256)
void k_prep_w3(const float* __restrict__ w, unsigned short* __restrict__ out)
{
  const int idx = blockIdx.x * 256 + threadIdx.x;
  if (idx < 9216) {
    const int kb = idx >> 10, co = (idx >> 5) & 31, ci = idx & 31;
    out[idx] = f2bf(w[(kb * 32 + ci) * 32 + co]);
  }
}

// ---------------- small bf16 MFMA GEMM, 64x64 tile, z-batched (patch/embed/AFNO)
// OMODE: 1=bf16 OB (+bias,+gelu opt), 2=EMB
template<int BIAS, int GELU, int OMODE>
__global__ __launch_bounds__(256)
void k_mgemm(const unsigned short* __restrict__ A, const unsigned short* __restrict__ Bt,
             const float* __restrict__ bias, unsigned short* __restrict__ OB,
             const float* __restrict__ pos, const float* __restrict__ temb,
             int K, int lda, int ldc,
             long long zsA, long long zsB, long long zsC, int zsBias)
{
  __shared__ __align__(16) unsigned short As[64 * 40];
  __shared__ __align__(16) unsigned short Bs[64 * 40];
  const int z = blockIdx.z;
  A  += (size_t)z * zsA;
  Bt += (size_t)z * zsB;
  if (BIAS) bias += (size_t)z * zsBias;
  OB += (size_t)z * zsC;
  const int m0 = blockIdx.y * 64, n0 = blockIdx.x * 64;
  const int tid = threadIdx.x;
  const int w = tid >> 6, l = tid & 63;
  const int lr = l & 15, lh = l >> 4;
  const int sr = tid >> 2, skq = (tid & 3) * 8;
  f4 acc[4] = {};
  for (int k0 = 0; k0 < K; k0 += 32) {
    const uint4 av = *(const uint4*)(A + (size_t)(m0 + sr) * lda + k0 + skq);
    *(uint4*)(&As[sr * 40 + skq]) = av;
    const uint4 bv = *(const uint4*)(Bt + (size_t)(n0 + sr) * K + k0 + skq);
    *(uint4*)(&Bs[sr * 40 + skq]) = bv;
    __syncthreads();
    const bh8 af = *(const bh8*)(&As[(w * 16 + lr) * 40 + lh * 8]);
    #pragma unroll
    for (int ct = 0; ct < 4; ++ct) {
      const bh8 bf = *(const bh8*)(&Bs[(ct * 16 + lr) * 40 + lh * 8]);
      acc[ct] = mfma16(af, bf, acc[ct]);
    }
    __syncthreads();
  }
  #pragma unroll
  for (int ct = 0; ct < 4; ++ct) {
    const int col = n0 + ct * 16 + lr;
    float bv = 0.f;
    if (BIAS) bv = bias[col];
    #pragma unroll
    for (int r = 0; r < 4; ++r) {
      const int row = m0 + w * 16 + lh * 4 + r;
      float v = acc[ct][r] + bv;
      if (GELU) v = gelu_f(v);
      if (OMODE == 2) {
        const int hw = (row >> 2) & 1023, t = row & 3;
        v = (v + pos[(size_t)hw * 512 + col]) * temb[t * 512 + col];
        OB[(size_t)row * 512 + col] = f2bf(v);
      } else {
        OB[(size_t)row * ldc + col] = f2bf(v);
      }
    }
  }
}

// ---------------- decoder tail: conv3x3 (MFMA) + gelu + 1x1 -> out
__global__ __launch_bounds__(256)
void k_tail(const unsigned short* __restrict__ Y1, const unsigned short* __restrict__ w3t,
            const float* __restrict__ c1w, const float* __restrict__ c1b,
            float* __restrict__ outp)
{
  __shared__ __align__(16) char lbuf[256 * 33 * 4];
  __shared__ float c1s[128];
  unsigned short* it = (unsigned short*)lbuf;
  float* y2 = (float*)lbuf;
  const int bx = blockIdx.x;
  const int b = bx >> 8, ty = (bx >> 4) & 15, tx = bx & 15;
  const int Y0 = ty * 16, X0 = tx * 16;
  const int tid = threadIdx.x;
  const int w = tid >> 6, l = tid & 63, lr = l & 15, lh = l >> 4;

  if (tid < 128) c1s[tid] = c1w[tid];
  for (int idx = tid; idx < 1296; idx += 256) {
    const int r = idx / 72, rem = idx - r * 72, c = rem >> 2, q = rem & 3;
    const int Yg = Y0 + r - 1, Xg = X0 + c - 1;
    uint4 v = make_uint4(0u, 0u, 0u, 0u);
    if (Yg >= 0 && Yg < 256 && Xg >= 0 && Xg < 256)
      v = *(const uint4*)(Y1 + (((size_t)(b * 256 + Yg)) * 256 + Xg) * 32 + q * 8);
    *(uint4*)(&it[(r * 18 + c) * 40 + q * 8]) = v;
  }
  bh8 bw[2][9];
  #pragma unroll
  for (int ct = 0; ct < 2; ++ct)
    #pragma unroll
    for (int kb = 0; kb < 9; ++kb)
      bw[ct][kb] = *(const bh8*)(w3t + (size_t)(kb * 32 + ct * 16 + lr) * 32 + lh * 8);
  __syncthreads();

  f4 acc[4][2] = {};
  #pragma unroll
  for (int kb = 0; kb < 9; ++kb) {
    const int dy = kb / 3, dx = kb % 3;
    #pragma unroll
    for (int yy = 0; yy < 4; ++yy) {
      const int y = w * 4 + yy;
      const bh8 af = *(const bh8*)(&it[((y + dy) * 18 + lr + dx) * 40 + lh * 8]);
      acc[yy][0] = mfma16(af, bw[0][kb], acc[yy][0]);
      acc[yy][1] = mfma16(af, bw[1][kb], acc[yy][1]);
    }
  }
  __syncthreads();
  #pragma unroll
  for (int yy = 0; yy < 4; ++yy) {
    const int y = w * 4 + yy;
    #pragma unroll
    for (int ct = 0; ct < 2; ++ct)
      #pragma unroll
      for (int r = 0; r < 4; ++r)
        y2[(y * 16 + lh * 4 + r) * 33 + ct * 16 + lr] = gelu_f(acc[yy][ct][r]);
  }
  __syncthreads();
  const int py = tid >> 4, px = tid & 15;
  float o0 = c1b[0], o1 = c1b[1], o2 = c1b[2], o3 = c1b[3];
  #pragma unroll 8
  for (int ci = 0; ci < 32; ++ci) {
    const float v = y2[tid * 33 + ci];
    o0 = fmaf(v, c1s[ci * 4 + 0], o0);
    o1 = fmaf(v, c1s[ci * 4 + 1], o1);
    o2 = fmaf(v, c1s[ci * 4 + 2], o2);
    o3 = fmaf(v, c1s[ci * 4 + 3], o3);
  }
  float4 ov; ov.x = o0; ov.y = o1; ov.z = o2; ov.w = o3;
  *(float4*)(outp + (((size_t)(b * 256 + Y0 + py)) * 256 + X0 + px) * 4) = ov;
}

// ---------------- GroupNorm partial sums
__global__ __launch_bounds__(256)
void k_gn_part(const float* __restrict__ in, float* __restrict__ part)
{
  __shared__ float r1[256], r2[256];
  const int blk = blockIdx.x;
  const int s = blk & 15, g = (blk >> 4) & 7, b = blk >> 7;
  const int tid = threadIdx.x;
  const int cc = tid & 63, pp = tid >> 6;
  const float* base = in + ((size_t)b * 1024 + s * 64) * 512 + g * 64;
  float s1 = 0.f, s2 = 0.f;
  for (int p = pp; p < 64; p += 4) {
    const float v = base[(size_t)p * 512 + cc];
    s1 += v; s2 += v * v;
  }
  r1[tid] = s1; r2[tid] = s2;
  __syncthreads();
  for (int o = 128; o > 0; o >>= 1) {
    if (tid < o) { r1[tid] += r1[tid + o]; r2[tid] += r2[tid + o]; }
    __syncthreads();
  }
  if (tid == 0) { part[blk] = r1[0]; part[1024 + blk] = r2[0]; }
}

__device__ __forceinline__ void gn_coef(const float* part, const float* sc,
                                        const float* bi, int b, int c,
                                        float& sca, float& sh)
{
  const int g = c >> 6;
  float s1 = 0.f, s2 = 0.f;
  #pragma unroll
  for (int q = 0; q < 16; ++q) {
    s1 += part[(b * 8 + g) * 16 + q];
    s2 += part[1024 + (b * 8 + g) * 16 + q];
  }
  const float mu = s1 * (1.0f / 65536.0f);
  const float var = s2 * (1.0f / 65536.0f) - mu * mu;
  const float rs = rsqrtf(var + 1e-5f);
  sca = sc[c] * rs;
  sh = bi[c] - mu * sca;
}

// ---------------- gn2 apply -> bf16
__global__ __launch_bounds__(256)
void k_gn_apply_bf(const float* __restrict__ in, const float* __restrict__ part,
                   const float* __restrict__ sc, const float* __restrict__ bi,
                   unsigned short* __restrict__ out)
{
  const int blk = blockIdx.x;
  const int s = blk & 15, g = (blk >> 4) & 7, b = blk >> 7;
  const int tid = threadIdx.x;
  const int cc = tid & 63, pp = tid >> 6;
  float sca, sh;
  gn_coef(part, sc, bi, b, g * 64 + cc, sca, sh);
  const float* base = in + ((size_t)b * 1024 + s * 64) * 512 + g * 64;
  unsigned short* ob = out + ((size_t)b * 1024 + s * 64) * 512 + g * 64;
  for (int p = pp; p < 64; p += 4)
    ob[(size_t)p * 512 + cc] = f2bf(fmaf(base[(size_t)p * 512 + cc], sca, sh));
}

// ---------------- forward DFT stage A with fused gn1 affine
__global__ __launch_bounds__(256)
void k_dft_a(const float* __restrict__ H, const float* __restrict__ part,
             const float* __restrict__ sc, const float* __restrict__ bi,
             float* __restrict__ Ar, float* __restrict__ Ai)
{
  __shared__ float ct[512], st[512];
  const int tid = threadIdx.x;
  for (int q = tid; q < 512; q += 256) {
    const int k = q >> 5, y = q & 31;
    const float ang = (float)((k * y) & 31) * 0.19634954084936207f;
    ct[q] = cosf(ang); st[q] = sinf(ang);
  }
  __syncthreads();
  const int blk = blockIdx.x;
  const int half = blk & 1, x = (blk >> 1) & 31, b = blk >> 6;
  const int c = half * 256 + tid;
  float sca, sh;
  gn_coef(part, sc, bi, b, c, sca, sh);
  float ar[16], ai[16];
  #pragma unroll
  for (int k = 0; k < 16; ++k) { ar[k] = 0.f; ai[k] = 0.f; }
  const float* zp = H + ((size_t)b * 1024 + x) * 512 + c;
  for (int y = 0; y < 32; ++y) {
    const float v = fmaf(zp[(size_t)y * 32 * 512], sca, sh);
    #pragma unroll
    for (int k = 0; k < 16; ++k) {
      ar[k] = fmaf(v, ct[k * 32 + y], ar[k]);
      ai[k] = fmaf(-v, st[k * 32 + y], ai[k]);
    }
  }
  #pragma unroll
  for (int k = 0; k < 16; ++k) {
    const size_t o = (((size_t)b * 16 + k) * 32 + x) * 512 + c;
    Ar[o] = ar[k]; Ai[o] = ai[k];
  }
}

// ---------------- forward DFT stage B -> stacked bf16 X [z][2048][128]
__global__ __launch_bounds__(256)
void k_dft_b(const float* __restrict__ Ar, const float* __restrict__ Ai,
             unsigned short* __restrict__ X)
{
  __shared__ float ct[512], st[512];
  const int tid = threadIdx.x;
  for (int q = tid; q < 512; q += 256) {
    const int k = q >> 5, xx = q & 31;
    const float ang = (float)((k * xx) & 31) * 0.19634954084936207f;
    ct[q] = cosf(ang); st[q] = sinf(ang);
  }
  __syncthreads();
  const int blk = blockIdx.x;
  const int half = blk & 1, kh = (blk >> 1) & 15, b = blk >> 5;
  const int c = half * 256 + tid;
  float gr[16], gi[16];
  #pragma unroll
  for (int k = 0; k < 16; ++k) { gr[k] = 0.f; gi[k] = 0.f; }
  const float* arp = Ar + (((size_t)b * 16 + kh) * 32) * 512 + c;
  const float* aip = Ai + (((size_t)b * 16 + kh) * 32) * 512 + c;
  for (int x = 0; x < 32; ++x) {
    const float vr = arp[(size_t)x * 512], vi = aip[(size_t)x * 512];
    #pragma unroll
    for (int k = 0; k < 16; ++k) {
      const float cc_ = ct[k * 32 + x], ss = st[k * 32 + x];
      gr[k] += vr * cc_ + vi * ss;
      gi[k] += vi * cc_ - vr * ss;
    }
  }
  const int blkc = c >> 6, ii = c & 63;
  #pragma unroll
  for (int k = 0; k < 16; ++k) {
    const size_t pos = (size_t)b * 256 + kh * 16 + k;
    unsigned short* xp = X + ((size_t)blkc * 2048 + pos) * 128 + ii;
    xp[0]  = f2bf(gr[k] * (1.0f / 32.0f));
    xp[64] = f2bf(gi[k] * (1.0f / 32.0f));
  }
}

// ---------------- merged AFNO weights: Sb bf16 [2][8][128(out)][128(in)] + SB f32
__global__ __launch_bounds__(256)
void k_mode_prep3(const float* __restrict__ aw1_d, const float* __restrict__ aw2_d,
                  const float* __restrict__ ab1_d, const float* __restrict__ ab2_d,
                  unsigned short* __restrict__ Sb, float* __restrict__ SB)
{
  const int idx = blockIdx.x * 256 + threadIdx.x;
  const int s = idx >> 17;
  const int blk = (idx >> 14) & 7;
  const int n = (idx >> 7) & 127;
  const int kk = idx & 127;
  const float* aw = s ? aw2_d : aw1_d;
  const int i = kk & 63, o = n & 63;
  const float wr = aw[(blk * 64 + i) * 64 + o];
  const float wi = aw[32768 + (blk * 64 + i) * 64 + o];
  float val;
  if (n < 64) val = (kk < 64) ? wr : -wi;
  else        val = (kk < 64) ? wi :  wr;
  Sb[idx] = f2bf(val);
  if (idx < 2048) {
    const int s2 = idx >> 10, r2 = idx & 1023, b2 = r2 >> 7, q2 = r2 & 127;
    const float* ab = s2 ? ab2_d : ab1_d;
    SB[idx] = (q2 < 64) ? ab[b2 * 64 + q2] : ab[512 + b2 * 64 + (q2 - 64)];
  }
}

// ---------------- inverse DFT stage D (reads bf16 X2 [z][2048][128])
__global__ __launch_bounds__(256)
void k_idft_d(const unsigned short* __restrict__ X2, float* __restrict__ Tr,
              float* __restrict__ Ti)
{
  __shared__ float ct[512], st[512];
  const int tid = threadIdx.x;
  for (int q = tid; q < 512; q += 256) {
    const int kw = q >> 5, xx = q & 31;
    const float w = (kw == 0) ? 1.0f : 2.0f;
    const float ang = (float)((kw * xx) & 31) * 0.19634954084936207f;
    ct[q] = w * cosf(ang); st[q] = w * sinf(ang);
  }
  __syncthreads();
  const int blk = blockIdx.x;
  const int half = blk & 1, kh = (blk >> 1) & 15, b = blk >> 5;
  const int c = half * 256 + tid;
  const int blkc = c >> 6, ii = c & 63;
  float gr[16], gi[16];
  #pragma unroll
  for (int kw = 0; kw < 16; ++kw) {
    const size_t pos = (size_t)b * 256 + kh * 16 + kw;
    gr[kw] = bf2f(X2[((size_t)blkc * 2048 + pos) * 128 + ii]);
    gi[kw] = bf2f(X2[((size_t)blkc * 2048 + pos) * 128 + 64 + ii]);
  }
  for (int x = 0; x < 32; ++x) {
    float tr = 0.f, ti = 0.f;
    #pragma unroll
    for (int kw = 0; kw < 16; ++kw) {
      const float cc_ = ct[kw * 32 + x], ss = st[kw * 32 + x];
      tr += gr[kw] * cc_ - gi[kw] * ss;
      ti += gi[kw] * cc_ + gr[kw] * ss;
    }
    const size_t o = (((size_t)b * 16 + kh) * 32 + x) * 512 + c;
    Tr[o] = tr; Ti[o] = ti;
  }
}

// ---------------- inverse DFT stage E + fused gn1-affine residual
__global__ __launch_bounds__(256)
void k_idft_e(const float* __restrict__ Tr, const float* __restrict__ Ti,
              const float* __restrict__ H, const float* __restrict__ part,
              const float* __restrict__ sc, const float* __restrict__ bi,
              float* __restrict__ za)
{
  __shared__ float ct[512], st[512];
  const int tid = threadIdx.x;
  for (int q = tid; q < 512; q += 256) {
    const int k = q >> 5, y = q & 31;
    const float ang = (float)((k * y) & 31) * 0.19634954084936207f;
    ct[q] = cosf(ang); st[q] = sinf(ang);
  }
  __syncthreads();
  const int blk = blockIdx.x;
  const int half = blk & 1, x = (blk >> 1) & 31, b = blk >> 6;
  const int c = half * 256 + tid;
  float sca, sh;
  gn_coef(part, sc, bi, b, c, sca, sh);
  float trv[16], tiv[16];
  #pragma unroll
  for (int k = 0; k < 16; ++k) {
    const size_t o = (((size_t)b * 16 + k) * 32 + x) * 512 + c;
    trv[k] = Tr[o]; tiv[k] = Ti[o];
  }
  for (int y = 0; y < 32; ++y) {
    float v = 0.f;
    #pragma unroll
    for (int k = 0; k < 16; ++k)
      v += trv[k] * ct[k * 32 + y] - tiv[k] * st[k * 32 + y];
    const size_t o = ((size_t)b * 1024 + y * 32 + x) * 512 + c;
    za[o] = v * (1.0f / 32.0f) + fmaf(H[o], sca, sh);
  }
}

// ---------------- cls mean partials: PART2[b][16][512]
__global__ __launch_bounds__(256)
void k_clsmean_p(const float* __restrict__ h, float* __restrict__ part2)
{
  const int blk = blockIdx.x;
  const int ch = blk & 15, b = blk >> 4;
  const int tid = threadIdx.x;
  const float* p = h + (size_t)b * 524288 + (size_t)ch * 64 * 512;
  #pragma unroll
  for (int half = 0; half < 2; ++half) {
    const int c = half * 256 + tid;
    float s = 0.f;
    for (int r = 0; r < 64; ++r) s += p[r * 512 + c];
    part2[(size_t)blk * 512 + c] = s;
  }
}

// ---------------- cls layers 1/2
template<int FIRST>
__global__ __launch_bounds__(256)
void k_cls_l(const float* __restrict__ src, const float* __restrict__ Wm,
             const float* __restrict__ bb, float* __restrict__ Cout)
{
  __shared__ float tok[512];
  __shared__ float red[256];
  const int b = blockIdx.y, oc = blockIdx.x;
  const int tid = threadIdx.x;
  for (int i = tid; i < 512; i += 256) {
    if (FIRST) {
      float s = 0.f;
      #pragma unroll
      for (int ch = 0; ch < 16; ++ch) s += src[((b * 16 + ch) << 9) + i];
      tok[i] = s * (1.0f / 1024.0f);
    } else {
      tok[i] = src[b * 512 + i];
    }
  }
  __syncthreads();
  const int to = tid & 63, iq = tid >> 6;
  const int o = oc * 64 + to;
  float acc = 0.f;
  for (int i = iq * 128; i < iq * 128 + 128; ++i)
    acc = fmaf(tok[i], Wm[(size_t)i * 512 + o], acc);
  red[tid] = acc;
  __syncthreads();
  if (tid < 64) {
    const float v = red[tid] + red[tid + 64] + red[tid + 128] + red[tid + 192] + bb[o];
    Cout[b * 512 + o] = gelu_f(v);
  }
}

// ---------------- cls layer 3
__global__ __launch_bounds__(768)
void k_cls3(const float* __restrict__ C2, const float* __restrict__ w3,
            const float* __restrict__ b3, float* __restrict__ outp)
{
  const int b = blockIdx.x, tid = threadIdx.x;
  const int o = tid >> 6, lane = tid & 63;
  float acc = 0.f;
  for (int i = lane; i < 512; i += 64)
    acc = fmaf(C2[b * 512 + i], w3[i * 12 + o], acc);
  #pragma unroll
  for (int s = 32; s > 0; s >>= 1) acc += __shfl_xor(acc, s, 64);
  if (lane == 0) outp[2097152 + b * 12 + o] = acc + b3[o];
}

extern "C" void kernel_launch(void* const* d_in, const int* in_sizes, int n_in,
                              void* d_out, int out_size, void* d_ws, size_t ws_size,
                              hipStream_t stream)
{
  (void)in_sizes; (void)n_in; (void)out_size; (void)ws_size;
  const float* x      = (const float*)d_in[0];
  const float* patch_w= (const float*)d_in[1];
  const float* patch_b= (const float*)d_in[2];
  const float* p1_w   = (const float*)d_in[3];
  const float* p1_b   = (const float*)d_in[4];
  const float* pos    = (const float*)d_in[5];
  const float* tagg_w = (const float*)d_in[6];
  const float* gamma  = (const float*)d_in[7];
  const float* gn1_s  = (const float*)d_in[8];
  const float* gn1_b  = (const float*)d_in[9];
  const float* aw1    = (const float*)d_in[10];
  const float* ab1    = (const float*)d_in[11];
  const float* aw2    = (const float*)d_in[12];
  const float* ab2    = (const float*)d_in[13];
  const float* gn2_s  = (const float*)d_in[14];
  const float* gn2_b  = (const float*)d_in[15];
  const float* mw1    = (const float*)d_in[16];
  const float* mb1    = (const float*)d_in[17];
  const float* mw2    = (const float*)d_in[18];
  const float* mb2    = (const float*)d_in[19];
  const float* cls_w1 = (const float*)d_in[20];
  const float* cls_b1 = (const float*)d_in[21];
  const float* cls_w2 = (const float*)d_in[22];
  const float* cls_b2 = (const float*)d_in[23];
  const float* cls_w3 = (const float*)d_in[24];
  const float* cls_b3 = (const float*)d_in[25];
  const float* dec_w  = (const float*)d_in[26];
  const float* dec_b  = (const float*)d_in[27];
  const float* c3_w   = (const float*)d_in[28];
  const float* c3_b   = (const float*)d_in[29];
  const float* c1_w   = (const float*)d_in[30];
  const float* c1_b   = (const float*)d_in[31];

  float* W    = (float*)d_ws;
  float* H    = W;                       // 4,194,304
  float* AR   = W + 4194304;             // 2,097,152  (Ar/Tr; Hb bf16 at end)
  float* AI   = W + 6291456;             // 2,097,152  (Ai/Ti)
  float* X    = W + 8388608;             // 2,097,152  (Xb/X2b bf16; Z2b bf16)
  float* O1   = W + 10485760;            // 2,097,152  (P1b/Ub bf16)
  float* S    = W + 12582912;            // 262,144    (Sb bf16)
  float* SB   = W + 12845056;            // 2,048
  float* PART = W + 12847104;            // 2,048
  float* TEMB = W + 12849152;            // 2,048
  float* PBP  = W + 12851200;            // 64
  float* R1   = W + 12851264;            // 8,388,608 (imat/H0b/ZA/Y1)
  unsigned short* taggT = (unsigned short*)(W + 21239872);
  unsigned short* mwT1  = (unsigned short*)(W + 21764160);
  unsigned short* mwT2  = (unsigned short*)(W + 23337024);
  unsigned short* decC  = (unsigned short*)(W + 24909888);
  unsigned short* w3t   = (unsigned short*)(W + 25434176);
  unsigned short* btp   = (unsigned short*)(W + 25442368);
  unsigned short* bte   = (unsigned short*)(W + 25456704);
  float* PART2 = W + 25473088;
  float* C1    = W + 25546816;
  float* C2    = W + 25550912;

  unsigned short* imat = (unsigned short*)R1;
  unsigned short* H0b  = (unsigned short*)R1;
  unsigned short* Y1   = (unsigned short*)R1;
  float* ZA = R1;
  unsigned short* P1b = (unsigned short*)O1;
  unsigned short* Xb  = (unsigned short*)X;
  unsigned short* X2b = Xb + 2097152;
  unsigned short* Z2b = (unsigned short*)X;
  unsigned short* O1b = (unsigned short*)O1;
  unsigned short* Ub  = (unsigned short*)O1;
  unsigned short* Sb  = (unsigned short*)S;
  unsigned short* Hb  = (unsigned short*)AR;
  float* out = (float*)d_out;

  // ---- weight prep
  k_cvt_trans<<<dim3(16,64,1),256,0,stream>>>(tagg_w, taggT, 2048, 512, 0, 0);
  k_cvt_trans<<<dim3(16,16,12),256,0,stream>>>(mw1, mwT1, 512, 512, 262144, 262144);
  k_cvt_trans<<<dim3(16,16,12),256,0,stream>>>(mw2, mwT2, 512, 512, 262144, 262144);
  k_cvt<<<4096,256,0,stream>>>(dec_w, decC, 1048576);
  k_prep_w3<<<36,256,0,stream>>>(c3_w, w3t);
  k_prep_btp<<<112,256,0,stream>>>(patch_w, patch_b, btp, PBP);
  k_prep_bte<<<128,256,0,stream>>>(p1_w, bte);
  k_temb<<<8,256,0,stream>>>(gamma, TEMB);

  // ---- encoder
  k_pack<<<8192,256,0,stream>>>(x, imat);
  k_mgemm<1,1,1><<<dim3(1,512),256,0,stream>>>(imat, btp, PBP, P1b,
      nullptr, nullptr, 448, 448, 64, 0, 0, 0, 0);
  k_mgemm<1,0,2><<<dim3(8,512),256,0,stream>>>(P1b, bte, p1_b, H0b,
      pos, TEMB, 64, 64, 512, 0, 0, 0, 0);
  k_bgemm<0><<<dim3(4,64),256,0,stream>>>(H0b, taggT, H, nullptr, nullptr, nullptr,
      2048, 512);

  for (int d = 0; d < 12; ++d) {
    k_gn_part<<<1024,256,0,stream>>>(H, PART);
    k_dft_a<<<512,256,0,stream>>>(H, PART, gn1_s + d*512, gn1_b + d*512, AR, AI);
    k_dft_b<<<256,256,0,stream>>>(AR, AI, Xb);
    k_mode_prep3<<<1024,256,0,stream>>>(aw1 + (size_t)d*65536, aw2 + (size_t)d*65536,
        ab1 + d*1024, ab2 + d*1024, Sb, SB);
    k_mgemm<1,1,1><<<dim3(2,32,8),256,0,stream>>>(Xb, Sb, SB, O1b,
        nullptr, nullptr, 128, 128, 128, 262144LL, 16384LL, 262144LL, 128);
    k_mgemm<1,0,1><<<dim3(2,32,8),256,0,stream>>>(O1b, Sb + 131072, SB + 1024, X2b,
        nullptr, nullptr, 128, 128, 128, 262144LL, 16384LL, 262144LL, 128);
    k_idft_d<<<256,256,0,stream>>>(X2b, AR, AI);
    k_idft_e<<<512,256,0,stream>>>(AR, AI, H, PART, gn1_s + d*512, gn1_b + d*512, ZA);
    k_gn_part<<<1024,256,0,stream>>>(ZA, PART);
    k_gn_apply_bf<<<1024,256,0,stream>>>(ZA, PART, gn2_s + d*512, gn2_b + d*512, Z2b);
    k_bgemm<1><<<dim3(4,64),256,0,stream>>>(Z2b, mwT1 + (size_t)d*262144, nullptr, Ub,
        mb1 + d*512, nullptr, 512, 512);
    k_bgemm<2><<<dim3(4,64),256,0,stream>>>(Ub, mwT2 + (size_t)d*262144, H, nullptr,
        mb2 + d*512, H, 512, 512);
  }

  k_clsmean_p<<<128,256,0,stream>>>(H, PART2);
  k_cls_l<1><<<dim3(8,8),256,0,stream>>>(PART2, cls_w1, cls_b1, C1);
  k_cls_l<0><<<dim3(8,8),256,0,stream>>>(C1, cls_w2, cls_b2, C2);
  k_cls3<<<8,768,0,stream>>>(C2, cls_w3, cls_b3, out);
  k_cvt<<<16384,256,0,stream>>>(H, Hb, 4194304);
  k_bgemm<3><<<dim3(16,64),256,0,stream>>>(Hb, decC, nullptr, Y1,
      dec_b, nullptr, 512, 2048);
  k_tail<<<2048,256,0,stream>>>(Y1, w3t, c1_w, c1_b, out);
}

// Round 7
// 1537.012 us; speedup vs baseline: 2.7327x; 1.2313x over previous
//
#include <hip/hip_runtime.h>
#include <cstddef>

typedef __attribute__((ext_vector_type(8))) short bh8;
typedef __attribute__((ext_vector_type(4))) float f4;

__device__ __forceinline__ float gelu_f(float x){
  return 0.5f * x * (1.0f + erff(x * 0.7071067811865476f));
}

__device__ __forceinline__ unsigned short f2bf(float f){
  unsigned int u = __float_as_uint(f);
  unsigned int r = (u + 0x7FFFu + ((u >> 16) & 1u)) >> 16;
  return (unsigned short)r;
}

__device__ __forceinline__ float bf2f(unsigned short u){
  return __uint_as_float(((unsigned int)u) << 16);
}

__device__ __forceinline__ f4 mfma16(bh8 a, bh8 b, f4 c){
  return __builtin_amdgcn_mfma_f32_16x16x32_bf16(a, b, c, 0, 0, 0);
}

__device__ __forceinline__ void gll16(const unsigned short* src, unsigned short* dst){
  __builtin_amdgcn_global_load_lds(
      (const __attribute__((address_space(1))) unsigned int*)src,
      (__attribute__((address_space(3))) unsigned int*)dst, 16, 0, 0);
}

// gn coef from 8-slice partials PA[(b*8+g)*8+q], s2 at +512
__device__ __forceinline__ void gn_coef8(const float* pa, const float* sc,
                                         const float* bi, int b, int c,
                                         float& sca, float& sh)
{
  const int g = c >> 6;
  float s1 = 0.f, s2 = 0.f;
  #pragma unroll
  for (int q = 0; q < 8; ++q) {
    s1 += pa[(b * 8 + g) * 8 + q];
    s2 += pa[512 + (b * 8 + g) * 8 + q];
  }
  const float mu = s1 * (1.0f / 65536.0f);
  const float var = s2 * (1.0f / 65536.0f) - mu * mu;
  const float rs = rsqrtf(var + 1e-5f);
  sca = sc[c] * rs;
  sh = bi[c] - mu * sca;
}

// ================= big bf16 MFMA GEMM: 128x128 tile, BK=64, 2-phase dbuf pipeline,
// XCD chunk swizzle. AMODE: 0=bf16 gll, 1=f32 reg-staged, 2=f32 + GN affine (gnc).
// OMODE: 0=f32 C + gn-partials; 1=bias+gelu->bf16 OB; 2=bias+Res->f32 C + gn-partials;
//        3=DEC gelu(+bias[col&31]) pixel-scatter; 4=bias+Res->f32 C + cls col-partials.
#define BG_STAGE(dbuf, kofs, BASE, DST) \
  _Pragma("unroll") \
  for (int i_ = 0; i_ < 4; ++i_) { \
    const int q_ = (w * 4 + i_) * 64 + lane; \
    const int r_ = q_ >> 3, s_ = q_ & 7; \
    gll16(BASE + (size_t)r_ * K + (kofs) + ((s_ ^ (r_ & 7)) << 3), &DST[dbuf][(w * 4 + i_) * 512]); \
  }

#define BG_LOADA(kofs) \
  _Pragma("unroll") \
  for (int i_ = 0; i_ < 4; ++i_) { \
    const int q_ = (w * 4 + i_) * 64 + lane; \
    const int r_ = q_ >> 3, s_ = q_ & 7; \
    const float* ap_ = Afbase + (size_t)r_ * K + (kofs) + s_ * 8; \
    ra[i_][0] = *(const float4*)ap_; \
    ra[i_][1] = *(const float4*)(ap_ + 4); \
    if (AMODE == 2) { \
      const int bb_ = (m0 + r_) >> 10; \
      const int ch_ = (kofs) + s_ * 8; \
      const float4 c0_ = *(const float4*)(gnc + bb_ * 512 + ch_); \
      const float4 c1_ = *(const float4*)(gnc + bb_ * 512 + ch_ + 4); \
      const float4 h0_ = *(const float4*)(gnc + 4096 + bb_ * 512 + ch_); \
      const float4 h1_ = *(const float4*)(gnc + 4096 + bb_ * 512 + ch_ + 4); \
      ra[i_][0].x = fmaf(ra[i_][0].x, c0_.x, h0_.x); \
      ra[i_][0].y = fmaf(ra[i_][0].y, c0_.y, h0_.y); \
      ra[i_][0].z = fmaf(ra[i_][0].z, c0_.z, h0_.z); \
      ra[i_][0].w = fmaf(ra[i_][0].w, c0_.w, h0_.w); \
      ra[i_][1].x = fmaf(ra[i_][1].x, c1_.x, h1_.x); \
      ra[i_][1].y = fmaf(ra[i_][1].y, c1_.y, h1_.y); \
      ra[i_][1].z = fmaf(ra[i_][1].z, c1_.z, h1_.z); \
      ra[i_][1].w = fmaf(ra[i_][1].w, c1_.w, h1_.w); \
    } \
  }

#define BG_WRITEA(dbuf) \
  _Pragma("unroll") \
  for (int i_ = 0; i_ < 4; ++i_) { \
    const int q_ = (w * 4 + i_) * 64 + lane; \
    const int r_ = q_ >> 3, s_ = q_ & 7; \
    const int slot_ = s_ ^ (r_ & 7); \
    bh8 av_; \
    av_[0] = (short)f2bf(ra[i_][0].x); av_[1] = (short)f2bf(ra[i_][0].y); \
    av_[2] = (short)f2bf(ra[i_][0].z); av_[3] = (short)f2bf(ra[i_][0].w); \
    av_[4] = (short)f2bf(ra[i_][1].x); av_[5] = (short)f2bf(ra[i_][1].y); \
    av_[6] = (short)f2bf(ra[i_][1].z); av_[7] = (short)f2bf(ra[i_][1].w); \
    *(bh8*)(&As[dbuf][r_ * 64 + slot_ * 8]) = av_; \
  }

template<int AMODE, int OMODE>
__global__ __launch_bounds__(256)
void k_bgemm(const void* __restrict__ Av, const unsigned short* __restrict__ Bt,
             float* __restrict__ C, unsigned short* __restrict__ OB,
             const float* __restrict__ bias, const float* __restrict__ Res,
             const float* __restrict__ gnc, float* __restrict__ gpart,
             int K, int ldc, int nn)
{
  __shared__ __align__(16) unsigned short As[2][8192];
  __shared__ __align__(16) unsigned short Bs[2][8192];
  const int bid = blockIdx.x, nwg = gridDim.x;
  const int wg = (bid & 7) * (nwg >> 3) + (bid >> 3);
  const int mb = wg / nn;
  const int m0 = mb * 128, n0 = (wg - mb * nn) * 128;
  const int tid = threadIdx.x;
  const int w = tid >> 6, lane = tid & 63;
  const int lr = lane & 15, lh = lane >> 4;
  const int wr = w >> 1, wc = w & 1;
  const unsigned short* Abase = (const unsigned short*)Av + (size_t)m0 * K;
  const float* Afbase = (const float*)Av + (size_t)m0 * K;
  const unsigned short* Bbase = Bt + (size_t)n0 * K;
  float4 ra[4][2];
  f4 acc[4][4] = {};

  const int nt = K >> 6;
  // prologue: stage tile 0
  if (AMODE == 0) { BG_STAGE(0, 0, Abase, As) }
  else            { BG_LOADA(0) BG_WRITEA(0) }
  BG_STAGE(0, 0, Bbase, Bs)
  __syncthreads();

  for (int t = 0; t < nt; ++t) {
    const int d = t & 1;
    const bool more = (t + 1 < nt);
    if (more) {
      const int kn = (t + 1) << 6;
      if (AMODE == 0) { BG_STAGE(d ^ 1, kn, Abase, As) }
      else            { BG_LOADA(kn) }
      BG_STAGE(d ^ 1, kn, Bbase, Bs)
    }
    #pragma unroll
    for (int kk = 0; kk < 2; ++kk) {
      bh8 af[4], bf[4];
      #pragma unroll
      for (int mi = 0; mi < 4; ++mi) {
        const int R = wr * 64 + mi * 16 + lr;
        af[mi] = *(const bh8*)((const char*)As[d] + R * 128 + (((kk * 4 + lh) ^ (R & 7)) * 16));
      }
      #pragma unroll
      for (int ni = 0; ni < 4; ++ni) {
        const int R = wc * 64 + ni * 16 + lr;
        bf[ni] = *(const bh8*)((const char*)Bs[d] + R * 128 + (((kk * 4 + lh) ^ (R & 7)) * 16));
      }
      #pragma unroll
      for (int mi = 0; mi < 4; ++mi)
        #pragma unroll
        for (int ni = 0; ni < 4; ++ni)
          acc[mi][ni] = mfma16(af[mi], bf[ni], acc[mi][ni]);
    }
    if (more && AMODE != 0) { BG_WRITEA(d ^ 1) }
    __syncthreads();
  }

  float cs1[4], cs2[4];
  #pragma unroll
  for (int ni = 0; ni < 4; ++ni) {
    const int col_l = wc * 64 + ni * 16 + lr;
    const int col = n0 + col_l;
    float bv = 0.f;
    if (OMODE == 1 || OMODE == 2 || OMODE == 4) bv = bias[col];
    if (OMODE == 3) bv = bias[col & 31];
    float s1 = 0.f, s2 = 0.f;
    #pragma unroll
    for (int mi = 0; mi < 4; ++mi) {
      #pragma unroll
      for (int r = 0; r < 4; ++r) {
        const int row = m0 + wr * 64 + mi * 16 + lh * 4 + r;
        float v = acc[mi][ni][r] + bv;
        if (OMODE == 0) {
          C[(size_t)row * ldc + col] = v;
          s1 += v; s2 += v * v;
        } else if (OMODE == 1) {
          OB[(size_t)row * ldc + col] = f2bf(gelu_f(v));
        } else if (OMODE == 2 || OMODE == 4) {
          const size_t ci = (size_t)row * ldc + col;
          v += Res[ci];
          C[ci] = v;
          s1 += v; s2 += v * v;
        } else {
          v = gelu_f(v);
          const int bb = row >> 10, hw = row & 1023, ii = hw >> 5, jj = hw & 31;
          const int dxy = col >> 5, dy = dxy >> 3, dx = dxy & 7, cc = col & 31;
          OB[(((size_t)(bb * 256 + ii * 8 + dy)) * 256 + jj * 8 + dx) * 32 + cc] = f2bf(v);
        }
      }
    }
    cs1[ni] = s1; cs2[ni] = s2;
  }
  if (OMODE == 0 || OMODE == 2 || OMODE == 4) {
    float* sr = (float*)As;   // 8KB scratch, safe after final barrier
    const int sub = wr * 4 + lh;
    #pragma unroll
    for (int ni = 0; ni < 4; ++ni) {
      const int col_l = wc * 64 + ni * 16 + lr;
      sr[col_l * 8 + sub] = cs1[ni];
      sr[1024 + col_l * 8 + sub] = cs2[ni];
    }
    __syncthreads();
    if (tid < 128) {
      float s1 = 0.f, s2 = 0.f;
      #pragma unroll
      for (int u = 0; u < 8; ++u) { s1 += sr[tid * 8 + u]; s2 += sr[1024 + tid * 8 + u]; }
      const int b = m0 >> 10, slice = (m0 >> 7) & 7;
      if (OMODE == 4) {
        gpart[(b * 8 + slice) * 512 + n0 + tid] = s1;
      } else {
        #pragma unroll
        for (int sft = 32; sft > 0; sft >>= 1) {
          s1 += __shfl_xor(s1, sft, 64);
          s2 += __shfl_xor(s2, sft, 64);
        }
        if ((tid & 63) == 0) {
          const int g = (n0 >> 6) + (tid >> 6);
          gpart[(b * 8 + g) * 8 + slice] = s1;
          gpart[512 + (b * 8 + g) * 8 + slice] = s2;
        }
      }
    }
  }
}

// ---------------- im2col pack: x -> bf16 imat [32768][448]
__global__ __launch_bounds__(256)
void k_pack(const float* __restrict__ x, unsigned short* __restrict__ imat)
{
  const int nb = blockIdx.x;
  const int j = nb & 31, i = (nb >> 5) & 31, b = nb >> 10;
  const int tid = threadIdx.x;
  const int tl = tid >> 6, px = tid & 63;
  const int dy = px >> 3, dx = px & 7;
  const int Y = i * 8 + dy, X = j * 8 + dx;
  const float4 v = *(const float4*)(x + (((size_t)(b * 256 + Y)) * 256 + X) * 16 + tl * 4);
  const size_t row = (size_t)nb * 4 + tl;
  ushort4 ov;
  ov.x = f2bf(v.x); ov.y = f2bf(v.y); ov.z = f2bf(v.z); ov.w = f2bf(v.w);
  *(ushort4*)(imat + row * 448 + px * 4) = ov;
  for (int q = tid; q < 768; q += 256) {
    const int tt = q / 192, r = q - tt * 192;
    const int sec = r >> 6, p2 = r & 63;
    float val;
    if (sec == 0)      val = (float)(i * 8 + (p2 >> 3)) * (1.0f / 255.0f);
    else if (sec == 1) val = (float)(j * 8 + (p2 & 7)) * (1.0f / 255.0f);
    else               val = (float)tt * (1.0f / 3.0f);
    imat[((size_t)nb * 4 + tt) * 448 + 256 + sec * 64 + p2] = f2bf(val);
  }
}

// ---------------- prep Bt_patch [64][448] (+ padded bias)
__global__ __launch_bounds__(256)
void k_prep_btp(const float* __restrict__ pw, const float* __restrict__ pb,
                unsigned short* __restrict__ btp, float* __restrict__ pbp)
{
  const int idx = blockIdx.x * 256 + threadIdx.x;
  if (idx < 28672) {
    const int n = idx / 448, k = idx - (idx / 448) * 448;
    int l;
    if (k < 256) { const int pxx = k >> 2, c = k & 3; l = pxx * 7 + c; }
    else { const int sec = (k - 256) >> 6, p2 = (k - 256) & 63; l = p2 * 7 + 4 + sec; }
    btp[n * 448 + k] = (n < 35) ? f2bf(pw[l * 35 + n]) : (unsigned short)0;
  }
  if (idx < 64) pbp[idx] = (idx < 35) ? pb[idx] : 0.0f;
}

// ---------------- prep Bt_embed [512][64]
__global__ __launch_bounds__(256)
void k_prep_bte(const float* __restrict__ w, unsigned short* __restrict__ bte)
{
  const int idx = blockIdx.x * 256 + threadIdx.x;
  const int n = idx >> 6, k = idx & 63;
  bte[idx] = (k < 35) ? f2bf(w[k * 512 + n]) : (unsigned short)0;
}

// ---------------- temb table [4][512]
__global__ __launch_bounds__(256)
void k_temb(const float* __restrict__ gamma, float* __restrict__ temb)
{
  const int idx = blockIdx.x * 256 + threadIdx.x;
  const int t = idx >> 9, e = idx & 511;
  temb[idx] = cosf((float)t * (1.0f / 3.0f) * gamma[e]);
}

// ---------------- weight prep: fp32 [K][N] -> bf16 [N][K]
__global__ __launch_bounds__(256)
void k_cvt_trans(const float* __restrict__ in, unsigned short* __restrict__ out,
                 int K, int N, long long sIn, long long sOut)
{
  __shared__ float tile[32][33];
  const int z = blockIdx.z;
  in  += (size_t)z * sIn;
  out += (size_t)z * sOut;
  const int n0 = blockIdx.x * 32, k0 = blockIdx.y * 32;
  const int tx = threadIdx.x & 31, ty = threadIdx.x >> 5;
  #pragma unroll
  for (int i = 0; i < 4; ++i)
    tile[ty + i * 8][tx] = in[(size_t)(k0 + ty + i * 8) * N + n0 + tx];
  __syncthreads();
  #pragma unroll
  for (int i = 0; i < 4; ++i)
    out[(size_t)(n0 + ty + i * 8) * K + k0 + tx] = f2bf(tile[tx][ty + i * 8]);
}

__global__ __launch_bounds__(256)
void k_cvt(const float* __restrict__ in, unsigned short* __restrict__ out, int n)
{
  const int idx = blockIdx.x * 256 + threadIdx.x;
  if (idx < n) out[idx] = f2bf(in[idx]);
}

__global__ __launch_bounds__(256)
void k_prep_w3(const float* __restrict__ w, unsigned short* __restrict__ out)
{
  const int idx = blockIdx.x * 256 + threadIdx.x;
  if (idx < 9216) {
    const int kb = idx >> 10, co = (idx >> 5) & 31, ci = idx & 31;
    out[idx] = f2bf(w[(kb * 32 + ci) * 32 + co]);
  }
}

// ---------------- small bf16 MFMA GEMM, 64x64 tile, z-batched (patch/embed/AFNO)
template<int BIAS, int GELU, int OMODE>
__global__ __launch_bounds__(256)
void k_mgemm(const unsigned short* __restrict__ A, const unsigned short* __restrict__ Bt,
             const float* __restrict__ bias, unsigned short* __restrict__ OB,
             const float* __restrict__ pos, const float* __restrict__ temb,
             int K, int lda, int ldc,
             long long zsA, long long zsB, long long zsC, int zsBias)
{
  __shared__ __align__(16) unsigned short As[64 * 40];
  __shared__ __align__(16) unsigned short Bs[64 * 40];
  const int z = blockIdx.z;
  A  += (size_t)z * zsA;
  Bt += (size_t)z * zsB;
  if (BIAS) bias += (size_t)z * zsBias;
  OB += (size_t)z * zsC;
  const int m0 = blockIdx.y * 64, n0 = blockIdx.x * 64;
  const int tid = threadIdx.x;
  const int w = tid >> 6, l = tid & 63;
  const int lr = l & 15, lh = l >> 4;
  const int sr = tid >> 2, skq = (tid & 3) * 8;
  f4 acc[4] = {};
  for (int k0 = 0; k0 < K; k0 += 32) {
    const uint4 av = *(const uint4*)(A + (size_t)(m0 + sr) * lda + k0 + skq);
    *(uint4*)(&As[sr * 40 + skq]) = av;
    const uint4 bv = *(const uint4*)(Bt + (size_t)(n0 + sr) * K + k0 + skq);
    *(uint4*)(&Bs[sr * 40 + skq]) = bv;
    __syncthreads();
    const bh8 af = *(const bh8*)(&As[(w * 16 + lr) * 40 + lh * 8]);
    #pragma unroll
    for (int ct = 0; ct < 4; ++ct) {
      const bh8 bf = *(const bh8*)(&Bs[(ct * 16 + lr) * 40 + lh * 8]);
      acc[ct] = mfma16(af, bf, acc[ct]);
    }
    __syncthreads();
  }
  #pragma unroll
  for (int ct = 0; ct < 4; ++ct) {
    const int col = n0 + ct * 16 + lr;
    float bv = 0.f;
    if (BIAS) bv = bias[col];
    #pragma unroll
    for (int r = 0; r < 4; ++r) {
      const int row = m0 + w * 16 + lh * 4 + r;
      float v = acc[ct][r] + bv;
      if (GELU) v = gelu_f(v);
      if (OMODE == 2) {
        const int hw = (row >> 2) & 1023, t = row & 3;
        v = (v + pos[(size_t)hw * 512 + col]) * temb[t * 512 + col];
        OB[(size_t)row * 512 + col] = f2bf(v);
      } else {
        OB[(size_t)row * ldc + col] = f2bf(v);
      }
    }
  }
}

// ---------------- decoder tail: conv3x3 (MFMA) + gelu + 1x1 -> out
__global__ __launch_bounds__(256)
void k_tail(const unsigned short* __restrict__ Y1, const unsigned short* __restrict__ w3t,
            const float* __restrict__ c1w, const float* __restrict__ c1b,
            float* __restrict__ outp)
{
  __shared__ __align__(16) char lbuf[256 * 33 * 4];
  __shared__ float c1s[128];
  unsigned short* it = (unsigned short*)lbuf;
  float* y2 = (float*)lbuf;
  const int bx = blockIdx.x;
  const int b = bx >> 8, ty = (bx >> 4) & 15, tx = bx & 15;
  const int Y0 = ty * 16, X0 = tx * 16;
  const int tid = threadIdx.x;
  const int w = tid >> 6, l = tid & 63, lr = l & 15, lh = l >> 4;

  if (tid < 128) c1s[tid] = c1w[tid];
  for (int idx = tid; idx < 1296; idx += 256) {
    const int r = idx / 72, rem = idx - r * 72, c = rem >> 2, q = rem & 3;
    const int Yg = Y0 + r - 1, Xg = X0 + c - 1;
    uint4 v = make_uint4(0u, 0u, 0u, 0u);
    if (Yg >= 0 && Yg < 256 && Xg >= 0 && Xg < 256)
      v = *(const uint4*)(Y1 + (((size_t)(b * 256 + Yg)) * 256 + Xg) * 32 + q * 8);
    *(uint4*)(&it[(r * 18 + c) * 40 + q * 8]) = v;
  }
  bh8 bw[2][9];
  #pragma unroll
  for (int ct = 0; ct < 2; ++ct)
    #pragma unroll
    for (int kb = 0; kb < 9; ++kb)
      bw[ct][kb] = *(const bh8*)(w3t + (size_t)(kb * 32 + ct * 16 + lr) * 32 + lh * 8);
  __syncthreads();

  f4 acc[4][2] = {};
  #pragma unroll
  for (int kb = 0; kb < 9; ++kb) {
    const int dy = kb / 3, dx = kb % 3;
    #pragma unroll
    for (int yy = 0; yy < 4; ++yy) {
      const int y = w * 4 + yy;
      const bh8 af = *(const bh8*)(&it[((y + dy) * 18 + lr + dx) * 40 + lh * 8]);
      acc[yy][0] = mfma16(af, bw[0][kb], acc[yy][0]);
      acc[yy][1] = mfma16(af, bw[1][kb], acc[yy][1]);
    }
  }
  __syncthreads();
  #pragma unroll
  for (int yy = 0; yy < 4; ++yy) {
    const int y = w * 4 + yy;
    #pragma unroll
    for (int ct = 0; ct < 2; ++ct)
      #pragma unroll
      for (int r = 0; r < 4; ++r)
        y2[(y * 16 + lh * 4 + r) * 33 + ct * 16 + lr] = gelu_f(acc[yy][ct][r]);
  }
  __syncthreads();
  const int py = tid >> 4, px = tid & 15;
  float o0 = c1b[0], o1 = c1b[1], o2 = c1b[2], o3 = c1b[3];
  #pragma unroll 8
  for (int ci = 0; ci < 32; ++ci) {
    const float v = y2[tid * 33 + ci];
    o0 = fmaf(v, c1s[ci * 4 + 0], o0);
    o1 = fmaf(v, c1s[ci * 4 + 1], o1);
    o2 = fmaf(v, c1s[ci * 4 + 2], o2);
    o3 = fmaf(v, c1s[ci * 4 + 3], o3);
  }
  float4 ov; ov.x = o0; ov.y = o1; ov.z = o2; ov.w = o3;
  *(float4*)(outp + (((size_t)(b * 256 + Y0 + py)) * 256 + X0 + px) * 4) = ov;
}

// ---------------- forward DFT stage A (fused gn1 affine via PA partials) -> packed bf16 AB
__global__ __launch_bounds__(256)
void k_dft_a(const float* __restrict__ H, const float* __restrict__ PA,
             const float* __restrict__ sc, const float* __restrict__ bi,
             unsigned int* __restrict__ AB)
{
  __shared__ float ct[512], st[512];
  const int tid = threadIdx.x;
  for (int q = tid; q < 512; q += 256) {
    const int k = q >> 5, y = q & 31;
    const float ang = (float)((k * y) & 31) * 0.19634954084936207f;
    ct[q] = cosf(ang); st[q] = sinf(ang);
  }
  __syncthreads();
  const int blk = blockIdx.x;
  const int half = blk & 1, x = (blk >> 1) & 31, b = blk >> 6;
  const int c = half * 256 + tid;
  float sca, sh;
  gn_coef8(PA, sc, bi, b, c, sca, sh);
  float ar[16], ai[16];
  #pragma unroll
  for (int k = 0; k < 16; ++k) { ar[k] = 0.f; ai[k] = 0.f; }
  const float* zp = H + ((size_t)b * 1024 + x) * 512 + c;
  for (int y = 0; y < 32; ++y) {
    const float v = fmaf(zp[(size_t)y * 32 * 512], sca, sh);
    #pragma unroll
    for (int k = 0; k < 16; ++k) {
      ar[k] = fmaf(v, ct[k * 32 + y], ar[k]);
      ai[k] = fmaf(-v, st[k * 32 + y], ai[k]);
    }
  }
  #pragma unroll
  for (int k = 0; k < 16; ++k) {
    const size_t o = (((size_t)b * 16 + k) * 32 + x) * 512 + c;
    AB[o] = (unsigned int)f2bf(ar[k]) | ((unsigned int)f2bf(ai[k]) << 16);
  }
}

// ---------------- forward DFT stage B (packed bf16 in) -> stacked bf16 X [z][2048][128]
__global__ __launch_bounds__(256)
void k_dft_b(const unsigned int* __restrict__ AB, unsigned short* __restrict__ X)
{
  __shared__ float ct[512], st[512];
  const int tid = threadIdx.x;
  for (int q = tid; q < 512; q += 256) {
    const int k = q >> 5, xx = q & 31;
    const float ang = (float)((k * xx) & 31) * 0.19634954084936207f;
    ct[q] = cosf(ang); st[q] = sinf(ang);
  }
  __syncthreads();
  const int blk = blockIdx.x;
  const int half = blk & 1, kh = (blk >> 1) & 15, b = blk >> 5;
  const int c = half * 256 + tid;
  float gr[16], gi[16];
  #pragma unroll
  for (int k = 0; k < 16; ++k) { gr[k] = 0.f; gi[k] = 0.f; }
  const unsigned int* abp = AB + (((size_t)b * 16 + kh) * 32) * 512 + c;
  for (int x = 0; x < 32; ++x) {
    const unsigned int pv = abp[(size_t)x * 512];
    const float vr = bf2f((unsigned short)(pv & 0xffffu));
    const float vi = bf2f((unsigned short)(pv >> 16));
    #pragma unroll
    for (int k = 0; k < 16; ++k) {
      const float cc_ = ct[k * 32 + x], ss = st[k * 32 + x];
      gr[k] += vr * cc_ + vi * ss;
      gi[k] += vi * cc_ - vr * ss;
    }
  }
  const int blkc = c >> 6, ii = c & 63;
  #pragma unroll
  for (int k = 0; k < 16; ++k) {
    const size_t pos = (size_t)b * 256 + kh * 16 + k;
    unsigned short* xp = X + ((size_t)blkc * 2048 + pos) * 128 + ii;
    xp[0]  = f2bf(gr[k] * (1.0f / 32.0f));
    xp[64] = f2bf(gi[k] * (1.0f / 32.0f));
  }
}

// ---------------- merged AFNO weights for ALL layers
__global__ __launch_bounds__(256)
void k_mode_prep_all(const float* __restrict__ aw1, const float* __restrict__ aw2,
                     const float* __restrict__ ab1, const float* __restrict__ ab2,
                     unsigned short* __restrict__ Sb, float* __restrict__ SB)
{
  const int gi = blockIdx.x * 256 + threadIdx.x;   // 12*262144
  const int dd = gi >> 18;
  const int idx = gi & 262143;
  const float* aw1_d = aw1 + (size_t)dd * 65536;
  const float* aw2_d = aw2 + (size_t)dd * 65536;
  const int s = idx >> 17;
  const int blk = (idx >> 14) & 7;
  const int n = (idx >> 7) & 127;
  const int kk = idx & 127;
  const float* aw = s ? aw2_d : aw1_d;
  const int i = kk & 63, o = n & 63;
  const float wr = aw[(blk * 64 + i) * 64 + o];
  const float wi = aw[32768 + (blk * 64 + i) * 64 + o];
  float val;
  if (n < 64) val = (kk < 64) ? wr : -wi;
  else        val = (kk < 64) ? wi :  wr;
  Sb[gi] = f2bf(val);
  if (idx < 2048) {
    const int s2 = idx >> 10, r2 = idx & 1023, b2 = r2 >> 7, q2 = r2 & 127;
    const float* ab = s2 ? (ab2 + dd * 1024) : (ab1 + dd * 1024);
    SB[dd * 2048 + idx] = (q2 < 64) ? ab[b2 * 64 + q2] : ab[512 + b2 * 64 + (q2 - 64)];
  }
}

// ---------------- inverse DFT stage D (bf16 X2 in) -> packed bf16 T
__global__ __launch_bounds__(256)
void k_idft_d(const unsigned short* __restrict__ X2, unsigned int* __restrict__ Tp)
{
  __shared__ float ct[512], st[512];
  const int tid = threadIdx.x;
  for (int q = tid; q < 512; q += 256) {
    const int kw = q >> 5, xx = q & 31;
    const float w = (kw == 0) ? 1.0f : 2.0f;
    const float ang = (float)((kw * xx) & 31) * 0.19634954084936207f;
    ct[q] = w * cosf(ang); st[q] = w * sinf(ang);
  }
  __syncthreads();
  const int blk = blockIdx.x;
  const int half = blk & 1, kh = (blk >> 1) & 15, b = blk >> 5;
  const int c = half * 256 + tid;
  const int blkc = c >> 6, ii = c & 63;
  float gr[16], gi[16];
  #pragma unroll
  for (int kw = 0; kw < 16; ++kw) {
    const size_t pos = (size_t)b * 256 + kh * 16 + kw;
    gr[kw] = bf2f(X2[((size_t)blkc * 2048 + pos) * 128 + ii]);
    gi[kw] = bf2f(X2[((size_t)blkc * 2048 + pos) * 128 + 64 + ii]);
  }
  for (int x = 0; x < 32; ++x) {
    float tr = 0.f, ti = 0.f;
    #pragma unroll
    for (int kw = 0; kw < 16; ++kw) {
      const float cc_ = ct[kw * 32 + x], ss = st[kw * 32 + x];
      tr += gr[kw] * cc_ - gi[kw] * ss;
      ti += gi[kw] * cc_ + gr[kw] * ss;
    }
    const size_t o = (((size_t)b * 16 + kh) * 32 + x) * 512 + c;
    Tp[o] = (unsigned int)f2bf(tr) | ((unsigned int)f2bf(ti) << 16);
  }
}

// ---------------- inverse DFT stage E + gn1-affine residual + gn2 partials (PB)
__global__ __launch_bounds__(256)
void k_idft_e(const unsigned int* __restrict__ Tp, const float* __restrict__ H,
              const float* __restrict__ PA, const float* __restrict__ sc,
              const float* __restrict__ bi, float* __restrict__ za,
              float* __restrict__ PB)
{
  __shared__ float ct[512], st[512];
  const int tid = threadIdx.x;
  for (int q = tid; q < 512; q += 256) {
    const int k = q >> 5, y = q & 31;
    const float ang = (float)((k * y) & 31) * 0.19634954084936207f;
    ct[q] = cosf(ang); st[q] = sinf(ang);
  }
  __syncthreads();
  const int blk = blockIdx.x;
  const int half = blk & 1, x = (blk >> 1) & 31, b = blk >> 6;
  const int c = half * 256 + tid;
  float sca, sh;
  gn_coef8(PA, sc, bi, b, c, sca, sh);
  float trv[16], tiv[16];
  #pragma unroll
  for (int k = 0; k < 16; ++k) {
    const size_t o = (((size_t)b * 16 + k) * 32 + x) * 512 + c;
    const unsigned int pv = Tp[o];
    trv[k] = bf2f((unsigned short)(pv & 0xffffu));
    tiv[k] = bf2f((unsigned short)(pv >> 16));
  }
  float s1 = 0.f, s2 = 0.f;
  for (int y = 0; y < 32; ++y) {
    float v = 0.f;
    #pragma unroll
    for (int k = 0; k < 16; ++k)
      v += trv[k] * ct[k * 32 + y] - tiv[k] * st[k * 32 + y];
    const size_t o = ((size_t)b * 1024 + y * 32 + x) * 512 + c;
    const float zv = v * (1.0f / 32.0f) + fmaf(H[o], sca, sh);
    za[o] = zv;
    s1 += zv; s2 += zv * zv;
  }
  #pragma unroll
  for (int sft = 32; sft > 0; sft >>= 1) {
    s1 += __shfl_xor(s1, sft, 64);
    s2 += __shfl_xor(s2, sft, 64);
  }
  if ((tid & 63) == 0) {
    const int g = half * 4 + (tid >> 6);
    PB[(b * 8 + g) * 32 + x] = s1;
    PB[2048 + (b * 8 + g) * 32 + x] = s2;
  }
}

// ---------------- gn2 coef table from PB (ns=32)
__global__ __launch_bounds__(256)
void k_gn_coef(const float* __restrict__ PB, const float* __restrict__ sc,
               const float* __restrict__ bi, float* __restrict__ gnc)
{
  const int idx = blockIdx.x * 256 + threadIdx.x;   // 4096
  const int b = idx >> 9, c = idx & 511, g = c >> 6;
  float s1 = 0.f, s2 = 0.f;
  #pragma unroll
  for (int q = 0; q < 32; ++q) {
    s1 += PB[(b * 8 + g) * 32 + q];
    s2 += PB[2048 + (b * 8 + g) * 32 + q];
  }
  const float mu = s1 * (1.0f / 65536.0f);
  const float var = s2 * (1.0f / 65536.0f) - mu * mu;
  const float rs = rsqrtf(var + 1e-5f);
  const float sca = sc[c] * rs;
  gnc[idx] = sca;
  gnc[4096 + idx] = bi[c] - mu * sca;
}

// ---------------- cls layers 1/2 (ILP-4 accumulators)
template<int FIRST>
__global__ __launch_bounds__(256)
void k_cls_l(const float* __restrict__ src, const float* __restrict__ Wm,
             const float* __restrict__ bb, float* __restrict__ Cout)
{
  __shared__ float tok[512];
  __shared__ float red[256];
  const int b = blockIdx.y, oc = blockIdx.x;
  const int tid = threadIdx.x;
  for (int i = tid; i < 512; i += 256) {
    if (FIRST) {
      float s = 0.f;
      #pragma unroll
      for (int q = 0; q < 8; ++q) s += src[((b * 8 + q) << 9) + i];
      tok[i] = s * (1.0f / 1024.0f);
    } else {
      tok[i] = src[b * 512 + i];
    }
  }
  __syncthreads();
  const int to = tid & 63, iq = tid >> 6;
  const int o = oc * 64 + to;
  const float* wp = Wm + (size_t)(iq * 128) * 512 + o;
  const float* tp = tok + iq * 128;
  float a0 = 0.f, a1 = 0.f, a2 = 0.f, a3 = 0.f;
  #pragma unroll 8
  for (int i = 0; i < 128; i += 4) {
    a0 = fmaf(tp[i + 0], wp[(size_t)(i + 0) * 512], a0);
    a1 = fmaf(tp[i + 1], wp[(size_t)(i + 1) * 512], a1);
    a2 = fmaf(tp[i + 2], wp[(size_t)(i + 2) * 512], a2);
    a3 = fmaf(tp[i + 3], wp[(size_t)(i + 3) * 512], a3);
  }
  red[tid] = (a0 + a1) + (a2 + a3);
  __syncthreads();
  if (tid < 64) {
    const int oo = oc * 64 + tid;
    const float v = red[tid] + red[tid + 64] + red[tid + 128] + red[tid + 192] + bb[oo];
    Cout[b * 512 + oo] = gelu_f(v);
  }
}

// ---------------- cls layer 3
__global__ __launch_bounds__(768)
void k_cls3(const float* __restrict__ C2, const float* __restrict__ w3,
            const float* __restrict__ b3, float* __restrict__ outp)
{
  const int b = blockIdx.x, tid = threadIdx.x;
  const int o = tid >> 6, lane = tid & 63;
  float acc = 0.f;
  for (int i = lane; i < 512; i += 64)
    acc = fmaf(C2[b * 512 + i], w3[i * 12 + o], acc);
  #pragma unroll
  for (int s = 32; s > 0; s >>= 1) acc += __shfl_xor(acc, s, 64);
  if (lane == 0) outp[2097152 + b * 12 + o] = acc + b3[o];
}

extern "C" void kernel_launch(void* const* d_in, const int* in_sizes, int n_in,
                              void* d_out, int out_size, void* d_ws, size_t ws_size,
                              hipStream_t stream)
{
  (void)in_sizes; (void)n_in; (void)out_size; (void)ws_size;
  const float* x      = (const float*)d_in[0];
  const float* patch_w= (const float*)d_in[1];
  const float* patch_b= (const float*)d_in[2];
  const float* p1_w   = (const float*)d_in[3];
  const float* p1_b   = (const float*)d_in[4];
  const float* pos    = (const float*)d_in[5];
  const float* tagg_w = (const float*)d_in[6];
  const float* gamma  = (const float*)d_in[7];
  const float* gn1_s  = (const float*)d_in[8];
  const float* gn1_b  = (const float*)d_in[9];
  const float* aw1    = (const float*)d_in[10];
  const float* ab1    = (const float*)d_in[11];
  const float* aw2    = (const float*)d_in[12];
  const float* ab2    = (const float*)d_in[13];
  const float* gn2_s  = (const float*)d_in[14];
  const float* gn2_b  = (const float*)d_in[15];
  const float* mw1    = (const float*)d_in[16];
  const float* mb1    = (const float*)d_in[17];
  const float* mw2    = (const float*)d_in[18];
  const float* mb2    = (const float*)d_in[19];
  const float* cls_w1 = (const float*)d_in[20];
  const float* cls_b1 = (const float*)d_in[21];
  const float* cls_w2 = (const float*)d_in[22];
  const float* cls_b2 = (const float*)d_in[23];
  const float* cls_w3 = (const float*)d_in[24];
  const float* cls_b3 = (const float*)d_in[25];
  const float* dec_w  = (const float*)d_in[26];
  const float* dec_b  = (const float*)d_in[27];
  const float* c3_w   = (const float*)d_in[28];
  const float* c3_b   = (const float*)d_in[29];
  const float* c1_w   = (const float*)d_in[30];
  const float* c1_b   = (const float*)d_in[31];

  float* W = (float*)d_ws;
  // ---- fixed layout (round-6 bug: R1/UO were undersized; H0b clobbered SbA,
  //      Ub raced with ZA). All sizes in float units; end = 24,761,408 f = 94.5MB.
  float* H            = W;                                  // 4,194,304 f
  unsigned int* ABT   = (unsigned int*)(W + 4194304);       // 2,097,152 u32 (AB / Tp)
  unsigned short* Xb  = (unsigned short*)(W + 6291456);     // 2,097,152 sh
  unsigned short* X2b = (unsigned short*)(W + 7340032);     // 2,097,152 sh
  unsigned short* UO  = (unsigned short*)(W + 8388608);     // 4,194,304 sh (P1b/O1b/Ub)
  float* R1           = W + 10485760;                       // 8,388,608 f (imat/H0b/ZA/Y1)
  unsigned short* SbA = (unsigned short*)(W + 18874368);    // 3,145,728 sh
  float* SBa          = W + 20447232;                       // 24,576 f
  unsigned short* taggT = (unsigned short*)(W + 20471808);  // 1,048,576 sh
  unsigned short* mwT1  = (unsigned short*)(W + 20996096);  // 3,145,728 sh
  unsigned short* mwT2  = (unsigned short*)(W + 22568960);  // 3,145,728 sh
  unsigned short* decC  = (unsigned short*)(W + 24141824);  // 1,048,576 sh
  unsigned short* w3t   = (unsigned short*)(W + 24666112);  // 16,384 sh
  unsigned short* btp   = (unsigned short*)(W + 24674304);  // 28,672 sh
  unsigned short* bte   = (unsigned short*)(W + 24688640);  // 32,768 sh
  float* TEMB  = W + 24705024;                              // 2,048
  float* PBP   = W + 24707072;                              // 64
  float* PA    = W + 24707136;                              // 1,024
  float* PB    = W + 24708160;                              // 4,096
  float* GNC   = W + 24712256;                              // 8,192
  float* PARTC = W + 24720448;                              // 32,768
  float* C1    = W + 24753216;                              // 4,096
  float* C2    = W + 24757312;                              // 4,096

  unsigned short* imat = (unsigned short*)R1;
  unsigned short* H0b  = (unsigned short*)R1;
  unsigned short* Y1   = (unsigned short*)R1;
  float* ZA = R1;
  unsigned short* P1b = UO;
  unsigned short* O1b = UO;
  unsigned short* Ub  = UO;
  float* out = (float*)d_out;

  // ---- weight prep (once)
  k_cvt_trans<<<dim3(16,64,1),256,0,stream>>>(tagg_w, taggT, 2048, 512, 0, 0);
  k_cvt_trans<<<dim3(16,16,12),256,0,stream>>>(mw1, mwT1, 512, 512, 262144, 262144);
  k_cvt_trans<<<dim3(16,16,12),256,0,stream>>>(mw2, mwT2, 512, 512, 262144, 262144);
  k_cvt<<<4096,256,0,stream>>>(dec_w, decC, 1048576);
  k_prep_w3<<<36,256,0,stream>>>(c3_w, w3t);
  k_prep_btp<<<112,256,0,stream>>>(patch_w, patch_b, btp, PBP);
  k_prep_bte<<<128,256,0,stream>>>(p1_w, bte);
  k_temb<<<8,256,0,stream>>>(gamma, TEMB);
  k_mode_prep_all<<<12288,256,0,stream>>>(aw1, aw2, ab1, ab2, SbA, SBa);

  // ---- encoder
  k_pack<<<8192,256,0,stream>>>(x, imat);
  k_mgemm<1,1,1><<<dim3(1,512),256,0,stream>>>(imat, btp, PBP, P1b,
      nullptr, nullptr, 448, 448, 64, 0, 0, 0, 0);
  k_mgemm<1,0,2><<<dim3(8,512),256,0,stream>>>(P1b, bte, p1_b, H0b,
      pos, TEMB, 64, 64, 512, 0, 0, 0, 0);
  // tagg: H0b @ taggT^T -> H (f32) + gn1 partials PA
  k_bgemm<0,0><<<256,256,0,stream>>>(H0b, taggT, H, nullptr, nullptr, nullptr,
      nullptr, PA, 2048, 512, 4);

  for (int d = 0; d < 12; ++d) {
    k_dft_a<<<512,256,0,stream>>>(H, PA, gn1_s + d*512, gn1_b + d*512, ABT);
    k_dft_b<<<256,256,0,stream>>>(ABT, Xb);
    k_mgemm<1,1,1><<<dim3(2,32,8),256,0,stream>>>(Xb, SbA + (size_t)d*262144,
        SBa + d*2048, O1b, nullptr, nullptr, 128, 128, 128, 262144LL, 16384LL, 262144LL, 128);
    k_mgemm<1,0,1><<<dim3(2,32,8),256,0,stream>>>(O1b, SbA + (size_t)d*262144 + 131072,
        SBa + d*2048 + 1024, X2b, nullptr, nullptr, 128, 128, 128, 262144LL, 16384LL, 262144LL, 128);
    k_idft_d<<<256,256,0,stream>>>(X2b, ABT);
    k_idft_e<<<512,256,0,stream>>>(ABT, H, PA, gn1_s + d*512, gn1_b + d*512, ZA, PB);
    k_gn_coef<<<16,256,0,stream>>>(PB, gn2_s + d*512, gn2_b + d*512, GNC);
    // mlp1: gn2(ZA) @ mwT1^T + b -> gelu -> Ub (bf16)
    k_bgemm<2,1><<<256,256,0,stream>>>(ZA, mwT1 + (size_t)d*262144, nullptr, Ub,
        mb1 + d*512, nullptr, GNC, nullptr, 512, 512, 4);
    // mlp2: Ub @ mwT2^T + b + H -> H (+ partials: gn1-next or cls)
    if (d < 11)
      k_bgemm<0,2><<<256,256,0,stream>>>(Ub, mwT2 + (size_t)d*262144, H, nullptr,
          mb2 + d*512, H, nullptr, PA, 512, 512, 4);
    else
      k_bgemm<0,4><<<256,256,0,stream>>>(Ub, mwT2 + (size_t)d*262144, H, nullptr,
          mb2 + d*512, H, nullptr, PARTC, 512, 512, 4);
  }

  k_cls_l<1><<<dim3(8,8),256,0,stream>>>(PARTC, cls_w1, cls_b1, C1);
  k_cls_l<0><<<dim3(8,8),256,0,stream>>>(C1, cls_w2, cls_b2, C2);
  k_cls3<<<8,768,0,stream>>>(C2, cls_w3, cls_b3, out);
  // decoder: H (f32) @ decC^T -> gelu(+dec_b) -> pixel-layout bf16 Y1
  k_bgemm<1,3><<<1024,256,0,stream>>>(H, decC, nullptr, Y1,
      dec_b, nullptr, nullptr, nullptr, 512, 0, 16);
  k_tail<<<2048,256,0,stream>>>(Y1, w3t, c1_w, c1_b, out);
}

// Round 8
// 1427.551 us; speedup vs baseline: 2.9422x; 1.0767x over previous
//
#include <hip/hip_runtime.h>
#include <cstddef>

typedef __attribute__((ext_vector_type(8))) short bh8;
typedef __attribute__((ext_vector_type(4))) float f4;

__device__ __forceinline__ float gelu_f(float x){
  return 0.5f * x * (1.0f + erff(x * 0.7071067811865476f));
}

__device__ __forceinline__ unsigned short f2bf(float f){
  unsigned int u = __float_as_uint(f);
  unsigned int r = (u + 0x7FFFu + ((u >> 16) & 1u)) >> 16;
  return (unsigned short)r;
}

__device__ __forceinline__ float bf2f(unsigned short u){
  return __uint_as_float(((unsigned int)u) << 16);
}

__device__ __forceinline__ f4 mfma16(bh8 a, bh8 b, f4 c){
  return __builtin_amdgcn_mfma_f32_16x16x32_bf16(a, b, c, 0, 0, 0);
}

__device__ __forceinline__ void gll16(const unsigned short* src, unsigned short* dst){
  __builtin_amdgcn_global_load_lds(
      (const __attribute__((address_space(1))) unsigned int*)src,
      (__attribute__((address_space(3))) unsigned int*)dst, 16, 0, 0);
}

// gn coef from 8-slice partials PA[(b*8+g)*8+q], s2 at +512
__device__ __forceinline__ void gn_coef8(const float* pa, const float* sc,
                                         const float* bi, int b, int c,
                                         float& sca, float& sh)
{
  const int g = c >> 6;
  float s1 = 0.f, s2 = 0.f;
  #pragma unroll
  for (int q = 0; q < 8; ++q) {
    s1 += pa[(b * 8 + g) * 8 + q];
    s2 += pa[512 + (b * 8 + g) * 8 + q];
  }
  const float mu = s1 * (1.0f / 65536.0f);
  const float var = s2 * (1.0f / 65536.0f) - mu * mu;
  const float rs = rsqrtf(var + 1e-5f);
  sca = sc[c] * rs;
  sh = bi[c] - mu * sca;
}

// ================= big bf16 MFMA GEMM: 128x128 tile, BK=64, 1024 thr (16 waves),
// 2-phase dbuf pipeline, XCD chunk swizzle.
// AMODE: 0=bf16 gll, 1=f32 reg-staged, 2=f32 + GN affine (gnc).
// OMODE: 0=f32 C + gn-partials; 1=bias+gelu->bf16 OB; 2=bias+Res->f32 C + gn-partials;
//        3=DEC gelu(+bias[col&31]) pixel-scatter; 4=bias+Res->f32 C + cls col-partials.
#define BG_STAGE(dbuf, kofs, BASE, DST) \
  gll16(BASE + (size_t)sr_ * K + (kofs) + ((ss_ ^ (sr_ & 7)) << 3), &DST[dbuf][tid * 8]);

#define BG_LOADA(kofs) { \
  const float* ap_ = Afbase + (size_t)sr_ * K + (kofs) + ss_ * 8; \
  ra0 = *(const float4*)ap_; \
  ra1 = *(const float4*)(ap_ + 4); \
  if (AMODE == 2) { \
    const int bb_ = (m0 + sr_) >> 10; \
    const int ch_ = (kofs) + ss_ * 8; \
    const float4 c0_ = *(const float4*)(gnc + bb_ * 512 + ch_); \
    const float4 c1_ = *(const float4*)(gnc + bb_ * 512 + ch_ + 4); \
    const float4 h0_ = *(const float4*)(gnc + 4096 + bb_ * 512 + ch_); \
    const float4 h1_ = *(const float4*)(gnc + 4096 + bb_ * 512 + ch_ + 4); \
    ra0.x = fmaf(ra0.x, c0_.x, h0_.x); ra0.y = fmaf(ra0.y, c0_.y, h0_.y); \
    ra0.z = fmaf(ra0.z, c0_.z, h0_.z); ra0.w = fmaf(ra0.w, c0_.w, h0_.w); \
    ra1.x = fmaf(ra1.x, c1_.x, h1_.x); ra1.y = fmaf(ra1.y, c1_.y, h1_.y); \
    ra1.z = fmaf(ra1.z, c1_.z, h1_.z); ra1.w = fmaf(ra1.w, c1_.w, h1_.w); \
  } }

#define BG_WRITEA(dbuf) { \
  const int slot_ = ss_ ^ (sr_ & 7); \
  bh8 av_; \
  av_[0] = (short)f2bf(ra0.x); av_[1] = (short)f2bf(ra0.y); \
  av_[2] = (short)f2bf(ra0.z); av_[3] = (short)f2bf(ra0.w); \
  av_[4] = (short)f2bf(ra1.x); av_[5] = (short)f2bf(ra1.y); \
  av_[6] = (short)f2bf(ra1.z); av_[7] = (short)f2bf(ra1.w); \
  *(bh8*)(&As[dbuf][sr_ * 64 + slot_ * 8]) = av_; }

template<int AMODE, int OMODE>
__global__ __launch_bounds__(1024)
void k_bgemm(const void* __restrict__ Av, const unsigned short* __restrict__ Bt,
             float* __restrict__ C, unsigned short* __restrict__ OB,
             const float* __restrict__ bias, const float* __restrict__ Res,
             const float* __restrict__ gnc, float* __restrict__ gpart,
             int K, int ldc, int nn)
{
  __shared__ __align__(16) unsigned short As[2][8192];
  __shared__ __align__(16) unsigned short Bs[2][8192];
  const int bid = blockIdx.x, nwg = gridDim.x;
  const int wg = (bid & 7) * (nwg >> 3) + (bid >> 3);
  const int mb = wg / nn;
  const int m0 = mb * 128, n0 = (wg - mb * nn) * 128;
  const int tid = threadIdx.x;
  const int w = tid >> 6, lane = tid & 63;
  const int lr = lane & 15, lh = lane >> 4;
  const int wr = w >> 2, wc = w & 3;
  const int sr_ = tid >> 3, ss_ = tid & 7;     // stage: row 0..127, 8-elem chunk 0..7
  const unsigned short* Abase = (const unsigned short*)Av + (size_t)m0 * K;
  const float* Afbase = (const float*)Av + (size_t)m0 * K;
  const unsigned short* Bbase = Bt + (size_t)n0 * K;
  float4 ra0, ra1;
  f4 acc[2][2] = {};

  const int nt = K >> 6;
  // prologue: stage tile 0
  if (AMODE == 0) { BG_STAGE(0, 0, Abase, As) }
  else            { BG_LOADA(0) BG_WRITEA(0) }
  BG_STAGE(0, 0, Bbase, Bs)
  __syncthreads();

  for (int t = 0; t < nt; ++t) {
    const int d = t & 1;
    const bool more = (t + 1 < nt);
    if (more) {
      const int kn = (t + 1) << 6;
      if (AMODE == 0) { BG_STAGE(d ^ 1, kn, Abase, As) }
      else            { BG_LOADA(kn) }
      BG_STAGE(d ^ 1, kn, Bbase, Bs)
    }
    #pragma unroll
    for (int kk = 0; kk < 2; ++kk) {
      bh8 af[2], bf[2];
      #pragma unroll
      for (int mi = 0; mi < 2; ++mi) {
        const int R = wr * 32 + mi * 16 + lr;
        af[mi] = *(const bh8*)((const char*)As[d] + R * 128 + (((kk * 4 + lh) ^ (R & 7)) * 16));
      }
      #pragma unroll
      for (int ni = 0; ni < 2; ++ni) {
        const int R = wc * 32 + ni * 16 + lr;
        bf[ni] = *(const bh8*)((const char*)Bs[d] + R * 128 + (((kk * 4 + lh) ^ (R & 7)) * 16));
      }
      #pragma unroll
      for (int mi = 0; mi < 2; ++mi)
        #pragma unroll
        for (int ni = 0; ni < 2; ++ni)
          acc[mi][ni] = mfma16(af[mi], bf[ni], acc[mi][ni]);
    }
    if (more && AMODE != 0) { BG_WRITEA(d ^ 1) }
    __syncthreads();
  }

  float cs1[2], cs2[2];
  #pragma unroll
  for (int ni = 0; ni < 2; ++ni) {
    const int col_l = wc * 32 + ni * 16 + lr;
    const int col = n0 + col_l;
    float bv = 0.f;
    if (OMODE == 1 || OMODE == 2 || OMODE == 4) bv = bias[col];
    if (OMODE == 3) bv = bias[col & 31];
    float s1 = 0.f, s2 = 0.f;
    #pragma unroll
    for (int mi = 0; mi < 2; ++mi) {
      #pragma unroll
      for (int r = 0; r < 4; ++r) {
        const int row = m0 + wr * 32 + mi * 16 + lh * 4 + r;
        float v = acc[mi][ni][r] + bv;
        if (OMODE == 0) {
          C[(size_t)row * ldc + col] = v;
          s1 += v; s2 += v * v;
        } else if (OMODE == 1) {
          OB[(size_t)row * ldc + col] = f2bf(gelu_f(v));
        } else if (OMODE == 2 || OMODE == 4) {
          const size_t ci = (size_t)row * ldc + col;
          v += Res[ci];
          C[ci] = v;
          s1 += v; s2 += v * v;
        } else {
          v = gelu_f(v);
          const int bb = row >> 10, hw = row & 1023, ii = hw >> 5, jj = hw & 31;
          const int dxy = col >> 5, dy = dxy >> 3, dx = dxy & 7, cc = col & 31;
          OB[(((size_t)(bb * 256 + ii * 8 + dy)) * 256 + jj * 8 + dx) * 32 + cc] = f2bf(v);
        }
      }
    }
    cs1[ni] = s1; cs2[ni] = s2;
  }
  if (OMODE == 0 || OMODE == 2 || OMODE == 4) {
    float* sp = (float*)As;   // 16KB scratch, safe after final barrier
    const int sub = wr * 4 + lh;
    #pragma unroll
    for (int ni = 0; ni < 2; ++ni) {
      const int col_l = wc * 32 + ni * 16 + lr;
      sp[col_l * 16 + sub] = cs1[ni];
      sp[2048 + col_l * 16 + sub] = cs2[ni];
    }
    __syncthreads();
    if (tid < 128) {
      float s1 = 0.f, s2 = 0.f;
      #pragma unroll
      for (int u = 0; u < 16; ++u) { s1 += sp[tid * 16 + u]; s2 += sp[2048 + tid * 16 + u]; }
      const int b = m0 >> 10, slice = (m0 >> 7) & 7;
      if (OMODE == 4) {
        gpart[(b * 8 + slice) * 512 + n0 + tid] = s1;
      } else {
        #pragma unroll
        for (int sft = 32; sft > 0; sft >>= 1) {
          s1 += __shfl_xor(s1, sft, 64);
          s2 += __shfl_xor(s2, sft, 64);
        }
        if ((tid & 63) == 0) {
          const int g = (n0 >> 6) + (tid >> 6);
          gpart[(b * 8 + g) * 8 + slice] = s1;
          gpart[512 + (b * 8 + g) * 8 + slice] = s2;
        }
      }
    }
  }
}

// ---------------- im2col pack: x -> bf16 imat [32768][448]
__global__ __launch_bounds__(256)
void k_pack(const float* __restrict__ x, unsigned short* __restrict__ imat)
{
  const int nb = blockIdx.x;
  const int j = nb & 31, i = (nb >> 5) & 31, b = nb >> 10;
  const int tid = threadIdx.x;
  const int tl = tid >> 6, px = tid & 63;
  const int dy = px >> 3, dx = px & 7;
  const int Y = i * 8 + dy, X = j * 8 + dx;
  const float4 v = *(const float4*)(x + (((size_t)(b * 256 + Y)) * 256 + X) * 16 + tl * 4);
  const size_t row = (size_t)nb * 4 + tl;
  ushort4 ov;
  ov.x = f2bf(v.x); ov.y = f2bf(v.y); ov.z = f2bf(v.z); ov.w = f2bf(v.w);
  *(ushort4*)(imat + row * 448 + px * 4) = ov;
  for (int q = tid; q < 768; q += 256) {
    const int tt = q / 192, r = q - tt * 192;
    const int sec = r >> 6, p2 = r & 63;
    float val;
    if (sec == 0)      val = (float)(i * 8 + (p2 >> 3)) * (1.0f / 255.0f);
    else if (sec == 1) val = (float)(j * 8 + (p2 & 7)) * (1.0f / 255.0f);
    else               val = (float)tt * (1.0f / 3.0f);
    imat[((size_t)nb * 4 + tt) * 448 + 256 + sec * 64 + p2] = f2bf(val);
  }
}

// ---------------- prep Bt_patch [64][448] (+ padded bias)
__global__ __launch_bounds__(256)
void k_prep_btp(const float* __restrict__ pw, const float* __restrict__ pb,
                unsigned short* __restrict__ btp, float* __restrict__ pbp)
{
  const int idx = blockIdx.x * 256 + threadIdx.x;
  if (idx < 28672) {
    const int n = idx / 448, k = idx - (idx / 448) * 448;
    int l;
    if (k < 256) { const int pxx = k >> 2, c = k & 3; l = pxx * 7 + c; }
    else { const int sec = (k - 256) >> 6, p2 = (k - 256) & 63; l = p2 * 7 + 4 + sec; }
    btp[n * 448 + k] = (n < 35) ? f2bf(pw[l * 35 + n]) : (unsigned short)0;
  }
  if (idx < 64) pbp[idx] = (idx < 35) ? pb[idx] : 0.0f;
}

// ---------------- prep Bt_embed [512][64]
__global__ __launch_bounds__(256)
void k_prep_bte(const float* __restrict__ w, unsigned short* __restrict__ bte)
{
  const int idx = blockIdx.x * 256 + threadIdx.x;
  const int n = idx >> 6, k = idx & 63;
  bte[idx] = (k < 35) ? f2bf(w[k * 512 + n]) : (unsigned short)0;
}

// ---------------- temb table [4][512]
__global__ __launch_bounds__(256)
void k_temb(const float* __restrict__ gamma, float* __restrict__ temb)
{
  const int idx = blockIdx.x * 256 + threadIdx.x;
  const int t = idx >> 9, e = idx & 511;
  temb[idx] = cosf((float)t * (1.0f / 3.0f) * gamma[e]);
}

// ---------------- weight prep: fp32 [K][N] -> bf16 [N][K]
__global__ __launch_bounds__(256)
void k_cvt_trans(const float* __restrict__ in, unsigned short* __restrict__ out,
                 int K, int N, long long sIn, long long sOut)
{
  __shared__ float tile[32][33];
  const int z = blockIdx.z;
  in  += (size_t)z * sIn;
  out += (size_t)z * sOut;
  const int n0 = blockIdx.x * 32, k0 = blockIdx.y * 32;
  const int tx = threadIdx.x & 31, ty = threadIdx.x >> 5;
  #pragma unroll
  for (int i = 0; i < 4; ++i)
    tile[ty + i * 8][tx] = in[(size_t)(k0 + ty + i * 8) * N + n0 + tx];
  __syncthreads();
  #pragma unroll
  for (int i = 0; i < 4; ++i)
    out[(size_t)(n0 + ty + i * 8) * K + k0 + tx] = f2bf(tile[tx][ty + i * 8]);
}

__global__ __launch_bounds__(256)
void k_cvt(const float* __restrict__ in, unsigned short* __restrict__ out, int n)
{
  const int idx = blockIdx.x * 256 + threadIdx.x;
  if (idx < n) out[idx] = f2bf(in[idx]);
}

__global__ __launch_bounds__(256)
void k_prep_w3(const float* __restrict__ w, unsigned short* __restrict__ out)
{
  const int idx = blockIdx.x * 256 + threadIdx.x;
  if (idx < 9216) {
    const int kb = idx >> 10, co = (idx >> 5) & 31, ci = idx & 31;
    out[idx] = f2bf(w[(kb * 32 + ci) * 32 + co]);
  }
}

// ---------------- small bf16 MFMA GEMM, 64x64 tile, z-batched (patch/embed/AFNO)
template<int BIAS, int GELU, int OMODE>
__global__ __launch_bounds__(256)
void k_mgemm(const unsigned short* __restrict__ A, const unsigned short* __restrict__ Bt,
             const float* __restrict__ bias, unsigned short* __restrict__ OB,
             const float* __restrict__ pos, const float* __restrict__ temb,
             int K, int lda, int ldc,
             long long zsA, long long zsB, long long zsC, int zsBias)
{
  __shared__ __align__(16) unsigned short As[64 * 40];
  __shared__ __align__(16) unsigned short Bs[64 * 40];
  const int z = blockIdx.z;
  A  += (size_t)z * zsA;
  Bt += (size_t)z * zsB;
  if (BIAS) bias += (size_t)z * zsBias;
  OB += (size_t)z * zsC;
  const int m0 = blockIdx.y * 64, n0 = blockIdx.x * 64;
  const int tid = threadIdx.x;
  const int w = tid >> 6, l = tid & 63;
  const int lr = l & 15, lh = l >> 4;
  const int sr = tid >> 2, skq = (tid & 3) * 8;
  f4 acc[4] = {};
  for (int k0 = 0; k0 < K; k0 += 32) {
    const uint4 av = *(const uint4*)(A + (size_t)(m0 + sr) * lda + k0 + skq);
    *(uint4*)(&As[sr * 40 + skq]) = av;
    const uint4 bv = *(const uint4*)(Bt + (size_t)(n0 + sr) * K + k0 + skq);
    *(uint4*)(&Bs[sr * 40 + skq]) = bv;
    __syncthreads();
    const bh8 af = *(const bh8*)(&As[(w * 16 + lr) * 40 + lh * 8]);
    #pragma unroll
    for (int ct = 0; ct < 4; ++ct) {
      const bh8 bf = *(const bh8*)(&Bs[(ct * 16 + lr) * 40 + lh * 8]);
      acc[ct] = mfma16(af, bf, acc[ct]);
    }
    __syncthreads();
  }
  #pragma unroll
  for (int ct = 0; ct < 4; ++ct) {
    const int col = n0 + ct * 16 + lr;
    float bv = 0.f;
    if (BIAS) bv = bias[col];
    #pragma unroll
    for (int r = 0; r < 4; ++r) {
      const int row = m0 + w * 16 + lh * 4 + r;
      float v = acc[ct][r] + bv;
      if (GELU) v = gelu_f(v);
      if (OMODE == 2) {
        const int hw = (row >> 2) & 1023, t = row & 3;
        v = (v + pos[(size_t)hw * 512 + col]) * temb[t * 512 + col];
        OB[(size_t)row * 512 + col] = f2bf(v);
      } else {
        OB[(size_t)row * ldc + col] = f2bf(v);
      }
    }
  }
}

// ---------------- decoder tail: conv3x3 (MFMA) + gelu + 1x1 -> out
__global__ __launch_bounds__(256)
void k_tail(const unsigned short* __restrict__ Y1, const unsigned short* __restrict__ w3t,
            const float* __restrict__ c1w, const float* __restrict__ c1b,
            float* __restrict__ outp)
{
  __shared__ __align__(16) char lbuf[256 * 33 * 4];
  __shared__ float c1s[128];
  unsigned short* it = (unsigned short*)lbuf;
  float* y2 = (float*)lbuf;
  const int bx = blockIdx.x;
  const int b = bx >> 8, ty = (bx >> 4) & 15, tx = bx & 15;
  const int Y0 = ty * 16, X0 = tx * 16;
  const int tid = threadIdx.x;
  const int w = tid >> 6, l = tid & 63, lr = l & 15, lh = l >> 4;

  if (tid < 128) c1s[tid] = c1w[tid];
  for (int idx = tid; idx < 1296; idx += 256) {
    const int r = idx / 72, rem = idx - r * 72, c = rem >> 2, q = rem & 3;
    const int Yg = Y0 + r - 1, Xg = X0 + c - 1;
    uint4 v = make_uint4(0u, 0u, 0u, 0u);
    if (Yg >= 0 && Yg < 256 && Xg >= 0 && Xg < 256)
      v = *(const uint4*)(Y1 + (((size_t)(b * 256 + Yg)) * 256 + Xg) * 32 + q * 8);
    *(uint4*)(&it[(r * 18 + c) * 40 + q * 8]) = v;
  }
  bh8 bw[2][9];
  #pragma unroll
  for (int ct = 0; ct < 2; ++ct)
    #pragma unroll
    for (int kb = 0; kb < 9; ++kb)
      bw[ct][kb] = *(const bh8*)(w3t + (size_t)(kb * 32 + ct * 16 + lr) * 32 + lh * 8);
  __syncthreads();

  f4 acc[4][2] = {};
  #pragma unroll
  for (int kb = 0; kb < 9; ++kb) {
    const int dy = kb / 3, dx = kb % 3;
    #pragma unroll
    for (int yy = 0; yy < 4; ++yy) {
      const int y = w * 4 + yy;
      const bh8 af = *(const bh8*)(&it[((y + dy) * 18 + lr + dx) * 40 + lh * 8]);
      acc[yy][0] = mfma16(af, bw[0][kb], acc[yy][0]);
      acc[yy][1] = mfma16(af, bw[1][kb], acc[yy][1]);
    }
  }
  __syncthreads();
  #pragma unroll
  for (int yy = 0; yy < 4; ++yy) {
    const int y = w * 4 + yy;
    #pragma unroll
    for (int ct = 0; ct < 2; ++ct)
      #pragma unroll
      for (int r = 0; r < 4; ++r)
        y2[(y * 16 + lh * 4 + r) * 33 + ct * 16 + lr] = gelu_f(acc[yy][ct][r]);
  }
  __syncthreads();
  const int py = tid >> 4, px = tid & 15;
  float o0 = c1b[0], o1 = c1b[1], o2 = c1b[2], o3 = c1b[3];
  #pragma unroll 8
  for (int ci = 0; ci < 32; ++ci) {
    const float v = y2[tid * 33 + ci];
    o0 = fmaf(v, c1s[ci * 4 + 0], o0);
    o1 = fmaf(v, c1s[ci * 4 + 1], o1);
    o2 = fmaf(v, c1s[ci * 4 + 2], o2);
    o3 = fmaf(v, c1s[ci * 4 + 3], o3);
  }
  float4 ov; ov.x = o0; ov.y = o1; ov.z = o2; ov.w = o3;
  *(float4*)(outp + (((size_t)(b * 256 + Y0 + py)) * 256 + X0 + px) * 4) = ov;
}

// ---------------- forward DFT stage A (fused gn1 affine via PA partials) -> packed bf16 AB
__global__ __launch_bounds__(256)
void k_dft_a(const float* __restrict__ H, const float* __restrict__ PA,
             const float* __restrict__ sc, const float* __restrict__ bi,
             unsigned int* __restrict__ AB)
{
  __shared__ float ct[512], st[512];
  const int tid = threadIdx.x;
  for (int q = tid; q < 512; q += 256) {
    const int k = q >> 5, y = q & 31;
    const float ang = (float)((k * y) & 31) * 0.19634954084936207f;
    ct[q] = cosf(ang); st[q] = sinf(ang);
  }
  __syncthreads();
  const int blk = blockIdx.x;
  const int half = blk & 1, x = (blk >> 1) & 31, b = blk >> 6;
  const int c = half * 256 + tid;
  float sca, sh;
  gn_coef8(PA, sc, bi, b, c, sca, sh);
  float ar[16], ai[16];
  #pragma unroll
  for (int k = 0; k < 16; ++k) { ar[k] = 0.f; ai[k] = 0.f; }
  const float* zp = H + ((size_t)b * 1024 + x) * 512 + c;
  for (int y = 0; y < 32; ++y) {
    const float v = fmaf(zp[(size_t)y * 32 * 512], sca, sh);
    #pragma unroll
    for (int k = 0; k < 16; ++k) {
      ar[k] = fmaf(v, ct[k * 32 + y], ar[k]);
      ai[k] = fmaf(-v, st[k * 32 + y], ai[k]);
    }
  }
  #pragma unroll
  for (int k = 0; k < 16; ++k) {
    const size_t o = (((size_t)b * 16 + k) * 32 + x) * 512 + c;
    AB[o] = (unsigned int)f2bf(ar[k]) | ((unsigned int)f2bf(ai[k]) << 16);
  }
}

// ---------------- forward DFT stage B (packed bf16 in) -> stacked bf16 X [z][2048][128]
__global__ __launch_bounds__(256)
void k_dft_b(const unsigned int* __restrict__ AB, unsigned short* __restrict__ X)
{
  __shared__ float ct[512], st[512];
  const int tid = threadIdx.x;
  for (int q = tid; q < 512; q += 256) {
    const int k = q >> 5, xx = q & 31;
    const float ang = (float)((k * xx) & 31) * 0.19634954084936207f;
    ct[q] = cosf(ang); st[q] = sinf(ang);
  }
  __syncthreads();
  const int blk = blockIdx.x;
  const int half = blk & 1, kh = (blk >> 1) & 15, b = blk >> 5;
  const int c = half * 256 + tid;
  float gr[16], gi[16];
  #pragma unroll
  for (int k = 0; k < 16; ++k) { gr[k] = 0.f; gi[k] = 0.f; }
  const unsigned int* abp = AB + (((size_t)b * 16 + kh) * 32) * 512 + c;
  for (int x = 0; x < 32; ++x) {
    const unsigned int pv = abp[(size_t)x * 512];
    const float vr = bf2f((unsigned short)(pv & 0xffffu));
    const float vi = bf2f((unsigned short)(pv >> 16));
    #pragma unroll
    for (int k = 0; k < 16; ++k) {
      const float cc_ = ct[k * 32 + x], ss = st[k * 32 + x];
      gr[k] += vr * cc_ + vi * ss;
      gi[k] += vi * cc_ - vr * ss;
    }
  }
  const int blkc = c >> 6, ii = c & 63;
  #pragma unroll
  for (int k = 0; k < 16; ++k) {
    const size_t pos = (size_t)b * 256 + kh * 16 + k;
    unsigned short* xp = X + ((size_t)blkc * 2048 + pos) * 128 + ii;
    xp[0]  = f2bf(gr[k] * (1.0f / 32.0f));
    xp[64] = f2bf(gi[k] * (1.0f / 32.0f));
  }
}

// ---------------- merged AFNO weights for ALL layers
__global__ __launch_bounds__(256)
void k_mode_prep_all(const float* __restrict__ aw1, const float* __restrict__ aw2,
                     const float* __restrict__ ab1, const float* __restrict__ ab2,
                     unsigned short* __restrict__ Sb, float* __restrict__ SB)
{
  const int gi = blockIdx.x * 256 + threadIdx.x;   // 12*262144
  const int dd = gi >> 18;
  const int idx = gi & 262143;
  const float* aw1_d = aw1 + (size_t)dd * 65536;
  const float* aw2_d = aw2 + (size_t)dd * 65536;
  const int s = idx >> 17;
  const int blk = (idx >> 14) & 7;
  const int n = (idx >> 7) & 127;
  const int kk = idx & 127;
  const float* aw = s ? aw2_d : aw1_d;
  const int i = kk & 63, o = n & 63;
  const float wr = aw[(blk * 64 + i) * 64 + o];
  const float wi = aw[32768 + (blk * 64 + i) * 64 + o];
  float val;
  if (n < 64) val = (kk < 64) ? wr : -wi;
  else        val = (kk < 64) ? wi :  wr;
  Sb[gi] = f2bf(val);
  if (idx < 2048) {
    const int s2 = idx >> 10, r2 = idx & 1023, b2 = r2 >> 7, q2 = r2 & 127;
    const float* ab = s2 ? (ab2 + dd * 1024) : (ab1 + dd * 1024);
    SB[dd * 2048 + idx] = (q2 < 64) ? ab[b2 * 64 + q2] : ab[512 + b2 * 64 + (q2 - 64)];
  }
}

// ---------------- inverse DFT stage D (bf16 X2 in) -> packed bf16 T
__global__ __launch_bounds__(256)
void k_idft_d(const unsigned short* __restrict__ X2, unsigned int* __restrict__ Tp)
{
  __shared__ float ct[512], st[512];
  const int tid = threadIdx.x;
  for (int q = tid; q < 512; q += 256) {
    const int kw = q >> 5, xx = q & 31;
    const float w = (kw == 0) ? 1.0f : 2.0f;
    const float ang = (float)((kw * xx) & 31) * 0.19634954084936207f;
    ct[q] = w * cosf(ang); st[q] = w * sinf(ang);
  }
  __syncthreads();
  const int blk = blockIdx.x;
  const int half = blk & 1, kh = (blk >> 1) & 15, b = blk >> 5;
  const int c = half * 256 + tid;
  const int blkc = c >> 6, ii = c & 63;
  float gr[16], gi[16];
  #pragma unroll
  for (int kw = 0; kw < 16; ++kw) {
    const size_t pos = (size_t)b * 256 + kh * 16 + kw;
    gr[kw] = bf2f(X2[((size_t)blkc * 2048 + pos) * 128 + ii]);
    gi[kw] = bf2f(X2[((size_t)blkc * 2048 + pos) * 128 + 64 + ii]);
  }
  for (int x = 0; x < 32; ++x) {
    float tr = 0.f, ti = 0.f;
    #pragma unroll
    for (int kw = 0; kw < 16; ++kw) {
      const float cc_ = ct[kw * 32 + x], ss = st[kw * 32 + x];
      tr += gr[kw] * cc_ - gi[kw] * ss;
      ti += gi[kw] * cc_ + gr[kw] * ss;
    }
    const size_t o = (((size_t)b * 16 + kh) * 32 + x) * 512 + c;
    Tp[o] = (unsigned int)f2bf(tr) | ((unsigned int)f2bf(ti) << 16);
  }
}

// ---------------- inverse DFT stage E + gn1-affine residual + gn2 partials (PB)
__global__ __launch_bounds__(256)
void k_idft_e(const unsigned int* __restrict__ Tp, const float* __restrict__ H,
              const float* __restrict__ PA, const float* __restrict__ sc,
              const float* __restrict__ bi, float* __restrict__ za,
              float* __restrict__ PB)
{
  __shared__ float ct[512], st[512];
  const int tid = threadIdx.x;
  for (int q = tid; q < 512; q += 256) {
    const int k = q >> 5, y = q & 31;
    const float ang = (float)((k * y) & 31) * 0.19634954084936207f;
    ct[q] = cosf(ang); st[q] = sinf(ang);
  }
  __syncthreads();
  const int blk = blockIdx.x;
  const int half = blk & 1, x = (blk >> 1) & 31, b = blk >> 6;
  const int c = half * 256 + tid;
  float sca, sh;
  gn_coef8(PA, sc, bi, b, c, sca, sh);
  float trv[16], tiv[16];
  #pragma unroll
  for (int k = 0; k < 16; ++k) {
    const size_t o = (((size_t)b * 16 + k) * 32 + x) * 512 + c;
    const unsigned int pv = Tp[o];
    trv[k] = bf2f((unsigned short)(pv & 0xffffu));
    tiv[k] = bf2f((unsigned short)(pv >> 16));
  }
  float s1 = 0.f, s2 = 0.f;
  for (int y = 0; y < 32; ++y) {
    float v = 0.f;
    #pragma unroll
    for (int k = 0; k < 16; ++k)
      v += trv[k] * ct[k * 32 + y] - tiv[k] * st[k * 32 + y];
    const size_t o = ((size_t)b * 1024 + y * 32 + x) * 512 + c;
    const float zv = v * (1.0f / 32.0f) + fmaf(H[o], sca, sh);
    za[o] = zv;
    s1 += zv; s2 += zv * zv;
  }
  #pragma unroll
  for (int sft = 32; sft > 0; sft >>= 1) {
    s1 += __shfl_xor(s1, sft, 64);
    s2 += __shfl_xor(s2, sft, 64);
  }
  if ((tid & 63) == 0) {
    const int g = half * 4 + (tid >> 6);
    PB[(b * 8 + g) * 32 + x] = s1;
    PB[2048 + (b * 8 + g) * 32 + x] = s2;
  }
}

// ---------------- gn2 coef table from PB (ns=32)
__global__ __launch_bounds__(256)
void k_gn_coef(const float* __restrict__ PB, const float* __restrict__ sc,
               const float* __restrict__ bi, float* __restrict__ gnc)
{
  const int idx = blockIdx.x * 256 + threadIdx.x;   // 4096
  const int b = idx >> 9, c = idx & 511, g = c >> 6;
  float s1 = 0.f, s2 = 0.f;
  #pragma unroll
  for (int q = 0; q < 32; ++q) {
    s1 += PB[(b * 8 + g) * 32 + q];
    s2 += PB[2048 + (b * 8 + g) * 32 + q];
  }
  const float mu = s1 * (1.0f / 65536.0f);
  const float var = s2 * (1.0f / 65536.0f) - mu * mu;
  const float rs = rsqrtf(var + 1e-5f);
  const float sca = sc[c] * rs;
  gnc[idx] = sca;
  gnc[4096 + idx] = bi[c] - mu * sca;
}

// ---------------- cls layers 1/2 (ILP-4 accumulators)
template<int FIRST>
__global__ __launch_bounds__(256)
void k_cls_l(const float* __restrict__ src, const float* __restrict__ Wm,
             const float* __restrict__ bb, float* __restrict__ Cout)
{
  __shared__ float tok[512];
  __shared__ float red[256];
  const int b = blockIdx.y, oc = blockIdx.x;
  const int tid = threadIdx.x;
  for (int i = tid; i < 512; i += 256) {
    if (FIRST) {
      float s = 0.f;
      #pragma unroll
      for (int q = 0; q < 8; ++q) s += src[((b * 8 + q) << 9) + i];
      tok[i] = s * (1.0f / 1024.0f);
    } else {
      tok[i] = src[b * 512 + i];
    }
  }
  __syncthreads();
  const int to = tid & 63, iq = tid >> 6;
  const int o = oc * 64 + to;
  const float* wp = Wm + (size_t)(iq * 128) * 512 + o;
  const float* tp = tok + iq * 128;
  float a0 = 0.f, a1 = 0.f, a2 = 0.f, a3 = 0.f;
  #pragma unroll 8
  for (int i = 0; i < 128; i += 4) {
    a0 = fmaf(tp[i + 0], wp[(size_t)(i + 0) * 512], a0);
    a1 = fmaf(tp[i + 1], wp[(size_t)(i + 1) * 512], a1);
    a2 = fmaf(tp[i + 2], wp[(size_t)(i + 2) * 512], a2);
    a3 = fmaf(tp[i + 3], wp[(size_t)(i + 3) * 512], a3);
  }
  red[tid] = (a0 + a1) + (a2 + a3);
  __syncthreads();
  if (tid < 64) {
    const int oo = oc * 64 + tid;
    const float v = red[tid] + red[tid + 64] + red[tid + 128] + red[tid + 192] + bb[oo];
    Cout[b * 512 + oo] = gelu_f(v);
  }
}

// ---------------- cls layer 3
__global__ __launch_bounds__(768)
void k_cls3(const float* __restrict__ C2, const float* __restrict__ w3,
            const float* __restrict__ b3, float* __restrict__ outp)
{
  const int b = blockIdx.x, tid = threadIdx.x;
  const int o = tid >> 6, lane = tid & 63;
  float acc = 0.f;
  for (int i = lane; i < 512; i += 64)
    acc = fmaf(C2[b * 512 + i], w3[i * 12 + o], acc);
  #pragma unroll
  for (int s = 32; s > 0; s >>= 1) acc += __shfl_xor(acc, s, 64);
  if (lane == 0) outp[2097152 + b * 12 + o] = acc + b3[o];
}

extern "C" void kernel_launch(void* const* d_in, const int* in_sizes, int n_in,
                              void* d_out, int out_size, void* d_ws, size_t ws_size,
                              hipStream_t stream)
{
  (void)in_sizes; (void)n_in; (void)out_size; (void)ws_size;
  const float* x      = (const float*)d_in[0];
  const float* patch_w= (const float*)d_in[1];
  const float* patch_b= (const float*)d_in[2];
  const float* p1_w   = (const float*)d_in[3];
  const float* p1_b   = (const float*)d_in[4];
  const float* pos    = (const float*)d_in[5];
  const float* tagg_w = (const float*)d_in[6];
  const float* gamma  = (const float*)d_in[7];
  const float* gn1_s  = (const float*)d_in[8];
  const float* gn1_b  = (const float*)d_in[9];
  const float* aw1    = (const float*)d_in[10];
  const float* ab1    = (const float*)d_in[11];
  const float* aw2    = (const float*)d_in[12];
  const float* ab2    = (const float*)d_in[13];
  const float* gn2_s  = (const float*)d_in[14];
  const float* gn2_b  = (const float*)d_in[15];
  const float* mw1    = (const float*)d_in[16];
  const float* mb1    = (const float*)d_in[17];
  const float* mw2    = (const float*)d_in[18];
  const float* mb2    = (const float*)d_in[19];
  const float* cls_w1 = (const float*)d_in[20];
  const float* cls_b1 = (const float*)d_in[21];
  const float* cls_w2 = (const float*)d_in[22];
  const float* cls_b2 = (const float*)d_in[23];
  const float* cls_w3 = (const float*)d_in[24];
  const float* cls_b3 = (const float*)d_in[25];
  const float* dec_w  = (const float*)d_in[26];
  const float* dec_b  = (const float*)d_in[27];
  const float* c3_w   = (const float*)d_in[28];
  const float* c3_b   = (const float*)d_in[29];
  const float* c1_w   = (const float*)d_in[30];
  const float* c1_b   = (const float*)d_in[31];

  float* W = (float*)d_ws;
  // ---- layout (round-7 verified): end = 24,761,408 f = 94.5MB.
  float* H            = W;                                  // 4,194,304 f
  unsigned int* ABT   = (unsigned int*)(W + 4194304);       // 2,097,152 u32 (AB / Tp)
  unsigned short* Xb  = (unsigned short*)(W + 6291456);     // 2,097,152 sh
  unsigned short* X2b = (unsigned short*)(W + 7340032);     // 2,097,152 sh
  unsigned short* UO  = (unsigned short*)(W + 8388608);     // 4,194,304 sh (P1b/O1b/Ub)
  float* R1           = W + 10485760;                       // 8,388,608 f (imat/H0b/ZA/Y1)
  unsigned short* SbA = (unsigned short*)(W + 18874368);    // 3,145,728 sh
  float* SBa          = W + 20447232;                       // 24,576 f
  unsigned short* taggT = (unsigned short*)(W + 20471808);  // 1,048,576 sh
  unsigned short* mwT1  = (unsigned short*)(W + 20996096);  // 3,145,728 sh
  unsigned short* mwT2  = (unsigned short*)(W + 22568960);  // 3,145,728 sh
  unsigned short* decC  = (unsigned short*)(W + 24141824);  // 1,048,576 sh
  unsigned short* w3t   = (unsigned short*)(W + 24666112);  // 16,384 sh
  unsigned short* btp   = (unsigned short*)(W + 24674304);  // 28,672 sh
  unsigned short* bte   = (unsigned short*)(W + 24688640);  // 32,768 sh
  float* TEMB  = W + 24705024;                              // 2,048
  float* PBP   = W + 24707072;                              // 64
  float* PA    = W + 24707136;                              // 1,024
  float* PB    = W + 24708160;                              // 4,096
  float* GNC   = W + 24712256;                              // 8,192
  float* PARTC = W + 24720448;                              // 32,768
  float* C1    = W + 24753216;                              // 4,096
  float* C2    = W + 24757312;                              // 4,096

  unsigned short* imat = (unsigned short*)R1;
  unsigned short* H0b  = (unsigned short*)R1;
  unsigned short* Y1   = (unsigned short*)R1;
  float* ZA = R1;
  unsigned short* P1b = UO;
  unsigned short* O1b = UO;
  unsigned short* Ub  = UO;
  float* out = (float*)d_out;

  // ---- weight prep (once)
  k_cvt_trans<<<dim3(16,64,1),256,0,stream>>>(tagg_w, taggT, 2048, 512, 0, 0);
  k_cvt_trans<<<dim3(16,16,12),256,0,stream>>>(mw1, mwT1, 512, 512, 262144, 262144);
  k_cvt_trans<<<dim3(16,16,12),256,0,stream>>>(mw2, mwT2, 512, 512, 262144, 262144);
  k_cvt<<<4096,256,0,stream>>>(dec_w, decC, 1048576);
  k_prep_w3<<<36,256,0,stream>>>(c3_w, w3t);
  k_prep_btp<<<112,256,0,stream>>>(patch_w, patch_b, btp, PBP);
  k_prep_bte<<<128,256,0,stream>>>(p1_w, bte);
  k_temb<<<8,256,0,stream>>>(gamma, TEMB);
  k_mode_prep_all<<<12288,256,0,stream>>>(aw1, aw2, ab1, ab2, SbA, SBa);

  // ---- encoder
  k_pack<<<8192,256,0,stream>>>(x, imat);
  k_mgemm<1,1,1><<<dim3(1,512),256,0,stream>>>(imat, btp, PBP, P1b,
      nullptr, nullptr, 448, 448, 64, 0, 0, 0, 0);
  k_mgemm<1,0,2><<<dim3(8,512),256,0,stream>>>(P1b, bte, p1_b, H0b,
      pos, TEMB, 64, 64, 512, 0, 0, 0, 0);
  // tagg: H0b @ taggT^T -> H (f32) + gn1 partials PA
  k_bgemm<0,0><<<256,1024,0,stream>>>(H0b, taggT, H, nullptr, nullptr, nullptr,
      nullptr, PA, 2048, 512, 4);

  for (int d = 0; d < 12; ++d) {
    k_dft_a<<<512,256,0,stream>>>(H, PA, gn1_s + d*512, gn1_b + d*512, ABT);
    k_dft_b<<<256,256,0,stream>>>(ABT, Xb);
    k_mgemm<1,1,1><<<dim3(2,32,8),256,0,stream>>>(Xb, SbA + (size_t)d*262144,
        SBa + d*2048, O1b, nullptr, nullptr, 128, 128, 128, 262144LL, 16384LL, 262144LL, 128);
    k_mgemm<1,0,1><<<dim3(2,32,8),256,0,stream>>>(O1b, SbA + (size_t)d*262144 + 131072,
        SBa + d*2048 + 1024, X2b, nullptr, nullptr, 128, 128, 128, 262144LL, 16384LL, 262144LL, 128);
    k_idft_d<<<256,256,0,stream>>>(X2b, ABT);
    k_idft_e<<<512,256,0,stream>>>(ABT, H, PA, gn1_s + d*512, gn1_b + d*512, ZA, PB);
    k_gn_coef<<<16,256,0,stream>>>(PB, gn2_s + d*512, gn2_b + d*512, GNC);
    // mlp1: gn2(ZA) @ mwT1^T + b -> gelu -> Ub (bf16)
    k_bgemm<2,1><<<256,1024,0,stream>>>(ZA, mwT1 + (size_t)d*262144, nullptr, Ub,
        mb1 + d*512, nullptr, GNC, nullptr, 512, 512, 4);
    // mlp2: Ub @ mwT2^T + b + H -> H (+ partials: gn1-next or cls)
    if (d < 11)
      k_bgemm<0,2><<<256,1024,0,stream>>>(Ub, mwT2 + (size_t)d*262144, H, nullptr,
          mb2 + d*512, H, nullptr, PA, 512, 512, 4);
    else
      k_bgemm<0,4><<<256,1024,0,stream>>>(Ub, mwT2 + (size_t)d*262144, H, nullptr,
          mb2 + d*512, H, nullptr, PARTC, 512, 512, 4);
  }

  k_cls_l<1><<<dim3(8,8),256,0,stream>>>(PARTC, cls_w1, cls_b1, C1);
  k_cls_l<0><<<dim3(8,8),256,0,stream>>>(C1, cls_w2, cls_b2, C2);
  k_cls3<<<8,768,0,stream>>>(C2, cls_w3, cls_b3, out);
  // decoder: H (f32) @ decC^T -> gelu(+dec_b) -> pixel-layout bf16 Y1
  k_bgemm<1,3><<<1024,1024,0,stream>>>(H, decC, nullptr, Y1,
      dec_b, nullptr, nullptr, nullptr, 512, 0, 16);
  k_tail<<<2048,256,0,stream>>>(Y1, w3t, c1_w, c1_b, out);
}

// Round 9
// 1330.396 us; speedup vs baseline: 3.1571x; 1.0730x over previous
//
#include <hip/hip_runtime.h>
#include <cstddef>

typedef __attribute__((ext_vector_type(8))) short bh8;
typedef __attribute__((ext_vector_type(4))) float f4;

__device__ __forceinline__ float gelu_f(float x){
  return 0.5f * x * (1.0f + erff(x * 0.7071067811865476f));
}

__device__ __forceinline__ unsigned short f2bf(float f){
  unsigned int u = __float_as_uint(f);
  unsigned int r = (u + 0x7FFFu + ((u >> 16) & 1u)) >> 16;
  return (unsigned short)r;
}

__device__ __forceinline__ float bf2f(unsigned short u){
  return __uint_as_float(((unsigned int)u) << 16);
}

__device__ __forceinline__ f4 mfma16(bh8 a, bh8 b, f4 c){
  return __builtin_amdgcn_mfma_f32_16x16x32_bf16(a, b, c, 0, 0, 0);
}

__device__ __forceinline__ void gll16(const unsigned short* src, unsigned short* dst){
  __builtin_amdgcn_global_load_lds(
      (const __attribute__((address_space(1))) unsigned int*)src,
      (__attribute__((address_space(3))) unsigned int*)dst, 16, 0, 0);
}

// gn coef from 8-slice partials PA[(b*8+g)*8+q], s2 at +512
__device__ __forceinline__ void gn_coef8(const float* pa, const float* sc,
                                         const float* bi, int b, int c,
                                         float& sca, float& sh)
{
  const int g = c >> 6;
  float s1 = 0.f, s2 = 0.f;
  #pragma unroll
  for (int q = 0; q < 8; ++q) {
    s1 += pa[(b * 8 + g) * 8 + q];
    s2 += pa[512 + (b * 8 + g) * 8 + q];
  }
  const float mu = s1 * (1.0f / 65536.0f);
  const float var = s2 * (1.0f / 65536.0f) - mu * mu;
  const float rs = rsqrtf(var + 1e-5f);
  sca = sc[c] * rs;
  sh = bi[c] - mu * sca;
}

// ================= big bf16 MFMA GEMM: 128x128 tile, BK=64, 1024 thr (16 waves),
// 2-phase dbuf pipeline, XCD chunk swizzle. (unchanged from round 8)
#define BG_STAGE(dbuf, kofs, BASE, DST) \
  gll16(BASE + (size_t)sr_ * K + (kofs) + ((ss_ ^ (sr_ & 7)) << 3), &DST[dbuf][tid * 8]);

#define BG_LOADA(kofs) { \
  const float* ap_ = Afbase + (size_t)sr_ * K + (kofs) + ss_ * 8; \
  ra0 = *(const float4*)ap_; \
  ra1 = *(const float4*)(ap_ + 4); \
  if (AMODE == 2) { \
    const int bb_ = (m0 + sr_) >> 10; \
    const int ch_ = (kofs) + ss_ * 8; \
    const float4 c0_ = *(const float4*)(gnc + bb_ * 512 + ch_); \
    const float4 c1_ = *(const float4*)(gnc + bb_ * 512 + ch_ + 4); \
    const float4 h0_ = *(const float4*)(gnc + 4096 + bb_ * 512 + ch_); \
    const float4 h1_ = *(const float4*)(gnc + 4096 + bb_ * 512 + ch_ + 4); \
    ra0.x = fmaf(ra0.x, c0_.x, h0_.x); ra0.y = fmaf(ra0.y, c0_.y, h0_.y); \
    ra0.z = fmaf(ra0.z, c0_.z, h0_.z); ra0.w = fmaf(ra0.w, c0_.w, h0_.w); \
    ra1.x = fmaf(ra1.x, c1_.x, h1_.x); ra1.y = fmaf(ra1.y, c1_.y, h1_.y); \
    ra1.z = fmaf(ra1.z, c1_.z, h1_.z); ra1.w = fmaf(ra1.w, c1_.w, h1_.w); \
  } }

#define BG_WRITEA(dbuf) { \
  const int slot_ = ss_ ^ (sr_ & 7); \
  bh8 av_; \
  av_[0] = (short)f2bf(ra0.x); av_[1] = (short)f2bf(ra0.y); \
  av_[2] = (short)f2bf(ra0.z); av_[3] = (short)f2bf(ra0.w); \
  av_[4] = (short)f2bf(ra1.x); av_[5] = (short)f2bf(ra1.y); \
  av_[6] = (short)f2bf(ra1.z); av_[7] = (short)f2bf(ra1.w); \
  *(bh8*)(&As[dbuf][sr_ * 64 + slot_ * 8]) = av_; }

template<int AMODE, int OMODE>
__global__ __launch_bounds__(1024)
void k_bgemm(const void* __restrict__ Av, const unsigned short* __restrict__ Bt,
             float* __restrict__ C, unsigned short* __restrict__ OB,
             const float* __restrict__ bias, const float* __restrict__ Res,
             const float* __restrict__ gnc, float* __restrict__ gpart,
             int K, int ldc, int nn)
{
  __shared__ __align__(16) unsigned short As[2][8192];
  __shared__ __align__(16) unsigned short Bs[2][8192];
  const int bid = blockIdx.x, nwg = gridDim.x;
  const int wg = (bid & 7) * (nwg >> 3) + (bid >> 3);
  const int mb = wg / nn;
  const int m0 = mb * 128, n0 = (wg - mb * nn) * 128;
  const int tid = threadIdx.x;
  const int w = tid >> 6, lane = tid & 63;
  const int lr = lane & 15, lh = lane >> 4;
  const int wr = w >> 2, wc = w & 3;
  const int sr_ = tid >> 3, ss_ = tid & 7;
  const unsigned short* Abase = (const unsigned short*)Av + (size_t)m0 * K;
  const float* Afbase = (const float*)Av + (size_t)m0 * K;
  const unsigned short* Bbase = Bt + (size_t)n0 * K;
  float4 ra0, ra1;
  f4 acc[2][2] = {};

  const int nt = K >> 6;
  if (AMODE == 0) { BG_STAGE(0, 0, Abase, As) }
  else            { BG_LOADA(0) BG_WRITEA(0) }
  BG_STAGE(0, 0, Bbase, Bs)
  __syncthreads();

  for (int t = 0; t < nt; ++t) {
    const int d = t & 1;
    const bool more = (t + 1 < nt);
    if (more) {
      const int kn = (t + 1) << 6;
      if (AMODE == 0) { BG_STAGE(d ^ 1, kn, Abase, As) }
      else            { BG_LOADA(kn) }
      BG_STAGE(d ^ 1, kn, Bbase, Bs)
    }
    #pragma unroll
    for (int kk = 0; kk < 2; ++kk) {
      bh8 af[2], bf[2];
      #pragma unroll
      for (int mi = 0; mi < 2; ++mi) {
        const int R = wr * 32 + mi * 16 + lr;
        af[mi] = *(const bh8*)((const char*)As[d] + R * 128 + (((kk * 4 + lh) ^ (R & 7)) * 16));
      }
      #pragma unroll
      for (int ni = 0; ni < 2; ++ni) {
        const int R = wc * 32 + ni * 16 + lr;
        bf[ni] = *(const bh8*)((const char*)Bs[d] + R * 128 + (((kk * 4 + lh) ^ (R & 7)) * 16));
      }
      #pragma unroll
      for (int mi = 0; mi < 2; ++mi)
        #pragma unroll
        for (int ni = 0; ni < 2; ++ni)
          acc[mi][ni] = mfma16(af[mi], bf[ni], acc[mi][ni]);
    }
    if (more && AMODE != 0) { BG_WRITEA(d ^ 1) }
    __syncthreads();
  }

  float cs1[2], cs2[2];
  #pragma unroll
  for (int ni = 0; ni < 2; ++ni) {
    const int col_l = wc * 32 + ni * 16 + lr;
    const int col = n0 + col_l;
    float bv = 0.f;
    if (OMODE == 1 || OMODE == 2 || OMODE == 4) bv = bias[col];
    if (OMODE == 3) bv = bias[col & 31];
    float s1 = 0.f, s2 = 0.f;
    #pragma unroll
    for (int mi = 0; mi < 2; ++mi) {
      #pragma unroll
      for (int r = 0; r < 4; ++r) {
        const int row = m0 + wr * 32 + mi * 16 + lh * 4 + r;
        float v = acc[mi][ni][r] + bv;
        if (OMODE == 0) {
          C[(size_t)row * ldc + col] = v;
          s1 += v; s2 += v * v;
        } else if (OMODE == 1) {
          OB[(size_t)row * ldc + col] = f2bf(gelu_f(v));
        } else if (OMODE == 2 || OMODE == 4) {
          const size_t ci = (size_t)row * ldc + col;
          v += Res[ci];
          C[ci] = v;
          s1 += v; s2 += v * v;
        } else {
          v = gelu_f(v);
          const int bb = row >> 10, hw = row & 1023, ii = hw >> 5, jj = hw & 31;
          const int dxy = col >> 5, dy = dxy >> 3, dx = dxy & 7, cc = col & 31;
          OB[(((size_t)(bb * 256 + ii * 8 + dy)) * 256 + jj * 8 + dx) * 32 + cc] = f2bf(v);
        }
      }
    }
    cs1[ni] = s1; cs2[ni] = s2;
  }
  if (OMODE == 0 || OMODE == 2 || OMODE == 4) {
    float* sp = (float*)As;
    const int sub = wr * 4 + lh;
    #pragma unroll
    for (int ni = 0; ni < 2; ++ni) {
      const int col_l = wc * 32 + ni * 16 + lr;
      sp[col_l * 16 + sub] = cs1[ni];
      sp[2048 + col_l * 16 + sub] = cs2[ni];
    }
    __syncthreads();
    if (tid < 128) {
      float s1 = 0.f, s2 = 0.f;
      #pragma unroll
      for (int u = 0; u < 16; ++u) { s1 += sp[tid * 16 + u]; s2 += sp[2048 + tid * 16 + u]; }
      const int b = m0 >> 10, slice = (m0 >> 7) & 7;
      if (OMODE == 4) {
        gpart[(b * 8 + slice) * 512 + n0 + tid] = s1;
      } else {
        #pragma unroll
        for (int sft = 32; sft > 0; sft >>= 1) {
          s1 += __shfl_xor(s1, sft, 64);
          s2 += __shfl_xor(s2, sft, 64);
        }
        if ((tid & 63) == 0) {
          const int g = (n0 >> 6) + (tid >> 6);
          gpart[(b * 8 + g) * 8 + slice] = s1;
          gpart[512 + (b * 8 + g) * 8 + slice] = s2;
        }
      }
    }
  }
}

// ================= fused AFNO block-MLP: X(64rows,128) @ W1 -> gelu -> @ W2 -> X2
// grid (32 pos-tiles, 8 z). LDS: Xs 16KB + Ws 32KB + O1s 16KB = 64KB, XOR-swizzled.
__global__ __launch_bounds__(256)
void k_afno(const unsigned short* __restrict__ Xb, const unsigned short* __restrict__ Sb_d,
            const float* __restrict__ SB_d, unsigned short* __restrict__ X2b)
{
  __shared__ __align__(16) unsigned short Xs[8192];
  __shared__ __align__(16) unsigned short Ws[16384];
  __shared__ __align__(16) unsigned short O1s[8192];
  const int pt = blockIdx.x, z = blockIdx.y;
  const int tid = threadIdx.x;
  const int w = tid >> 6, lane = tid & 63;
  const int lr = lane & 15, lh = lane >> 4;
  const unsigned short* Xrow = Xb + (size_t)z * 262144 + (size_t)pt * 8192;
  const unsigned short* W1 = Sb_d + (size_t)z * 16384;
  const unsigned short* W2 = Sb_d + 131072 + (size_t)z * 16384;
  #pragma unroll
  for (int p = 0; p < 4; ++p) {
    const int q = p * 256 + tid, r = q >> 4, c = q & 15;
    gll16(Xrow + r * 128 + ((c ^ (r & 7)) << 3), &Xs[q * 8]);
  }
  #pragma unroll
  for (int p = 0; p < 8; ++p) {
    const int q = p * 256 + tid, r = q >> 4, c = q & 15;
    gll16(W1 + r * 128 + ((c ^ (r & 7)) << 3), &Ws[q * 8]);
  }
  __syncthreads();
  f4 acc[8] = {};
  #pragma unroll
  for (int kk = 0; kk < 4; ++kk) {
    const int R = w * 16 + lr;
    const bh8 a = *(const bh8*)((const char*)Xs + R * 256 + (((kk * 4 + lh) ^ (R & 7)) << 4));
    #pragma unroll
    for (int ct = 0; ct < 8; ++ct) {
      const int R2 = ct * 16 + lr;
      const bh8 b = *(const bh8*)((const char*)Ws + R2 * 256 + (((kk * 4 + lh) ^ (R2 & 7)) << 4));
      acc[ct] = mfma16(a, b, acc[ct]);
    }
  }
  __syncthreads();   // stage-1 Ws reads complete
  #pragma unroll
  for (int ct = 0; ct < 8; ++ct) {
    const int col = ct * 16 + lr;
    const float bv = SB_d[z * 128 + col];
    #pragma unroll
    for (int r = 0; r < 4; ++r) {
      const int row = w * 16 + lh * 4 + r;
      const unsigned short hv = f2bf(gelu_f(acc[ct][r] + bv));
      const int ch = (col >> 3) ^ (row & 7);
      *(unsigned short*)((char*)O1s + row * 256 + (ch << 4) + ((col & 7) << 1)) = hv;
    }
  }
  #pragma unroll
  for (int p = 0; p < 8; ++p) {
    const int q = p * 256 + tid, r = q >> 4, c = q & 15;
    gll16(W2 + r * 128 + ((c ^ (r & 7)) << 3), &Ws[q * 8]);
  }
  __syncthreads();
  f4 acc2[8] = {};
  #pragma unroll
  for (int kk = 0; kk < 4; ++kk) {
    const int R = w * 16 + lr;
    const bh8 a = *(const bh8*)((const char*)O1s + R * 256 + (((kk * 4 + lh) ^ (R & 7)) << 4));
    #pragma unroll
    for (int ct = 0; ct < 8; ++ct) {
      const int R2 = ct * 16 + lr;
      const bh8 b = *(const bh8*)((const char*)Ws + R2 * 256 + (((kk * 4 + lh) ^ (R2 & 7)) << 4));
      acc2[ct] = mfma16(a, b, acc2[ct]);
    }
  }
  unsigned short* OB = X2b + (size_t)z * 262144 + (size_t)pt * 8192;
  #pragma unroll
  for (int ct = 0; ct < 8; ++ct) {
    const int col = ct * 16 + lr;
    const float bv = SB_d[1024 + z * 128 + col];
    #pragma unroll
    for (int r = 0; r < 4; ++r) {
      const int row = w * 16 + lh * 4 + r;
      OB[(size_t)row * 128 + col] = f2bf(acc2[ct][r] + bv);
    }
  }
}

// ---------------- im2col pack: x -> bf16 imat [32768][448]
__global__ __launch_bounds__(256)
void k_pack(const float* __restrict__ x, unsigned short* __restrict__ imat)
{
  const int nb = blockIdx.x;
  const int j = nb & 31, i = (nb >> 5) & 31, b = nb >> 10;
  const int tid = threadIdx.x;
  const int tl = tid >> 6, px = tid & 63;
  const int dy = px >> 3, dx = px & 7;
  const int Y = i * 8 + dy, X = j * 8 + dx;
  const float4 v = *(const float4*)(x + (((size_t)(b * 256 + Y)) * 256 + X) * 16 + tl * 4);
  const size_t row = (size_t)nb * 4 + tl;
  ushort4 ov;
  ov.x = f2bf(v.x); ov.y = f2bf(v.y); ov.z = f2bf(v.z); ov.w = f2bf(v.w);
  *(ushort4*)(imat + row * 448 + px * 4) = ov;
  for (int q = tid; q < 768; q += 256) {
    const int tt = q / 192, r = q - tt * 192;
    const int sec = r >> 6, p2 = r & 63;
    float val;
    if (sec == 0)      val = (float)(i * 8 + (p2 >> 3)) * (1.0f / 255.0f);
    else if (sec == 1) val = (float)(j * 8 + (p2 & 7)) * (1.0f / 255.0f);
    else               val = (float)tt * (1.0f / 3.0f);
    imat[((size_t)nb * 4 + tt) * 448 + 256 + sec * 64 + p2] = f2bf(val);
  }
}

// ---------------- prep Bt_patch [64][448] (+ padded bias)
__global__ __launch_bounds__(256)
void k_prep_btp(const float* __restrict__ pw, const float* __restrict__ pb,
                unsigned short* __restrict__ btp, float* __restrict__ pbp)
{
  const int idx = blockIdx.x * 256 + threadIdx.x;
  if (idx < 28672) {
    const int n = idx / 448, k = idx - (idx / 448) * 448;
    int l;
    if (k < 256) { const int pxx = k >> 2, c = k & 3; l = pxx * 7 + c; }
    else { const int sec = (k - 256) >> 6, p2 = (k - 256) & 63; l = p2 * 7 + 4 + sec; }
    btp[n * 448 + k] = (n < 35) ? f2bf(pw[l * 35 + n]) : (unsigned short)0;
  }
  if (idx < 64) pbp[idx] = (idx < 35) ? pb[idx] : 0.0f;
}

// ---------------- prep Bt_embed [512][64]
__global__ __launch_bounds__(256)
void k_prep_bte(const float* __restrict__ w, unsigned short* __restrict__ bte)
{
  const int idx = blockIdx.x * 256 + threadIdx.x;
  const int n = idx >> 6, k = idx & 63;
  bte[idx] = (k < 35) ? f2bf(w[k * 512 + n]) : (unsigned short)0;
}

// ---------------- temb table [4][512]
__global__ __launch_bounds__(256)
void k_temb(const float* __restrict__ gamma, float* __restrict__ temb)
{
  const int idx = blockIdx.x * 256 + threadIdx.x;
  const int t = idx >> 9, e = idx & 511;
  temb[idx] = cosf((float)t * (1.0f / 3.0f) * gamma[e]);
}

// ---------------- weight prep: fp32 [K][N] -> bf16 [N][K]
__global__ __launch_bounds__(256)
void k_cvt_trans(const float* __restrict__ in, unsigned short* __restrict__ out,
                 int K, int N, long long sIn, long long sOut)
{
  __shared__ float tile[32][33];
  const int z = blockIdx.z;
  in  += (size_t)z * sIn;
  out += (size_t)z * sOut;
  const int n0 = blockIdx.x * 32, k0 = blockIdx.y * 32;
  const int tx = threadIdx.x & 31, ty = threadIdx.x >> 5;
  #pragma unroll
  for (int i = 0; i < 4; ++i)
    tile[ty + i * 8][tx] = in[(size_t)(k0 + ty + i * 8) * N + n0 + tx];
  __syncthreads();
  #pragma unroll
  for (int i = 0; i < 4; ++i)
    out[(size_t)(n0 + ty + i * 8) * K + k0 + tx] = f2bf(tile[tx][ty + i * 8]);
}

__global__ __launch_bounds__(256)
void k_cvt(const float* __restrict__ in, unsigned short* __restrict__ out, int n)
{
  const int idx = blockIdx.x * 256 + threadIdx.x;
  if (idx < n) out[idx] = f2bf(in[idx]);
}

__global__ __launch_bounds__(256)
void k_prep_w3(const float* __restrict__ w, unsigned short* __restrict__ out)
{
  const int idx = blockIdx.x * 256 + threadIdx.x;
  if (idx < 9216) {
    const int kb = idx >> 10, co = (idx >> 5) & 31, ci = idx & 31;
    out[idx] = f2bf(w[(kb * 32 + ci) * 32 + co]);
  }
}

// ---------------- small bf16 MFMA GEMM, 64x64 tile, z-batched (patch/embed)
template<int BIAS, int GELU, int OMODE>
__global__ __launch_bounds__(256)
void k_mgemm(const unsigned short* __restrict__ A, const unsigned short* __restrict__ Bt,
             const float* __restrict__ bias, unsigned short* __restrict__ OB,
             const float* __restrict__ pos, const float* __restrict__ temb,
             int K, int lda, int ldc,
             long long zsA, long long zsB, long long zsC, int zsBias)
{
  __shared__ __align__(16) unsigned short As[64 * 40];
  __shared__ __align__(16) unsigned short Bs[64 * 40];
  const int z = blockIdx.z;
  A  += (size_t)z * zsA;
  Bt += (size_t)z * zsB;
  if (BIAS) bias += (size_t)z * zsBias;
  OB += (size_t)z * zsC;
  const int m0 = blockIdx.y * 64, n0 = blockIdx.x * 64;
  const int tid = threadIdx.x;
  const int w = tid >> 6, l = tid & 63;
  const int lr = l & 15, lh = l >> 4;
  const int sr = tid >> 2, skq = (tid & 3) * 8;
  f4 acc[4] = {};
  for (int k0 = 0; k0 < K; k0 += 32) {
    const uint4 av = *(const uint4*)(A + (size_t)(m0 + sr) * lda + k0 + skq);
    *(uint4*)(&As[sr * 40 + skq]) = av;
    const uint4 bv = *(const uint4*)(Bt + (size_t)(n0 + sr) * K + k0 + skq);
    *(uint4*)(&Bs[sr * 40 + skq]) = bv;
    __syncthreads();
    const bh8 af = *(const bh8*)(&As[(w * 16 + lr) * 40 + lh * 8]);
    #pragma unroll
    for (int ct = 0; ct < 4; ++ct) {
      const bh8 bf = *(const bh8*)(&Bs[(ct * 16 + lr) * 40 + lh * 8]);
      acc[ct] = mfma16(af, bf, acc[ct]);
    }
    __syncthreads();
  }
  #pragma unroll
  for (int ct = 0; ct < 4; ++ct) {
    const int col = n0 + ct * 16 + lr;
    float bv = 0.f;
    if (BIAS) bv = bias[col];
    #pragma unroll
    for (int r = 0; r < 4; ++r) {
      const int row = m0 + w * 16 + lh * 4 + r;
      float v = acc[ct][r] + bv;
      if (GELU) v = gelu_f(v);
      if (OMODE == 2) {
        const int hw = (row >> 2) & 1023, t = row & 3;
        v = (v + pos[(size_t)hw * 512 + col]) * temb[t * 512 + col];
        OB[(size_t)row * 512 + col] = f2bf(v);
      } else {
        OB[(size_t)row * ldc + col] = f2bf(v);
      }
    }
  }
}

// ---------------- decoder tail: conv3x3 (MFMA) + gelu + 1x1 -> out
__global__ __launch_bounds__(256)
void k_tail(const unsigned short* __restrict__ Y1, const unsigned short* __restrict__ w3t,
            const float* __restrict__ c1w, const float* __restrict__ c1b,
            float* __restrict__ outp)
{
  __shared__ __align__(16) char lbuf[256 * 33 * 4];
  __shared__ float c1s[128];
  unsigned short* it = (unsigned short*)lbuf;
  float* y2 = (float*)lbuf;
  const int bx = blockIdx.x;
  const int b = bx >> 8, ty = (bx >> 4) & 15, tx = bx & 15;
  const int Y0 = ty * 16, X0 = tx * 16;
  const int tid = threadIdx.x;
  const int w = tid >> 6, l = tid & 63, lr = l & 15, lh = l >> 4;

  if (tid < 128) c1s[tid] = c1w[tid];
  for (int idx = tid; idx < 1296; idx += 256) {
    const int r = idx / 72, rem = idx - r * 72, c = rem >> 2, q = rem & 3;
    const int Yg = Y0 + r - 1, Xg = X0 + c - 1;
    uint4 v = make_uint4(0u, 0u, 0u, 0u);
    if (Yg >= 0 && Yg < 256 && Xg >= 0 && Xg < 256)
      v = *(const uint4*)(Y1 + (((size_t)(b * 256 + Yg)) * 256 + Xg) * 32 + q * 8);
    *(uint4*)(&it[(r * 18 + c) * 40 + q * 8]) = v;
  }
  bh8 bw[2][9];
  #pragma unroll
  for (int ct = 0; ct < 2; ++ct)
    #pragma unroll
    for (int kb = 0; kb < 9; ++kb)
      bw[ct][kb] = *(const bh8*)(w3t + (size_t)(kb * 32 + ct * 16 + lr) * 32 + lh * 8);
  __syncthreads();

  f4 acc[4][2] = {};
  #pragma unroll
  for (int kb = 0; kb < 9; ++kb) {
    const int dy = kb / 3, dx = kb % 3;
    #pragma unroll
    for (int yy = 0; yy < 4; ++yy) {
      const int y = w * 4 + yy;
      const bh8 af = *(const bh8*)(&it[((y + dy) * 18 + lr + dx) * 40 + lh * 8]);
      acc[yy][0] = mfma16(af, bw[0][kb], acc[yy][0]);
      acc[yy][1] = mfma16(af, bw[1][kb], acc[yy][1]);
    }
  }
  __syncthreads();
  #pragma unroll
  for (int yy = 0; yy < 4; ++yy) {
    const int y = w * 4 + yy;
    #pragma unroll
    for (int ct = 0; ct < 2; ++ct)
      #pragma unroll
      for (int r = 0; r < 4; ++r)
        y2[(y * 16 + lh * 4 + r) * 33 + ct * 16 + lr] = gelu_f(acc[yy][ct][r]);
  }
  __syncthreads();
  const int py = tid >> 4, px = tid & 15;
  float o0 = c1b[0], o1 = c1b[1], o2 = c1b[2], o3 = c1b[3];
  #pragma unroll 8
  for (int ci = 0; ci < 32; ++ci) {
    const float v = y2[tid * 33 + ci];
    o0 = fmaf(v, c1s[ci * 4 + 0], o0);
    o1 = fmaf(v, c1s[ci * 4 + 1], o1);
    o2 = fmaf(v, c1s[ci * 4 + 2], o2);
    o3 = fmaf(v, c1s[ci * 4 + 3], o3);
  }
  float4 ov; ov.x = o0; ov.y = o1; ov.z = o2; ov.w = o3;
  *(float4*)(outp + (((size_t)(b * 256 + Y0 + py)) * 256 + X0 + px) * 4) = ov;
}

// ---------------- forward DFT stage A (k-split x2) -> packed bf16 AB
__global__ __launch_bounds__(256)
void k_dft_a(const float* __restrict__ H, const float* __restrict__ PA,
             const float* __restrict__ sc, const float* __restrict__ bi,
             unsigned int* __restrict__ AB)
{
  __shared__ float ct[512], st[512];
  const int tid = threadIdx.x;
  for (int q = tid; q < 512; q += 256) {
    const int k = q >> 5, y = q & 31;
    const float ang = (float)((k * y) & 31) * 0.19634954084936207f;
    ct[q] = cosf(ang); st[q] = sinf(ang);
  }
  __syncthreads();
  const int blk = blockIdx.x;                    // b*128 + x*4 + half*2 + kh8
  const int kh8 = blk & 1, half = (blk >> 1) & 1, x = (blk >> 2) & 31, b = blk >> 7;
  const int c = half * 256 + tid;
  float sca, sh;
  gn_coef8(PA, sc, bi, b, c, sca, sh);
  float ar[8], ai[8];
  #pragma unroll
  for (int k = 0; k < 8; ++k) { ar[k] = 0.f; ai[k] = 0.f; }
  const float* zp = H + ((size_t)b * 1024 + x) * 512 + c;
  for (int y = 0; y < 32; ++y) {
    const float v = fmaf(zp[(size_t)y * 32 * 512], sca, sh);
    #pragma unroll
    for (int k = 0; k < 8; ++k) {
      const int kg = kh8 * 8 + k;
      ar[k] = fmaf(v, ct[kg * 32 + y], ar[k]);
      ai[k] = fmaf(-v, st[kg * 32 + y], ai[k]);
    }
  }
  #pragma unroll
  for (int k = 0; k < 8; ++k) {
    const int kg = kh8 * 8 + k;
    const size_t o = (((size_t)b * 16 + kg) * 32 + x) * 512 + c;
    AB[o] = (unsigned int)f2bf(ar[k]) | ((unsigned int)f2bf(ai[k]) << 16);
  }
}

// ---------------- forward DFT stage B (kw-split x2) -> stacked bf16 X [z][2048][128]
__global__ __launch_bounds__(256)
void k_dft_b(const unsigned int* __restrict__ AB, unsigned short* __restrict__ X)
{
  __shared__ float ct[512], st[512];
  const int tid = threadIdx.x;
  for (int q = tid; q < 512; q += 256) {
    const int k = q >> 5, xx = q & 31;
    const float ang = (float)((k * xx) & 31) * 0.19634954084936207f;
    ct[q] = cosf(ang); st[q] = sinf(ang);
  }
  __syncthreads();
  const int blk = blockIdx.x;                   // b*64 + kh*4 + half*2 + kw8
  const int kw8 = blk & 1, half = (blk >> 1) & 1, kh = (blk >> 2) & 15, b = blk >> 6;
  const int c = half * 256 + tid;
  float gr[8], gi[8];
  #pragma unroll
  for (int k = 0; k < 8; ++k) { gr[k] = 0.f; gi[k] = 0.f; }
  const unsigned int* abp = AB + (((size_t)b * 16 + kh) * 32) * 512 + c;
  for (int x = 0; x < 32; ++x) {
    const unsigned int pv = abp[(size_t)x * 512];
    const float vr = bf2f((unsigned short)(pv & 0xffffu));
    const float vi = bf2f((unsigned short)(pv >> 16));
    #pragma unroll
    for (int k = 0; k < 8; ++k) {
      const int kg = kw8 * 8 + k;
      const float cc_ = ct[kg * 32 + x], ss = st[kg * 32 + x];
      gr[k] += vr * cc_ + vi * ss;
      gi[k] += vi * cc_ - vr * ss;
    }
  }
  const int blkc = c >> 6, ii = c & 63;
  #pragma unroll
  for (int k = 0; k < 8; ++k) {
    const size_t pos = (size_t)b * 256 + kh * 16 + kw8 * 8 + k;
    unsigned short* xp = X + ((size_t)blkc * 2048 + pos) * 128 + ii;
    xp[0]  = f2bf(gr[k] * (1.0f / 32.0f));
    xp[64] = f2bf(gi[k] * (1.0f / 32.0f));
  }
}

// ---------------- merged AFNO weights for ALL layers
__global__ __launch_bounds__(256)
void k_mode_prep_all(const float* __restrict__ aw1, const float* __restrict__ aw2,
                     const float* __restrict__ ab1, const float* __restrict__ ab2,
                     unsigned short* __restrict__ Sb, float* __restrict__ SB)
{
  const int gi = blockIdx.x * 256 + threadIdx.x;
  const int dd = gi >> 18;
  const int idx = gi & 262143;
  const float* aw1_d = aw1 + (size_t)dd * 65536;
  const float* aw2_d = aw2 + (size_t)dd * 65536;
  const int s = idx >> 17;
  const int blk = (idx >> 14) & 7;
  const int n = (idx >> 7) & 127;
  const int kk = idx & 127;
  const float* aw = s ? aw2_d : aw1_d;
  const int i = kk & 63, o = n & 63;
  const float wr = aw[(blk * 64 + i) * 64 + o];
  const float wi = aw[32768 + (blk * 64 + i) * 64 + o];
  float val;
  if (n < 64) val = (kk < 64) ? wr : -wi;
  else        val = (kk < 64) ? wi :  wr;
  Sb[gi] = f2bf(val);
  if (idx < 2048) {
    const int s2 = idx >> 10, r2 = idx & 1023, b2 = r2 >> 7, q2 = r2 & 127;
    const float* ab = s2 ? (ab2 + dd * 1024) : (ab1 + dd * 1024);
    SB[dd * 2048 + idx] = (q2 < 64) ? ab[b2 * 64 + q2] : ab[512 + b2 * 64 + (q2 - 64)];
  }
}

// ---------------- inverse DFT stage D (x-split x2) -> packed bf16 T
__global__ __launch_bounds__(256)
void k_idft_d(const unsigned short* __restrict__ X2, unsigned int* __restrict__ Tp)
{
  __shared__ float ct[512], st[512];
  const int tid = threadIdx.x;
  for (int q = tid; q < 512; q += 256) {
    const int kw = q >> 5, xx = q & 31;
    const float w = (kw == 0) ? 1.0f : 2.0f;
    const float ang = (float)((kw * xx) & 31) * 0.19634954084936207f;
    ct[q] = w * cosf(ang); st[q] = w * sinf(ang);
  }
  __syncthreads();
  const int blk = blockIdx.x;                  // b*64 + kh*4 + half*2 + xh
  const int xh = blk & 1, half = (blk >> 1) & 1, kh = (blk >> 2) & 15, b = blk >> 6;
  const int c = half * 256 + tid;
  const int blkc = c >> 6, ii = c & 63;
  float gr[16], gi[16];
  #pragma unroll
  for (int kw = 0; kw < 16; ++kw) {
    const size_t pos = (size_t)b * 256 + kh * 16 + kw;
    gr[kw] = bf2f(X2[((size_t)blkc * 2048 + pos) * 128 + ii]);
    gi[kw] = bf2f(X2[((size_t)blkc * 2048 + pos) * 128 + 64 + ii]);
  }
  for (int x = xh * 16; x < xh * 16 + 16; ++x) {
    float tr = 0.f, ti = 0.f;
    #pragma unroll
    for (int kw = 0; kw < 16; ++kw) {
      const float cc_ = ct[kw * 32 + x], ss = st[kw * 32 + x];
      tr += gr[kw] * cc_ - gi[kw] * ss;
      ti += gi[kw] * cc_ + gr[kw] * ss;
    }
    const size_t o = (((size_t)b * 16 + kh) * 32 + x) * 512 + c;
    Tp[o] = (unsigned int)f2bf(tr) | ((unsigned int)f2bf(ti) << 16);
  }
}

// ---------------- inverse DFT stage E (y-split x2) + residual + gn2 partials (64-slice)
__global__ __launch_bounds__(256)
void k_idft_e(const unsigned int* __restrict__ Tp, const float* __restrict__ H,
              const float* __restrict__ PA, const float* __restrict__ sc,
              const float* __restrict__ bi, float* __restrict__ za,
              float* __restrict__ PB)
{
  __shared__ float ct[512], st[512];
  const int tid = threadIdx.x;
  for (int q = tid; q < 512; q += 256) {
    const int k = q >> 5, y = q & 31;
    const float ang = (float)((k * y) & 31) * 0.19634954084936207f;
    ct[q] = cosf(ang); st[q] = sinf(ang);
  }
  __syncthreads();
  const int blk = blockIdx.x;                 // b*128 + x*4 + half*2 + yh
  const int yh = blk & 1, half = (blk >> 1) & 1, x = (blk >> 2) & 31, b = blk >> 7;
  const int c = half * 256 + tid;
  float sca, sh;
  gn_coef8(PA, sc, bi, b, c, sca, sh);
  float trv[16], tiv[16];
  #pragma unroll
  for (int k = 0; k < 16; ++k) {
    const size_t o = (((size_t)b * 16 + k) * 32 + x) * 512 + c;
    const unsigned int pv = Tp[o];
    trv[k] = bf2f((unsigned short)(pv & 0xffffu));
    tiv[k] = bf2f((unsigned short)(pv >> 16));
  }
  float s1 = 0.f, s2 = 0.f;
  for (int y = yh * 16; y < yh * 16 + 16; ++y) {
    float v = 0.f;
    #pragma unroll
    for (int k = 0; k < 16; ++k)
      v += trv[k] * ct[k * 32 + y] - tiv[k] * st[k * 32 + y];
    const size_t o = ((size_t)b * 1024 + y * 32 + x) * 512 + c;
    const float zv = v * (1.0f / 32.0f) + fmaf(H[o], sca, sh);
    za[o] = zv;
    s1 += zv; s2 += zv * zv;
  }
  #pragma unroll
  for (int sft = 32; sft > 0; sft >>= 1) {
    s1 += __shfl_xor(s1, sft, 64);
    s2 += __shfl_xor(s2, sft, 64);
  }
  if ((tid & 63) == 0) {
    const int g = half * 4 + (tid >> 6);
    PB[(b * 8 + g) * 64 + x * 2 + yh] = s1;
    PB[4096 + (b * 8 + g) * 64 + x * 2 + yh] = s2;
  }
}

// ---------------- gn2 coef table from PB (64 slices)
__global__ __launch_bounds__(256)
void k_gn_coef(const float* __restrict__ PB, const float* __restrict__ sc,
               const float* __restrict__ bi, float* __restrict__ gnc)
{
  const int idx = blockIdx.x * 256 + threadIdx.x;   // 4096
  const int b = idx >> 9, c = idx & 511, g = c >> 6;
  float s1 = 0.f, s2 = 0.f;
  #pragma unroll
  for (int q = 0; q < 64; ++q) {
    s1 += PB[(b * 8 + g) * 64 + q];
    s2 += PB[4096 + (b * 8 + g) * 64 + q];
  }
  const float mu = s1 * (1.0f / 65536.0f);
  const float var = s2 * (1.0f / 65536.0f) - mu * mu;
  const float rs = rsqrtf(var + 1e-5f);
  const float sca = sc[c] * rs;
  gnc[idx] = sca;
  gnc[4096 + idx] = bi[c] - mu * sca;
}

// ---------------- cls layers 1/2 (ILP-4 accumulators)
template<int FIRST>
__global__ __launch_bounds__(256)
void k_cls_l(const float* __restrict__ src, const float* __restrict__ Wm,
             const float* __restrict__ bb, float* __restrict__ Cout)
{
  __shared__ float tok[512];
  __shared__ float red[256];
  const int b = blockIdx.y, oc = blockIdx.x;
  const int tid = threadIdx.x;
  for (int i = tid; i < 512; i += 256) {
    if (FIRST) {
      float s = 0.f;
      #pragma unroll
      for (int q = 0; q < 8; ++q) s += src[((b * 8 + q) << 9) + i];
      tok[i] = s * (1.0f / 1024.0f);
    } else {
      tok[i] = src[b * 512 + i];
    }
  }
  __syncthreads();
  const int to = tid & 63, iq = tid >> 6;
  const int o = oc * 64 + to;
  const float* wp = Wm + (size_t)(iq * 128) * 512 + o;
  const float* tp = tok + iq * 128;
  float a0 = 0.f, a1 = 0.f, a2 = 0.f, a3 = 0.f;
  #pragma unroll 8
  for (int i = 0; i < 128; i += 4) {
    a0 = fmaf(tp[i + 0], wp[(size_t)(i + 0) * 512], a0);
    a1 = fmaf(tp[i + 1], wp[(size_t)(i + 1) * 512], a1);
    a2 = fmaf(tp[i + 2], wp[(size_t)(i + 2) * 512], a2);
    a3 = fmaf(tp[i + 3], wp[(size_t)(i + 3) * 512], a3);
  }
  red[tid] = (a0 + a1) + (a2 + a3);
  __syncthreads();
  if (tid < 64) {
    const int oo = oc * 64 + tid;
    const float v = red[tid] + red[tid + 64] + red[tid + 128] + red[tid + 192] + bb[oo];
    Cout[b * 512 + oo] = gelu_f(v);
  }
}

// ---------------- cls layer 3
__global__ __launch_bounds__(768)
void k_cls3(const float* __restrict__ C2, const float* __restrict__ w3,
            const float* __restrict__ b3, float* __restrict__ outp)
{
  const int b = blockIdx.x, tid = threadIdx.x;
  const int o = tid >> 6, lane = tid & 63;
  float acc = 0.f;
  for (int i = lane; i < 512; i += 64)
    acc = fmaf(C2[b * 512 + i], w3[i * 12 + o], acc);
  #pragma unroll
  for (int s = 32; s > 0; s >>= 1) acc += __shfl_xor(acc, s, 64);
  if (lane == 0) outp[2097152 + b * 12 + o] = acc + b3[o];
}

extern "C" void kernel_launch(void* const* d_in, const int* in_sizes, int n_in,
                              void* d_out, int out_size, void* d_ws, size_t ws_size,
                              hipStream_t stream)
{
  (void)in_sizes; (void)n_in; (void)out_size; (void)ws_size;
  const float* x      = (const float*)d_in[0];
  const float* patch_w= (const float*)d_in[1];
  const float* patch_b= (const float*)d_in[2];
  const float* p1_w   = (const float*)d_in[3];
  const float* p1_b   = (const float*)d_in[4];
  const float* pos    = (const float*)d_in[5];
  const float* tagg_w = (const float*)d_in[6];
  const float* gamma  = (const float*)d_in[7];
  const float* gn1_s  = (const float*)d_in[8];
  const float* gn1_b  = (const float*)d_in[9];
  const float* aw1    = (const float*)d_in[10];
  const float* ab1    = (const float*)d_in[11];
  const float* aw2    = (const float*)d_in[12];
  const float* ab2    = (const float*)d_in[13];
  const float* gn2_s  = (const float*)d_in[14];
  const float* gn2_b  = (const float*)d_in[15];
  const float* mw1    = (const float*)d_in[16];
  const float* mb1    = (const float*)d_in[17];
  const float* mw2    = (const float*)d_in[18];
  const float* mb2    = (const float*)d_in[19];
  const float* cls_w1 = (const float*)d_in[20];
  const float* cls_b1 = (const float*)d_in[21];
  const float* cls_w2 = (const float*)d_in[22];
  const float* cls_b2 = (const float*)d_in[23];
  const float* cls_w3 = (const float*)d_in[24];
  const float* cls_b3 = (const float*)d_in[25];
  const float* dec_w  = (const float*)d_in[26];
  const float* dec_b  = (const float*)d_in[27];
  const float* c3_w   = (const float*)d_in[28];
  const float* c3_b   = (const float*)d_in[29];
  const float* c1_w   = (const float*)d_in[30];
  const float* c1_b   = (const float*)d_in[31];

  float* W = (float*)d_ws;
  float* H            = W;                                  // 4,194,304 f
  unsigned int* ABT   = (unsigned int*)(W + 4194304);       // 2,097,152 u32 (AB / Tp)
  unsigned short* Xb  = (unsigned short*)(W + 6291456);     // 2,097,152 sh
  unsigned short* X2b = (unsigned short*)(W + 7340032);     // 2,097,152 sh
  unsigned short* UO  = (unsigned short*)(W + 8388608);     // 4,194,304 sh (P1b/Ub)
  float* R1           = W + 10485760;                       // 8,388,608 f (imat/H0b/ZA/Y1)
  unsigned short* SbA = (unsigned short*)(W + 18874368);    // 3,145,728 sh
  float* SBa          = W + 20447232;                       // 24,576 f
  unsigned short* taggT = (unsigned short*)(W + 20471808);  // 1,048,576 sh
  unsigned short* mwT1  = (unsigned short*)(W + 20996096);  // 3,145,728 sh
  unsigned short* mwT2  = (unsigned short*)(W + 22568960);  // 3,145,728 sh
  unsigned short* decC  = (unsigned short*)(W + 24141824);  // 1,048,576 sh
  unsigned short* w3t   = (unsigned short*)(W + 24666112);  // 16,384 sh
  unsigned short* btp   = (unsigned short*)(W + 24674304);  // 28,672 sh
  unsigned short* bte   = (unsigned short*)(W + 24688640);  // 32,768 sh
  float* TEMB  = W + 24705024;                              // 2,048
  float* PBP   = W + 24707072;                              // 64
  float* PA    = W + 24707136;                              // 1,024
  float* PB    = W + 24708160;                              // 8,192
  float* GNC   = W + 24716352;                              // 8,192
  float* PARTC = W + 24724544;                              // 32,768
  float* C1    = W + 24757312;                              // 4,096
  float* C2    = W + 24761408;                              // 4,096

  unsigned short* imat = (unsigned short*)R1;
  unsigned short* H0b  = (unsigned short*)R1;
  unsigned short* Y1   = (unsigned short*)R1;
  float* ZA = R1;
  unsigned short* P1b = UO;
  unsigned short* Ub  = UO;
  float* out = (float*)d_out;

  // ---- weight prep (once)
  k_cvt_trans<<<dim3(16,64,1),256,0,stream>>>(tagg_w, taggT, 2048, 512, 0, 0);
  k_cvt_trans<<<dim3(16,16,12),256,0,stream>>>(mw1, mwT1, 512, 512, 262144, 262144);
  k_cvt_trans<<<dim3(16,16,12),256,0,stream>>>(mw2, mwT2, 512, 512, 262144, 262144);
  k_cvt<<<4096,256,0,stream>>>(dec_w, decC, 1048576);
  k_prep_w3<<<36,256,0,stream>>>(c3_w, w3t);
  k_prep_btp<<<112,256,0,stream>>>(patch_w, patch_b, btp, PBP);
  k_prep_bte<<<128,256,0,stream>>>(p1_w, bte);
  k_temb<<<8,256,0,stream>>>(gamma, TEMB);
  k_mode_prep_all<<<12288,256,0,stream>>>(aw1, aw2, ab1, ab2, SbA, SBa);

  // ---- encoder
  k_pack<<<8192,256,0,stream>>>(x, imat);
  k_mgemm<1,1,1><<<dim3(1,512),256,0,stream>>>(imat, btp, PBP, P1b,
      nullptr, nullptr, 448, 448, 64, 0, 0, 0, 0);
  k_mgemm<1,0,2><<<dim3(8,512),256,0,stream>>>(P1b, bte, p1_b, H0b,
      pos, TEMB, 64, 64, 512, 0, 0, 0, 0);
  k_bgemm<0,0><<<256,1024,0,stream>>>(H0b, taggT, H, nullptr, nullptr, nullptr,
      nullptr, PA, 2048, 512, 4);

  for (int d = 0; d < 12; ++d) {
    k_dft_a<<<1024,256,0,stream>>>(H, PA, gn1_s + d*512, gn1_b + d*512, ABT);
    k_dft_b<<<512,256,0,stream>>>(ABT, Xb);
    k_afno<<<dim3(32,8),256,0,stream>>>(Xb, SbA + (size_t)d*262144, SBa + d*2048, X2b);
    k_idft_d<<<512,256,0,stream>>>(X2b, ABT);
    k_idft_e<<<1024,256,0,stream>>>(ABT, H, PA, gn1_s + d*512, gn1_b + d*512, ZA, PB);
    k_gn_coef<<<16,256,0,stream>>>(PB, gn2_s + d*512, gn2_b + d*512, GNC);
    k_bgemm<2,1><<<256,1024,0,stream>>>(ZA, mwT1 + (size_t)d*262144, nullptr, Ub,
        mb1 + d*512, nullptr, GNC, nullptr, 512, 512, 4);
    if (d < 11)
      k_bgemm<0,2><<<256,1024,0,stream>>>(Ub, mwT2 + (size_t)d*262144, H, nullptr,
          mb2 + d*512, H, nullptr, PA, 512, 512, 4);
    else
      k_bgemm<0,4><<<256,1024,0,stream>>>(Ub, mwT2 + (size_t)d*262144, H, nullptr,
          mb2 + d*512, H, nullptr, PARTC, 512, 512, 4);
  }

  k_cls_l<1><<<dim3(8,8),256,0,stream>>>(PARTC, cls_w1, cls_b1, C1);
  k_cls_l<0><<<dim3(8,8),256,0,stream>>>(C1, cls_w2, cls_b2, C2);
  k_cls3<<<8,768,0,stream>>>(C2, cls_w3, cls_b3, out);
  k_bgemm<1,3><<<1024,1024,0,stream>>>(H, decC, nullptr, Y1,
      dec_b, nullptr, nullptr, nullptr, 512, 0, 16);
  k_tail<<<2048,256,0,stream>>>(Y1, w3t, c1_w, c1_b, out);
}

// Round 10
// 1186.657 us; speedup vs baseline: 3.5395x; 1.1211x over previous
//
#include <hip/hip_runtime.h>
#include <cstddef>

typedef __attribute__((ext_vector_type(8))) short bh8;
typedef __attribute__((ext_vector_type(4))) float f4;

__device__ __forceinline__ float gelu_f(float x){
  return 0.5f * x * (1.0f + erff(x * 0.7071067811865476f));
}

__device__ __forceinline__ unsigned short f2bf(float f){
  unsigned int u = __float_as_uint(f);
  unsigned int r = (u + 0x7FFFu + ((u >> 16) & 1u)) >> 16;
  return (unsigned short)r;
}

__device__ __forceinline__ float bf2f(unsigned short u){
  return __uint_as_float(((unsigned int)u) << 16);
}

__device__ __forceinline__ f4 mfma16(bh8 a, bh8 b, f4 c){
  return __builtin_amdgcn_mfma_f32_16x16x32_bf16(a, b, c, 0, 0, 0);
}

__device__ __forceinline__ void gll16(const unsigned short* src, unsigned short* dst){
  __builtin_amdgcn_global_load_lds(
      (const __attribute__((address_space(1))) unsigned int*)src,
      (__attribute__((address_space(3))) unsigned int*)dst, 16, 0, 0);
}

// gn coef from 8-slice partials PA[(b*8+g)*8+q], s2 at +512
__device__ __forceinline__ void gn_coef8(const float* pa, const float* sc,
                                         const float* bi, int b, int c,
                                         float& sca, float& sh)
{
  const int g = c >> 6;
  float s1 = 0.f, s2 = 0.f;
  #pragma unroll
  for (int q = 0; q < 8; ++q) {
    s1 += pa[(b * 8 + g) * 8 + q];
    s2 += pa[512 + (b * 8 + g) * 8 + q];
  }
  const float mu = s1 * (1.0f / 65536.0f);
  const float var = s2 * (1.0f / 65536.0f) - mu * mu;
  const float rs = rsqrtf(var + 1e-5f);
  sca = sc[c] * rs;
  sh = bi[c] - mu * sca;
}

// ================= big bf16 MFMA GEMM: 128x128 tile, BK=64, 1024 thr (16 waves),
// 2-phase dbuf pipeline, XCD chunk swizzle.
// AMODE: 0=bf16 gll, 1=f32 reg-staged, 2=f32 + GN affine (gnc), 3=bf16 + GN affine.
// OMODE: 0=f32 C + gn-partials; 1=bias+gelu->bf16 OB; 2=bias+Res->f32 C + gn-partials;
//        3=DEC gelu(+bias[col&31]) pixel-scatter; 4=bias+Res->f32 C + cls col-partials.
#define BG_STAGE(dbuf, kofs, BASE, DST) \
  gll16(BASE + (size_t)sr_ * K + (kofs) + ((ss_ ^ (sr_ & 7)) << 3), &DST[dbuf][tid * 8]);

#define BG_LOADA(kofs) { \
  if (AMODE == 3) { \
    const unsigned short* ap16 = Ab16 + (size_t)sr_ * K + (kofs) + ss_ * 8; \
    const uint4 uv = *(const uint4*)ap16; \
    ra0.x = bf2f((unsigned short)(uv.x & 0xffffu)); ra0.y = bf2f((unsigned short)(uv.x >> 16)); \
    ra0.z = bf2f((unsigned short)(uv.y & 0xffffu)); ra0.w = bf2f((unsigned short)(uv.y >> 16)); \
    ra1.x = bf2f((unsigned short)(uv.z & 0xffffu)); ra1.y = bf2f((unsigned short)(uv.z >> 16)); \
    ra1.z = bf2f((unsigned short)(uv.w & 0xffffu)); ra1.w = bf2f((unsigned short)(uv.w >> 16)); \
  } else { \
    const float* ap_ = Afbase + (size_t)sr_ * K + (kofs) + ss_ * 8; \
    ra0 = *(const float4*)ap_; \
    ra1 = *(const float4*)(ap_ + 4); \
  } \
  if (AMODE >= 2) { \
    const int bb_ = (m0 + sr_) >> 10; \
    const int ch_ = (kofs) + ss_ * 8; \
    const float4 c0_ = *(const float4*)(gnc + bb_ * 512 + ch_); \
    const float4 c1_ = *(const float4*)(gnc + bb_ * 512 + ch_ + 4); \
    const float4 h0_ = *(const float4*)(gnc + 4096 + bb_ * 512 + ch_); \
    const float4 h1_ = *(const float4*)(gnc + 4096 + bb_ * 512 + ch_ + 4); \
    ra0.x = fmaf(ra0.x, c0_.x, h0_.x); ra0.y = fmaf(ra0.y, c0_.y, h0_.y); \
    ra0.z = fmaf(ra0.z, c0_.z, h0_.z); ra0.w = fmaf(ra0.w, c0_.w, h0_.w); \
    ra1.x = fmaf(ra1.x, c1_.x, h1_.x); ra1.y = fmaf(ra1.y, c1_.y, h1_.y); \
    ra1.z = fmaf(ra1.z, c1_.z, h1_.z); ra1.w = fmaf(ra1.w, c1_.w, h1_.w); \
  } }

#define BG_WRITEA(dbuf) { \
  const int slot_ = ss_ ^ (sr_ & 7); \
  bh8 av_; \
  av_[0] = (short)f2bf(ra0.x); av_[1] = (short)f2bf(ra0.y); \
  av_[2] = (short)f2bf(ra0.z); av_[3] = (short)f2bf(ra0.w); \
  av_[4] = (short)f2bf(ra1.x); av_[5] = (short)f2bf(ra1.y); \
  av_[6] = (short)f2bf(ra1.z); av_[7] = (short)f2bf(ra1.w); \
  *(bh8*)(&As[dbuf][sr_ * 64 + slot_ * 8]) = av_; }

template<int AMODE, int OMODE>
__global__ __launch_bounds__(1024)
void k_bgemm(const void* __restrict__ Av, const unsigned short* __restrict__ Bt,
             float* __restrict__ C, unsigned short* __restrict__ OB,
             const float* __restrict__ bias, const float* __restrict__ Res,
             const float* __restrict__ gnc, float* __restrict__ gpart,
             int K, int ldc, int nn)
{
  __shared__ __align__(16) unsigned short As[2][8192];
  __shared__ __align__(16) unsigned short Bs[2][8192];
  const int bid = blockIdx.x, nwg = gridDim.x;
  const int wg = (bid & 7) * (nwg >> 3) + (bid >> 3);
  const int mb = wg / nn;
  const int m0 = mb * 128, n0 = (wg - mb * nn) * 128;
  const int tid = threadIdx.x;
  const int w = tid >> 6, lane = tid & 63;
  const int lr = lane & 15, lh = lane >> 4;
  const int wr = w >> 2, wc = w & 3;
  const int sr_ = tid >> 3, ss_ = tid & 7;
  const unsigned short* Abase = (const unsigned short*)Av + (size_t)m0 * K;
  const unsigned short* Ab16 = (const unsigned short*)Av + (size_t)m0 * K;
  const float* Afbase = (const float*)Av + (size_t)m0 * K;
  const unsigned short* Bbase = Bt + (size_t)n0 * K;
  float4 ra0, ra1;
  f4 acc[2][2] = {};

  const int nt = K >> 6;
  if (AMODE == 0) { BG_STAGE(0, 0, Abase, As) }
  else            { BG_LOADA(0) BG_WRITEA(0) }
  BG_STAGE(0, 0, Bbase, Bs)
  __syncthreads();

  for (int t = 0; t < nt; ++t) {
    const int d = t & 1;
    const bool more = (t + 1 < nt);
    if (more) {
      const int kn = (t + 1) << 6;
      if (AMODE == 0) { BG_STAGE(d ^ 1, kn, Abase, As) }
      else            { BG_LOADA(kn) }
      BG_STAGE(d ^ 1, kn, Bbase, Bs)
    }
    #pragma unroll
    for (int kk = 0; kk < 2; ++kk) {
      bh8 af[2], bf[2];
      #pragma unroll
      for (int mi = 0; mi < 2; ++mi) {
        const int R = wr * 32 + mi * 16 + lr;
        af[mi] = *(const bh8*)((const char*)As[d] + R * 128 + (((kk * 4 + lh) ^ (R & 7)) * 16));
      }
      #pragma unroll
      for (int ni = 0; ni < 2; ++ni) {
        const int R = wc * 32 + ni * 16 + lr;
        bf[ni] = *(const bh8*)((const char*)Bs[d] + R * 128 + (((kk * 4 + lh) ^ (R & 7)) * 16));
      }
      #pragma unroll
      for (int mi = 0; mi < 2; ++mi)
        #pragma unroll
        for (int ni = 0; ni < 2; ++ni)
          acc[mi][ni] = mfma16(af[mi], bf[ni], acc[mi][ni]);
    }
    if (more && AMODE != 0) { BG_WRITEA(d ^ 1) }
    __syncthreads();
  }

  float cs1[2], cs2[2];
  #pragma unroll
  for (int ni = 0; ni < 2; ++ni) {
    const int col_l = wc * 32 + ni * 16 + lr;
    const int col = n0 + col_l;
    float bv = 0.f;
    if (OMODE == 1 || OMODE == 2 || OMODE == 4) bv = bias[col];
    if (OMODE == 3) bv = bias[col & 31];
    float s1 = 0.f, s2 = 0.f;
    #pragma unroll
    for (int mi = 0; mi < 2; ++mi) {
      #pragma unroll
      for (int r = 0; r < 4; ++r) {
        const int row = m0 + wr * 32 + mi * 16 + lh * 4 + r;
        float v = acc[mi][ni][r] + bv;
        if (OMODE == 0) {
          C[(size_t)row * ldc + col] = v;
          s1 += v; s2 += v * v;
        } else if (OMODE == 1) {
          OB[(size_t)row * ldc + col] = f2bf(gelu_f(v));
        } else if (OMODE == 2 || OMODE == 4) {
          const size_t ci = (size_t)row * ldc + col;
          v += Res[ci];
          C[ci] = v;
          s1 += v; s2 += v * v;
        } else {
          v = gelu_f(v);
          const int bb = row >> 10, hw = row & 1023, ii = hw >> 5, jj = hw & 31;
          const int dxy = col >> 5, dy = dxy >> 3, dx = dxy & 7, cc = col & 31;
          OB[(((size_t)(bb * 256 + ii * 8 + dy)) * 256 + jj * 8 + dx) * 32 + cc] = f2bf(v);
        }
      }
    }
    cs1[ni] = s1; cs2[ni] = s2;
  }
  if (OMODE == 0 || OMODE == 2 || OMODE == 4) {
    float* sp = (float*)As;
    const int sub = wr * 4 + lh;
    #pragma unroll
    for (int ni = 0; ni < 2; ++ni) {
      const int col_l = wc * 32 + ni * 16 + lr;
      sp[col_l * 16 + sub] = cs1[ni];
      sp[2048 + col_l * 16 + sub] = cs2[ni];
    }
    __syncthreads();
    if (tid < 128) {
      float s1 = 0.f, s2 = 0.f;
      #pragma unroll
      for (int u = 0; u < 16; ++u) { s1 += sp[tid * 16 + u]; s2 += sp[2048 + tid * 16 + u]; }
      const int b = m0 >> 10, slice = (m0 >> 7) & 7;
      if (OMODE == 4) {
        gpart[(b * 8 + slice) * 512 + n0 + tid] = s1;
      } else {
        #pragma unroll
        for (int sft = 32; sft > 0; sft >>= 1) {
          s1 += __shfl_xor(s1, sft, 64);
          s2 += __shfl_xor(s2, sft, 64);
        }
        if ((tid & 63) == 0) {
          const int g = (n0 >> 6) + (tid >> 6);
          gpart[(b * 8 + g) * 8 + slice] = s1;
          gpart[512 + (b * 8 + g) * 8 + slice] = s2;
        }
      }
    }
  }
}

// ================= fused mode pipeline: dft_b + AFNO 2-layer MLP + idft_d.
// block = (b, kh, c-half of 256ch). Reads AB slice, writes Tp IN-PLACE (disjoint slices).
__global__ __launch_bounds__(512)
void k_modes(unsigned int* __restrict__ AB, const unsigned short* __restrict__ Sb_d,
             const float* __restrict__ SB_d)
{
  __shared__ __align__(16) unsigned int ABs[8192];       // 32KB  [x][cc]; reused as M2
  __shared__ __align__(16) unsigned short Ws[2][16384];  // 64KB  W dbuf (swizzled)
  __shared__ __align__(16) unsigned short Ps[8192];      // 16KB  [cblk][kw][128] swz
  __shared__ __align__(16) unsigned short O1s[8192];     // 16KB  same layout
  __shared__ float ct[512], st[512];                     // 4KB
  unsigned short* M2 = (unsigned short*)ABs;

  const int bx = blockIdx.x;
  const int chalf = bx & 1, kh = (bx >> 1) & 15, b = bx >> 5;
  const int tid = threadIdx.x;
  const int w = tid >> 6, lane = tid & 63, lr = lane & 15, lh = lane >> 4;
  unsigned int* ABbase = AB + (((size_t)b * 16 + kh) * 32) * 512 + chalf * 256;

  // stage AB slice (linear) + W1[cblk0] (pre-swizzled source)
  #pragma unroll
  for (int p = 0; p < 4; ++p) {
    const int q = p * 512 + tid;                 // 16B chunks, 2048 total
    const int x = q >> 6, c4 = (q & 63) * 4;
    gll16((const unsigned short*)(ABbase + (size_t)x * 512 + c4),
          (unsigned short*)&ABs[q * 4]);
  }
  {
    const unsigned short* Wsrc = Sb_d + (size_t)(chalf * 4) * 16384;
    #pragma unroll
    for (int p = 0; p < 4; ++p) {
      const int q = p * 512 + tid;
      const int r = q >> 4, c = q & 15;
      gll16(Wsrc + r * 128 + ((c ^ (r & 7)) << 3), &Ws[0][q * 8]);
    }
  }
  {
    const int k = tid >> 5, xx = tid & 31;
    const float ang = (float)((k * xx) & 31) * 0.19634954084936207f;
    ct[tid] = cosf(ang); st[tid] = sinf(ang);
  }
  __syncthreads();

  // ---- dft_b: kw modes over x
  const int cc = tid & 255, kwh = tid >> 8;
  {
    float gr[8], gi[8];
    #pragma unroll
    for (int j = 0; j < 8; ++j) { gr[j] = 0.f; gi[j] = 0.f; }
    for (int x = 0; x < 32; ++x) {
      const unsigned int pv = ABs[x * 256 + cc];
      const float vr = bf2f((unsigned short)(pv & 0xffffu));
      const float vi = bf2f((unsigned short)(pv >> 16));
      #pragma unroll
      for (int j = 0; j < 8; ++j) {
        const int kg = kwh * 8 + j;
        const float c_ = ct[kg * 32 + x], s_ = st[kg * 32 + x];
        gr[j] += vr * c_ + vi * s_;
        gi[j] += vi * c_ - vr * s_;
      }
    }
    const int cblk = cc >> 6, ci = cc & 63;
    #pragma unroll
    for (int j = 0; j < 8; ++j) {
      const int kw = kwh * 8 + j;
      const int base = cblk * 2048 + kw * 128;
      const int chr = (ci >> 3) ^ (kw & 7);
      const int chi = ((64 + ci) >> 3) ^ (kw & 7);
      Ps[base + (chr << 3) + (ci & 7)] = f2bf(gr[j] * (1.0f / 32.0f));
      Ps[base + (chi << 3) + (ci & 7)] = f2bf(gi[j] * (1.0f / 32.0f));
    }
  }
  __syncthreads();

  // ---- AFNO: 8 iters (i<4: stage1 cblk=i; i>=4: stage2 cblk=i-4), W prefetch dbuf
  for (int i = 0; i < 8; ++i) {
    if (i + 1 < 8) {
      const int j2 = i + 1;
      const unsigned short* Wsrc = Sb_d + (j2 >= 4 ? 131072 : 0)
                                 + (size_t)(chalf * 4 + (j2 & 3)) * 16384;
      #pragma unroll
      for (int p = 0; p < 4; ++p) {
        const int q = p * 512 + tid;
        const int r = q >> 4, c = q & 15;
        gll16(Wsrc + r * 128 + ((c ^ (r & 7)) << 3), &Ws[j2 & 1][q * 8]);
      }
    }
    const int cblk = i & 3;
    const unsigned short* src = (i < 4) ? Ps : O1s;
    f4 acc = {};
    #pragma unroll
    for (int ks = 0; ks < 4; ++ks) {
      const bh8 a = *(const bh8*)(&src[cblk * 2048 + lr * 128
                      + (((ks * 4 + lh) ^ (lr & 7)) << 3)]);
      const int rw = w * 16 + lr;
      const bh8 bb = *(const bh8*)(&Ws[i & 1][rw * 128
                      + (((ks * 4 + lh) ^ (rw & 7)) << 3)]);
      acc = mfma16(a, bb, acc);
    }
    const int o = w * 16 + lr;
    if (i < 4) {
      const float bv = SB_d[(chalf * 4 + cblk) * 128 + o];
      #pragma unroll
      for (int r = 0; r < 4; ++r) {
        const int kw = lh * 4 + r;
        const int ch = (o >> 3) ^ (kw & 7);
        O1s[cblk * 2048 + kw * 128 + (ch << 3) + (o & 7)] = f2bf(gelu_f(acc[r] + bv));
      }
    } else {
      const float bv = SB_d[1024 + (chalf * 4 + cblk) * 128 + o];
      #pragma unroll
      for (int r = 0; r < 4; ++r) {
        const int kw = lh * 4 + r;
        M2[cblk * 2048 + kw * 128 + o] = f2bf(acc[r] + bv);
      }
    }
    __syncthreads();
  }

  // ---- idft_d: kw -> x, write packed Tp in-place over AB slice
  {
    const int xh = tid >> 8;
    const int cblk = cc >> 6, ci = cc & 63;
    float gr[16], gi[16];
    #pragma unroll
    for (int kw = 0; kw < 16; ++kw) {
      const float wf = (kw == 0) ? 1.0f : 2.0f;
      gr[kw] = wf * bf2f(M2[cblk * 2048 + kw * 128 + ci]);
      gi[kw] = wf * bf2f(M2[cblk * 2048 + kw * 128 + 64 + ci]);
    }
    for (int x = xh * 16; x < xh * 16 + 16; ++x) {
      float tr = 0.f, ti = 0.f;
      #pragma unroll
      for (int kw = 0; kw < 16; ++kw) {
        const float c_ = ct[kw * 32 + x], s_ = st[kw * 32 + x];
        tr += gr[kw] * c_ - gi[kw] * s_;
        ti += gi[kw] * c_ + gr[kw] * s_;
      }
      ABbase[(size_t)x * 512 + cc] = (unsigned int)f2bf(tr) | ((unsigned int)f2bf(ti) << 16);
    }
  }
}

// ---------------- im2col pack: x -> bf16 imat [32768][448]
__global__ __launch_bounds__(256)
void k_pack(const float* __restrict__ x, unsigned short* __restrict__ imat)
{
  const int nb = blockIdx.x;
  const int j = nb & 31, i = (nb >> 5) & 31, b = nb >> 10;
  const int tid = threadIdx.x;
  const int tl = tid >> 6, px = tid & 63;
  const int dy = px >> 3, dx = px & 7;
  const int Y = i * 8 + dy, X = j * 8 + dx;
  const float4 v = *(const float4*)(x + (((size_t)(b * 256 + Y)) * 256 + X) * 16 + tl * 4);
  const size_t row = (size_t)nb * 4 + tl;
  ushort4 ov;
  ov.x = f2bf(v.x); ov.y = f2bf(v.y); ov.z = f2bf(v.z); ov.w = f2bf(v.w);
  *(ushort4*)(imat + row * 448 + px * 4) = ov;
  for (int q = tid; q < 768; q += 256) {
    const int tt = q / 192, r = q - tt * 192;
    const int sec = r >> 6, p2 = r & 63;
    float val;
    if (sec == 0)      val = (float)(i * 8 + (p2 >> 3)) * (1.0f / 255.0f);
    else if (sec == 1) val = (float)(j * 8 + (p2 & 7)) * (1.0f / 255.0f);
    else               val = (float)tt * (1.0f / 3.0f);
    imat[((size_t)nb * 4 + tt) * 448 + 256 + sec * 64 + p2] = f2bf(val);
  }
}

// ---------------- prep Bt_patch [64][448] (+ padded bias)
__global__ __launch_bounds__(256)
void k_prep_btp(const float* __restrict__ pw, const float* __restrict__ pb,
                unsigned short* __restrict__ btp, float* __restrict__ pbp)
{
  const int idx = blockIdx.x * 256 + threadIdx.x;
  if (idx < 28672) {
    const int n = idx / 448, k = idx - (idx / 448) * 448;
    int l;
    if (k < 256) { const int pxx = k >> 2, c = k & 3; l = pxx * 7 + c; }
    else { const int sec = (k - 256) >> 6, p2 = (k - 256) & 63; l = p2 * 7 + 4 + sec; }
    btp[n * 448 + k] = (n < 35) ? f2bf(pw[l * 35 + n]) : (unsigned short)0;
  }
  if (idx < 64) pbp[idx] = (idx < 35) ? pb[idx] : 0.0f;
}

// ---------------- prep Bt_embed [512][64]
__global__ __launch_bounds__(256)
void k_prep_bte(const float* __restrict__ w, unsigned short* __restrict__ bte)
{
  const int idx = blockIdx.x * 256 + threadIdx.x;
  const int n = idx >> 6, k = idx & 63;
  bte[idx] = (k < 35) ? f2bf(w[k * 512 + n]) : (unsigned short)0;
}

// ---------------- temb table [4][512]
__global__ __launch_bounds__(256)
void k_temb(const float* __restrict__ gamma, float* __restrict__ temb)
{
  const int idx = blockIdx.x * 256 + threadIdx.x;
  const int t = idx >> 9, e = idx & 511;
  temb[idx] = cosf((float)t * (1.0f / 3.0f) * gamma[e]);
}

// ---------------- weight prep: fp32 [K][N] -> bf16 [N][K]
__global__ __launch_bounds__(256)
void k_cvt_trans(const float* __restrict__ in, unsigned short* __restrict__ out,
                 int K, int N, long long sIn, long long sOut)
{
  __shared__ float tile[32][33];
  const int z = blockIdx.z;
  in  += (size_t)z * sIn;
  out += (size_t)z * sOut;
  const int n0 = blockIdx.x * 32, k0 = blockIdx.y * 32;
  const int tx = threadIdx.x & 31, ty = threadIdx.x >> 5;
  #pragma unroll
  for (int i = 0; i < 4; ++i)
    tile[ty + i * 8][tx] = in[(size_t)(k0 + ty + i * 8) * N + n0 + tx];
  __syncthreads();
  #pragma unroll
  for (int i = 0; i < 4; ++i)
    out[(size_t)(n0 + ty + i * 8) * K + k0 + tx] = f2bf(tile[tx][ty + i * 8]);
}

__global__ __launch_bounds__(256)
void k_cvt(const float* __restrict__ in, unsigned short* __restrict__ out, int n)
{
  const int idx = blockIdx.x * 256 + threadIdx.x;
  if (idx < n) out[idx] = f2bf(in[idx]);
}

__global__ __launch_bounds__(256)
void k_prep_w3(const float* __restrict__ w, unsigned short* __restrict__ out)
{
  const int idx = blockIdx.x * 256 + threadIdx.x;
  if (idx < 9216) {
    const int kb = idx >> 10, co = (idx >> 5) & 31, ci = idx & 31;
    out[idx] = f2bf(w[(kb * 32 + ci) * 32 + co]);
  }
}

// ---------------- small bf16 MFMA GEMM, 64x64 tile, z-batched (patch/embed)
template<int BIAS, int GELU, int OMODE>
__global__ __launch_bounds__(256)
void k_mgemm(const unsigned short* __restrict__ A, const unsigned short* __restrict__ Bt,
             const float* __restrict__ bias, unsigned short* __restrict__ OB,
             const float* __restrict__ pos, const float* __restrict__ temb,
             int K, int lda, int ldc,
             long long zsA, long long zsB, long long zsC, int zsBias)
{
  __shared__ __align__(16) unsigned short As[64 * 40];
  __shared__ __align__(16) unsigned short Bs[64 * 40];
  const int z = blockIdx.z;
  A  += (size_t)z * zsA;
  Bt += (size_t)z * zsB;
  if (BIAS) bias += (size_t)z * zsBias;
  OB += (size_t)z * zsC;
  const int m0 = blockIdx.y * 64, n0 = blockIdx.x * 64;
  const int tid = threadIdx.x;
  const int w = tid >> 6, l = tid & 63;
  const int lr = l & 15, lh = l >> 4;
  const int sr = tid >> 2, skq = (tid & 3) * 8;
  f4 acc[4] = {};
  for (int k0 = 0; k0 < K; k0 += 32) {
    const uint4 av = *(const uint4*)(A + (size_t)(m0 + sr) * lda + k0 + skq);
    *(uint4*)(&As[sr * 40 + skq]) = av;
    const uint4 bv = *(const uint4*)(Bt + (size_t)(n0 + sr) * K + k0 + skq);
    *(uint4*)(&Bs[sr * 40 + skq]) = bv;
    __syncthreads();
    const bh8 af = *(const bh8*)(&As[(w * 16 + lr) * 40 + lh * 8]);
    #pragma unroll
    for (int ct = 0; ct < 4; ++ct) {
      const bh8 bf = *(const bh8*)(&Bs[(ct * 16 + lr) * 40 + lh * 8]);
      acc[ct] = mfma16(af, bf, acc[ct]);
    }
    __syncthreads();
  }
  #pragma unroll
  for (int ct = 0; ct < 4; ++ct) {
    const int col = n0 + ct * 16 + lr;
    float bv = 0.f;
    if (BIAS) bv = bias[col];
    #pragma unroll
    for (int r = 0; r < 4; ++r) {
      const int row = m0 + w * 16 + lh * 4 + r;
      float v = acc[ct][r] + bv;
      if (GELU) v = gelu_f(v);
      if (OMODE == 2) {
        const int hw = (row >> 2) & 1023, t = row & 3;
        v = (v + pos[(size_t)hw * 512 + col]) * temb[t * 512 + col];
        OB[(size_t)row * 512 + col] = f2bf(v);
      } else {
        OB[(size_t)row * ldc + col] = f2bf(v);
      }
    }
  }
}

// ---------------- decoder tail: conv3x3 (MFMA) + gelu + 1x1 -> out
__global__ __launch_bounds__(256)
void k_tail(const unsigned short* __restrict__ Y1, const unsigned short* __restrict__ w3t,
            const float* __restrict__ c1w, const float* __restrict__ c1b,
            float* __restrict__ outp)
{
  __shared__ __align__(16) char lbuf[256 * 33 * 4];
  __shared__ float c1s[128];
  unsigned short* it = (unsigned short*)lbuf;
  float* y2 = (float*)lbuf;
  const int bx = blockIdx.x;
  const int b = bx >> 8, ty = (bx >> 4) & 15, tx = bx & 15;
  const int Y0 = ty * 16, X0 = tx * 16;
  const int tid = threadIdx.x;
  const int w = tid >> 6, l = tid & 63, lr = l & 15, lh = l >> 4;

  if (tid < 128) c1s[tid] = c1w[tid];
  for (int idx = tid; idx < 1296; idx += 256) {
    const int r = idx / 72, rem = idx - r * 72, c = rem >> 2, q = rem & 3;
    const int Yg = Y0 + r - 1, Xg = X0 + c - 1;
    uint4 v = make_uint4(0u, 0u, 0u, 0u);
    if (Yg >= 0 && Yg < 256 && Xg >= 0 && Xg < 256)
      v = *(const uint4*)(Y1 + (((size_t)(b * 256 + Yg)) * 256 + Xg) * 32 + q * 8);
    *(uint4*)(&it[(r * 18 + c) * 40 + q * 8]) = v;
  }
  bh8 bw[2][9];
  #pragma unroll
  for (int ct = 0; ct < 2; ++ct)
    #pragma unroll
    for (int kb = 0; kb < 9; ++kb)
      bw[ct][kb] = *(const bh8*)(w3t + (size_t)(kb * 32 + ct * 16 + lr) * 32 + lh * 8);
  __syncthreads();

  f4 acc[4][2] = {};
  #pragma unroll
  for (int kb = 0; kb < 9; ++kb) {
    const int dy = kb / 3, dx = kb % 3;
    #pragma unroll
    for (int yy = 0; yy < 4; ++yy) {
      const int y = w * 4 + yy;
      const bh8 af = *(const bh8*)(&it[((y + dy) * 18 + lr + dx) * 40 + lh * 8]);
      acc[yy][0] = mfma16(af, bw[0][kb], acc[yy][0]);
      acc[yy][1] = mfma16(af, bw[1][kb], acc[yy][1]);
    }
  }
  __syncthreads();
  #pragma unroll
  for (int yy = 0; yy < 4; ++yy) {
    const int y = w * 4 + yy;
    #pragma unroll
    for (int ct = 0; ct < 2; ++ct)
      #pragma unroll
      for (int r = 0; r < 4; ++r)
        y2[(y * 16 + lh * 4 + r) * 33 + ct * 16 + lr] = gelu_f(acc[yy][ct][r]);
  }
  __syncthreads();
  const int py = tid >> 4, px = tid & 15;
  float o0 = c1b[0], o1 = c1b[1], o2 = c1b[2], o3 = c1b[3];
  #pragma unroll 8
  for (int ci = 0; ci < 32; ++ci) {
    const float v = y2[tid * 33 + ci];
    o0 = fmaf(v, c1s[ci * 4 + 0], o0);
    o1 = fmaf(v, c1s[ci * 4 + 1], o1);
    o2 = fmaf(v, c1s[ci * 4 + 2], o2);
    o3 = fmaf(v, c1s[ci * 4 + 3], o3);
  }
  float4 ov; ov.x = o0; ov.y = o1; ov.z = o2; ov.w = o3;
  *(float4*)(outp + (((size_t)(b * 256 + Y0 + py)) * 256 + X0 + px) * 4) = ov;
}

// ---------------- forward DFT stage A (k-split x2) -> packed bf16 AB
__global__ __launch_bounds__(256)
void k_dft_a(const float* __restrict__ H, const float* __restrict__ PA,
             const float* __restrict__ sc, const float* __restrict__ bi,
             unsigned int* __restrict__ AB)
{
  __shared__ float ct[512], st[512];
  const int tid = threadIdx.x;
  for (int q = tid; q < 512; q += 256) {
    const int k = q >> 5, y = q & 31;
    const float ang = (float)((k * y) & 31) * 0.19634954084936207f;
    ct[q] = cosf(ang); st[q] = sinf(ang);
  }
  __syncthreads();
  const int blk = blockIdx.x;                    // b*128 + x*4 + half*2 + kh8
  const int kh8 = blk & 1, half = (blk >> 1) & 1, x = (blk >> 2) & 31, b = blk >> 7;
  const int c = half * 256 + tid;
  float sca, sh;
  gn_coef8(PA, sc, bi, b, c, sca, sh);
  float ar[8], ai[8];
  #pragma unroll
  for (int k = 0; k < 8; ++k) { ar[k] = 0.f; ai[k] = 0.f; }
  const float* zp = H + ((size_t)b * 1024 + x) * 512 + c;
  for (int y = 0; y < 32; ++y) {
    const float v = fmaf(zp[(size_t)y * 32 * 512], sca, sh);
    #pragma unroll
    for (int k = 0; k < 8; ++k) {
      const int kg = kh8 * 8 + k;
      ar[k] = fmaf(v, ct[kg * 32 + y], ar[k]);
      ai[k] = fmaf(-v, st[kg * 32 + y], ai[k]);
    }
  }
  #pragma unroll
  for (int k = 0; k < 8; ++k) {
    const int kg = kh8 * 8 + k;
    const size_t o = (((size_t)b * 16 + kg) * 32 + x) * 512 + c;
    AB[o] = (unsigned int)f2bf(ar[k]) | ((unsigned int)f2bf(ai[k]) << 16);
  }
}

// ---------------- merged AFNO weights for ALL layers
__global__ __launch_bounds__(256)
void k_mode_prep_all(const float* __restrict__ aw1, const float* __restrict__ aw2,
                     const float* __restrict__ ab1, const float* __restrict__ ab2,
                     unsigned short* __restrict__ Sb, float* __restrict__ SB)
{
  const int gi = blockIdx.x * 256 + threadIdx.x;
  const int dd = gi >> 18;
  const int idx = gi & 262143;
  const float* aw1_d = aw1 + (size_t)dd * 65536;
  const float* aw2_d = aw2 + (size_t)dd * 65536;
  const int s = idx >> 17;
  const int blk = (idx >> 14) & 7;
  const int n = (idx >> 7) & 127;
  const int kk = idx & 127;
  const float* aw = s ? aw2_d : aw1_d;
  const int i = kk & 63, o = n & 63;
  const float wr = aw[(blk * 64 + i) * 64 + o];
  const float wi = aw[32768 + (blk * 64 + i) * 64 + o];
  float val;
  if (n < 64) val = (kk < 64) ? wr : -wi;
  else        val = (kk < 64) ? wi :  wr;
  Sb[gi] = f2bf(val);
  if (idx < 2048) {
    const int s2 = idx >> 10, r2 = idx & 1023, b2 = r2 >> 7, q2 = r2 & 127;
    const float* ab = s2 ? (ab2 + dd * 1024) : (ab1 + dd * 1024);
    SB[dd * 2048 + idx] = (q2 < 64) ? ab[b2 * 64 + q2] : ab[512 + b2 * 64 + (q2 - 64)];
  }
}

// ---------------- inverse DFT stage E (y-split x2) + residual + gn2 partials; ZA bf16
__global__ __launch_bounds__(256)
void k_idft_e(const unsigned int* __restrict__ Tp, const float* __restrict__ H,
              const float* __restrict__ PA, const float* __restrict__ sc,
              const float* __restrict__ bi, unsigned short* __restrict__ zab,
              float* __restrict__ PB)
{
  __shared__ float ct[512], st[512];
  const int tid = threadIdx.x;
  for (int q = tid; q < 512; q += 256) {
    const int k = q >> 5, y = q & 31;
    const float ang = (float)((k * y) & 31) * 0.19634954084936207f;
    ct[q] = cosf(ang); st[q] = sinf(ang);
  }
  __syncthreads();
  const int blk = blockIdx.x;                 // b*128 + x*4 + half*2 + yh
  const int yh = blk & 1, half = (blk >> 1) & 1, x = (blk >> 2) & 31, b = blk >> 7;
  const int c = half * 256 + tid;
  float sca, sh;
  gn_coef8(PA, sc, bi, b, c, sca, sh);
  float trv[16], tiv[16];
  #pragma unroll
  for (int k = 0; k < 16; ++k) {
    const size_t o = (((size_t)b * 16 + k) * 32 + x) * 512 + c;
    const unsigned int pv = Tp[o];
    trv[k] = bf2f((unsigned short)(pv & 0xffffu));
    tiv[k] = bf2f((unsigned short)(pv >> 16));
  }
  float s1 = 0.f, s2 = 0.f;
  for (int y = yh * 16; y < yh * 16 + 16; ++y) {
    float v = 0.f;
    #pragma unroll
    for (int k = 0; k < 16; ++k)
      v += trv[k] * ct[k * 32 + y] - tiv[k] * st[k * 32 + y];
    const size_t o = ((size_t)b * 1024 + y * 32 + x) * 512 + c;
    const float zv = v * (1.0f / 32.0f) + fmaf(H[o], sca, sh);
    zab[o] = f2bf(zv);
    s1 += zv; s2 += zv * zv;
  }
  #pragma unroll
  for (int sft = 32; sft > 0; sft >>= 1) {
    s1 += __shfl_xor(s1, sft, 64);
    s2 += __shfl_xor(s2, sft, 64);
  }
  if ((tid & 63) == 0) {
    const int g = half * 4 + (tid >> 6);
    PB[(b * 8 + g) * 64 + x * 2 + yh] = s1;
    PB[4096 + (b * 8 + g) * 64 + x * 2 + yh] = s2;
  }
}

// ---------------- gn2 coef table from PB (64 slices)
__global__ __launch_bounds__(256)
void k_gn_coef(const float* __restrict__ PB, const float* __restrict__ sc,
               const float* __restrict__ bi, float* __restrict__ gnc)
{
  const int idx = blockIdx.x * 256 + threadIdx.x;   // 4096
  const int b = idx >> 9, c = idx & 511, g = c >> 6;
  float s1 = 0.f, s2 = 0.f;
  #pragma unroll
  for (int q = 0; q < 64; ++q) {
    s1 += PB[(b * 8 + g) * 64 + q];
    s2 += PB[4096 + (b * 8 + g) * 64 + q];
  }
  const float mu = s1 * (1.0f / 65536.0f);
  const float var = s2 * (1.0f / 65536.0f) - mu * mu;
  const float rs = rsqrtf(var + 1e-5f);
  const float sca = sc[c] * rs;
  gnc[idx] = sca;
  gnc[4096 + idx] = bi[c] - mu * sca;
}

// ---------------- cls layers 1/2 (ILP-4 accumulators)
template<int FIRST>
__global__ __launch_bounds__(256)
void k_cls_l(const float* __restrict__ src, const float* __restrict__ Wm,
             const float* __restrict__ bb, float* __restrict__ Cout)
{
  __shared__ float tok[512];
  __shared__ float red[256];
  const int b = blockIdx.y, oc = blockIdx.x;
  const int tid = threadIdx.x;
  for (int i = tid; i < 512; i += 256) {
    if (FIRST) {
      float s = 0.f;
      #pragma unroll
      for (int q = 0; q < 8; ++q) s += src[((b * 8 + q) << 9) + i];
      tok[i] = s * (1.0f / 1024.0f);
    } else {
      tok[i] = src[b * 512 + i];
    }
  }
  __syncthreads();
  const int to = tid & 63, iq = tid >> 6;
  const int o = oc * 64 + to;
  const float* wp = Wm + (size_t)(iq * 128) * 512 + o;
  const float* tp = tok + iq * 128;
  float a0 = 0.f, a1 = 0.f, a2 = 0.f, a3 = 0.f;
  #pragma unroll 8
  for (int i = 0; i < 128; i += 4) {
    a0 = fmaf(tp[i + 0], wp[(size_t)(i + 0) * 512], a0);
    a1 = fmaf(tp[i + 1], wp[(size_t)(i + 1) * 512], a1);
    a2 = fmaf(tp[i + 2], wp[(size_t)(i + 2) * 512], a2);
    a3 = fmaf(tp[i + 3], wp[(size_t)(i + 3) * 512], a3);
  }
  red[tid] = (a0 + a1) + (a2 + a3);
  __syncthreads();
  if (tid < 64) {
    const int oo = oc * 64 + tid;
    const float v = red[tid] + red[tid + 64] + red[tid + 128] + red[tid + 192] + bb[oo];
    Cout[b * 512 + oo] = gelu_f(v);
  }
}

// ---------------- cls layer 3
__global__ __launch_bounds__(768)
void k_cls3(const float* __restrict__ C2, const float* __restrict__ w3,
            const float* __restrict__ b3, float* __restrict__ outp)
{
  const int b = blockIdx.x, tid = threadIdx.x;
  const int o = tid >> 6, lane = tid & 63;
  float acc = 0.f;
  for (int i = lane; i < 512; i += 64)
    acc = fmaf(C2[b * 512 + i], w3[i * 12 + o], acc);
  #pragma unroll
  for (int s = 32; s > 0; s >>= 1) acc += __shfl_xor(acc, s, 64);
  if (lane == 0) outp[2097152 + b * 12 + o] = acc + b3[o];
}

extern "C" void kernel_launch(void* const* d_in, const int* in_sizes, int n_in,
                              void* d_out, int out_size, void* d_ws, size_t ws_size,
                              hipStream_t stream)
{
  (void)in_sizes; (void)n_in; (void)out_size; (void)ws_size;
  const float* x      = (const float*)d_in[0];
  const float* patch_w= (const float*)d_in[1];
  const float* patch_b= (const float*)d_in[2];
  const float* p1_w   = (const float*)d_in[3];
  const float* p1_b   = (const float*)d_in[4];
  const float* pos    = (const float*)d_in[5];
  const float* tagg_w = (const float*)d_in[6];
  const float* gamma  = (const float*)d_in[7];
  const float* gn1_s  = (const float*)d_in[8];
  const float* gn1_b  = (const float*)d_in[9];
  const float* aw1    = (const float*)d_in[10];
  const float* ab1    = (const float*)d_in[11];
  const float* aw2    = (const float*)d_in[12];
  const float* ab2    = (const float*)d_in[13];
  const float* gn2_s  = (const float*)d_in[14];
  const float* gn2_b  = (const float*)d_in[15];
  const float* mw1    = (const float*)d_in[16];
  const float* mb1    = (const float*)d_in[17];
  const float* mw2    = (const float*)d_in[18];
  const float* mb2    = (const float*)d_in[19];
  const float* cls_w1 = (const float*)d_in[20];
  const float* cls_b1 = (const float*)d_in[21];
  const float* cls_w2 = (const float*)d_in[22];
  const float* cls_b2 = (const float*)d_in[23];
  const float* cls_w3 = (const float*)d_in[24];
  const float* cls_b3 = (const float*)d_in[25];
  const float* dec_w  = (const float*)d_in[26];
  const float* dec_b  = (const float*)d_in[27];
  const float* c3_w   = (const float*)d_in[28];
  const float* c3_b   = (const float*)d_in[29];
  const float* c1_w   = (const float*)d_in[30];
  const float* c1_b   = (const float*)d_in[31];

  float* W = (float*)d_ws;
  float* H            = W;                                  // 4,194,304 f
  unsigned int* ABT   = (unsigned int*)(W + 4194304);       // 2,097,152 u32 (AB / Tp in-place)
  unsigned short* UO  = (unsigned short*)(W + 8388608);     // 4,194,304 sh (P1b/Ub)
  float* R1           = W + 10485760;                       // 8,388,608 f (imat/H0b/ZAb/Y1)
  unsigned short* SbA = (unsigned short*)(W + 18874368);    // 3,145,728 sh
  float* SBa          = W + 20447232;                       // 24,576 f
  unsigned short* taggT = (unsigned short*)(W + 20471808);  // 1,048,576 sh
  unsigned short* mwT1  = (unsigned short*)(W + 20996096);  // 3,145,728 sh
  unsigned short* mwT2  = (unsigned short*)(W + 22568960);  // 3,145,728 sh
  unsigned short* decC  = (unsigned short*)(W + 24141824);  // 1,048,576 sh
  unsigned short* w3t   = (unsigned short*)(W + 24666112);  // 16,384 sh
  unsigned short* btp   = (unsigned short*)(W + 24674304);  // 28,672 sh
  unsigned short* bte   = (unsigned short*)(W + 24688640);  // 32,768 sh
  float* TEMB  = W + 24705024;                              // 2,048
  float* PBP   = W + 24707072;                              // 64
  float* PA    = W + 24707136;                              // 1,024
  float* PB    = W + 24708160;                              // 8,192
  float* GNC   = W + 24716352;                              // 8,192
  float* PARTC = W + 24724544;                              // 32,768
  float* C1    = W + 24757312;                              // 4,096
  float* C2    = W + 24761408;                              // 4,096

  unsigned short* imat = (unsigned short*)R1;
  unsigned short* H0b  = (unsigned short*)R1;
  unsigned short* Y1   = (unsigned short*)R1;
  unsigned short* ZAb  = (unsigned short*)R1;
  unsigned short* P1b = UO;
  unsigned short* Ub  = UO;
  float* out = (float*)d_out;

  // ---- weight prep (once)
  k_cvt_trans<<<dim3(16,64,1),256,0,stream>>>(tagg_w, taggT, 2048, 512, 0, 0);
  k_cvt_trans<<<dim3(16,16,12),256,0,stream>>>(mw1, mwT1, 512, 512, 262144, 262144);
  k_cvt_trans<<<dim3(16,16,12),256,0,stream>>>(mw2, mwT2, 512, 512, 262144, 262144);
  k_cvt<<<4096,256,0,stream>>>(dec_w, decC, 1048576);
  k_prep_w3<<<36,256,0,stream>>>(c3_w, w3t);
  k_prep_btp<<<112,256,0,stream>>>(patch_w, patch_b, btp, PBP);
  k_prep_bte<<<128,256,0,stream>>>(p1_w, bte);
  k_temb<<<8,256,0,stream>>>(gamma, TEMB);
  k_mode_prep_all<<<12288,256,0,stream>>>(aw1, aw2, ab1, ab2, SbA, SBa);

  // ---- encoder
  k_pack<<<8192,256,0,stream>>>(x, imat);
  k_mgemm<1,1,1><<<dim3(1,512),256,0,stream>>>(imat, btp, PBP, P1b,
      nullptr, nullptr, 448, 448, 64, 0, 0, 0, 0);
  k_mgemm<1,0,2><<<dim3(8,512),256,0,stream>>>(P1b, bte, p1_b, H0b,
      pos, TEMB, 64, 64, 512, 0, 0, 0, 0);
  k_bgemm<0,0><<<256,1024,0,stream>>>(H0b, taggT, H, nullptr, nullptr, nullptr,
      nullptr, PA, 2048, 512, 4);

  for (int d = 0; d < 12; ++d) {
    k_dft_a<<<1024,256,0,stream>>>(H, PA, gn1_s + d*512, gn1_b + d*512, ABT);
    k_modes<<<256,512,0,stream>>>(ABT, SbA + (size_t)d*262144, SBa + d*2048);
    k_idft_e<<<1024,256,0,stream>>>(ABT, H, PA, gn1_s + d*512, gn1_b + d*512, ZAb, PB);
    k_gn_coef<<<16,256,0,stream>>>(PB, gn2_s + d*512, gn2_b + d*512, GNC);
    k_bgemm<3,1><<<256,1024,0,stream>>>(ZAb, mwT1 + (size_t)d*262144, nullptr, Ub,
        mb1 + d*512, nullptr, GNC, nullptr, 512, 512, 4);
    if (d < 11)
      k_bgemm<0,2><<<256,1024,0,stream>>>(Ub, mwT2 + (size_t)d*262144, H, nullptr,
          mb2 + d*512, H, nullptr, PA, 512, 512, 4);
    else
      k_bgemm<0,4><<<256,1024,0,stream>>>(Ub, mwT2 + (size_t)d*262144, H, nullptr,
          mb2 + d*512, H, nullptr, PARTC, 512, 512, 4);
  }

  k_cls_l<1><<<dim3(8,8),256,0,stream>>>(PARTC, cls_w1, cls_b1, C1);
  k_cls_l<0><<<dim3(8,8),256,0,stream>>>(C1, cls_w2, cls_b2, C2);
  k_cls3<<<8,768,0,stream>>>(C2, cls_w3, cls_b3, out);
  k_bgemm<1,3><<<1024,1024,0,stream>>>(H, decC, nullptr, Y1,
      dec_b, nullptr, nullptr, nullptr, 512, 0, 16);
  k_tail<<<2048,256,0,stream>>>(Y1, w3t, c1_w, c1_b, out);
}

// Round 11
// 1136.682 us; speedup vs baseline: 3.6951x; 1.0440x over previous
//
#include <hip/hip_runtime.h>
#include <cstddef>

typedef __attribute__((ext_vector_type(8))) short bh8;
typedef __attribute__((ext_vector_type(4))) float f4;

__device__ __forceinline__ float gelu_f(float x){
  return 0.5f * x * (1.0f + erff(x * 0.7071067811865476f));
}

__device__ __forceinline__ unsigned short f2bf(float f){
  unsigned int u = __float_as_uint(f);
  unsigned int r = (u + 0x7FFFu + ((u >> 16) & 1u)) >> 16;
  return (unsigned short)r;
}

__device__ __forceinline__ float bf2f(unsigned short u){
  return __uint_as_float(((unsigned int)u) << 16);
}

__device__ __forceinline__ f4 mfma16(bh8 a, bh8 b, f4 c){
  return __builtin_amdgcn_mfma_f32_16x16x32_bf16(a, b, c, 0, 0, 0);
}

__device__ __forceinline__ void gll16(const unsigned short* src, unsigned short* dst){
  __builtin_amdgcn_global_load_lds(
      (const __attribute__((address_space(1))) unsigned int*)src,
      (__attribute__((address_space(3))) unsigned int*)dst, 16, 0, 0);
}

// gn coef from 8-slice partials PA[(b*8+g)*8+q], s2 at +512
__device__ __forceinline__ void gn_coef8(const float* pa, const float* sc,
                                         const float* bi, int b, int c,
                                         float& sca, float& sh)
{
  const int g = c >> 6;
  float s1 = 0.f, s2 = 0.f;
  #pragma unroll
  for (int q = 0; q < 8; ++q) {
    s1 += pa[(b * 8 + g) * 8 + q];
    s2 += pa[512 + (b * 8 + g) * 8 + q];
  }
  const float mu = s1 * (1.0f / 65536.0f);
  const float var = s2 * (1.0f / 65536.0f) - mu * mu;
  const float rs = rsqrtf(var + 1e-5f);
  sca = sc[c] * rs;
  sh = bi[c] - mu * sca;
}

// ================= big bf16 MFMA GEMM: 128x128 tile, BK=64, 1024 thr (16 waves),
// 2-phase dbuf pipeline, XCD chunk swizzle.
// AMODE: 0=bf16 gll, 1=f32 reg-staged, 2=f32+GN(global gnc), 3=bf16+GN(global gnc),
//        4=bf16 + GN coefs computed in-block from PB (gnc=PB, Res=gn_s, gpart=gn_b).
// OMODE: 0=f32 C + gn-partials; 1=bias+gelu->bf16 OB; 2=bias+Res->f32 C + gn-partials;
//        3=DEC gelu(+bias[col&31]) pixel-scatter; 4=bias+Res->f32 C + cls col-partials.
#define BG_STAGE(dbuf, kofs, BASE, DST) \
  gll16(BASE + (size_t)sr_ * K + (kofs) + ((ss_ ^ (sr_ & 7)) << 3), &DST[dbuf][tid * 8]);

#define BG_LOADA(kofs) { \
  if (AMODE == 3 || AMODE == 4) { \
    const unsigned short* ap16 = Ab16 + (size_t)sr_ * K + (kofs) + ss_ * 8; \
    const uint4 uv = *(const uint4*)ap16; \
    ra0.x = bf2f((unsigned short)(uv.x & 0xffffu)); ra0.y = bf2f((unsigned short)(uv.x >> 16)); \
    ra0.z = bf2f((unsigned short)(uv.y & 0xffffu)); ra0.w = bf2f((unsigned short)(uv.y >> 16)); \
    ra1.x = bf2f((unsigned short)(uv.z & 0xffffu)); ra1.y = bf2f((unsigned short)(uv.z >> 16)); \
    ra1.z = bf2f((unsigned short)(uv.w & 0xffffu)); ra1.w = bf2f((unsigned short)(uv.w >> 16)); \
  } else { \
    const float* ap_ = Afbase + (size_t)sr_ * K + (kofs) + ss_ * 8; \
    ra0 = *(const float4*)ap_; \
    ra1 = *(const float4*)(ap_ + 4); \
  } \
  if (AMODE == 2 || AMODE == 3) { \
    const int bb_ = (m0 + sr_) >> 10; \
    const int ch_ = (kofs) + ss_ * 8; \
    const float4 c0_ = *(const float4*)(gnc + bb_ * 512 + ch_); \
    const float4 c1_ = *(const float4*)(gnc + bb_ * 512 + ch_ + 4); \
    const float4 h0_ = *(const float4*)(gnc + 4096 + bb_ * 512 + ch_); \
    const float4 h1_ = *(const float4*)(gnc + 4096 + bb_ * 512 + ch_ + 4); \
    ra0.x = fmaf(ra0.x, c0_.x, h0_.x); ra0.y = fmaf(ra0.y, c0_.y, h0_.y); \
    ra0.z = fmaf(ra0.z, c0_.z, h0_.z); ra0.w = fmaf(ra0.w, c0_.w, h0_.w); \
    ra1.x = fmaf(ra1.x, c1_.x, h1_.x); ra1.y = fmaf(ra1.y, c1_.y, h1_.y); \
    ra1.z = fmaf(ra1.z, c1_.z, h1_.z); ra1.w = fmaf(ra1.w, c1_.w, h1_.w); \
  } \
  if (AMODE == 4) { \
    const int ch_ = (kofs) + ss_ * 8; \
    const float4 c0_ = *(const float4*)(gncs + ch_); \
    const float4 c1_ = *(const float4*)(gncs + ch_ + 4); \
    const float4 h0_ = *(const float4*)(gncs + 512 + ch_); \
    const float4 h1_ = *(const float4*)(gncs + 512 + ch_ + 4); \
    ra0.x = fmaf(ra0.x, c0_.x, h0_.x); ra0.y = fmaf(ra0.y, c0_.y, h0_.y); \
    ra0.z = fmaf(ra0.z, c0_.z, h0_.z); ra0.w = fmaf(ra0.w, c0_.w, h0_.w); \
    ra1.x = fmaf(ra1.x, c1_.x, h1_.x); ra1.y = fmaf(ra1.y, c1_.y, h1_.y); \
    ra1.z = fmaf(ra1.z, c1_.z, h1_.z); ra1.w = fmaf(ra1.w, c1_.w, h1_.w); \
  } }

#define BG_WRITEA(dbuf) { \
  const int slot_ = ss_ ^ (sr_ & 7); \
  bh8 av_; \
  av_[0] = (short)f2bf(ra0.x); av_[1] = (short)f2bf(ra0.y); \
  av_[2] = (short)f2bf(ra0.z); av_[3] = (short)f2bf(ra0.w); \
  av_[4] = (short)f2bf(ra1.x); av_[5] = (short)f2bf(ra1.y); \
  av_[6] = (short)f2bf(ra1.z); av_[7] = (short)f2bf(ra1.w); \
  *(bh8*)(&As[dbuf][sr_ * 64 + slot_ * 8]) = av_; }

template<int AMODE, int OMODE>
__global__ __launch_bounds__(1024)
void k_bgemm(const void* __restrict__ Av, const unsigned short* __restrict__ Bt,
             float* __restrict__ C, unsigned short* __restrict__ OB,
             const float* __restrict__ bias, const float* __restrict__ Res,
             const float* __restrict__ gnc, float* __restrict__ gpart,
             int K, int ldc, int nn)
{
  __shared__ __align__(16) unsigned short As[2][8192];
  __shared__ __align__(16) unsigned short Bs[2][8192];
  __shared__ __align__(16) float gncs[1024];
  const int bid = blockIdx.x, nwg = gridDim.x;
  const int wg = (bid & 7) * (nwg >> 3) + (bid >> 3);
  const int mb = wg / nn;
  const int m0 = mb * 128, n0 = (wg - mb * nn) * 128;
  const int tid = threadIdx.x;
  const int w = tid >> 6, lane = tid & 63;
  const int lr = lane & 15, lh = lane >> 4;
  const int wr = w >> 2, wc = w & 3;
  const int sr_ = tid >> 3, ss_ = tid & 7;
  const unsigned short* Abase = (const unsigned short*)Av + (size_t)m0 * K;
  const unsigned short* Ab16 = (const unsigned short*)Av + (size_t)m0 * K;
  const float* Afbase = (const float*)Av + (size_t)m0 * K;
  const unsigned short* Bbase = Bt + (size_t)n0 * K;
  float4 ra0, ra1;
  f4 acc[2][2] = {};

  if (AMODE == 4) {
    // compute gn coefs for this block's b from PB (64-slice partials), identical order
    if (tid < 512) {
      const int bq = m0 >> 10, g = tid >> 6;
      float s1 = 0.f, s2 = 0.f;
      #pragma unroll
      for (int q = 0; q < 64; ++q) {
        s1 += gnc[(bq * 8 + g) * 64 + q];
        s2 += gnc[4096 + (bq * 8 + g) * 64 + q];
      }
      const float mu = s1 * (1.0f / 65536.0f);
      const float var = s2 * (1.0f / 65536.0f) - mu * mu;
      const float rs = rsqrtf(var + 1e-5f);
      const float sca = Res[tid] * rs;
      gncs[tid] = sca;
      gncs[512 + tid] = gpart[tid] - mu * sca;
    }
    __syncthreads();
  }

  const int nt = K >> 6;
  if (AMODE == 0) { BG_STAGE(0, 0, Abase, As) }
  else            { BG_LOADA(0) BG_WRITEA(0) }
  BG_STAGE(0, 0, Bbase, Bs)
  __syncthreads();

  for (int t = 0; t < nt; ++t) {
    const int d = t & 1;
    const bool more = (t + 1 < nt);
    if (more) {
      const int kn = (t + 1) << 6;
      if (AMODE == 0) { BG_STAGE(d ^ 1, kn, Abase, As) }
      else            { BG_LOADA(kn) }
      BG_STAGE(d ^ 1, kn, Bbase, Bs)
    }
    #pragma unroll
    for (int kk = 0; kk < 2; ++kk) {
      bh8 af[2], bf[2];
      #pragma unroll
      for (int mi = 0; mi < 2; ++mi) {
        const int R = wr * 32 + mi * 16 + lr;
        af[mi] = *(const bh8*)((const char*)As[d] + R * 128 + (((kk * 4 + lh) ^ (R & 7)) * 16));
      }
      #pragma unroll
      for (int ni = 0; ni < 2; ++ni) {
        const int R = wc * 32 + ni * 16 + lr;
        bf[ni] = *(const bh8*)((const char*)Bs[d] + R * 128 + (((kk * 4 + lh) ^ (R & 7)) * 16));
      }
      #pragma unroll
      for (int mi = 0; mi < 2; ++mi)
        #pragma unroll
        for (int ni = 0; ni < 2; ++ni)
          acc[mi][ni] = mfma16(af[mi], bf[ni], acc[mi][ni]);
    }
    if (more && AMODE != 0) { BG_WRITEA(d ^ 1) }
    __syncthreads();
  }

  float cs1[2], cs2[2];
  #pragma unroll
  for (int ni = 0; ni < 2; ++ni) {
    const int col_l = wc * 32 + ni * 16 + lr;
    const int col = n0 + col_l;
    float bv = 0.f;
    if (OMODE == 1 || OMODE == 2 || OMODE == 4) bv = bias[col];
    if (OMODE == 3) bv = bias[col & 31];
    float s1 = 0.f, s2 = 0.f;
    #pragma unroll
    for (int mi = 0; mi < 2; ++mi) {
      #pragma unroll
      for (int r = 0; r < 4; ++r) {
        const int row = m0 + wr * 32 + mi * 16 + lh * 4 + r;
        float v = acc[mi][ni][r] + bv;
        if (OMODE == 0) {
          C[(size_t)row * ldc + col] = v;
          s1 += v; s2 += v * v;
        } else if (OMODE == 1) {
          OB[(size_t)row * ldc + col] = f2bf(gelu_f(v));
        } else if (OMODE == 2 || OMODE == 4) {
          const size_t ci = (size_t)row * ldc + col;
          v += Res[ci];
          C[ci] = v;
          s1 += v; s2 += v * v;
        } else {
          v = gelu_f(v);
          const int bb = row >> 10, hw = row & 1023, ii = hw >> 5, jj = hw & 31;
          const int dxy = col >> 5, dy = dxy >> 3, dx = dxy & 7, cc = col & 31;
          OB[(((size_t)(bb * 256 + ii * 8 + dy)) * 256 + jj * 8 + dx) * 32 + cc] = f2bf(v);
        }
      }
    }
    cs1[ni] = s1; cs2[ni] = s2;
  }
  if (OMODE == 0 || OMODE == 2 || OMODE == 4) {
    float* sp = (float*)As;
    const int sub = wr * 4 + lh;
    #pragma unroll
    for (int ni = 0; ni < 2; ++ni) {
      const int col_l = wc * 32 + ni * 16 + lr;
      sp[col_l * 16 + sub] = cs1[ni];
      sp[2048 + col_l * 16 + sub] = cs2[ni];
    }
    __syncthreads();
    if (tid < 128) {
      float s1 = 0.f, s2 = 0.f;
      #pragma unroll
      for (int u = 0; u < 16; ++u) { s1 += sp[tid * 16 + u]; s2 += sp[2048 + tid * 16 + u]; }
      const int b = m0 >> 10, slice = (m0 >> 7) & 7;
      if (OMODE == 4) {
        gpart[(b * 8 + slice) * 512 + n0 + tid] = s1;
      } else {
        #pragma unroll
        for (int sft = 32; sft > 0; sft >>= 1) {
          s1 += __shfl_xor(s1, sft, 64);
          s2 += __shfl_xor(s2, sft, 64);
        }
        if ((tid & 63) == 0) {
          const int g = (n0 >> 6) + (tid >> 6);
          gpart[(b * 8 + g) * 8 + slice] = s1;
          gpart[512 + (b * 8 + g) * 8 + slice] = s2;
        }
      }
    }
  }
}

// ================= fused mode pipeline: dft_b + AFNO 2-layer MLP + idft_d.
// block = (b, kh, c-quarter of 128ch = 2 AFNO z-blocks). 68KB LDS -> 2 blocks/CU.
__global__ __launch_bounds__(256)
void k_modes(unsigned int* __restrict__ AB, const unsigned short* __restrict__ Sb_d,
             const float* __restrict__ SB_d)
{
  __shared__ __align__(16) unsigned int ABs[4096];       // 16KB [x][128c]; reused as M2
  __shared__ __align__(16) unsigned short Ws[16384];     // 32KB W single-buffer (swz)
  __shared__ __align__(16) unsigned short Ps[4096];      // 8KB [2cblk][16kw][128] swz
  __shared__ __align__(16) unsigned short O1s[4096];     // 8KB same layout
  __shared__ float ct[512], st[512];                     // 4KB
  unsigned short* M2 = (unsigned short*)ABs;

  const int bx = blockIdx.x;
  const int cq = bx & 3, kh = (bx >> 2) & 15, b = bx >> 6;
  const int tid = threadIdx.x;
  const int w = tid >> 6, lane = tid & 63, lr = lane & 15, lh = lane >> 4;
  unsigned int* ABbase = AB + (((size_t)b * 16 + kh) * 32) * 512 + cq * 128;

  // stage AB slice (linear, 1024 x 16B) + W1[z0] (pre-swizzled source) + trig
  #pragma unroll
  for (int p = 0; p < 4; ++p) {
    const int q = p * 256 + tid;
    const int x = q >> 5, c4 = (q & 31) * 4;
    gll16((const unsigned short*)(ABbase + (size_t)x * 512 + c4),
          (unsigned short*)&ABs[q * 4]);
  }
  {
    const unsigned short* Wsrc = Sb_d + (size_t)(cq * 2) * 16384;
    #pragma unroll
    for (int p = 0; p < 8; ++p) {
      const int q = p * 256 + tid;
      const int r = q >> 4, c = q & 15;
      gll16(Wsrc + r * 128 + ((c ^ (r & 7)) << 3), &Ws[q * 8]);
    }
  }
  for (int q = tid; q < 512; q += 256) {
    const int k = q >> 5, xx = q & 31;
    const float ang = (float)((k * xx) & 31) * 0.19634954084936207f;
    ct[q] = cosf(ang); st[q] = sinf(ang);
  }
  __syncthreads();

  // ---- dft_b: kw modes over x
  const int cc = tid & 127, kwh = tid >> 7;
  {
    float gr[8], gi[8];
    #pragma unroll
    for (int j = 0; j < 8; ++j) { gr[j] = 0.f; gi[j] = 0.f; }
    for (int x = 0; x < 32; ++x) {
      const unsigned int pv = ABs[x * 128 + cc];
      const float vr = bf2f((unsigned short)(pv & 0xffffu));
      const float vi = bf2f((unsigned short)(pv >> 16));
      #pragma unroll
      for (int j = 0; j < 8; ++j) {
        const int kg = kwh * 8 + j;
        const float c_ = ct[kg * 32 + x], s_ = st[kg * 32 + x];
        gr[j] += vr * c_ + vi * s_;
        gi[j] += vi * c_ - vr * s_;
      }
    }
    const int cblk = cc >> 6, ci = cc & 63;
    #pragma unroll
    for (int j = 0; j < 8; ++j) {
      const int kw = kwh * 8 + j;
      const int base = cblk * 2048 + kw * 128;
      const int chr = (ci >> 3) ^ (kw & 7);
      const int chi = ((64 + ci) >> 3) ^ (kw & 7);
      Ps[base + (chr << 3) + (ci & 7)] = f2bf(gr[j] * (1.0f / 32.0f));
      Ps[base + (chi << 3) + (ci & 7)] = f2bf(gi[j] * (1.0f / 32.0f));
    }
  }
  __syncthreads();

  // ---- AFNO: 4 iters (i<2: stage1 cblk=i; i>=2: stage2 cblk=i-2), W single-buffer
  for (int i = 0; i < 4; ++i) {
    const int cblk = i & 1;
    const unsigned short* src = (i < 2) ? Ps : O1s;
    f4 acc[2] = {};
    #pragma unroll
    for (int ks = 0; ks < 4; ++ks) {
      const bh8 a = *(const bh8*)(&src[cblk * 2048 + lr * 128
                      + (((ks * 4 + lh) ^ (lr & 7)) << 3)]);
      #pragma unroll
      for (int j = 0; j < 2; ++j) {
        const int rw = (w * 2 + j) * 16 + lr;
        const bh8 bb = *(const bh8*)(&Ws[rw * 128 + (((ks * 4 + lh) ^ (rw & 7)) << 3)]);
        acc[j] = mfma16(a, bb, acc[j]);
      }
    }
    const int z = cq * 2 + cblk;
    #pragma unroll
    for (int j = 0; j < 2; ++j) {
      const int o = (w * 2 + j) * 16 + lr;
      if (i < 2) {
        const float bv = SB_d[z * 128 + o];
        #pragma unroll
        for (int r = 0; r < 4; ++r) {
          const int kw = lh * 4 + r;
          const int ch = (o >> 3) ^ (kw & 7);
          O1s[cblk * 2048 + kw * 128 + (ch << 3) + (o & 7)] = f2bf(gelu_f(acc[j][r] + bv));
        }
      } else {
        const float bv = SB_d[1024 + z * 128 + o];
        #pragma unroll
        for (int r = 0; r < 4; ++r) {
          const int kw = lh * 4 + r;
          M2[cblk * 2048 + kw * 128 + o] = f2bf(acc[j][r] + bv);
        }
      }
    }
    __syncthreads();
    if (i < 3) {
      const int j2 = i + 1;
      const unsigned short* Wsrc = Sb_d + (j2 >= 2 ? 131072 : 0)
                                 + (size_t)(cq * 2 + (j2 & 1)) * 16384;
      #pragma unroll
      for (int p = 0; p < 8; ++p) {
        const int q = p * 256 + tid;
        const int r = q >> 4, c = q & 15;
        gll16(Wsrc + r * 128 + ((c ^ (r & 7)) << 3), &Ws[q * 8]);
      }
      __syncthreads();
    }
  }

  // ---- idft_d: kw -> x, packed Tp written in-place over AB slice
  {
    const int xh = tid >> 7;
    const int cblk = cc >> 6, ci = cc & 63;
    float gr[16], gi[16];
    #pragma unroll
    for (int kw = 0; kw < 16; ++kw) {
      const float wf = (kw == 0) ? 1.0f : 2.0f;
      gr[kw] = wf * bf2f(M2[cblk * 2048 + kw * 128 + ci]);
      gi[kw] = wf * bf2f(M2[cblk * 2048 + kw * 128 + 64 + ci]);
    }
    for (int x = xh * 16; x < xh * 16 + 16; ++x) {
      float tr = 0.f, ti = 0.f;
      #pragma unroll
      for (int kw = 0; kw < 16; ++kw) {
        const float c_ = ct[kw * 32 + x], s_ = st[kw * 32 + x];
        tr += gr[kw] * c_ - gi[kw] * s_;
        ti += gi[kw] * c_ + gr[kw] * s_;
      }
      ABbase[(size_t)x * 512 + cc] = (unsigned int)f2bf(tr) | ((unsigned int)f2bf(ti) << 16);
    }
  }
}

// ---------------- im2col pack: x -> bf16 imat [32768][448]
__global__ __launch_bounds__(256)
void k_pack(const float* __restrict__ x, unsigned short* __restrict__ imat)
{
  const int nb = blockIdx.x;
  const int j = nb & 31, i = (nb >> 5) & 31, b = nb >> 10;
  const int tid = threadIdx.x;
  const int tl = tid >> 6, px = tid & 63;
  const int dy = px >> 3, dx = px & 7;
  const int Y = i * 8 + dy, X = j * 8 + dx;
  const float4 v = *(const float4*)(x + (((size_t)(b * 256 + Y)) * 256 + X) * 16 + tl * 4);
  const size_t row = (size_t)nb * 4 + tl;
  ushort4 ov;
  ov.x = f2bf(v.x); ov.y = f2bf(v.y); ov.z = f2bf(v.z); ov.w = f2bf(v.w);
  *(ushort4*)(imat + row * 448 + px * 4) = ov;
  for (int q = tid; q < 768; q += 256) {
    const int tt = q / 192, r = q - tt * 192;
    const int sec = r >> 6, p2 = r & 63;
    float val;
    if (sec == 0)      val = (float)(i * 8 + (p2 >> 3)) * (1.0f / 255.0f);
    else if (sec == 1) val = (float)(j * 8 + (p2 & 7)) * (1.0f / 255.0f);
    else               val = (float)tt * (1.0f / 3.0f);
    imat[((size_t)nb * 4 + tt) * 448 + 256 + sec * 64 + p2] = f2bf(val);
  }
}

// ---------------- prep Bt_patch [64][448] (+ padded bias)
__global__ __launch_bounds__(256)
void k_prep_btp(const float* __restrict__ pw, const float* __restrict__ pb,
                unsigned short* __restrict__ btp, float* __restrict__ pbp)
{
  const int idx = blockIdx.x * 256 + threadIdx.x;
  if (idx < 28672) {
    const int n = idx / 448, k = idx - (idx / 448) * 448;
    int l;
    if (k < 256) { const int pxx = k >> 2, c = k & 3; l = pxx * 7 + c; }
    else { const int sec = (k - 256) >> 6, p2 = (k - 256) & 63; l = p2 * 7 + 4 + sec; }
    btp[n * 448 + k] = (n < 35) ? f2bf(pw[l * 35 + n]) : (unsigned short)0;
  }
  if (idx < 64) pbp[idx] = (idx < 35) ? pb[idx] : 0.0f;
}

// ---------------- prep Bt_embed [512][64]
__global__ __launch_bounds__(256)
void k_prep_bte(const float* __restrict__ w, unsigned short* __restrict__ bte)
{
  const int idx = blockIdx.x * 256 + threadIdx.x;
  const int n = idx >> 6, k = idx & 63;
  bte[idx] = (k < 35) ? f2bf(w[k * 512 + n]) : (unsigned short)0;
}

// ---------------- temb table [4][512]
__global__ __launch_bounds__(256)
void k_temb(const float* __restrict__ gamma, float* __restrict__ temb)
{
  const int idx = blockIdx.x * 256 + threadIdx.x;
  const int t = idx >> 9, e = idx & 511;
  temb[idx] = cosf((float)t * (1.0f / 3.0f) * gamma[e]);
}

// ---------------- weight prep: fp32 [K][N] -> bf16 [N][K]
__global__ __launch_bounds__(256)
void k_cvt_trans(const float* __restrict__ in, unsigned short* __restrict__ out,
                 int K, int N, long long sIn, long long sOut)
{
  __shared__ float tile[32][33];
  const int z = blockIdx.z;
  in  += (size_t)z * sIn;
  out += (size_t)z * sOut;
  const int n0 = blockIdx.x * 32, k0 = blockIdx.y * 32;
  const int tx = threadIdx.x & 31, ty = threadIdx.x >> 5;
  #pragma unroll
  for (int i = 0; i < 4; ++i)
    tile[ty + i * 8][tx] = in[(size_t)(k0 + ty + i * 8) * N + n0 + tx];
  __syncthreads();
  #pragma unroll
  for (int i = 0; i < 4; ++i)
    out[(size_t)(n0 + ty + i * 8) * K + k0 + tx] = f2bf(tile[tx][ty + i * 8]);
}

__global__ __launch_bounds__(256)
void k_cvt(const float* __restrict__ in, unsigned short* __restrict__ out, int n)
{
  const int idx = blockIdx.x * 256 + threadIdx.x;
  if (idx < n) out[idx] = f2bf(in[idx]);
}

__global__ __launch_bounds__(256)
void k_prep_w3(const float* __restrict__ w, unsigned short* __restrict__ out)
{
  const int idx = blockIdx.x * 256 + threadIdx.x;
  if (idx < 9216) {
    const int kb = idx >> 10, co = (idx >> 5) & 31, ci = idx & 31;
    out[idx] = f2bf(w[(kb * 32 + ci) * 32 + co]);
  }
}

// ---------------- small bf16 MFMA GEMM, 64x64 tile, z-batched (patch/embed)
template<int BIAS, int GELU, int OMODE>
__global__ __launch_bounds__(256)
void k_mgemm(const unsigned short* __restrict__ A, const unsigned short* __restrict__ Bt,
             const float* __restrict__ bias, unsigned short* __restrict__ OB,
             const float* __restrict__ pos, const float* __restrict__ temb,
             int K, int lda, int ldc,
             long long zsA, long long zsB, long long zsC, int zsBias)
{
  __shared__ __align__(16) unsigned short As[64 * 40];
  __shared__ __align__(16) unsigned short Bs[64 * 40];
  const int z = blockIdx.z;
  A  += (size_t)z * zsA;
  Bt += (size_t)z * zsB;
  if (BIAS) bias += (size_t)z * zsBias;
  OB += (size_t)z * zsC;
  const int m0 = blockIdx.y * 64, n0 = blockIdx.x * 64;
  const int tid = threadIdx.x;
  const int w = tid >> 6, l = tid & 63;
  const int lr = l & 15, lh = l >> 4;
  const int sr = tid >> 2, skq = (tid & 3) * 8;
  f4 acc[4] = {};
  for (int k0 = 0; k0 < K; k0 += 32) {
    const uint4 av = *(const uint4*)(A + (size_t)(m0 + sr) * lda + k0 + skq);
    *(uint4*)(&As[sr * 40 + skq]) = av;
    const uint4 bv = *(const uint4*)(Bt + (size_t)(n0 + sr) * K + k0 + skq);
    *(uint4*)(&Bs[sr * 40 + skq]) = bv;
    __syncthreads();
    const bh8 af = *(const bh8*)(&As[(w * 16 + lr) * 40 + lh * 8]);
    #pragma unroll
    for (int ct = 0; ct < 4; ++ct) {
      const bh8 bf = *(const bh8*)(&Bs[(ct * 16 + lr) * 40 + lh * 8]);
      acc[ct] = mfma16(af, bf, acc[ct]);
    }
    __syncthreads();
  }
  #pragma unroll
  for (int ct = 0; ct < 4; ++ct) {
    const int col = n0 + ct * 16 + lr;
    float bv = 0.f;
    if (BIAS) bv = bias[col];
    #pragma unroll
    for (int r = 0; r < 4; ++r) {
      const int row = m0 + w * 16 + lh * 4 + r;
      float v = acc[ct][r] + bv;
      if (GELU) v = gelu_f(v);
      if (OMODE == 2) {
        const int hw = (row >> 2) & 1023, t = row & 3;
        v = (v + pos[(size_t)hw * 512 + col]) * temb[t * 512 + col];
        OB[(size_t)row * 512 + col] = f2bf(v);
      } else {
        OB[(size_t)row * ldc + col] = f2bf(v);
      }
    }
  }
}

// ---------------- decoder tail: conv3x3 (MFMA) + gelu + 1x1 -> out
__global__ __launch_bounds__(256)
void k_tail(const unsigned short* __restrict__ Y1, const unsigned short* __restrict__ w3t,
            const float* __restrict__ c1w, const float* __restrict__ c1b,
            float* __restrict__ outp)
{
  __shared__ __align__(16) char lbuf[256 * 33 * 4];
  __shared__ float c1s[128];
  unsigned short* it = (unsigned short*)lbuf;
  float* y2 = (float*)lbuf;
  const int bx = blockIdx.x;
  const int b = bx >> 8, ty = (bx >> 4) & 15, tx = bx & 15;
  const int Y0 = ty * 16, X0 = tx * 16;
  const int tid = threadIdx.x;
  const int w = tid >> 6, l = tid & 63, lr = l & 15, lh = l >> 4;

  if (tid < 128) c1s[tid] = c1w[tid];
  for (int idx = tid; idx < 1296; idx += 256) {
    const int r = idx / 72, rem = idx - r * 72, c = rem >> 2, q = rem & 3;
    const int Yg = Y0 + r - 1, Xg = X0 + c - 1;
    uint4 v = make_uint4(0u, 0u, 0u, 0u);
    if (Yg >= 0 && Yg < 256 && Xg >= 0 && Xg < 256)
      v = *(const uint4*)(Y1 + (((size_t)(b * 256 + Yg)) * 256 + Xg) * 32 + q * 8);
    *(uint4*)(&it[(r * 18 + c) * 40 + q * 8]) = v;
  }
  bh8 bw[2][9];
  #pragma unroll
  for (int ct = 0; ct < 2; ++ct)
    #pragma unroll
    for (int kb = 0; kb < 9; ++kb)
      bw[ct][kb] = *(const bh8*)(w3t + (size_t)(kb * 32 + ct * 16 + lr) * 32 + lh * 8);
  __syncthreads();

  f4 acc[4][2] = {};
  #pragma unroll
  for (int kb = 0; kb < 9; ++kb) {
    const int dy = kb / 3, dx = kb % 3;
    #pragma unroll
    for (int yy = 0; yy < 4; ++yy) {
      const int y = w * 4 + yy;
      const bh8 af = *(const bh8*)(&it[((y + dy) * 18 + lr + dx) * 40 + lh * 8]);
      acc[yy][0] = mfma16(af, bw[0][kb], acc[yy][0]);
      acc[yy][1] = mfma16(af, bw[1][kb], acc[yy][1]);
    }
  }
  __syncthreads();
  #pragma unroll
  for (int yy = 0; yy < 4; ++yy) {
    const int y = w * 4 + yy;
    #pragma unroll
    for (int ct = 0; ct < 2; ++ct)
      #pragma unroll
      for (int r = 0; r < 4; ++r)
        y2[(y * 16 + lh * 4 + r) * 33 + ct * 16 + lr] = gelu_f(acc[yy][ct][r]);
  }
  __syncthreads();
  const int py = tid >> 4, px = tid & 15;
  float o0 = c1b[0], o1 = c1b[1], o2 = c1b[2], o3 = c1b[3];
  #pragma unroll 8
  for (int ci = 0; ci < 32; ++ci) {
    const float v = y2[tid * 33 + ci];
    o0 = fmaf(v, c1s[ci * 4 + 0], o0);
    o1 = fmaf(v, c1s[ci * 4 + 1], o1);
    o2 = fmaf(v, c1s[ci * 4 + 2], o2);
    o3 = fmaf(v, c1s[ci * 4 + 3], o3);
  }
  float4 ov; ov.x = o0; ov.y = o1; ov.z = o2; ov.w = o3;
  *(float4*)(outp + (((size_t)(b * 256 + Y0 + py)) * 256 + X0 + px) * 4) = ov;
}

// ---------------- forward DFT stage A (k-split x2) -> packed bf16 AB
__global__ __launch_bounds__(256)
void k_dft_a(const float* __restrict__ H, const float* __restrict__ PA,
             const float* __restrict__ sc, const float* __restrict__ bi,
             unsigned int* __restrict__ AB)
{
  __shared__ float ct[512], st[512];
  const int tid = threadIdx.x;
  for (int q = tid; q < 512; q += 256) {
    const int k = q >> 5, y = q & 31;
    const float ang = (float)((k * y) & 31) * 0.19634954084936207f;
    ct[q] = cosf(ang); st[q] = sinf(ang);
  }
  __syncthreads();
  const int blk = blockIdx.x;                    // b*128 + x*4 + half*2 + kh8
  const int kh8 = blk & 1, half = (blk >> 1) & 1, x = (blk >> 2) & 31, b = blk >> 7;
  const int c = half * 256 + tid;
  float sca, sh;
  gn_coef8(PA, sc, bi, b, c, sca, sh);
  float ar[8], ai[8];
  #pragma unroll
  for (int k = 0; k < 8; ++k) { ar[k] = 0.f; ai[k] = 0.f; }
  const float* zp = H + ((size_t)b * 1024 + x) * 512 + c;
  for (int y = 0; y < 32; ++y) {
    const float v = fmaf(zp[(size_t)y * 32 * 512], sca, sh);
    #pragma unroll
    for (int k = 0; k < 8; ++k) {
      const int kg = kh8 * 8 + k;
      ar[k] = fmaf(v, ct[kg * 32 + y], ar[k]);
      ai[k] = fmaf(-v, st[kg * 32 + y], ai[k]);
    }
  }
  #pragma unroll
  for (int k = 0; k < 8; ++k) {
    const int kg = kh8 * 8 + k;
    const size_t o = (((size_t)b * 16 + kg) * 32 + x) * 512 + c;
    AB[o] = (unsigned int)f2bf(ar[k]) | ((unsigned int)f2bf(ai[k]) << 16);
  }
}

// ---------------- merged AFNO weights for ALL layers
__global__ __launch_bounds__(256)
void k_mode_prep_all(const float* __restrict__ aw1, const float* __restrict__ aw2,
                     const float* __restrict__ ab1, const float* __restrict__ ab2,
                     unsigned short* __restrict__ Sb, float* __restrict__ SB)
{
  const int gi = blockIdx.x * 256 + threadIdx.x;
  const int dd = gi >> 18;
  const int idx = gi & 262143;
  const float* aw1_d = aw1 + (size_t)dd * 65536;
  const float* aw2_d = aw2 + (size_t)dd * 65536;
  const int s = idx >> 17;
  const int blk = (idx >> 14) & 7;
  const int n = (idx >> 7) & 127;
  const int kk = idx & 127;
  const float* aw = s ? aw2_d : aw1_d;
  const int i = kk & 63, o = n & 63;
  const float wr = aw[(blk * 64 + i) * 64 + o];
  const float wi = aw[32768 + (blk * 64 + i) * 64 + o];
  float val;
  if (n < 64) val = (kk < 64) ? wr : -wi;
  else        val = (kk < 64) ? wi :  wr;
  Sb[gi] = f2bf(val);
  if (idx < 2048) {
    const int s2 = idx >> 10, r2 = idx & 1023, b2 = r2 >> 7, q2 = r2 & 127;
    const float* ab = s2 ? (ab2 + dd * 1024) : (ab1 + dd * 1024);
    SB[dd * 2048 + idx] = (q2 < 64) ? ab[b2 * 64 + q2] : ab[512 + b2 * 64 + (q2 - 64)];
  }
}

// ---------------- inverse DFT stage E (y-split x2) + residual + gn2 partials; ZA bf16
__global__ __launch_bounds__(256)
void k_idft_e(const unsigned int* __restrict__ Tp, const float* __restrict__ H,
              const float* __restrict__ PA, const float* __restrict__ sc,
              const float* __restrict__ bi, unsigned short* __restrict__ zab,
              float* __restrict__ PB)
{
  __shared__ float ct[512], st[512];
  const int tid = threadIdx.x;
  for (int q = tid; q < 512; q += 256) {
    const int k = q >> 5, y = q & 31;
    const float ang = (float)((k * y) & 31) * 0.19634954084936207f;
    ct[q] = cosf(ang); st[q] = sinf(ang);
  }
  __syncthreads();
  const int blk = blockIdx.x;                 // b*128 + x*4 + half*2 + yh
  const int yh = blk & 1, half = (blk >> 1) & 1, x = (blk >> 2) & 31, b = blk >> 7;
  const int c = half * 256 + tid;
  float sca, sh;
  gn_coef8(PA, sc, bi, b, c, sca, sh);
  float trv[16], tiv[16];
  #pragma unroll
  for (int k = 0; k < 16; ++k) {
    const size_t o = (((size_t)b * 16 + k) * 32 + x) * 512 + c;
    const unsigned int pv = Tp[o];
    trv[k] = bf2f((unsigned short)(pv & 0xffffu));
    tiv[k] = bf2f((unsigned short)(pv >> 16));
  }
  float s1 = 0.f, s2 = 0.f;
  for (int y = yh * 16; y < yh * 16 + 16; ++y) {
    float v = 0.f;
    #pragma unroll
    for (int k = 0; k < 16; ++k)
      v += trv[k] * ct[k * 32 + y] - tiv[k] * st[k * 32 + y];
    const size_t o = ((size_t)b * 1024 + y * 32 + x) * 512 + c;
    const float zv = v * (1.0f / 32.0f) + fmaf(H[o], sca, sh);
    zab[o] = f2bf(zv);
    s1 += zv; s2 += zv * zv;
  }
  #pragma unroll
  for (int sft = 32; sft > 0; sft >>= 1) {
    s1 += __shfl_xor(s1, sft, 64);
    s2 += __shfl_xor(s2, sft, 64);
  }
  if ((tid & 63) == 0) {
    const int g = half * 4 + (tid >> 6);
    PB[(b * 8 + g) * 64 + x * 2 + yh] = s1;
    PB[4096 + (b * 8 + g) * 64 + x * 2 + yh] = s2;
  }
}

// ---------------- cls layers 1/2 (ILP-4 accumulators)
template<int FIRST>
__global__ __launch_bounds__(256)
void k_cls_l(const float* __restrict__ src, const float* __restrict__ Wm,
             const float* __restrict__ bb, float* __restrict__ Cout)
{
  __shared__ float tok[512];
  __shared__ float red[256];
  const int b = blockIdx.y, oc = blockIdx.x;
  const int tid = threadIdx.x;
  for (int i = tid; i < 512; i += 256) {
    if (FIRST) {
      float s = 0.f;
      #pragma unroll
      for (int q = 0; q < 8; ++q) s += src[((b * 8 + q) << 9) + i];
      tok[i] = s * (1.0f / 1024.0f);
    } else {
      tok[i] = src[b * 512 + i];
    }
  }
  __syncthreads();
  const int to = tid & 63, iq = tid >> 6;
  const int o = oc * 64 + to;
  const float* wp = Wm + (size_t)(iq * 128) * 512 + o;
  const float* tp = tok + iq * 128;
  float a0 = 0.f, a1 = 0.f, a2 = 0.f, a3 = 0.f;
  #pragma unroll 8
  for (int i = 0; i < 128; i += 4) {
    a0 = fmaf(tp[i + 0], wp[(size_t)(i + 0) * 512], a0);
    a1 = fmaf(tp[i + 1], wp[(size_t)(i + 1) * 512], a1);
    a2 = fmaf(tp[i + 2], wp[(size_t)(i + 2) * 512], a2);
    a3 = fmaf(tp[i + 3], wp[(size_t)(i + 3) * 512], a3);
  }
  red[tid] = (a0 + a1) + (a2 + a3);
  __syncthreads();
  if (tid < 64) {
    const int oo = oc * 64 + tid;
    const float v = red[tid] + red[tid + 64] + red[tid + 128] + red[tid + 192] + bb[oo];
    Cout[b * 512 + oo] = gelu_f(v);
  }
}

// ---------------- cls layer 3
__global__ __launch_bounds__(768)
void k_cls3(const float* __restrict__ C2, const float* __restrict__ w3,
            const float* __restrict__ b3, float* __restrict__ outp)
{
  const int b = blockIdx.x, tid = threadIdx.x;
  const int o = tid >> 6, lane = tid & 63;
  float acc = 0.f;
  for (int i = lane; i < 512; i += 64)
    acc = fmaf(C2[b * 512 + i], w3[i * 12 + o], acc);
  #pragma unroll
  for (int s = 32; s > 0; s >>= 1) acc += __shfl_xor(acc, s, 64);
  if (lane == 0) outp[2097152 + b * 12 + o] = acc + b3[o];
}

extern "C" void kernel_launch(void* const* d_in, const int* in_sizes, int n_in,
                              void* d_out, int out_size, void* d_ws, size_t ws_size,
                              hipStream_t stream)
{
  (void)in_sizes; (void)n_in; (void)out_size; (void)ws_size;
  const float* x      = (const float*)d_in[0];
  const float* patch_w= (const float*)d_in[1];
  const float* patch_b= (const float*)d_in[2];
  const float* p1_w   = (const float*)d_in[3];
  const float* p1_b   = (const float*)d_in[4];
  const float* pos    = (const float*)d_in[5];
  const float* tagg_w = (const float*)d_in[6];
  const float* gamma  = (const float*)d_in[7];
  const float* gn1_s  = (const float*)d_in[8];
  const float* gn1_b  = (const float*)d_in[9];
  const float* aw1    = (const float*)d_in[10];
  const float* ab1    = (const float*)d_in[11];
  const float* aw2    = (const float*)d_in[12];
  const float* ab2    = (const float*)d_in[13];
  const float* gn2_s  = (const float*)d_in[14];
  const float* gn2_b  = (const float*)d_in[15];
  const float* mw1    = (const float*)d_in[16];
  const float* mb1    = (const float*)d_in[17];
  const float* mw2    = (const float*)d_in[18];
  const float* mb2    = (const float*)d_in[19];
  const float* cls_w1 = (const float*)d_in[20];
  const float* cls_b1 = (const float*)d_in[21];
  const float* cls_w2 = (const float*)d_in[22];
  const float* cls_b2 = (const float*)d_in[23];
  const float* cls_w3 = (const float*)d_in[24];
  const float* cls_b3 = (const float*)d_in[25];
  const float* dec_w  = (const float*)d_in[26];
  const float* dec_b  = (const float*)d_in[27];
  const float* c3_w   = (const float*)d_in[28];
  const float* c3_b   = (const float*)d_in[29];
  const float* c1_w   = (const float*)d_in[30];
  const float* c1_b   = (const float*)d_in[31];

  float* W = (float*)d_ws;
  float* H            = W;                                  // 4,194,304 f
  unsigned int* ABT   = (unsigned int*)(W + 4194304);       // 2,097,152 u32 (AB / Tp in-place)
  unsigned short* UO  = (unsigned short*)(W + 8388608);     // 4,194,304 sh (P1b/Ub)
  float* R1           = W + 10485760;                       // 8,388,608 f (imat/H0b/ZAb/Y1)
  unsigned short* SbA = (unsigned short*)(W + 18874368);    // 3,145,728 sh
  float* SBa          = W + 20447232;                       // 24,576 f
  unsigned short* taggT = (unsigned short*)(W + 20471808);  // 1,048,576 sh
  unsigned short* mwT1  = (unsigned short*)(W + 20996096);  // 3,145,728 sh
  unsigned short* mwT2  = (unsigned short*)(W + 22568960);  // 3,145,728 sh
  unsigned short* decC  = (unsigned short*)(W + 24141824);  // 1,048,576 sh
  unsigned short* w3t   = (unsigned short*)(W + 24666112);  // 16,384 sh
  unsigned short* btp   = (unsigned short*)(W + 24674304);  // 28,672 sh
  unsigned short* bte   = (unsigned short*)(W + 24688640);  // 32,768 sh
  float* TEMB  = W + 24705024;                              // 2,048
  float* PBP   = W + 24707072;                              // 64
  float* PA    = W + 24707136;                              // 1,024
  float* PB    = W + 24708160;                              // 8,192
  float* PARTC = W + 24716352;                              // 32,768
  float* C1    = W + 24749120;                              // 4,096
  float* C2    = W + 24753216;                              // 4,096

  unsigned short* imat = (unsigned short*)R1;
  unsigned short* H0b  = (unsigned short*)R1;
  unsigned short* Y1   = (unsigned short*)R1;
  unsigned short* ZAb  = (unsigned short*)R1;
  unsigned short* P1b = UO;
  unsigned short* Ub  = UO;
  float* out = (float*)d_out;

  // ---- weight prep (once)
  k_cvt_trans<<<dim3(16,64,1),256,0,stream>>>(tagg_w, taggT, 2048, 512, 0, 0);
  k_cvt_trans<<<dim3(16,16,12),256,0,stream>>>(mw1, mwT1, 512, 512, 262144, 262144);
  k_cvt_trans<<<dim3(16,16,12),256,0,stream>>>(mw2, mwT2, 512, 512, 262144, 262144);
  k_cvt<<<4096,256,0,stream>>>(dec_w, decC, 1048576);
  k_prep_w3<<<36,256,0,stream>>>(c3_w, w3t);
  k_prep_btp<<<112,256,0,stream>>>(patch_w, patch_b, btp, PBP);
  k_prep_bte<<<128,256,0,stream>>>(p1_w, bte);
  k_temb<<<8,256,0,stream>>>(gamma, TEMB);
  k_mode_prep_all<<<12288,256,0,stream>>>(aw1, aw2, ab1, ab2, SbA, SBa);

  // ---- encoder
  k_pack<<<8192,256,0,stream>>>(x, imat);
  k_mgemm<1,1,1><<<dim3(1,512),256,0,stream>>>(imat, btp, PBP, P1b,
      nullptr, nullptr, 448, 448, 64, 0, 0, 0, 0);
  k_mgemm<1,0,2><<<dim3(8,512),256,0,stream>>>(P1b, bte, p1_b, H0b,
      pos, TEMB, 64, 64, 512, 0, 0, 0, 0);
  k_bgemm<0,0><<<256,1024,0,stream>>>(H0b, taggT, H, nullptr, nullptr, nullptr,
      nullptr, PA, 2048, 512, 4);

  for (int d = 0; d < 12; ++d) {
    k_dft_a<<<1024,256,0,stream>>>(H, PA, gn1_s + d*512, gn1_b + d*512, ABT);
    k_modes<<<512,256,0,stream>>>(ABT, SbA + (size_t)d*262144, SBa + d*2048);
    k_idft_e<<<1024,256,0,stream>>>(ABT, H, PA, gn1_s + d*512, gn1_b + d*512, ZAb, PB);
    // mlp1: gn2(ZAb) @ mwT1^T + b -> gelu -> Ub; gn coefs computed in-block from PB
    k_bgemm<4,1><<<256,1024,0,stream>>>(ZAb, mwT1 + (size_t)d*262144, nullptr, Ub,
        mb1 + d*512, gn2_s + d*512, PB, const_cast<float*>(gn2_b) + d*512, 512, 512, 4);
    if (d < 11)
      k_bgemm<0,2><<<256,1024,0,stream>>>(Ub, mwT2 + (size_t)d*262144, H, nullptr,
          mb2 + d*512, H, nullptr, PA, 512, 512, 4);
    else
      k_bgemm<0,4><<<256,1024,0,stream>>>(Ub, mwT2 + (size_t)d*262144, H, nullptr,
          mb2 + d*512, H, nullptr, PARTC, 512, 512, 4);
  }

  k_cls_l<1><<<dim3(8,8),256,0,stream>>>(PARTC, cls_w1, cls_b1, C1);
  k_cls_l<0><<<dim3(8,8),256,0,stream>>>(C1, cls_w2, cls_b2, C2);
  k_cls3<<<8,768,0,stream>>>(C2, cls_w3, cls_b3, out);
  k_bgemm<1,3><<<1024,1024,0,stream>>>(H, decC, nullptr, Y1,
      dec_b, nullptr, nullptr, nullptr, 512, 0, 16);
  k_tail<<<2048,256,0,stream>>>(Y1, w3t, c1_w, c1_b, out);
}

// Round 12
// 953.327 us; speedup vs baseline: 4.4058x; 1.1923x over previous
//
#include <hip/hip_runtime.h>
#include <cstddef>

typedef __attribute__((ext_vector_type(8))) short bh8;
typedef __attribute__((ext_vector_type(4))) float f4;

__device__ __forceinline__ float gelu_f(float x){
  return 0.5f * x * (1.0f + erff(x * 0.7071067811865476f));
}

__device__ __forceinline__ unsigned short f2bf(float f){
  unsigned int u = __float_as_uint(f);
  unsigned int r = (u + 0x7FFFu + ((u >> 16) & 1u)) >> 16;
  return (unsigned short)r;
}

__device__ __forceinline__ float bf2f(unsigned short u){
  return __uint_as_float(((unsigned int)u) << 16);
}

__device__ __forceinline__ f4 mfma16(bh8 a, bh8 b, f4 c){
  return __builtin_amdgcn_mfma_f32_16x16x32_bf16(a, b, c, 0, 0, 0);
}

__device__ __forceinline__ void gll16(const unsigned short* src, unsigned short* dst){
  __builtin_amdgcn_global_load_lds(
      (const __attribute__((address_space(1))) unsigned int*)src,
      (__attribute__((address_space(3))) unsigned int*)dst, 16, 0, 0);
}

// gn coef from 8-slice partials PA[(b*8+g)*8+q], s2 at +512
__device__ __forceinline__ void gn_coef8(const float* pa, const float* sc,
                                         const float* bi, int b, int c,
                                         float& sca, float& sh)
{
  const int g = c >> 6;
  float s1 = 0.f, s2 = 0.f;
  #pragma unroll
  for (int q = 0; q < 8; ++q) {
    s1 += pa[(b * 8 + g) * 8 + q];
    s2 += pa[512 + (b * 8 + g) * 8 + q];
  }
  const float mu = s1 * (1.0f / 65536.0f);
  const float var = s2 * (1.0f / 65536.0f) - mu * mu;
  const float rs = rsqrtf(var + 1e-5f);
  sca = sc[c] * rs;
  sh = bi[c] - mu * sca;
}

// ================= big bf16 MFMA GEMM (unchanged from round 11)
#define BG_STAGE(dbuf, kofs, BASE, DST) \
  gll16(BASE + (size_t)sr_ * K + (kofs) + ((ss_ ^ (sr_ & 7)) << 3), &DST[dbuf][tid * 8]);

#define BG_LOADA(kofs) { \
  if (AMODE == 3 || AMODE == 4) { \
    const unsigned short* ap16 = Ab16 + (size_t)sr_ * K + (kofs) + ss_ * 8; \
    const uint4 uv = *(const uint4*)ap16; \
    ra0.x = bf2f((unsigned short)(uv.x & 0xffffu)); ra0.y = bf2f((unsigned short)(uv.x >> 16)); \
    ra0.z = bf2f((unsigned short)(uv.y & 0xffffu)); ra0.w = bf2f((unsigned short)(uv.y >> 16)); \
    ra1.x = bf2f((unsigned short)(uv.z & 0xffffu)); ra1.y = bf2f((unsigned short)(uv.z >> 16)); \
    ra1.z = bf2f((unsigned short)(uv.w & 0xffffu)); ra1.w = bf2f((unsigned short)(uv.w >> 16)); \
  } else { \
    const float* ap_ = Afbase + (size_t)sr_ * K + (kofs) + ss_ * 8; \
    ra0 = *(const float4*)ap_; \
    ra1 = *(const float4*)(ap_ + 4); \
  } \
  if (AMODE == 2 || AMODE == 3) { \
    const int bb_ = (m0 + sr_) >> 10; \
    const int ch_ = (kofs) + ss_ * 8; \
    const float4 c0_ = *(const float4*)(gnc + bb_ * 512 + ch_); \
    const float4 c1_ = *(const float4*)(gnc + bb_ * 512 + ch_ + 4); \
    const float4 h0_ = *(const float4*)(gnc + 4096 + bb_ * 512 + ch_); \
    const float4 h1_ = *(const float4*)(gnc + 4096 + bb_ * 512 + ch_ + 4); \
    ra0.x = fmaf(ra0.x, c0_.x, h0_.x); ra0.y = fmaf(ra0.y, c0_.y, h0_.y); \
    ra0.z = fmaf(ra0.z, c0_.z, h0_.z); ra0.w = fmaf(ra0.w, c0_.w, h0_.w); \
    ra1.x = fmaf(ra1.x, c1_.x, h1_.x); ra1.y = fmaf(ra1.y, c1_.y, h1_.y); \
    ra1.z = fmaf(ra1.z, c1_.z, h1_.z); ra1.w = fmaf(ra1.w, c1_.w, h1_.w); \
  } \
  if (AMODE == 4) { \
    const int ch_ = (kofs) + ss_ * 8; \
    const float4 c0_ = *(const float4*)(gncs + ch_); \
    const float4 c1_ = *(const float4*)(gncs + ch_ + 4); \
    const float4 h0_ = *(const float4*)(gncs + 512 + ch_); \
    const float4 h1_ = *(const float4*)(gncs + 512 + ch_ + 4); \
    ra0.x = fmaf(ra0.x, c0_.x, h0_.x); ra0.y = fmaf(ra0.y, c0_.y, h0_.y); \
    ra0.z = fmaf(ra0.z, c0_.z, h0_.z); ra0.w = fmaf(ra0.w, c0_.w, h0_.w); \
    ra1.x = fmaf(ra1.x, c1_.x, h1_.x); ra1.y = fmaf(ra1.y, c1_.y, h1_.y); \
    ra1.z = fmaf(ra1.z, c1_.z, h1_.z); ra1.w = fmaf(ra1.w, c1_.w, h1_.w); \
  } }

#define BG_WRITEA(dbuf) { \
  const int slot_ = ss_ ^ (sr_ & 7); \
  bh8 av_; \
  av_[0] = (short)f2bf(ra0.x); av_[1] = (short)f2bf(ra0.y); \
  av_[2] = (short)f2bf(ra0.z); av_[3] = (short)f2bf(ra0.w); \
  av_[4] = (short)f2bf(ra1.x); av_[5] = (short)f2bf(ra1.y); \
  av_[6] = (short)f2bf(ra1.z); av_[7] = (short)f2bf(ra1.w); \
  *(bh8*)(&As[dbuf][sr_ * 64 + slot_ * 8]) = av_; }

template<int AMODE, int OMODE>
__global__ __launch_bounds__(1024)
void k_bgemm(const void* __restrict__ Av, const unsigned short* __restrict__ Bt,
             float* __restrict__ C, unsigned short* __restrict__ OB,
             const float* __restrict__ bias, const float* __restrict__ Res,
             const float* __restrict__ gnc, float* __restrict__ gpart,
             int K, int ldc, int nn)
{
  __shared__ __align__(16) unsigned short As[2][8192];
  __shared__ __align__(16) unsigned short Bs[2][8192];
  __shared__ __align__(16) float gncs[1024];
  const int bid = blockIdx.x, nwg = gridDim.x;
  const int wg = (bid & 7) * (nwg >> 3) + (bid >> 3);
  const int mb = wg / nn;
  const int m0 = mb * 128, n0 = (wg - mb * nn) * 128;
  const int tid = threadIdx.x;
  const int w = tid >> 6, lane = tid & 63;
  const int lr = lane & 15, lh = lane >> 4;
  const int wr = w >> 2, wc = w & 3;
  const int sr_ = tid >> 3, ss_ = tid & 7;
  const unsigned short* Abase = (const unsigned short*)Av + (size_t)m0 * K;
  const unsigned short* Ab16 = (const unsigned short*)Av + (size_t)m0 * K;
  const float* Afbase = (const float*)Av + (size_t)m0 * K;
  const unsigned short* Bbase = Bt + (size_t)n0 * K;
  float4 ra0, ra1;
  f4 acc[2][2] = {};

  if (AMODE == 4) {
    if (tid < 512) {
      const int bq = m0 >> 10, g = tid >> 6;
      float s1 = 0.f, s2 = 0.f;
      #pragma unroll
      for (int q = 0; q < 64; ++q) {
        s1 += gnc[(bq * 8 + g) * 64 + q];
        s2 += gnc[4096 + (bq * 8 + g) * 64 + q];
      }
      const float mu = s1 * (1.0f / 65536.0f);
      const float var = s2 * (1.0f / 65536.0f) - mu * mu;
      const float rs = rsqrtf(var + 1e-5f);
      const float sca = Res[tid] * rs;
      gncs[tid] = sca;
      gncs[512 + tid] = gpart[tid] - mu * sca;
    }
    __syncthreads();
  }

  const int nt = K >> 6;
  if (AMODE == 0) { BG_STAGE(0, 0, Abase, As) }
  else            { BG_LOADA(0) BG_WRITEA(0) }
  BG_STAGE(0, 0, Bbase, Bs)
  __syncthreads();

  for (int t = 0; t < nt; ++t) {
    const int d = t & 1;
    const bool more = (t + 1 < nt);
    if (more) {
      const int kn = (t + 1) << 6;
      if (AMODE == 0) { BG_STAGE(d ^ 1, kn, Abase, As) }
      else            { BG_LOADA(kn) }
      BG_STAGE(d ^ 1, kn, Bbase, Bs)
    }
    #pragma unroll
    for (int kk = 0; kk < 2; ++kk) {
      bh8 af[2], bf[2];
      #pragma unroll
      for (int mi = 0; mi < 2; ++mi) {
        const int R = wr * 32 + mi * 16 + lr;
        af[mi] = *(const bh8*)((const char*)As[d] + R * 128 + (((kk * 4 + lh) ^ (R & 7)) * 16));
      }
      #pragma unroll
      for (int ni = 0; ni < 2; ++ni) {
        const int R = wc * 32 + ni * 16 + lr;
        bf[ni] = *(const bh8*)((const char*)Bs[d] + R * 128 + (((kk * 4 + lh) ^ (R & 7)) * 16));
      }
      #pragma unroll
      for (int mi = 0; mi < 2; ++mi)
        #pragma unroll
        for (int ni = 0; ni < 2; ++ni)
          acc[mi][ni] = mfma16(af[mi], bf[ni], acc[mi][ni]);
    }
    if (more && AMODE != 0) { BG_WRITEA(d ^ 1) }
    __syncthreads();
  }

  float cs1[2], cs2[2];
  #pragma unroll
  for (int ni = 0; ni < 2; ++ni) {
    const int col_l = wc * 32 + ni * 16 + lr;
    const int col = n0 + col_l;
    float bv = 0.f;
    if (OMODE == 1 || OMODE == 2 || OMODE == 4) bv = bias[col];
    if (OMODE == 3) bv = bias[col & 31];
    float s1 = 0.f, s2 = 0.f;
    #pragma unroll
    for (int mi = 0; mi < 2; ++mi) {
      #pragma unroll
      for (int r = 0; r < 4; ++r) {
        const int row = m0 + wr * 32 + mi * 16 + lh * 4 + r;
        float v = acc[mi][ni][r] + bv;
        if (OMODE == 0) {
          C[(size_t)row * ldc + col] = v;
          s1 += v; s2 += v * v;
        } else if (OMODE == 1) {
          OB[(size_t)row * ldc + col] = f2bf(gelu_f(v));
        } else if (OMODE == 2 || OMODE == 4) {
          const size_t ci = (size_t)row * ldc + col;
          v += Res[ci];
          C[ci] = v;
          s1 += v; s2 += v * v;
        } else {
          v = gelu_f(v);
          const int bb = row >> 10, hw = row & 1023, ii = hw >> 5, jj = hw & 31;
          const int dxy = col >> 5, dy = dxy >> 3, dx = dxy & 7, cc = col & 31;
          OB[(((size_t)(bb * 256 + ii * 8 + dy)) * 256 + jj * 8 + dx) * 32 + cc] = f2bf(v);
        }
      }
    }
    cs1[ni] = s1; cs2[ni] = s2;
  }
  if (OMODE == 0 || OMODE == 2 || OMODE == 4) {
    float* sp = (float*)As;
    const int sub = wr * 4 + lh;
    #pragma unroll
    for (int ni = 0; ni < 2; ++ni) {
      const int col_l = wc * 32 + ni * 16 + lr;
      sp[col_l * 16 + sub] = cs1[ni];
      sp[2048 + col_l * 16 + sub] = cs2[ni];
    }
    __syncthreads();
    if (tid < 128) {
      float s1 = 0.f, s2 = 0.f;
      #pragma unroll
      for (int u = 0; u < 16; ++u) { s1 += sp[tid * 16 + u]; s2 += sp[2048 + tid * 16 + u]; }
      const int b = m0 >> 10, slice = (m0 >> 7) & 7;
      if (OMODE == 4) {
        gpart[(b * 8 + slice) * 512 + n0 + tid] = s1;
      } else {
        #pragma unroll
        for (int sft = 32; sft > 0; sft >>= 1) {
          s1 += __shfl_xor(s1, sft, 64);
          s2 += __shfl_xor(s2, sft, 64);
        }
        if ((tid & 63) == 0) {
          const int g = (n0 >> 6) + (tid >> 6);
          gpart[(b * 8 + g) * 8 + slice] = s1;
          gpart[512 + (b * 8 + g) * 8 + slice] = s2;
        }
      }
    }
  }
}

// ================= fused mode pipeline: dft_b + AFNO MLP + idft_d (radix-2 DFTs)
__global__ __launch_bounds__(256)
void k_modes(unsigned int* __restrict__ AB, const unsigned short* __restrict__ Sb_d,
             const float* __restrict__ SB_d)
{
  __shared__ __align__(16) unsigned int ABs[4096];       // 16KB [x][128c]; reused as M2
  __shared__ __align__(16) unsigned short Ws[16384];     // 32KB W single-buffer (swz)
  __shared__ __align__(16) unsigned short Ps[4096];      // 8KB [2cblk][16kw][128] swz
  __shared__ __align__(16) unsigned short O1s[4096];     // 8KB same layout
  __shared__ float ct[512], st[512];                     // 4KB
  unsigned short* M2 = (unsigned short*)ABs;

  const int bx = blockIdx.x;
  const int cq = bx & 3, kh = (bx >> 2) & 15, b = bx >> 6;
  const int tid = threadIdx.x;
  const int w = tid >> 6, lane = tid & 63, lr = lane & 15, lh = lane >> 4;
  unsigned int* ABbase = AB + (((size_t)b * 16 + kh) * 32) * 512 + cq * 128;

  #pragma unroll
  for (int p = 0; p < 4; ++p) {
    const int q = p * 256 + tid;
    const int x = q >> 5, c4 = (q & 31) * 4;
    gll16((const unsigned short*)(ABbase + (size_t)x * 512 + c4),
          (unsigned short*)&ABs[q * 4]);
  }
  {
    const unsigned short* Wsrc = Sb_d + (size_t)(cq * 2) * 16384;
    #pragma unroll
    for (int p = 0; p < 8; ++p) {
      const int q = p * 256 + tid;
      const int r = q >> 4, c = q & 15;
      gll16(Wsrc + r * 128 + ((c ^ (r & 7)) << 3), &Ws[q * 8]);
    }
  }
  for (int q = tid; q < 512; q += 256) {
    const int k = q >> 5, xx = q & 31;
    const float ang = (float)((k * xx) & 31) * 0.19634954084936207f;
    ct[q] = cosf(ang); st[q] = sinf(ang);
  }
  __syncthreads();

  // ---- dft_b (radix-2): kp2 selects kw parity; pair (x, x+16)
  const int cc = tid & 127, kp2 = tid >> 7;
  {
    float gr[8], gi[8];
    #pragma unroll
    for (int j = 0; j < 8; ++j) { gr[j] = 0.f; gi[j] = 0.f; }
    for (int x = 0; x < 16; ++x) {
      const unsigned int p1 = ABs[x * 128 + cc];
      const unsigned int p2 = ABs[(x + 16) * 128 + cc];
      const float vr1 = bf2f((unsigned short)(p1 & 0xffffu));
      const float vi1 = bf2f((unsigned short)(p1 >> 16));
      const float vr2 = bf2f((unsigned short)(p2 & 0xffffu));
      const float vi2 = bf2f((unsigned short)(p2 >> 16));
      const float vr = kp2 ? (vr1 - vr2) : (vr1 + vr2);
      const float vi = kp2 ? (vi1 - vi2) : (vi1 + vi2);
      #pragma unroll
      for (int j = 0; j < 8; ++j) {
        const int kg = 2 * j + kp2;
        const float c_ = ct[kg * 32 + x], s_ = st[kg * 32 + x];
        gr[j] += vr * c_ + vi * s_;
        gi[j] += vi * c_ - vr * s_;
      }
    }
    const int cblk = cc >> 6, ci = cc & 63;
    #pragma unroll
    for (int j = 0; j < 8; ++j) {
      const int kw = 2 * j + kp2;
      const int base = cblk * 2048 + kw * 128;
      const int chr = (ci >> 3) ^ (kw & 7);
      const int chi = ((64 + ci) >> 3) ^ (kw & 7);
      Ps[base + (chr << 3) + (ci & 7)] = f2bf(gr[j] * (1.0f / 32.0f));
      Ps[base + (chi << 3) + (ci & 7)] = f2bf(gi[j] * (1.0f / 32.0f));
    }
  }
  __syncthreads();

  // ---- AFNO: 4 iters, W single-buffer (unchanged)
  for (int i = 0; i < 4; ++i) {
    const int cblk = i & 1;
    const unsigned short* src = (i < 2) ? Ps : O1s;
    f4 acc[2] = {};
    #pragma unroll
    for (int ks = 0; ks < 4; ++ks) {
      const bh8 a = *(const bh8*)(&src[cblk * 2048 + lr * 128
                      + (((ks * 4 + lh) ^ (lr & 7)) << 3)]);
      #pragma unroll
      for (int j = 0; j < 2; ++j) {
        const int rw = (w * 2 + j) * 16 + lr;
        const bh8 bb = *(const bh8*)(&Ws[rw * 128 + (((ks * 4 + lh) ^ (rw & 7)) << 3)]);
        acc[j] = mfma16(a, bb, acc[j]);
      }
    }
    const int z = cq * 2 + cblk;
    #pragma unroll
    for (int j = 0; j < 2; ++j) {
      const int o = (w * 2 + j) * 16 + lr;
      if (i < 2) {
        const float bv = SB_d[z * 128 + o];
        #pragma unroll
        for (int r = 0; r < 4; ++r) {
          const int kw = lh * 4 + r;
          const int ch = (o >> 3) ^ (kw & 7);
          O1s[cblk * 2048 + kw * 128 + (ch << 3) + (o & 7)] = f2bf(gelu_f(acc[j][r] + bv));
        }
      } else {
        const float bv = SB_d[1024 + z * 128 + o];
        #pragma unroll
        for (int r = 0; r < 4; ++r) {
          const int kw = lh * 4 + r;
          M2[cblk * 2048 + kw * 128 + o] = f2bf(acc[j][r] + bv);
        }
      }
    }
    __syncthreads();
    if (i < 3) {
      const int j2 = i + 1;
      const unsigned short* Wsrc = Sb_d + (j2 >= 2 ? 131072 : 0)
                                 + (size_t)(cq * 2 + (j2 & 1)) * 16384;
      #pragma unroll
      for (int p = 0; p < 8; ++p) {
        const int q = p * 256 + tid;
        const int r = q >> 4, c = q & 15;
        gll16(Wsrc + r * 128 + ((c ^ (r & 7)) << 3), &Ws[q * 8]);
      }
      __syncthreads();
    }
  }

  // ---- idft_d (radix-2): pair outputs (x, x+16); even/odd kw split sums
  {
    const int xh = tid >> 7;
    const int cblk = cc >> 6, ci = cc & 63;
    float gr[16], gi[16];
    #pragma unroll
    for (int kw = 0; kw < 16; ++kw) {
      const float wf = (kw == 0) ? 1.0f : 2.0f;
      gr[kw] = wf * bf2f(M2[cblk * 2048 + kw * 128 + ci]);
      gi[kw] = wf * bf2f(M2[cblk * 2048 + kw * 128 + 64 + ci]);
    }
    for (int x = xh * 8; x < xh * 8 + 8; ++x) {
      float Er = 0.f, Ei = 0.f, Or = 0.f, Oi = 0.f;
      #pragma unroll
      for (int j = 0; j < 8; ++j) {
        const int ke = 2 * j, ko = 2 * j + 1;
        const float ce = ct[ke * 32 + x], se = st[ke * 32 + x];
        const float co = ct[ko * 32 + x], so = st[ko * 32 + x];
        Er += gr[ke] * ce - gi[ke] * se;
        Ei += gi[ke] * ce + gr[ke] * se;
        Or += gr[ko] * co - gi[ko] * so;
        Oi += gi[ko] * co + gr[ko] * so;
      }
      ABbase[(size_t)x * 512 + cc] =
          (unsigned int)f2bf(Er + Or) | ((unsigned int)f2bf(Ei + Oi) << 16);
      ABbase[(size_t)(x + 16) * 512 + cc] =
          (unsigned int)f2bf(Er - Or) | ((unsigned int)f2bf(Ei - Oi) << 16);
    }
  }
}

// ---------------- im2col pack: x -> bf16 imat [32768][448]
__global__ __launch_bounds__(256)
void k_pack(const float* __restrict__ x, unsigned short* __restrict__ imat)
{
  const int nb = blockIdx.x;
  const int j = nb & 31, i = (nb >> 5) & 31, b = nb >> 10;
  const int tid = threadIdx.x;
  const int tl = tid >> 6, px = tid & 63;
  const int dy = px >> 3, dx = px & 7;
  const int Y = i * 8 + dy, X = j * 8 + dx;
  const float4 v = *(const float4*)(x + (((size_t)(b * 256 + Y)) * 256 + X) * 16 + tl * 4);
  const size_t row = (size_t)nb * 4 + tl;
  ushort4 ov;
  ov.x = f2bf(v.x); ov.y = f2bf(v.y); ov.z = f2bf(v.z); ov.w = f2bf(v.w);
  *(ushort4*)(imat + row * 448 + px * 4) = ov;
  for (int q = tid; q < 768; q += 256) {
    const int tt = q / 192, r = q - tt * 192;
    const int sec = r >> 6, p2 = r & 63;
    float val;
    if (sec == 0)      val = (float)(i * 8 + (p2 >> 3)) * (1.0f / 255.0f);
    else if (sec == 1) val = (float)(j * 8 + (p2 & 7)) * (1.0f / 255.0f);
    else               val = (float)tt * (1.0f / 3.0f);
    imat[((size_t)nb * 4 + tt) * 448 + 256 + sec * 64 + p2] = f2bf(val);
  }
}

// ---------------- prep Bt_patch [64][448] (+ padded bias)
__global__ __launch_bounds__(256)
void k_prep_btp(const float* __restrict__ pw, const float* __restrict__ pb,
                unsigned short* __restrict__ btp, float* __restrict__ pbp)
{
  const int idx = blockIdx.x * 256 + threadIdx.x;
  if (idx < 28672) {
    const int n = idx / 448, k = idx - (idx / 448) * 448;
    int l;
    if (k < 256) { const int pxx = k >> 2, c = k & 3; l = pxx * 7 + c; }
    else { const int sec = (k - 256) >> 6, p2 = (k - 256) & 63; l = p2 * 7 + 4 + sec; }
    btp[n * 448 + k] = (n < 35) ? f2bf(pw[l * 35 + n]) : (unsigned short)0;
  }
  if (idx < 64) pbp[idx] = (idx < 35) ? pb[idx] : 0.0f;
}

// ---------------- prep Bt_embed [512][64]
__global__ __launch_bounds__(256)
void k_prep_bte(const float* __restrict__ w, unsigned short* __restrict__ bte)
{
  const int idx = blockIdx.x * 256 + threadIdx.x;
  const int n = idx >> 6, k = idx & 63;
  bte[idx] = (k < 35) ? f2bf(w[k * 512 + n]) : (unsigned short)0;
}

// ---------------- temb table [4][512]
__global__ __launch_bounds__(256)
void k_temb(const float* __restrict__ gamma, float* __restrict__ temb)
{
  const int idx = blockIdx.x * 256 + threadIdx.x;
  const int t = idx >> 9, e = idx & 511;
  temb[idx] = cosf((float)t * (1.0f / 3.0f) * gamma[e]);
}

// ---------------- weight prep: fp32 [K][N] -> bf16 [N][K]
__global__ __launch_bounds__(256)
void k_cvt_trans(const float* __restrict__ in, unsigned short* __restrict__ out,
                 int K, int N, long long sIn, long long sOut)
{
  __shared__ float tile[32][33];
  const int z = blockIdx.z;
  in  += (size_t)z * sIn;
  out += (size_t)z * sOut;
  const int n0 = blockIdx.x * 32, k0 = blockIdx.y * 32;
  const int tx = threadIdx.x & 31, ty = threadIdx.x >> 5;
  #pragma unroll
  for (int i = 0; i < 4; ++i)
    tile[ty + i * 8][tx] = in[(size_t)(k0 + ty + i * 8) * N + n0 + tx];
  __syncthreads();
  #pragma unroll
  for (int i = 0; i < 4; ++i)
    out[(size_t)(n0 + ty + i * 8) * K + k0 + tx] = f2bf(tile[tx][ty + i * 8]);
}

__global__ __launch_bounds__(256)
void k_cvt(const float* __restrict__ in, unsigned short* __restrict__ out, int n)
{
  const int idx = blockIdx.x * 256 + threadIdx.x;
  if (idx < n) out[idx] = f2bf(in[idx]);
}

__global__ __launch_bounds__(256)
void k_prep_w3(const float* __restrict__ w, unsigned short* __restrict__ out)
{
  const int idx = blockIdx.x * 256 + threadIdx.x;
  if (idx < 9216) {
    const int kb = idx >> 10, co = (idx >> 5) & 31, ci = idx & 31;
    out[idx] = f2bf(w[(kb * 32 + ci) * 32 + co]);
  }
}

// ---------------- small bf16 MFMA GEMM, 64x64 tile, z-batched (patch/embed)
template<int BIAS, int GELU, int OMODE>
__global__ __launch_bounds__(256)
void k_mgemm(const unsigned short* __restrict__ A, const unsigned short* __restrict__ Bt,
             const float* __restrict__ bias, unsigned short* __restrict__ OB,
             const float* __restrict__ pos, const float* __restrict__ temb,
             int K, int lda, int ldc,
             long long zsA, long long zsB, long long zsC, int zsBias)
{
  __shared__ __align__(16) unsigned short As[64 * 40];
  __shared__ __align__(16) unsigned short Bs[64 * 40];
  const int z = blockIdx.z;
  A  += (size_t)z * zsA;
  Bt += (size_t)z * zsB;
  if (BIAS) bias += (size_t)z * zsBias;
  OB += (size_t)z * zsC;
  const int m0 = blockIdx.y * 64, n0 = blockIdx.x * 64;
  const int tid = threadIdx.x;
  const int w = tid >> 6, l = tid & 63;
  const int lr = l & 15, lh = l >> 4;
  const int sr = tid >> 2, skq = (tid & 3) * 8;
  f4 acc[4] = {};
  for (int k0 = 0; k0 < K; k0 += 32) {
    const uint4 av = *(const uint4*)(A + (size_t)(m0 + sr) * lda + k0 + skq);
    *(uint4*)(&As[sr * 40 + skq]) = av;
    const uint4 bv = *(const uint4*)(Bt + (size_t)(n0 + sr) * K + k0 + skq);
    *(uint4*)(&Bs[sr * 40 + skq]) = bv;
    __syncthreads();
    const bh8 af = *(const bh8*)(&As[(w * 16 + lr) * 40 + lh * 8]);
    #pragma unroll
    for (int ct = 0; ct < 4; ++ct) {
      const bh8 bf = *(const bh8*)(&Bs[(ct * 16 + lr) * 40 + lh * 8]);
      acc[ct] = mfma16(af, bf, acc[ct]);
    }
    __syncthreads();
  }
  #pragma unroll
  for (int ct = 0; ct < 4; ++ct) {
    const int col = n0 + ct * 16 + lr;
    float bv = 0.f;
    if (BIAS) bv = bias[col];
    #pragma unroll
    for (int r = 0; r < 4; ++r) {
      const int row = m0 + w * 16 + lh * 4 + r;
      float v = acc[ct][r] + bv;
      if (GELU) v = gelu_f(v);
      if (OMODE == 2) {
        const int hw = (row >> 2) & 1023, t = row & 3;
        v = (v + pos[(size_t)hw * 512 + col]) * temb[t * 512 + col];
        OB[(size_t)row * 512 + col] = f2bf(v);
      } else {
        OB[(size_t)row * ldc + col] = f2bf(v);
      }
    }
  }
}

// ---------------- decoder tail: conv3x3 (MFMA) + gelu + 1x1 -> out
__global__ __launch_bounds__(256)
void k_tail(const unsigned short* __restrict__ Y1, const unsigned short* __restrict__ w3t,
            const float* __restrict__ c1w, const float* __restrict__ c1b,
            float* __restrict__ outp)
{
  __shared__ __align__(16) char lbuf[256 * 33 * 4];
  __shared__ float c1s[128];
  unsigned short* it = (unsigned short*)lbuf;
  float* y2 = (float*)lbuf;
  const int bx = blockIdx.x;
  const int b = bx >> 8, ty = (bx >> 4) & 15, tx = bx & 15;
  const int Y0 = ty * 16, X0 = tx * 16;
  const int tid = threadIdx.x;
  const int w = tid >> 6, l = tid & 63, lr = l & 15, lh = l >> 4;

  if (tid < 128) c1s[tid] = c1w[tid];
  for (int idx = tid; idx < 1296; idx += 256) {
    const int r = idx / 72, rem = idx - r * 72, c = rem >> 2, q = rem & 3;
    const int Yg = Y0 + r - 1, Xg = X0 + c - 1;
    uint4 v = make_uint4(0u, 0u, 0u, 0u);
    if (Yg >= 0 && Yg < 256 && Xg >= 0 && Xg < 256)
      v = *(const uint4*)(Y1 + (((size_t)(b * 256 + Yg)) * 256 + Xg) * 32 + q * 8);
    *(uint4*)(&it[(r * 18 + c) * 40 + q * 8]) = v;
  }
  bh8 bw[2][9];
  #pragma unroll
  for (int ct = 0; ct < 2; ++ct)
    #pragma unroll
    for (int kb = 0; kb < 9; ++kb)
      bw[ct][kb] = *(const bh8*)(w3t + (size_t)(kb * 32 + ct * 16 + lr) * 32 + lh * 8);
  __syncthreads();

  f4 acc[4][2] = {};
  #pragma unroll
  for (int kb = 0; kb < 9; ++kb) {
    const int dy = kb / 3, dx = kb % 3;
    #pragma unroll
    for (int yy = 0; yy < 4; ++yy) {
      const int y = w * 4 + yy;
      const bh8 af = *(const bh8*)(&it[((y + dy) * 18 + lr + dx) * 40 + lh * 8]);
      acc[yy][0] = mfma16(af, bw[0][kb], acc[yy][0]);
      acc[yy][1] = mfma16(af, bw[1][kb], acc[yy][1]);
    }
  }
  __syncthreads();
  #pragma unroll
  for (int yy = 0; yy < 4; ++yy) {
    const int y = w * 4 + yy;
    #pragma unroll
    for (int ct = 0; ct < 2; ++ct)
      #pragma unroll
      for (int r = 0; r < 4; ++r)
        y2[(y * 16 + lh * 4 + r) * 33 + ct * 16 + lr] = gelu_f(acc[yy][ct][r]);
  }
  __syncthreads();
  const int py = tid >> 4, px = tid & 15;
  float o0 = c1b[0], o1 = c1b[1], o2 = c1b[2], o3 = c1b[3];
  #pragma unroll 8
  for (int ci = 0; ci < 32; ++ci) {
    const float v = y2[tid * 33 + ci];
    o0 = fmaf(v, c1s[ci * 4 + 0], o0);
    o1 = fmaf(v, c1s[ci * 4 + 1], o1);
    o2 = fmaf(v, c1s[ci * 4 + 2], o2);
    o3 = fmaf(v, c1s[ci * 4 + 3], o3);
  }
  float4 ov; ov.x = o0; ov.y = o1; ov.z = o2; ov.w = o3;
  *(float4*)(outp + (((size_t)(b * 256 + Y0 + py)) * 256 + X0 + px) * 4) = ov;
}

// ---------------- forward DFT stage A (radix-2; kp = k parity) -> packed bf16 AB
__global__ __launch_bounds__(256)
void k_dft_a(const float* __restrict__ H, const float* __restrict__ PA,
             const float* __restrict__ sc, const float* __restrict__ bi,
             unsigned int* __restrict__ AB)
{
  __shared__ float ct[512], st[512];
  const int tid = threadIdx.x;
  for (int q = tid; q < 512; q += 256) {
    const int k = q >> 5, y = q & 31;
    const float ang = (float)((k * y) & 31) * 0.19634954084936207f;
    ct[q] = cosf(ang); st[q] = sinf(ang);
  }
  __syncthreads();
  const int blk = blockIdx.x;                    // b*128 + x*4 + half*2 + kp
  const int kp = blk & 1, half = (blk >> 1) & 1, x = (blk >> 2) & 31, b = blk >> 7;
  const int c = half * 256 + tid;
  float sca, sh;
  gn_coef8(PA, sc, bi, b, c, sca, sh);
  float ar[8], ai[8];
  #pragma unroll
  for (int k = 0; k < 8; ++k) { ar[k] = 0.f; ai[k] = 0.f; }
  const float* zp = H + ((size_t)b * 1024 + x) * 512 + c;
  for (int y = 0; y < 16; ++y) {
    const float u  = fmaf(zp[(size_t)y * 16384], sca, sh);
    const float w2 = fmaf(zp[(size_t)(y + 16) * 16384], sca, sh);
    const float v = kp ? (u - w2) : (u + w2);
    #pragma unroll
    for (int k = 0; k < 8; ++k) {
      const int kg = 2 * k + kp;
      ar[k] = fmaf(v, ct[kg * 32 + y], ar[k]);
      ai[k] = fmaf(-v, st[kg * 32 + y], ai[k]);
    }
  }
  #pragma unroll
  for (int k = 0; k < 8; ++k) {
    const int kg = 2 * k + kp;
    const size_t o = (((size_t)b * 16 + kg) * 32 + x) * 512 + c;
    AB[o] = (unsigned int)f2bf(ar[k]) | ((unsigned int)f2bf(ai[k]) << 16);
  }
}

// ---------------- merged AFNO weights for ALL layers
__global__ __launch_bounds__(256)
void k_mode_prep_all(const float* __restrict__ aw1, const float* __restrict__ aw2,
                     const float* __restrict__ ab1, const float* __restrict__ ab2,
                     unsigned short* __restrict__ Sb, float* __restrict__ SB)
{
  const int gi = blockIdx.x * 256 + threadIdx.x;
  const int dd = gi >> 18;
  const int idx = gi & 262143;
  const float* aw1_d = aw1 + (size_t)dd * 65536;
  const float* aw2_d = aw2 + (size_t)dd * 65536;
  const int s = idx >> 17;
  const int blk = (idx >> 14) & 7;
  const int n = (idx >> 7) & 127;
  const int kk = idx & 127;
  const float* aw = s ? aw2_d : aw1_d;
  const int i = kk & 63, o = n & 63;
  const float wr = aw[(blk * 64 + i) * 64 + o];
  const float wi = aw[32768 + (blk * 64 + i) * 64 + o];
  float val;
  if (n < 64) val = (kk < 64) ? wr : -wi;
  else        val = (kk < 64) ? wi :  wr;
  Sb[gi] = f2bf(val);
  if (idx < 2048) {
    const int s2 = idx >> 10, r2 = idx & 1023, b2 = r2 >> 7, q2 = r2 & 127;
    const float* ab = s2 ? (ab2 + dd * 1024) : (ab1 + dd * 1024);
    SB[dd * 2048 + idx] = (q2 < 64) ? ab[b2 * 64 + q2] : ab[512 + b2 * 64 + (q2 - 64)];
  }
}

// ---------------- inverse DFT stage E (radix-2 y-pairs) + residual + gn2 partials
__global__ __launch_bounds__(256)
void k_idft_e(const unsigned int* __restrict__ Tp, const float* __restrict__ H,
              const float* __restrict__ PA, const float* __restrict__ sc,
              const float* __restrict__ bi, unsigned short* __restrict__ zab,
              float* __restrict__ PB)
{
  __shared__ float ct[512], st[512];
  const int tid = threadIdx.x;
  for (int q = tid; q < 512; q += 256) {
    const int k = q >> 5, y = q & 31;
    const float ang = (float)((k * y) & 31) * 0.19634954084936207f;
    ct[q] = cosf(ang); st[q] = sinf(ang);
  }
  __syncthreads();
  const int blk = blockIdx.x;                 // b*128 + x*4 + half*2 + yh
  const int yh = blk & 1, half = (blk >> 1) & 1, x = (blk >> 2) & 31, b = blk >> 7;
  const int c = half * 256 + tid;
  float sca, sh;
  gn_coef8(PA, sc, bi, b, c, sca, sh);
  float trv[16], tiv[16];
  #pragma unroll
  for (int k = 0; k < 16; ++k) {
    const size_t o = (((size_t)b * 16 + k) * 32 + x) * 512 + c;
    const unsigned int pv = Tp[o];
    trv[k] = bf2f((unsigned short)(pv & 0xffffu));
    tiv[k] = bf2f((unsigned short)(pv >> 16));
  }
  float s1 = 0.f, s2 = 0.f;
  for (int y = yh * 8; y < yh * 8 + 8; ++y) {
    float Ev = 0.f, Ov = 0.f;
    #pragma unroll
    for (int j = 0; j < 8; ++j) {
      const int ke = 2 * j, ko = 2 * j + 1;
      Ev += trv[ke] * ct[ke * 32 + y] - tiv[ke] * st[ke * 32 + y];
      Ov += trv[ko] * ct[ko * 32 + y] - tiv[ko] * st[ko * 32 + y];
    }
    const size_t o1 = ((size_t)b * 1024 + y * 32 + x) * 512 + c;
    const size_t o2 = ((size_t)b * 1024 + (y + 16) * 32 + x) * 512 + c;
    const float zv1 = (Ev + Ov) * (1.0f / 32.0f) + fmaf(H[o1], sca, sh);
    const float zv2 = (Ev - Ov) * (1.0f / 32.0f) + fmaf(H[o2], sca, sh);
    zab[o1] = f2bf(zv1);
    zab[o2] = f2bf(zv2);
    s1 += zv1 + zv2; s2 += zv1 * zv1 + zv2 * zv2;
  }
  #pragma unroll
  for (int sft = 32; sft > 0; sft >>= 1) {
    s1 += __shfl_xor(s1, sft, 64);
    s2 += __shfl_xor(s2, sft, 64);
  }
  if ((tid & 63) == 0) {
    const int g = half * 4 + (tid >> 6);
    PB[(b * 8 + g) * 64 + x * 2 + yh] = s1;
    PB[4096 + (b * 8 + g) * 64 + x * 2 + yh] = s2;
  }
}

// ---------------- cls layers 1/2 (ILP-4 accumulators)
template<int FIRST>
__global__ __launch_bounds__(256)
void k_cls_l(const float* __restrict__ src, const float* __restrict__ Wm,
             const float* __restrict__ bb, float* __restrict__ Cout)
{
  __shared__ float tok[512];
  __shared__ float red[256];
  const int b = blockIdx.y, oc = blockIdx.x;
  const int tid = threadIdx.x;
  for (int i = tid; i < 512; i += 256) {
    if (FIRST) {
      float s = 0.f;
      #pragma unroll
      for (int q = 0; q < 8; ++q) s += src[((b * 8 + q) << 9) + i];
      tok[i] = s * (1.0f / 1024.0f);
    } else {
      tok[i] = src[b * 512 + i];
    }
  }
  __syncthreads();
  const int to = tid & 63, iq = tid >> 6;
  const int o = oc * 64 + to;
  const float* wp = Wm + (size_t)(iq * 128) * 512 + o;
  const float* tp = tok + iq * 128;
  float a0 = 0.f, a1 = 0.f, a2 = 0.f, a3 = 0.f;
  #pragma unroll 8
  for (int i = 0; i < 128; i += 4) {
    a0 = fmaf(tp[i + 0], wp[(size_t)(i + 0) * 512], a0);
    a1 = fmaf(tp[i + 1], wp[(size_t)(i + 1) * 512], a1);
    a2 = fmaf(tp[i + 2], wp[(size_t)(i + 2) * 512], a2);
    a3 = fmaf(tp[i + 3], wp[(size_t)(i + 3) * 512], a3);
  }
  red[tid] = (a0 + a1) + (a2 + a3);
  __syncthreads();
  if (tid < 64) {
    const int oo = oc * 64 + tid;
    const float v = red[tid] + red[tid + 64] + red[tid + 128] + red[tid + 192] + bb[oo];
    Cout[b * 512 + oo] = gelu_f(v);
  }
}

// ---------------- cls layer 3
__global__ __launch_bounds__(768)
void k_cls3(const float* __restrict__ C2, const float* __restrict__ w3,
            const float* __restrict__ b3, float* __restrict__ outp)
{
  const int b = blockIdx.x, tid = threadIdx.x;
  const int o = tid >> 6, lane = tid & 63;
  float acc = 0.f;
  for (int i = lane; i < 512; i += 64)
    acc = fmaf(C2[b * 512 + i], w3[i * 12 + o], acc);
  #pragma unroll
  for (int s = 32; s > 0; s >>= 1) acc += __shfl_xor(acc, s, 64);
  if (lane == 0) outp[2097152 + b * 12 + o] = acc + b3[o];
}

extern "C" void kernel_launch(void* const* d_in, const int* in_sizes, int n_in,
                              void* d_out, int out_size, void* d_ws, size_t ws_size,
                              hipStream_t stream)
{
  (void)in_sizes; (void)n_in; (void)out_size; (void)ws_size;
  const float* x      = (const float*)d_in[0];
  const float* patch_w= (const float*)d_in[1];
  const float* patch_b= (const float*)d_in[2];
  const float* p1_w   = (const float*)d_in[3];
  const float* p1_b   = (const float*)d_in[4];
  const float* pos    = (const float*)d_in[5];
  const float* tagg_w = (const float*)d_in[6];
  const float* gamma  = (const float*)d_in[7];
  const float* gn1_s  = (const float*)d_in[8];
  const float* gn1_b  = (const float*)d_in[9];
  const float* aw1    = (const float*)d_in[10];
  const float* ab1    = (const float*)d_in[11];
  const float* aw2    = (const float*)d_in[12];
  const float* ab2    = (const float*)d_in[13];
  const float* gn2_s  = (const float*)d_in[14];
  const float* gn2_b  = (const float*)d_in[15];
  const float* mw1    = (const float*)d_in[16];
  const float* mb1    = (const float*)d_in[17];
  const float* mw2    = (const float*)d_in[18];
  const float* mb2    = (const float*)d_in[19];
  const float* cls_w1 = (const float*)d_in[20];
  const float* cls_b1 = (const float*)d_in[21];
  const float* cls_w2 = (const float*)d_in[22];
  const float* cls_b2 = (const float*)d_in[23];
  const float* cls_w3 = (const float*)d_in[24];
  const float* cls_b3 = (const float*)d_in[25];
  const float* dec_w  = (const float*)d_in[26];
  const float* dec_b  = (const float*)d_in[27];
  const float* c3_w   = (const float*)d_in[28];
  const float* c3_b   = (const float*)d_in[29];
  const float* c1_w   = (const float*)d_in[30];
  const float* c1_b   = (const float*)d_in[31];

  float* W = (float*)d_ws;
  float* H            = W;                                  // 4,194,304 f
  unsigned int* ABT   = (unsigned int*)(W + 4194304);       // 2,097,152 u32
  unsigned short* UO  = (unsigned short*)(W + 8388608);     // 4,194,304 sh (P1b/Ub)
  float* R1           = W + 10485760;                       // 8,388,608 f (imat/H0b/ZAb/Y1)
  unsigned short* SbA = (unsigned short*)(W + 18874368);    // 3,145,728 sh
  float* SBa          = W + 20447232;                       // 24,576 f
  unsigned short* taggT = (unsigned short*)(W + 20471808);  // 1,048,576 sh
  unsigned short* mwT1  = (unsigned short*)(W + 20996096);  // 3,145,728 sh
  unsigned short* mwT2  = (unsigned short*)(W + 22568960);  // 3,145,728 sh
  unsigned short* decC  = (unsigned short*)(W + 24141824);  // 1,048,576 sh
  unsigned short* w3t   = (unsigned short*)(W + 24666112);  // 16,384 sh
  unsigned short* btp   = (unsigned short*)(W + 24674304);  // 28,672 sh
  unsigned short* bte   = (unsigned short*)(W + 24688640);  // 32,768 sh
  float* TEMB  = W + 24705024;                              // 2,048
  float* PBP   = W + 24707072;                              // 64
  float* PA    = W + 24707136;                              // 1,024
  float* PB    = W + 24708160;                              // 8,192
  float* PARTC = W + 24716352;                              // 32,768
  float* C1    = W + 24749120;                              // 4,096
  float* C2    = W + 24753216;                              // 4,096

  unsigned short* imat = (unsigned short*)R1;
  unsigned short* H0b  = (unsigned short*)R1;
  unsigned short* Y1   = (unsigned short*)R1;
  unsigned short* ZAb  = (unsigned short*)R1;
  unsigned short* P1b = UO;
  unsigned short* Ub  = UO;
  float* out = (float*)d_out;

  // ---- weight prep (once)
  k_cvt_trans<<<dim3(16,64,1),256,0,stream>>>(tagg_w, taggT, 2048, 512, 0, 0);
  k_cvt_trans<<<dim3(16,16,12),256,0,stream>>>(mw1, mwT1, 512, 512, 262144, 262144);
  k_cvt_trans<<<dim3(16,16,12),256,0,stream>>>(mw2, mwT2, 512, 512, 262144, 262144);
  k_cvt<<<4096,256,0,stream>>>(dec_w, decC, 1048576);
  k_prep_w3<<<36,256,0,stream>>>(c3_w, w3t);
  k_prep_btp<<<112,256,0,stream>>>(patch_w, patch_b, btp, PBP);
  k_prep_bte<<<128,256,0,stream>>>(p1_w, bte);
  k_temb<<<8,256,0,stream>>>(gamma, TEMB);
  k_mode_prep_all<<<12288,256,0,stream>>>(aw1, aw2, ab1, ab2, SbA, SBa);

  // ---- encoder
  k_pack<<<8192,256,0,stream>>>(x, imat);
  k_mgemm<1,1,1><<<dim3(1,512),256,0,stream>>>(imat, btp, PBP, P1b,
      nullptr, nullptr, 448, 448, 64, 0, 0, 0, 0);
  k_mgemm<1,0,2><<<dim3(8,512),256,0,stream>>>(P1b, bte, p1_b, H0b,
      pos, TEMB, 64, 64, 512, 0, 0, 0, 0);
  k_bgemm<0,0><<<256,1024,0,stream>>>(H0b, taggT, H, nullptr, nullptr, nullptr,
      nullptr, PA, 2048, 512, 4);

  for (int d = 0; d < 12; ++d) {
    k_dft_a<<<1024,256,0,stream>>>(H, PA, gn1_s + d*512, gn1_b + d*512, ABT);
    k_modes<<<512,256,0,stream>>>(ABT, SbA + (size_t)d*262144, SBa + d*2048);
    k_idft_e<<<1024,256,0,stream>>>(ABT, H, PA, gn1_s + d*512, gn1_b + d*512, ZAb, PB);
    k_bgemm<4,1><<<256,1024,0,stream>>>(ZAb, mwT1 + (size_t)d*262144, nullptr, Ub,
        mb1 + d*512, gn2_s + d*512, PB, const_cast<float*>(gn2_b) + d*512, 512, 512, 4);
    if (d < 11)
      k_bgemm<0,2><<<256,1024,0,stream>>>(Ub, mwT2 + (size_t)d*262144, H, nullptr,
          mb2 + d*512, H, nullptr, PA, 512, 512, 4);
    else
      k_bgemm<0,4><<<256,1024,0,stream>>>(Ub, mwT2 + (size_t)d*262144, H, nullptr,
          mb2 + d*512, H, nullptr, PARTC, 512, 512, 4);
  }

  k_cls_l<1><<<dim3(8,8),256,0,stream>>>(PARTC, cls_w1, cls_b1, C1);
  k_cls_l<0><<<dim3(8,8),256,0,stream>>>(C1, cls_w2, cls_b2, C2);
  k_cls3<<<8,768,0,stream>>>(C2, cls_w3, cls_b3, out);
  k_bgemm<1,3><<<1024,1024,0,stream>>>(H, decC, nullptr, Y1,
      dec_b, nullptr, nullptr, nullptr, 512, 0, 16);
  k_tail<<<2048,256,0,stream>>>(Y1, w3t, c1_w, c1_b, out);
}